// Round 1
// baseline (29103.033 us; speedup 1.0000x reference)
//
#include <hip/hip_runtime.h>
#include <cstdint>
#include <cstddef>

#define S_LEN 1024
#define D_DIM 1024
#define NH 16
#define DHD 64
#define NL 8
#define FF_DIM 4096
#define HI_N 4
#define DI_N 64
#define TOPK_N 512
#define BSROWS 2048  // B * S

// ---------------- embed + positional ----------------
__global__ __launch_bounds__(256) void embed_kernel(
    const int* __restrict__ tokens, const float* __restrict__ E,
    const float* __restrict__ P, float* __restrict__ X)
{
  int bs = blockIdx.x;             // b*S + s
  int s = bs & (S_LEN - 1);
  int tid = threadIdx.x;
  int tok = tokens[bs];
  float4 e = ((const float4*)(E + (size_t)tok * D_DIM))[tid];
  float4 p = ((const float4*)(P + (size_t)s * D_DIM))[tid];
  float4 o; o.x = e.x + p.x; o.y = e.y + p.y; o.z = e.z + p.z; o.w = e.w + p.w;
  ((float4*)(X + (size_t)bs * D_DIM))[tid] = o;
}

// ---------------- rmsnorm: out = w * x / (||x||*D^-0.5 + eps) ----------------
__global__ __launch_bounds__(256) void rmsnorm_kernel(
    const float* __restrict__ X, const float* __restrict__ W, float* __restrict__ O)
{
  int r = blockIdx.x;
  int tid = threadIdx.x;
  float4 v = ((const float4*)(X + (size_t)r * D_DIM))[tid];
  float ss = v.x * v.x + v.y * v.y + v.z * v.z + v.w * v.w;
  __shared__ float red[4];
  __shared__ float sh_inv;
  for (int o = 32; o; o >>= 1) ss += __shfl_down(ss, o);
  if ((tid & 63) == 0) red[tid >> 6] = ss;
  __syncthreads();
  if (tid == 0) {
    float s = red[0] + red[1] + red[2] + red[3];
    sh_inv = 1.0f / (sqrtf(s) * 0.03125f + 1e-6f);  // D^-0.5 = 1/32
  }
  __syncthreads();
  float inv = sh_inv;
  float4 w = ((const float4*)W)[tid];
  float4 o;
  o.x = w.x * v.x * inv; o.y = w.y * v.y * inv;
  o.z = w.z * v.z * inv; o.w = w.w * v.w * inv;
  ((float4*)(O + (size_t)r * D_DIM))[tid] = o;
}

// ---------------- fp32 GEMM, 128x128 tile, BK=16, 256 thr, 8x8/thread ----------
// act: 0 none, 1 exact GELU. R: optional residual added after act.
#define GBM 128
#define GBN 128
#define GBK 16

__global__ __launch_bounds__(256) void gemm_nn_kernel(
    const float* __restrict__ A, const float* __restrict__ B,
    const float* __restrict__ R, float* __restrict__ C,
    int M, int N, int K, int act)
{
  __shared__ float As[GBK][GBM];
  __shared__ float Bs[GBK][GBN];
  int tid = threadIdx.x;
  int tx = tid & 15, ty = tid >> 4;
  int m0 = blockIdx.y * GBM, n0 = blockIdx.x * GBN;
  float acc[8][8];
#pragma unroll
  for (int i = 0; i < 8; ++i)
#pragma unroll
    for (int j = 0; j < 8; ++j) acc[i][j] = 0.f;

  for (int k0 = 0; k0 < K; k0 += GBK) {
    __syncthreads();
#pragma unroll
    for (int f = 0; f < 2; ++f) {
      int idx = tid + f * 256;
      int row = idx >> 2;
      int kk = (idx & 3) << 2;
      float4 v = *(const float4*)(A + (size_t)(m0 + row) * K + (k0 + kk));
      As[kk + 0][row] = v.x; As[kk + 1][row] = v.y;
      As[kk + 2][row] = v.z; As[kk + 3][row] = v.w;
    }
#pragma unroll
    for (int f = 0; f < 2; ++f) {
      int idx = tid + f * 256;
      int kk = idx >> 5;
      int n = (idx & 31) << 2;
      int gn = n0 + n;
      const float* bp = B + (size_t)(k0 + kk) * N;
      float4 v;
      if (gn + 3 < N) {
        v = *(const float4*)(bp + gn);
      } else {
        v.x = (gn + 0 < N) ? bp[gn + 0] : 0.f;
        v.y = (gn + 1 < N) ? bp[gn + 1] : 0.f;
        v.z = (gn + 2 < N) ? bp[gn + 2] : 0.f;
        v.w = (gn + 3 < N) ? bp[gn + 3] : 0.f;
      }
      *(float4*)&Bs[kk][n] = v;
    }
    __syncthreads();
#pragma unroll
    for (int kk = 0; kk < GBK; ++kk) {
      float a[8], bb[8];
      *(float4*)(a + 0) = *(const float4*)&As[kk][ty * 8 + 0];
      *(float4*)(a + 4) = *(const float4*)&As[kk][ty * 8 + 4];
      *(float4*)(bb + 0) = *(const float4*)&Bs[kk][tx * 8 + 0];
      *(float4*)(bb + 4) = *(const float4*)&Bs[kk][tx * 8 + 4];
#pragma unroll
      for (int i = 0; i < 8; ++i)
#pragma unroll
        for (int j = 0; j < 8; ++j)
          acc[i][j] = fmaf(a[i], bb[j], acc[i][j]);
    }
  }
#pragma unroll
  for (int i = 0; i < 8; ++i) {
    int m = m0 + ty * 8 + i;
#pragma unroll
    for (int j = 0; j < 8; ++j) {
      int n = n0 + tx * 8 + j;
      if (n < N) {
        float v = acc[i][j];
        if (act == 1) v = 0.5f * v * (1.0f + erff(v * 0.70710678118654752f));
        if (R) v += R[(size_t)m * N + n];
        C[(size_t)m * N + n] = v;
      }
    }
  }
}

// B stored [N, K] row-major (i.e. C = A @ B^T). Used for tied lm_head.
__global__ __launch_bounds__(256) void gemm_nt_kernel(
    const float* __restrict__ A, const float* __restrict__ B,
    float* __restrict__ C, int M, int N, int K)
{
  __shared__ float As[GBK][GBM];
  __shared__ float Bs[GBK][GBN];
  int tid = threadIdx.x;
  int tx = tid & 15, ty = tid >> 4;
  int m0 = blockIdx.y * GBM, n0 = blockIdx.x * GBN;
  float acc[8][8];
#pragma unroll
  for (int i = 0; i < 8; ++i)
#pragma unroll
    for (int j = 0; j < 8; ++j) acc[i][j] = 0.f;

  for (int k0 = 0; k0 < K; k0 += GBK) {
    __syncthreads();
#pragma unroll
    for (int f = 0; f < 2; ++f) {
      int idx = tid + f * 256;
      int row = idx >> 2;
      int kk = (idx & 3) << 2;
      float4 v = *(const float4*)(A + (size_t)(m0 + row) * K + (k0 + kk));
      As[kk + 0][row] = v.x; As[kk + 1][row] = v.y;
      As[kk + 2][row] = v.z; As[kk + 3][row] = v.w;
    }
#pragma unroll
    for (int f = 0; f < 2; ++f) {
      int idx = tid + f * 256;
      int nr = idx >> 2;
      int kk = (idx & 3) << 2;
      int gn = n0 + nr;
      float4 v = make_float4(0.f, 0.f, 0.f, 0.f);
      if (gn < N) v = *(const float4*)(B + (size_t)gn * K + (k0 + kk));
      Bs[kk + 0][nr] = v.x; Bs[kk + 1][nr] = v.y;
      Bs[kk + 2][nr] = v.z; Bs[kk + 3][nr] = v.w;
    }
    __syncthreads();
#pragma unroll
    for (int kk = 0; kk < GBK; ++kk) {
      float a[8], bb[8];
      *(float4*)(a + 0) = *(const float4*)&As[kk][ty * 8 + 0];
      *(float4*)(a + 4) = *(const float4*)&As[kk][ty * 8 + 4];
      *(float4*)(bb + 0) = *(const float4*)&Bs[kk][tx * 8 + 0];
      *(float4*)(bb + 4) = *(const float4*)&Bs[kk][tx * 8 + 4];
#pragma unroll
      for (int i = 0; i < 8; ++i)
#pragma unroll
        for (int j = 0; j < 8; ++j)
          acc[i][j] = fmaf(a[i], bb[j], acc[i][j]);
    }
  }
#pragma unroll
  for (int i = 0; i < 8; ++i) {
    int m = m0 + ty * 8 + i;
#pragma unroll
    for (int j = 0; j < 8; ++j) {
      int n = n0 + tx * 8 + j;
      if (n < N) C[(size_t)m * N + n] = acc[i][j];
    }
  }
}

// ---------------- indexer scores + exact stable top-k -> bitmask ----------------
__device__ __forceinline__ unsigned int ford(float f) {
  unsigned int u = __float_as_uint(f);
  return (u & 0x80000000u) ? ~u : (u | 0x80000000u);
}

__global__ __launch_bounds__(256) void idx_topk_kernel(
    const float* __restrict__ QI,  // [B*S, HI*DI] (h-major)
    const float* __restrict__ KI,  // [B*S, DI]
    const float* __restrict__ WT,  // [B*S, HI]
    unsigned int* __restrict__ MASK)  // [B*S, 32] bit k set = allowed
{
  int bq = blockIdx.x;
  int q = bq & (S_LEN - 1);
  int b = bq >> 10;
  int tid = threadIdx.x;
  int n = q + 1;
  if (n <= TOPK_N) {
    // all causal keys allowed
    if (tid < 32) {
      int full = n >> 5, rem = n & 31;
      unsigned int w = 0u;
      if (tid < full) w = 0xFFFFFFFFu;
      else if (tid == full && rem) w = (1u << rem) - 1u;
      MASK[(size_t)bq * 32 + tid] = w;
    }
    return;
  }
  __shared__ float qi_s[HI_N * DI_N];
  __shared__ float wt_s[HI_N];
  __shared__ float sc[S_LEN];
  __shared__ unsigned long long keys[S_LEN];
  __shared__ unsigned int mw[32];
  qi_s[tid] = QI[(size_t)bq * (HI_N * DI_N) + tid];
  if (tid < HI_N) wt_s[tid] = WT[(size_t)bq * HI_N + tid];
  __syncthreads();
  // scores: sum_h wt[h] * relu(qi[h,:] . ki[k,:])  -- exact zeros matter for ties
  for (int k = tid; k < n; k += 256) {
    const float* kr = KI + (size_t)(b * S_LEN + k) * DI_N;
    float d0 = 0.f, d1 = 0.f, d2 = 0.f, d3 = 0.f;
#pragma unroll
    for (int d = 0; d < DI_N; ++d) {
      float kv = kr[d];
      d0 = fmaf(qi_s[d], kv, d0);
      d1 = fmaf(qi_s[64 + d], kv, d1);
      d2 = fmaf(qi_s[128 + d], kv, d2);
      d3 = fmaf(qi_s[192 + d], kv, d3);
    }
    sc[k] = wt_s[0] * fmaxf(d0, 0.f) + wt_s[1] * fmaxf(d1, 0.f)
          + wt_s[2] * fmaxf(d2, 0.f) + wt_s[3] * fmaxf(d3, 0.f);
  }
  __syncthreads();
  // keys: (ordered score)<<32 | (1023-k); descending sort => stable top-k
  for (int i = tid; i < S_LEN; i += 256) {
    unsigned long long kk = 0ull;  // padding sorts last (real keys have high word >= 0x007fffff)
    if (i < n) kk = ((unsigned long long)ford(sc[i]) << 32) | (unsigned int)(S_LEN - 1 - i);
    keys[i] = kk;
  }
  __syncthreads();
  for (int size = 2; size <= S_LEN; size <<= 1) {
    for (int stride = size >> 1; stride > 0; stride >>= 1) {
      for (int t = tid; t < S_LEN / 2; t += 256) {
        int j = t & (stride - 1);
        int lo = ((t ^ j) << 1) | j;
        int hi = lo | stride;
        unsigned long long a = keys[lo], c = keys[hi];
        bool desc = ((lo & size) == 0);
        bool sw = desc ? (a < c) : (a > c);
        if (sw) { keys[lo] = c; keys[hi] = a; }
      }
      __syncthreads();
    }
  }
  if (tid < 32) mw[tid] = 0u;
  __syncthreads();
  for (int i = tid; i < TOPK_N; i += 256) {
    int k = S_LEN - 1 - (int)(keys[i] & 0xFFFFFFFFull);
    atomicOr(&mw[k >> 5], 1u << (k & 31));
  }
  __syncthreads();
  if (tid < 32) MASK[(size_t)bq * 32 + tid] = mw[tid];
}

// ---------------- masked attention, one block per (b,h,q) ----------------
__global__ __launch_bounds__(256) void attn_kernel(
    const float* __restrict__ Q, const float* __restrict__ K,
    const float* __restrict__ V, const unsigned int* __restrict__ MASK,
    float* __restrict__ O)
{
  int q = blockIdx.x, h = blockIdx.y, b = blockIdx.z;
  int tid = threadIdx.x;
  int n = q + 1;
  size_t rowq = ((size_t)(b * S_LEN + q)) * D_DIM + h * DHD;
  __shared__ float qv[DHD];
  __shared__ float p[S_LEN];
  __shared__ float red[4];
  __shared__ float sh_m, sh_s;
  __shared__ float racc[256];
  if (tid < DHD) qv[tid] = Q[rowq + tid];
  __syncthreads();
  const unsigned int* mrow = MASK + (size_t)(b * S_LEN + q) * 32;
  float lmax = -3.402823466e38f;
  for (int k = tid; k < n; k += 256) {
    float s = -3.402823466e38f;
    if ((mrow[k >> 5] >> (k & 31)) & 1u) {
      const float* kr = K + ((size_t)(b * S_LEN + k)) * D_DIM + h * DHD;
      float acc = 0.f;
#pragma unroll
      for (int d = 0; d < DHD; ++d) acc = fmaf(qv[d], kr[d], acc);
      s = acc * 0.125f;
    }
    p[k] = s;
    lmax = fmaxf(lmax, s);
  }
  for (int o = 32; o; o >>= 1) lmax = fmaxf(lmax, __shfl_down(lmax, o));
  if ((tid & 63) == 0) red[tid >> 6] = lmax;
  __syncthreads();
  if (tid == 0) sh_m = fmaxf(fmaxf(red[0], red[1]), fmaxf(red[2], red[3]));
  __syncthreads();
  float m = sh_m;
  float lsum = 0.f;
  for (int k = tid; k < n; k += 256) {
    float e = expf(p[k] - m);  // masked rows underflow to exactly 0
    p[k] = e;
    lsum += e;
  }
  for (int o = 32; o; o >>= 1) lsum += __shfl_down(lsum, o);
  __syncthreads();  // p[] complete + red[] reusable
  if ((tid & 63) == 0) red[tid >> 6] = lsum;
  __syncthreads();
  if (tid == 0) sh_s = red[0] + red[1] + red[2] + red[3];
  // PV: thread = (slice of k, dim d)
  int d = tid & 63, sl = tid >> 6;
  float acc = 0.f;
  for (int k = sl; k < n; k += 4)
    acc = fmaf(p[k], V[((size_t)(b * S_LEN + k)) * D_DIM + h * DHD + d], acc);
  racc[tid] = acc;
  __syncthreads();
  if (tid < 64) {
    float o = racc[tid] + racc[tid + 64] + racc[tid + 128] + racc[tid + 192];
    O[rowq + tid] = o / sh_s;
  }
}

// ---------------- host orchestration ----------------
static inline void launch_gemm_nn(const float* A, const float* B, const float* R,
                                  float* C, int M, int N, int K, int act, hipStream_t st)
{
  dim3 grid((N + GBN - 1) / GBN, (M + GBM - 1) / GBM);
  hipLaunchKernelGGL(gemm_nn_kernel, grid, dim3(256), 0, st, A, B, R, C, M, N, K, act);
}

extern "C" void kernel_launch(void* const* d_in, const int* in_sizes, int n_in,
                              void* d_out, int out_size, void* d_ws, size_t ws_size,
                              hipStream_t stream) {
  (void)in_sizes; (void)n_in; (void)out_size; (void)ws_size;
  const int*   tokens  = (const int*)d_in[0];
  const float* embed_w = (const float*)d_in[1];
  const float* pos_w   = (const float*)d_in[2];
  const float* wq      = (const float*)d_in[3];
  const float* wk      = (const float*)d_in[4];
  const float* wv      = (const float*)d_in[5];
  const float* wo      = (const float*)d_in[6];
  const float* iqw     = (const float*)d_in[7];
  const float* ikw     = (const float*)d_in[8];
  const float* iww     = (const float*)d_in[9];
  const float* w1      = (const float*)d_in[10];
  const float* w2      = (const float*)d_in[11];
  const float* n1      = (const float*)d_in[12];
  const float* n2      = (const float*)d_in[13];
  const float* nf      = (const float*)d_in[14];
  float* logits = (float*)d_out;

  // H (rmsnorm out) must survive into the final logits GEMM -> lives in ws.
  float* H = (float*)d_ws;  // 2M floats = 8 MB
  // All other transients are dead before the final GEMM -> stash in d_out (412 MB).
  float* X   = logits;                 // [2048,1024]
  float* Qb  = X   + (size_t)BSROWS * D_DIM;
  float* Kb  = Qb  + (size_t)BSROWS * D_DIM;
  float* Vb  = Kb  + (size_t)BSROWS * D_DIM;
  float* AO  = Vb  + (size_t)BSROWS * D_DIM;
  float* FF  = AO  + (size_t)BSROWS * D_DIM;          // [2048,4096]
  float* QI  = FF  + (size_t)BSROWS * FF_DIM;         // [2048,256]
  float* KI  = QI  + (size_t)BSROWS * (HI_N * DI_N);  // [2048,64]
  float* WTb = KI  + (size_t)BSROWS * DI_N;           // [2048,4]
  unsigned int* MASKb = (unsigned int*)(WTb + (size_t)BSROWS * HI_N);  // [2048,32] u32

  hipLaunchKernelGGL(embed_kernel, dim3(BSROWS), dim3(256), 0, stream,
                     tokens, embed_w, pos_w, X);

  for (int l = 0; l < NL; ++l) {
    const float* lwq = wq + (size_t)l * D_DIM * D_DIM;
    const float* lwk = wk + (size_t)l * D_DIM * D_DIM;
    const float* lwv = wv + (size_t)l * D_DIM * D_DIM;
    const float* lwo = wo + (size_t)l * D_DIM * D_DIM;
    const float* liq = iqw + (size_t)l * D_DIM * (HI_N * DI_N);
    const float* lik = ikw + (size_t)l * D_DIM * DI_N;
    const float* liw = iww + (size_t)l * D_DIM * HI_N;
    const float* lw1 = w1 + (size_t)l * D_DIM * FF_DIM;
    const float* lw2 = w2 + (size_t)l * FF_DIM * D_DIM;

    hipLaunchKernelGGL(rmsnorm_kernel, dim3(BSROWS), dim3(256), 0, stream,
                       X, n1 + (size_t)l * D_DIM, H);
    launch_gemm_nn(H, lwq, nullptr, Qb, BSROWS, D_DIM, D_DIM, 0, stream);
    launch_gemm_nn(H, lwk, nullptr, Kb, BSROWS, D_DIM, D_DIM, 0, stream);
    launch_gemm_nn(H, lwv, nullptr, Vb, BSROWS, D_DIM, D_DIM, 0, stream);
    launch_gemm_nn(H, liq, nullptr, QI, BSROWS, HI_N * DI_N, D_DIM, 0, stream);
    launch_gemm_nn(H, lik, nullptr, KI, BSROWS, DI_N, D_DIM, 0, stream);
    launch_gemm_nn(H, liw, nullptr, WTb, BSROWS, HI_N, D_DIM, 0, stream);
    hipLaunchKernelGGL(idx_topk_kernel, dim3(BSROWS), dim3(256), 0, stream,
                       QI, KI, WTb, MASKb);
    hipLaunchKernelGGL(attn_kernel, dim3(S_LEN, NH, 2), dim3(256), 0, stream,
                       Qb, Kb, Vb, MASKb, AO);
    // x = x + AO @ wo
    launch_gemm_nn(AO, lwo, X, X, BSROWS, D_DIM, D_DIM, 0, stream);
    // FFN
    hipLaunchKernelGGL(rmsnorm_kernel, dim3(BSROWS), dim3(256), 0, stream,
                       X, n2 + (size_t)l * D_DIM, H);
    launch_gemm_nn(H, lw1, nullptr, FF, BSROWS, FF_DIM, D_DIM, 1, stream);   // gelu
    launch_gemm_nn(FF, lw2, X, X, BSROWS, D_DIM, FF_DIM, 0, stream);         // + residual
  }

  hipLaunchKernelGGL(rmsnorm_kernel, dim3(BSROWS), dim3(256), 0, stream, X, nf, H);
  // logits = H @ embed_w^T  (overwrites all scratch in d_out)
  {
    dim3 grid((50257 + GBN - 1) / GBN, (BSROWS + GBM - 1) / GBM);
    hipLaunchKernelGGL(gemm_nt_kernel, grid, dim3(256), 0, stream,
                       H, embed_w, logits, BSROWS, 50257, D_DIM);
  }
}

// Round 2
// 20544.542 us; speedup vs baseline: 1.4166x; 1.4166x over previous
//
#include <hip/hip_runtime.h>
#include <cstdint>
#include <cstddef>

#define S_LEN 1024
#define D_DIM 1024
#define NH 16
#define DHD 64
#define NL 8
#define FF_DIM 4096
#define HI_N 4
#define DI_N 64
#define TOPK_N 512
#define BSROWS 2048  // B * S

// packed projection layout: [Q 0..1023 | K 1024..2047 | V 2048..3071 |
//                            QI 3072..3327 | KI 3328..3391 | WT 3392..3395]
#define PLD 3396
#define COL_Q 0
#define COL_K 1024
#define COL_V 2048
#define COL_QI 3072
#define COL_KI 3328
#define COL_WT 3392

// ---------------- embed + positional ----------------
__global__ __launch_bounds__(256) void embed_kernel(
    const int* __restrict__ tokens, const float* __restrict__ E,
    const float* __restrict__ P, float* __restrict__ X)
{
  int bs = blockIdx.x;             // b*S + s
  int s = bs & (S_LEN - 1);
  int tid = threadIdx.x;
  int tok = tokens[bs];
  float4 e = ((const float4*)(E + (size_t)tok * D_DIM))[tid];
  float4 p = ((const float4*)(P + (size_t)s * D_DIM))[tid];
  float4 o; o.x = e.x + p.x; o.y = e.y + p.y; o.z = e.z + p.z; o.w = e.w + p.w;
  ((float4*)(X + (size_t)bs * D_DIM))[tid] = o;
}

// ---------------- rmsnorm: out = w * x / (||x||*D^-0.5 + eps) ----------------
__global__ __launch_bounds__(256) void rmsnorm_kernel(
    const float* __restrict__ X, const float* __restrict__ W, float* __restrict__ O)
{
  int r = blockIdx.x;
  int tid = threadIdx.x;
  float4 v = ((const float4*)(X + (size_t)r * D_DIM))[tid];
  float ss = v.x * v.x + v.y * v.y + v.z * v.z + v.w * v.w;
  __shared__ float red[4];
  __shared__ float sh_inv;
  for (int o = 32; o; o >>= 1) ss += __shfl_down(ss, o);
  if ((tid & 63) == 0) red[tid >> 6] = ss;
  __syncthreads();
  if (tid == 0) {
    float s = red[0] + red[1] + red[2] + red[3];
    sh_inv = 1.0f / (sqrtf(s) * 0.03125f + 1e-6f);  // D^-0.5 = 1/32
  }
  __syncthreads();
  float inv = sh_inv;
  float4 w = ((const float4*)W)[tid];
  float4 o;
  o.x = w.x * v.x * inv; o.y = w.y * v.y * inv;
  o.z = w.z * v.z * inv; o.w = w.w * v.w * inv;
  ((float4*)(O + (size_t)r * D_DIM))[tid] = o;
}

// ---------------- weight packing: Bcat[k, :] = wq|wk|wv|iq|ik|iw ----------------
__global__ __launch_bounds__(256) void pack_w_kernel(
    const float* __restrict__ wq, const float* __restrict__ wk,
    const float* __restrict__ wv, const float* __restrict__ iq,
    const float* __restrict__ ik, const float* __restrict__ iw,
    float* __restrict__ B)
{
  int k = blockIdx.x;   // 0..1023 (input dim)
  int tid = threadIdx.x;
  float* dst = B + (size_t)k * PLD;
  ((float4*)(dst + COL_Q))[tid] = ((const float4*)(wq + (size_t)k * D_DIM))[tid];
  ((float4*)(dst + COL_K))[tid] = ((const float4*)(wk + (size_t)k * D_DIM))[tid];
  ((float4*)(dst + COL_V))[tid] = ((const float4*)(wv + (size_t)k * D_DIM))[tid];
  if (tid < 64)
    ((float4*)(dst + COL_QI))[tid] = ((const float4*)(iq + (size_t)k * (HI_N * DI_N)))[tid];
  if (tid < 16)
    ((float4*)(dst + COL_KI))[tid] = ((const float4*)(ik + (size_t)k * DI_N))[tid];
  if (tid < 4) dst[COL_WT + tid] = iw[(size_t)k * HI_N + tid];
}

// ---------------- fp32 GEMM template: BMxBN tile, BK=16, 256 thr ----------------
// act: 0 none, 1 exact GELU. R: optional residual added after act.
#define GBN 128
#define GBK 16

template<int BM, int RM>
__global__ __launch_bounds__(256) void gemm_nn_t(
    const float* __restrict__ A, const float* __restrict__ B,
    const float* __restrict__ R, float* __restrict__ C,
    int M, int N, int K, int act)
{
  __shared__ float As[GBK][BM];
  __shared__ float Bs[GBK][GBN];
  int tid = threadIdx.x;
  int tx = tid & 15, ty = tid >> 4;
  int m0 = blockIdx.y * BM, n0 = blockIdx.x * GBN;
  float acc[RM][8];
#pragma unroll
  for (int i = 0; i < RM; ++i)
#pragma unroll
    for (int j = 0; j < 8; ++j) acc[i][j] = 0.f;

  for (int k0 = 0; k0 < K; k0 += GBK) {
    __syncthreads();
#pragma unroll
    for (int f = 0; f < BM / 64; ++f) {
      int idx = tid + f * 256;
      int row = idx >> 2;
      int kk = (idx & 3) << 2;
      float4 v = *(const float4*)(A + (size_t)(m0 + row) * K + (k0 + kk));
      As[kk + 0][row] = v.x; As[kk + 1][row] = v.y;
      As[kk + 2][row] = v.z; As[kk + 3][row] = v.w;
    }
#pragma unroll
    for (int f = 0; f < 2; ++f) {
      int idx = tid + f * 256;
      int kk = idx >> 5;
      int n = (idx & 31) << 2;
      int gn = n0 + n;
      const float* bp = B + (size_t)(k0 + kk) * N;
      float4 v;
      if (gn + 3 < N) {
        v = *(const float4*)(bp + gn);
      } else {
        v.x = (gn + 0 < N) ? bp[gn + 0] : 0.f;
        v.y = (gn + 1 < N) ? bp[gn + 1] : 0.f;
        v.z = (gn + 2 < N) ? bp[gn + 2] : 0.f;
        v.w = (gn + 3 < N) ? bp[gn + 3] : 0.f;
      }
      *(float4*)&Bs[kk][n] = v;
    }
    __syncthreads();
#pragma unroll
    for (int kk = 0; kk < GBK; ++kk) {
      float a[RM], bb[8];
#pragma unroll
      for (int r = 0; r < RM / 4; ++r)
        *(float4*)(a + 4 * r) = *(const float4*)&As[kk][ty * RM + 4 * r];
      *(float4*)(bb + 0) = *(const float4*)&Bs[kk][tx * 8 + 0];
      *(float4*)(bb + 4) = *(const float4*)&Bs[kk][tx * 8 + 4];
#pragma unroll
      for (int i = 0; i < RM; ++i)
#pragma unroll
        for (int j = 0; j < 8; ++j)
          acc[i][j] = fmaf(a[i], bb[j], acc[i][j]);
    }
  }
#pragma unroll
  for (int i = 0; i < RM; ++i) {
    int m = m0 + ty * RM + i;
#pragma unroll
    for (int j = 0; j < 8; ++j) {
      int n = n0 + tx * 8 + j;
      if (n < N) {
        float v = acc[i][j];
        if (act == 1) v = 0.5f * v * (1.0f + erff(v * 0.70710678118654752f));
        if (R) v += R[(size_t)m * N + n];
        C[(size_t)m * N + n] = v;
      }
    }
  }
}

// B stored [N, K] row-major (i.e. C = A @ B^T). Used for tied lm_head.
__global__ __launch_bounds__(256) void gemm_nt_kernel(
    const float* __restrict__ A, const float* __restrict__ B,
    float* __restrict__ C, int M, int N, int K)
{
  __shared__ float As[GBK][128];
  __shared__ float Bs[GBK][GBN];
  int tid = threadIdx.x;
  int tx = tid & 15, ty = tid >> 4;
  int m0 = blockIdx.y * 128, n0 = blockIdx.x * GBN;
  float acc[8][8];
#pragma unroll
  for (int i = 0; i < 8; ++i)
#pragma unroll
    for (int j = 0; j < 8; ++j) acc[i][j] = 0.f;

  for (int k0 = 0; k0 < K; k0 += GBK) {
    __syncthreads();
#pragma unroll
    for (int f = 0; f < 2; ++f) {
      int idx = tid + f * 256;
      int row = idx >> 2;
      int kk = (idx & 3) << 2;
      float4 v = *(const float4*)(A + (size_t)(m0 + row) * K + (k0 + kk));
      As[kk + 0][row] = v.x; As[kk + 1][row] = v.y;
      As[kk + 2][row] = v.z; As[kk + 3][row] = v.w;
    }
#pragma unroll
    for (int f = 0; f < 2; ++f) {
      int idx = tid + f * 256;
      int nr = idx >> 2;
      int kk = (idx & 3) << 2;
      int gn = n0 + nr;
      float4 v = make_float4(0.f, 0.f, 0.f, 0.f);
      if (gn < N) v = *(const float4*)(B + (size_t)gn * K + (k0 + kk));
      Bs[kk + 0][nr] = v.x; Bs[kk + 1][nr] = v.y;
      Bs[kk + 2][nr] = v.z; Bs[kk + 3][nr] = v.w;
    }
    __syncthreads();
#pragma unroll
    for (int kk = 0; kk < GBK; ++kk) {
      float a[8], bb[8];
      *(float4*)(a + 0) = *(const float4*)&As[kk][ty * 8 + 0];
      *(float4*)(a + 4) = *(const float4*)&As[kk][ty * 8 + 4];
      *(float4*)(bb + 0) = *(const float4*)&Bs[kk][tx * 8 + 0];
      *(float4*)(bb + 4) = *(const float4*)&Bs[kk][tx * 8 + 4];
#pragma unroll
      for (int i = 0; i < 8; ++i)
#pragma unroll
        for (int j = 0; j < 8; ++j)
          acc[i][j] = fmaf(a[i], bb[j], acc[i][j]);
    }
  }
#pragma unroll
  for (int i = 0; i < 8; ++i) {
    int m = m0 + ty * 8 + i;
#pragma unroll
    for (int j = 0; j < 8; ++j) {
      int n = n0 + tx * 8 + j;
      if (n < N) C[(size_t)m * N + n] = acc[i][j];
    }
  }
}

// ---------------- indexer scores + exact stable top-k -> bitmask ----------------
__device__ __forceinline__ unsigned int ford(float f) {
  unsigned int u = __float_as_uint(f);
  return (u & 0x80000000u) ? ~u : (u | 0x80000000u);
}

__global__ __launch_bounds__(256) void idx_topk_kernel(
    const float* __restrict__ Hp,   // packed projections [B*S, PLD]
    unsigned int* __restrict__ MASK)  // [B*S, 32] bit k set = allowed
{
  int bq = blockIdx.x;
  int q = bq & (S_LEN - 1);
  int b = bq >> 10;
  int tid = threadIdx.x;
  int n = q + 1;
  if (n <= TOPK_N) {
    // all causal keys allowed
    if (tid < 32) {
      int full = n >> 5, rem = n & 31;
      unsigned int w = 0u;
      if (tid < full) w = 0xFFFFFFFFu;
      else if (tid == full && rem) w = (1u << rem) - 1u;
      MASK[(size_t)bq * 32 + tid] = w;
    }
    return;
  }
  __shared__ float qi_s[HI_N * DI_N];
  __shared__ float wt_s[HI_N];
  __shared__ float sc[S_LEN];
  __shared__ unsigned long long keys[S_LEN];
  __shared__ unsigned int mw[32];
  qi_s[tid] = Hp[(size_t)bq * PLD + COL_QI + tid];
  if (tid < HI_N) wt_s[tid] = Hp[(size_t)bq * PLD + COL_WT + tid];
  __syncthreads();
  // scores: sum_h wt[h] * relu(qi[h,:] . ki[k,:])  -- exact zeros matter for ties
  for (int k = tid; k < n; k += 256) {
    const float* kr = Hp + (size_t)(b * S_LEN + k) * PLD + COL_KI;
    float d0 = 0.f, d1 = 0.f, d2 = 0.f, d3 = 0.f;
#pragma unroll
    for (int d = 0; d < DI_N; ++d) {
      float kv = kr[d];
      d0 = fmaf(qi_s[d], kv, d0);
      d1 = fmaf(qi_s[64 + d], kv, d1);
      d2 = fmaf(qi_s[128 + d], kv, d2);
      d3 = fmaf(qi_s[192 + d], kv, d3);
    }
    sc[k] = wt_s[0] * fmaxf(d0, 0.f) + wt_s[1] * fmaxf(d1, 0.f)
          + wt_s[2] * fmaxf(d2, 0.f) + wt_s[3] * fmaxf(d3, 0.f);
  }
  __syncthreads();
  // keys: (ordered score)<<32 | (1023-k); descending sort => stable top-k
  for (int i = tid; i < S_LEN; i += 256) {
    unsigned long long kk = 0ull;  // padding sorts last
    if (i < n) kk = ((unsigned long long)ford(sc[i]) << 32) | (unsigned int)(S_LEN - 1 - i);
    keys[i] = kk;
  }
  __syncthreads();
  for (int size = 2; size <= S_LEN; size <<= 1) {
    for (int stride = size >> 1; stride > 0; stride >>= 1) {
      for (int t = tid; t < S_LEN / 2; t += 256) {
        int j = t & (stride - 1);
        int lo = ((t ^ j) << 1) | j;
        int hi = lo | stride;
        unsigned long long a = keys[lo], c = keys[hi];
        bool desc = ((lo & size) == 0);
        bool sw = desc ? (a < c) : (a > c);
        if (sw) { keys[lo] = c; keys[hi] = a; }
      }
      __syncthreads();
    }
  }
  if (tid < 32) mw[tid] = 0u;
  __syncthreads();
  for (int i = tid; i < TOPK_N; i += 256) {
    int k = S_LEN - 1 - (int)(keys[i] & 0xFFFFFFFFull);
    atomicOr(&mw[k >> 5], 1u << (k & 31));
  }
  __syncthreads();
  if (tid < 32) MASK[(size_t)bq * 32 + tid] = mw[tid];
}

// ---------------- masked attention, one block per (b,h,q) ----------------
__global__ __launch_bounds__(256) void attn_kernel(
    const float* __restrict__ Hp, const unsigned int* __restrict__ MASK,
    float* __restrict__ O)
{
  int q = blockIdx.x, h = blockIdx.y, b = blockIdx.z;
  int tid = threadIdx.x;
  int n = q + 1;
  size_t rowq = ((size_t)(b * S_LEN + q)) * PLD + COL_Q + h * DHD;
  __shared__ float qv[DHD];
  __shared__ float p[S_LEN];
  __shared__ float red[4];
  __shared__ float sh_m, sh_s;
  __shared__ float racc[256];
  if (tid < DHD) qv[tid] = Hp[rowq + tid];
  __syncthreads();
  const unsigned int* mrow = MASK + (size_t)(b * S_LEN + q) * 32;
  float lmax = -3.402823466e38f;
  for (int k = tid; k < n; k += 256) {
    float s = -3.402823466e38f;
    if ((mrow[k >> 5] >> (k & 31)) & 1u) {
      const float* kr = Hp + ((size_t)(b * S_LEN + k)) * PLD + COL_K + h * DHD;
      float acc = 0.f;
#pragma unroll
      for (int d = 0; d < DHD; ++d) acc = fmaf(qv[d], kr[d], acc);
      s = acc * 0.125f;
    }
    p[k] = s;
    lmax = fmaxf(lmax, s);
  }
  for (int o = 32; o; o >>= 1) lmax = fmaxf(lmax, __shfl_down(lmax, o));
  if ((tid & 63) == 0) red[tid >> 6] = lmax;
  __syncthreads();
  if (tid == 0) sh_m = fmaxf(fmaxf(red[0], red[1]), fmaxf(red[2], red[3]));
  __syncthreads();
  float m = sh_m;
  float lsum = 0.f;
  for (int k = tid; k < n; k += 256) {
    float e = expf(p[k] - m);  // masked rows underflow to exactly 0
    p[k] = e;
    lsum += e;
  }
  for (int o = 32; o; o >>= 1) lsum += __shfl_down(lsum, o);
  __syncthreads();  // p[] complete + red[] reusable
  if ((tid & 63) == 0) red[tid >> 6] = lsum;
  __syncthreads();
  if (tid == 0) sh_s = red[0] + red[1] + red[2] + red[3];
  // PV: thread = (slice of k, dim d)
  int d = tid & 63, sl = tid >> 6;
  float acc = 0.f;
  for (int k = sl; k < n; k += 4)
    acc = fmaf(p[k], Hp[((size_t)(b * S_LEN + k)) * PLD + COL_V + h * DHD + d], acc);
  racc[tid] = acc;
  __syncthreads();
  if (tid < 64) {
    float o = racc[tid] + racc[tid + 64] + racc[tid + 128] + racc[tid + 192];
    O[((size_t)(b * S_LEN + q)) * D_DIM + h * DHD + tid] = o / sh_s;
  }
}

// ---------------- host orchestration ----------------
static inline void launch_gemm128(const float* A, const float* B, const float* R,
                                  float* C, int M, int N, int K, int act, hipStream_t st)
{
  dim3 grid((N + GBN - 1) / GBN, (M + 127) / 128);
  hipLaunchKernelGGL((gemm_nn_t<128, 8>), grid, dim3(256), 0, st, A, B, R, C, M, N, K, act);
}
static inline void launch_gemm64(const float* A, const float* B, const float* R,
                                 float* C, int M, int N, int K, int act, hipStream_t st)
{
  dim3 grid((N + GBN - 1) / GBN, (M + 63) / 64);
  hipLaunchKernelGGL((gemm_nn_t<64, 4>), grid, dim3(256), 0, st, A, B, R, C, M, N, K, act);
}

extern "C" void kernel_launch(void* const* d_in, const int* in_sizes, int n_in,
                              void* d_out, int out_size, void* d_ws, size_t ws_size,
                              hipStream_t stream) {
  (void)in_sizes; (void)n_in; (void)out_size; (void)ws_size;
  const int*   tokens  = (const int*)d_in[0];
  const float* embed_w = (const float*)d_in[1];
  const float* pos_w   = (const float*)d_in[2];
  const float* wq      = (const float*)d_in[3];
  const float* wk      = (const float*)d_in[4];
  const float* wv      = (const float*)d_in[5];
  const float* wo      = (const float*)d_in[6];
  const float* iqw     = (const float*)d_in[7];
  const float* ikw     = (const float*)d_in[8];
  const float* iww     = (const float*)d_in[9];
  const float* w1      = (const float*)d_in[10];
  const float* w2      = (const float*)d_in[11];
  const float* n1      = (const float*)d_in[12];
  const float* n2      = (const float*)d_in[13];
  const float* nf      = (const float*)d_in[14];
  float* logits = (float*)d_out;

  // H (rmsnorm out) must survive into the final logits GEMM -> lives in ws.
  float* H = (float*)d_ws;  // 2M floats = 8 MB
  // All other transients are dead before the final GEMM -> stash in d_out (412 MB).
  float* X    = logits;                               // [2048,1024]
  float* Hp   = X    + (size_t)BSROWS * D_DIM;        // [2048,3396] packed projections
  float* AO   = Hp   + (size_t)BSROWS * PLD;          // [2048,1024]
  float* FF   = AO   + (size_t)BSROWS * D_DIM;        // [2048,4096]
  float* Bcat = FF   + (size_t)BSROWS * FF_DIM;       // [1024,3396] packed weights
  unsigned int* MASKb = (unsigned int*)(Bcat + (size_t)D_DIM * PLD);  // [2048,32] u32

  hipLaunchKernelGGL(embed_kernel, dim3(BSROWS), dim3(256), 0, stream,
                     tokens, embed_w, pos_w, X);

  for (int l = 0; l < NL; ++l) {
    const float* lwq = wq + (size_t)l * D_DIM * D_DIM;
    const float* lwk = wk + (size_t)l * D_DIM * D_DIM;
    const float* lwv = wv + (size_t)l * D_DIM * D_DIM;
    const float* lwo = wo + (size_t)l * D_DIM * D_DIM;
    const float* liq = iqw + (size_t)l * D_DIM * (HI_N * DI_N);
    const float* lik = ikw + (size_t)l * D_DIM * DI_N;
    const float* liw = iww + (size_t)l * D_DIM * HI_N;
    const float* lw1 = w1 + (size_t)l * D_DIM * FF_DIM;
    const float* lw2 = w2 + (size_t)l * FF_DIM * D_DIM;

    hipLaunchKernelGGL(rmsnorm_kernel, dim3(BSROWS), dim3(256), 0, stream,
                       X, n1 + (size_t)l * D_DIM, H);
    hipLaunchKernelGGL(pack_w_kernel, dim3(D_DIM), dim3(256), 0, stream,
                       lwq, lwk, lwv, liq, lik, liw, Bcat);
    // all projections in one GEMM: Hp = H @ Bcat   [2048 x 3396]
    launch_gemm64(H, Bcat, nullptr, Hp, BSROWS, PLD, D_DIM, 0, stream);
    hipLaunchKernelGGL(idx_topk_kernel, dim3(BSROWS), dim3(256), 0, stream,
                       Hp, MASKb);
    hipLaunchKernelGGL(attn_kernel, dim3(S_LEN, NH, 2), dim3(256), 0, stream,
                       Hp, MASKb, AO);
    // x = x + AO @ wo
    launch_gemm64(AO, lwo, X, X, BSROWS, D_DIM, D_DIM, 0, stream);
    // FFN
    hipLaunchKernelGGL(rmsnorm_kernel, dim3(BSROWS), dim3(256), 0, stream,
                       X, n2 + (size_t)l * D_DIM, H);
    launch_gemm128(H, lw1, nullptr, FF, BSROWS, FF_DIM, D_DIM, 1, stream);   // gelu
    launch_gemm64(FF, lw2, X, X, BSROWS, D_DIM, FF_DIM, 0, stream);          // + residual
  }

  hipLaunchKernelGGL(rmsnorm_kernel, dim3(BSROWS), dim3(256), 0, stream, X, nf, H);
  // logits = H @ embed_w^T  (overwrites all scratch in d_out)
  {
    dim3 grid((50257 + GBN - 1) / GBN, (BSROWS + 127) / 128);
    hipLaunchKernelGGL(gemm_nt_kernel, grid, dim3(256), 0, stream,
                       H, embed_w, logits, BSROWS, 50257, D_DIM);
  }
}

// Round 4
// 12578.117 us; speedup vs baseline: 2.3138x; 1.6334x over previous
//
#include <hip/hip_runtime.h>
#include <cstdint>
#include <cstddef>

#define S_LEN 1024
#define D_DIM 1024
#define NH 16
#define DHD 64
#define NL 8
#define FF_DIM 4096
#define HI_N 4
#define DI_N 64
#define TOPK_N 512
#define BSROWS 2048  // B * S

// packed projection layout (columns of Hp): [Q|K|V|QI|KI|WT]
#define PLD 3396
#define COL_Q 0
#define COL_K 1024
#define COL_V 2048
#define COL_QI 3072
#define COL_KI 3328
#define COL_WT 3392
#define PROJ_NPAD 3456  // padded row count of BT_proj (multiple of 128)

typedef __attribute__((ext_vector_type(8))) short short8;
typedef __attribute__((ext_vector_type(4))) float f32x4;

__device__ __forceinline__ short f2bf(float x) {  // RNE fp32->bf16
  unsigned u = __float_as_uint(x);
  u += 0x7FFFu + ((u >> 16) & 1u);
  return (short)(u >> 16);
}
__device__ __forceinline__ float bf2f(short h) {
  return __uint_as_float(((unsigned)(unsigned short)h) << 16);
}
// two-term split: x ~= hi + lo with rel err ~2^-17
__device__ __forceinline__ void split_bf(float x, short& hi, short& lo) {
  hi = f2bf(x);
  lo = f2bf(x - bf2f(hi));
}

// ---------------- embed + positional ----------------
__global__ __launch_bounds__(256) void embed_kernel(
    const int* __restrict__ tokens, const float* __restrict__ E,
    const float* __restrict__ P, float* __restrict__ X)
{
  int bs = blockIdx.x;
  int s = bs & (S_LEN - 1);
  int tid = threadIdx.x;
  int tok = tokens[bs];
  float4 e = ((const float4*)(E + (size_t)tok * D_DIM))[tid];
  float4 p = ((const float4*)(P + (size_t)s * D_DIM))[tid];
  float4 o; o.x = e.x + p.x; o.y = e.y + p.y; o.z = e.z + p.z; o.w = e.w + p.w;
  ((float4*)(X + (size_t)bs * D_DIM))[tid] = o;
}

// ---------------- rmsnorm -> split bf16 (hi plane, lo plane) ----------------
__global__ __launch_bounds__(256) void rmsnorm_split_kernel(
    const float* __restrict__ X, const float* __restrict__ W,
    short* __restrict__ O /* [2][BSROWS][D] */)
{
  int r = blockIdx.x;
  int tid = threadIdx.x;
  float4 v = ((const float4*)(X + (size_t)r * D_DIM))[tid];
  float ss = v.x * v.x + v.y * v.y + v.z * v.z + v.w * v.w;
  __shared__ float red[4];
  __shared__ float sh_inv;
  for (int o = 32; o; o >>= 1) ss += __shfl_down(ss, o);
  if ((tid & 63) == 0) red[tid >> 6] = ss;
  __syncthreads();
  if (tid == 0) {
    float s = red[0] + red[1] + red[2] + red[3];
    sh_inv = 1.0f / (sqrtf(s) * 0.03125f + 1e-6f);
  }
  __syncthreads();
  float inv = sh_inv;
  float4 w = ((const float4*)W)[tid];
  float o0 = w.x * v.x * inv, o1 = w.y * v.y * inv;
  float o2 = w.z * v.z * inv, o3 = w.w * v.w * inv;
  short4 hi, lo;
  split_bf(o0, hi.x, lo.x); split_bf(o1, hi.y, lo.y);
  split_bf(o2, hi.z, lo.z); split_bf(o3, hi.w, lo.w);
  ((short4*)(O + (size_t)r * D_DIM))[tid] = hi;
  ((short4*)(O + (size_t)BSROWS * D_DIM + (size_t)r * D_DIM))[tid] = lo;
}

// ---------------- rmsnorm -> plain bf16 (for logits A-operand) ----------------
__global__ __launch_bounds__(256) void rmsnorm_bf_kernel(
    const float* __restrict__ X, const float* __restrict__ W, short* __restrict__ O)
{
  int r = blockIdx.x;
  int tid = threadIdx.x;
  float4 v = ((const float4*)(X + (size_t)r * D_DIM))[tid];
  float ss = v.x * v.x + v.y * v.y + v.z * v.z + v.w * v.w;
  __shared__ float red[4];
  __shared__ float sh_inv;
  for (int o = 32; o; o >>= 1) ss += __shfl_down(ss, o);
  if ((tid & 63) == 0) red[tid >> 6] = ss;
  __syncthreads();
  if (tid == 0) {
    float s = red[0] + red[1] + red[2] + red[3];
    sh_inv = 1.0f / (sqrtf(s) * 0.03125f + 1e-6f);
  }
  __syncthreads();
  float inv = sh_inv;
  float4 w = ((const float4*)W)[tid];
  short4 o4 = make_short4(f2bf(w.x * v.x * inv), f2bf(w.y * v.y * inv),
                          f2bf(w.z * v.z * inv), f2bf(w.w * v.w * inv));
  ((short4*)(O + (size_t)r * D_DIM))[tid] = o4;
}

// ---------------- transpose-pack W[K][N] fp32 -> BT[2][N][K] split bf16 --------
__global__ __launch_bounds__(256) void packT_split_kernel(
    const float* __restrict__ W, short* __restrict__ BT, size_t plane, int K, int N)
{
  __shared__ float t[32][33];
  int n0 = blockIdx.x * 32, k0 = blockIdx.y * 32;
  int tx = threadIdx.x, ty = threadIdx.y;
#pragma unroll
  for (int r = 0; r < 32; r += 8)
    t[ty + r][tx] = W[(size_t)(k0 + ty + r) * N + n0 + tx];
  __syncthreads();
#pragma unroll
  for (int r = 0; r < 32; r += 8) {
    short hi, lo;
    split_bf(t[tx][ty + r], hi, lo);
    size_t o = (size_t)(n0 + ty + r) * K + k0 + tx;
    BT[o] = hi;
    BT[plane + o] = lo;
  }
}

// pack wq|wk|wv|iq|ik|iw columns into BT_proj [2][PROJ_NPAD][1024] split bf16
__global__ __launch_bounds__(256) void pack_proj_kernel(
    const float* __restrict__ wq, const float* __restrict__ wk,
    const float* __restrict__ wv, const float* __restrict__ iq,
    const float* __restrict__ ik, const float* __restrict__ iw,
    short* __restrict__ BT)
{
  __shared__ float t[32][33];
  const size_t plane = (size_t)PROJ_NPAD * D_DIM;
  int n0 = blockIdx.x * 32, k0 = blockIdx.y * 32;
  int tx = threadIdx.x, ty = threadIdx.y;
  const float* src = nullptr; int ld = 0, c0 = 0;
  if (n0 < 1024)       { src = wq; ld = 1024; c0 = n0; }
  else if (n0 < 2048)  { src = wk; ld = 1024; c0 = n0 - 1024; }
  else if (n0 < 3072)  { src = wv; ld = 1024; c0 = n0 - 2048; }
  else if (n0 < 3328)  { src = iq; ld = 256;  c0 = n0 - 3072; }
  else if (n0 < 3392)  { src = ik; ld = 64;   c0 = n0 - 3328; }
  else if (n0 == 3392) { src = iw; ld = 4;    c0 = 0; }
#pragma unroll
  for (int r = 0; r < 32; r += 8) {
    float v = 0.f;
    int c = c0 + tx;
    if (src && c < ld) v = src[(size_t)(k0 + ty + r) * ld + c];
    t[ty + r][tx] = v;
  }
  __syncthreads();
#pragma unroll
  for (int r = 0; r < 32; r += 8) {
    short hi, lo;
    split_bf(t[tx][ty + r], hi, lo);
    size_t o = (size_t)(n0 + ty + r) * D_DIM + k0 + tx;
    BT[o] = hi;
    BT[plane + o] = lo;
  }
}

// ------- split-bf16 GEMM (fp32-accurate): C = A @ BT^T -------
// A split [2][M][K] bf16; BT split [2][NB][K] bf16. 128x128 tile, BK=32, 4 waves.
// epi: 0 store fp32; 1 store fp32 + R; 2 exact-GELU -> split bf16 (C hi, C+cplane lo)
#define RA 40  // LDS row pitch (elems): 32 + 8 pad, 16B-aligned

__global__ __launch_bounds__(256) void gemm_split_kernel(
    const short* __restrict__ A, size_t aplane,
    const short* __restrict__ BT, size_t bplane,
    const float* __restrict__ R, void* __restrict__ C, size_t cplane,
    int M, int N, int K, int epi)
{
  __shared__ short Al[2 * 128 * RA];
  __shared__ short Bl[2 * 128 * RA];
  int tid = threadIdx.x;
  int wave = tid >> 6, lane = tid & 63;
  int wr = (wave >> 1) * 64, wc = (wave & 1) * 64;
  int lr = lane & 15, lk = lane >> 4;
  int m0 = blockIdx.y * 128, n0 = blockIdx.x * 128;
  f32x4 acc[4][4] = {};

  for (int k0 = 0; k0 < K; k0 += 32) {
    __syncthreads();
    // stage A hi+lo planes: 2 x 128 rows x 32 k
#pragma unroll
    for (int f = 0; f < 4; ++f) {
      int idx = tid + f * 256;
      int p = idx >> 9, r2 = idx & 511;
      int row = r2 >> 2, sub = r2 & 3;
      uint4 v = *(const uint4*)(A + (size_t)p * aplane + (size_t)(m0 + row) * K + k0 + sub * 8);
      *(uint4*)(Al + p * 128 * RA + row * RA + sub * 8) = v;
    }
    // stage B hi+lo planes (rows n0..n0+127 of BT; NB padded to grid)
#pragma unroll
    for (int f = 0; f < 4; ++f) {
      int idx = tid + f * 256;
      int p = idx >> 9, r2 = idx & 511;
      int row = r2 >> 2, sub = r2 & 3;
      uint4 v = *(const uint4*)(BT + (size_t)p * bplane + (size_t)(n0 + row) * K + k0 + sub * 8);
      *(uint4*)(Bl + p * 128 * RA + row * RA + sub * 8) = v;
    }
    __syncthreads();
    short8 ah[4], al[4], bh[4], bl[4];
#pragma unroll
    for (int i = 0; i < 4; ++i) {
      ah[i] = *(const short8*)(Al + (wr + i * 16 + lr) * RA + lk * 8);
      al[i] = *(const short8*)(Al + 128 * RA + (wr + i * 16 + lr) * RA + lk * 8);
    }
#pragma unroll
    for (int j = 0; j < 4; ++j) {
      bh[j] = *(const short8*)(Bl + (wc + j * 16 + lr) * RA + lk * 8);
      bl[j] = *(const short8*)(Bl + 128 * RA + (wc + j * 16 + lr) * RA + lk * 8);
    }
#pragma unroll
    for (int i = 0; i < 4; ++i)
#pragma unroll
      for (int j = 0; j < 4; ++j) {
        f32x4 a = acc[i][j];
        a = __builtin_amdgcn_mfma_f32_16x16x32_bf16(al[i], bh[j], a, 0, 0, 0);
        a = __builtin_amdgcn_mfma_f32_16x16x32_bf16(ah[i], bl[j], a, 0, 0, 0);
        a = __builtin_amdgcn_mfma_f32_16x16x32_bf16(ah[i], bh[j], a, 0, 0, 0);
        acc[i][j] = a;
      }
  }
  // epilogue: C/D layout col=lane&15, row=(lane>>4)*4+reg
#pragma unroll
  for (int i = 0; i < 4; ++i) {
#pragma unroll
    for (int r = 0; r < 4; ++r) {
      int m = m0 + wr + i * 16 + lk * 4 + r;
#pragma unroll
      for (int j = 0; j < 4; ++j) {
        int n = n0 + wc + j * 16 + lr;
        if (n < N) {
          float v = acc[i][j][r];
          if (epi == 1) v += R[(size_t)m * N + n];
          if (epi == 2) {
            v = 0.5f * v * (1.0f + erff(v * 0.70710678118654752f));
            short hi, lo;
            split_bf(v, hi, lo);
            ((short*)C)[(size_t)m * N + n] = hi;
            ((short*)C)[cplane + (size_t)m * N + n] = lo;
          } else {
            ((float*)C)[(size_t)m * N + n] = v;
          }
        }
      }
    }
  }
}

// ------- plain bf16 GEMM for logits: C = A @ E^T, E fp32 [N][K] inline-cvt -------
__global__ __launch_bounds__(256) void gemm_logits_kernel(
    const short* __restrict__ A, const float* __restrict__ BT,
    float* __restrict__ C, int M, int N, int K)
{
  __shared__ short Al[128 * RA];
  __shared__ short Bl[128 * RA];
  int tid = threadIdx.x;
  int wave = tid >> 6, lane = tid & 63;
  int wr = (wave >> 1) * 64, wc = (wave & 1) * 64;
  int lr = lane & 15, lk = lane >> 4;
  int m0 = blockIdx.y * 128, n0 = blockIdx.x * 128;
  f32x4 acc[4][4] = {};

  for (int k0 = 0; k0 < K; k0 += 32) {
    __syncthreads();
#pragma unroll
    for (int f = 0; f < 2; ++f) {
      int idx = tid + f * 256, row = idx >> 2, sub = idx & 3;
      uint4 v = *(const uint4*)(A + (size_t)(m0 + row) * K + k0 + sub * 8);
      *(uint4*)(Al + row * RA + sub * 8) = v;
    }
#pragma unroll
    for (int f = 0; f < 4; ++f) {
      int idx = tid + f * 256, row = idx >> 3, qq = idx & 7;
      int gn = n0 + row;
      float4 v = make_float4(0.f, 0.f, 0.f, 0.f);
      if (gn < N) v = *(const float4*)(BT + (size_t)gn * K + k0 + qq * 4);
      *(short4*)(Bl + row * RA + qq * 4) =
          make_short4(f2bf(v.x), f2bf(v.y), f2bf(v.z), f2bf(v.w));
    }
    __syncthreads();
    short8 af[4], bfr[4];
#pragma unroll
    for (int i = 0; i < 4; ++i)
      af[i] = *(const short8*)(Al + (wr + i * 16 + lr) * RA + lk * 8);
#pragma unroll
    for (int j = 0; j < 4; ++j)
      bfr[j] = *(const short8*)(Bl + (wc + j * 16 + lr) * RA + lk * 8);
#pragma unroll
    for (int i = 0; i < 4; ++i)
#pragma unroll
      for (int j = 0; j < 4; ++j)
        acc[i][j] = __builtin_amdgcn_mfma_f32_16x16x32_bf16(af[i], bfr[j], acc[i][j], 0, 0, 0);
  }
#pragma unroll
  for (int i = 0; i < 4; ++i)
#pragma unroll
    for (int r = 0; r < 4; ++r) {
      int m = m0 + wr + i * 16 + lk * 4 + r;
#pragma unroll
      for (int j = 0; j < 4; ++j) {
        int n = n0 + wc + j * 16 + lr;
        if (n < N) C[(size_t)m * N + n] = acc[i][j][r];
      }
    }
}

// ---------------- indexer scores + exact stable top-k -> index list ------------
__device__ __forceinline__ unsigned int ford(float f) {
  unsigned int u = __float_as_uint(f);
  return (u & 0x80000000u) ? ~u : (u | 0x80000000u);
}

__global__ __launch_bounds__(256) void idx_topk_kernel(
    const float* __restrict__ Hp, int* __restrict__ TOPI)
{
  int bq = blockIdx.x;
  int q = bq & (S_LEN - 1);
  int b = bq >> 10;
  int tid = threadIdx.x;
  int n = q + 1;
  if (n <= TOPK_N) {
    for (int i = tid; i < n; i += 256) TOPI[(size_t)bq * TOPK_N + i] = i;
    return;
  }
  __shared__ float qi_s[HI_N * DI_N];
  __shared__ float wt_s[HI_N];
  __shared__ float sc[S_LEN];
  __shared__ unsigned long long keys[S_LEN];
  qi_s[tid] = Hp[(size_t)bq * PLD + COL_QI + tid];
  if (tid < HI_N) wt_s[tid] = Hp[(size_t)bq * PLD + COL_WT + tid];
  __syncthreads();
  // scores: sum_h wt[h]*relu(qi[h,:].ki[k,:]) -- exact zeros matter for ties
  for (int k = tid; k < n; k += 256) {
    const float* kr = Hp + (size_t)(b * S_LEN + k) * PLD + COL_KI;
    float d0 = 0.f, d1 = 0.f, d2 = 0.f, d3 = 0.f;
#pragma unroll
    for (int d = 0; d < DI_N; ++d) {
      float kv = kr[d];
      d0 = fmaf(qi_s[d], kv, d0);
      d1 = fmaf(qi_s[64 + d], kv, d1);
      d2 = fmaf(qi_s[128 + d], kv, d2);
      d3 = fmaf(qi_s[192 + d], kv, d3);
    }
    sc[k] = wt_s[0] * fmaxf(d0, 0.f) + wt_s[1] * fmaxf(d1, 0.f)
          + wt_s[2] * fmaxf(d2, 0.f) + wt_s[3] * fmaxf(d3, 0.f);
  }
  __syncthreads();
  // keys: (ordered score)<<32 | (1023-k); descending sort => stable top-k
  for (int i = tid; i < S_LEN; i += 256) {
    unsigned long long kk = 0ull;  // padding sorts last
    if (i < n) kk = ((unsigned long long)ford(sc[i]) << 32) | (unsigned int)(S_LEN - 1 - i);
    keys[i] = kk;
  }
  __syncthreads();
  for (int size = 2; size <= S_LEN; size <<= 1) {
    for (int stride = size >> 1; stride > 0; stride >>= 1) {
      for (int t = tid; t < S_LEN / 2; t += 256) {
        int j = t & (stride - 1);
        int lo = ((t ^ j) << 1) | j;
        int hi = lo | stride;
        unsigned long long a = keys[lo], c = keys[hi];
        bool desc = ((lo & size) == 0);
        bool sw = desc ? (a < c) : (a > c);
        if (sw) { keys[lo] = c; keys[hi] = a; }
      }
      __syncthreads();
    }
  }
  for (int i = tid; i < TOPK_N; i += 256)
    TOPI[(size_t)bq * TOPK_N + i] = S_LEN - 1 - (int)(keys[i] & 0xFFFFFFFFull);
}

// ------- masked attention via compact index list; split-bf16 output -------
__global__ __launch_bounds__(256) void attn_kernel(
    const float* __restrict__ Hp, const int* __restrict__ TOPI,
    short* __restrict__ O /* [2][BSROWS][D] */)
{
  int q = blockIdx.x, h = blockIdx.y, b = blockIdx.z;
  int tid = threadIdx.x;
  int bq = b * S_LEN + q;
  int cnt = min(q + 1, TOPK_N);
  __shared__ float qv[DHD];
  __shared__ float p[TOPK_N];
  __shared__ float red[4];
  __shared__ float sh_m, sh_s;
  __shared__ float racc[256];
  if (tid < DHD) qv[tid] = Hp[(size_t)bq * PLD + COL_Q + h * DHD + tid];
  __syncthreads();
  const int* list = TOPI + (size_t)bq * TOPK_N;
  float lmax = -3.402823466e38f;
  for (int i = tid; i < cnt; i += 256) {
    int k = list[i];
    const float* kr = Hp + ((size_t)(b * S_LEN + k)) * PLD + COL_K + h * DHD;
    float acc = 0.f;
#pragma unroll
    for (int d = 0; d < DHD; ++d) acc = fmaf(qv[d], kr[d], acc);
    float s = acc * 0.125f;
    p[i] = s;
    lmax = fmaxf(lmax, s);
  }
  for (int o = 32; o; o >>= 1) lmax = fmaxf(lmax, __shfl_down(lmax, o));
  if ((tid & 63) == 0) red[tid >> 6] = lmax;
  __syncthreads();
  if (tid == 0) sh_m = fmaxf(fmaxf(red[0], red[1]), fmaxf(red[2], red[3]));
  __syncthreads();
  float m = sh_m;
  float lsum = 0.f;
  for (int i = tid; i < cnt; i += 256) {
    float e = expf(p[i] - m);
    p[i] = e;
    lsum += e;
  }
  for (int o = 32; o; o >>= 1) lsum += __shfl_down(lsum, o);
  __syncthreads();
  if ((tid & 63) == 0) red[tid >> 6] = lsum;
  __syncthreads();
  if (tid == 0) sh_s = red[0] + red[1] + red[2] + red[3];
  int d = tid & 63, sl = tid >> 6;
  float acc = 0.f;
  for (int i = sl; i < cnt; i += 4) {
    int k = list[i];
    acc = fmaf(p[i], Hp[((size_t)(b * S_LEN + k)) * PLD + COL_V + h * DHD + d], acc);
  }
  racc[tid] = acc;
  __syncthreads();
  if (tid < 64) {
    float o = (racc[tid] + racc[tid + 64] + racc[tid + 128] + racc[tid + 192]) / sh_s;
    short hi, lo;
    split_bf(o, hi, lo);
    size_t ofs = (size_t)bq * D_DIM + h * DHD + tid;
    O[ofs] = hi;
    O[(size_t)BSROWS * D_DIM + ofs] = lo;
  }
}

// ---------------- host orchestration ----------------
extern "C" void kernel_launch(void* const* d_in, const int* in_sizes, int n_in,
                              void* d_out, int out_size, void* d_ws, size_t ws_size,
                              hipStream_t stream) {
  (void)in_sizes; (void)n_in; (void)out_size; (void)ws_size;
  const int*   tokens  = (const int*)d_in[0];
  const float* embed_w = (const float*)d_in[1];
  const float* pos_w   = (const float*)d_in[2];
  const float* wq      = (const float*)d_in[3];
  const float* wk      = (const float*)d_in[4];
  const float* wv      = (const float*)d_in[5];
  const float* wo      = (const float*)d_in[6];
  const float* iqw     = (const float*)d_in[7];
  const float* ikw     = (const float*)d_in[8];
  const float* iww     = (const float*)d_in[9];
  const float* w1      = (const float*)d_in[10];
  const float* w2      = (const float*)d_in[11];
  const float* n1      = (const float*)d_in[12];
  const float* n2      = (const float*)d_in[13];
  const float* nf      = (const float*)d_in[14];
  float* logits = (float*)d_out;

  // final-norm bf16 A operand (must survive to logits GEMM) -> ws (4.2 MB)
  short* Hbf = (short*)d_ws;
  // everything else in d_out scratch (412 MB; dead before logits GEMM writes)
  float* X     = logits;                                      // [2048,1024] fp32
  float* Hp    = X + (size_t)BSROWS * D_DIM;                  // [2048,3396] fp32
  short* Hsp   = (short*)(Hp + (size_t)BSROWS * PLD);         // [2][2048][1024]
  short* AOsp  = Hsp  + (size_t)2 * BSROWS * D_DIM;           // [2][2048][1024]
  short* FFsp  = AOsp + (size_t)2 * BSROWS * D_DIM;           // [2][2048][4096]
  int*   TOPI  = (int*)(FFsp + (size_t)2 * BSROWS * FF_DIM);  // [2048][512]
  short* BTproj = (short*)(TOPI + (size_t)BSROWS * TOPK_N);   // [2][3456][1024]
  short* BTwo  = BTproj + (size_t)2 * PROJ_NPAD * D_DIM;      // [2][1024][1024]
  short* BTw1  = BTwo + (size_t)2 * D_DIM * D_DIM;            // [2][4096][1024]
  short* BTw2  = BTw1 + (size_t)2 * FF_DIM * D_DIM;           // [2][1024][4096]

  const size_t plH  = (size_t)BSROWS * D_DIM;
  const size_t plFF = (size_t)BSROWS * FF_DIM;
  const size_t plPj = (size_t)PROJ_NPAD * D_DIM;
  const size_t plDD = (size_t)D_DIM * D_DIM;
  const size_t plFD = (size_t)FF_DIM * D_DIM;

  hipLaunchKernelGGL(embed_kernel, dim3(BSROWS), dim3(256), 0, stream,
                     tokens, embed_w, pos_w, X);

  for (int l = 0; l < NL; ++l) {
    const float* lwq = wq + (size_t)l * plDD;
    const float* lwk = wk + (size_t)l * plDD;
    const float* lwv = wv + (size_t)l * plDD;
    const float* lwo = wo + (size_t)l * plDD;
    const float* liq = iqw + (size_t)l * D_DIM * (HI_N * DI_N);
    const float* lik = ikw + (size_t)l * D_DIM * DI_N;
    const float* liw = iww + (size_t)l * D_DIM * HI_N;
    const float* lw1 = w1 + (size_t)l * plFD;
    const float* lw2 = w2 + (size_t)l * plFD;

    hipLaunchKernelGGL(rmsnorm_split_kernel, dim3(BSROWS), dim3(256), 0, stream,
                       X, n1 + (size_t)l * D_DIM, Hsp);
    hipLaunchKernelGGL(pack_proj_kernel, dim3(PROJ_NPAD / 32, 32), dim3(32, 8), 0, stream,
                       lwq, lwk, lwv, liq, lik, liw, BTproj);
    hipLaunchKernelGGL(gemm_split_kernel, dim3(PROJ_NPAD / 128, 16), dim3(256), 0, stream,
                       Hsp, plH, BTproj, plPj, nullptr, Hp, 0, BSROWS, PLD, D_DIM, 0);
    hipLaunchKernelGGL(idx_topk_kernel, dim3(BSROWS), dim3(256), 0, stream, Hp, TOPI);
    hipLaunchKernelGGL(attn_kernel, dim3(S_LEN, NH, 2), dim3(256), 0, stream,
                       Hp, TOPI, AOsp);
    hipLaunchKernelGGL(packT_split_kernel, dim3(32, 32), dim3(32, 8), 0, stream,
                       lwo, BTwo, plDD, D_DIM, D_DIM);
    hipLaunchKernelGGL(gemm_split_kernel, dim3(8, 16), dim3(256), 0, stream,
                       AOsp, plH, BTwo, plDD, X, X, 0, BSROWS, D_DIM, D_DIM, 1);
    hipLaunchKernelGGL(rmsnorm_split_kernel, dim3(BSROWS), dim3(256), 0, stream,
                       X, n2 + (size_t)l * D_DIM, Hsp);
    hipLaunchKernelGGL(packT_split_kernel, dim3(FF_DIM / 32, 32), dim3(32, 8), 0, stream,
                       lw1, BTw1, plFD, D_DIM, FF_DIM);
    hipLaunchKernelGGL(gemm_split_kernel, dim3(32, 16), dim3(256), 0, stream,
                       Hsp, plH, BTw1, plFD, nullptr, FFsp, plFF, BSROWS, FF_DIM, D_DIM, 2);
    hipLaunchKernelGGL(packT_split_kernel, dim3(D_DIM / 32, FF_DIM / 32), dim3(32, 8), 0, stream,
                       lw2, BTw2, plFD, FF_DIM, D_DIM);
    hipLaunchKernelGGL(gemm_split_kernel, dim3(8, 16), dim3(256), 0, stream,
                       FFsp, plFF, BTw2, plFD, X, X, 0, BSROWS, D_DIM, FF_DIM, 1);
  }

  hipLaunchKernelGGL(rmsnorm_bf_kernel, dim3(BSROWS), dim3(256), 0, stream, X, nf, Hbf);
  // logits = Hbf @ embed^T ; embed [V][K] fp32 is already B^T layout -> inline cvt
  hipLaunchKernelGGL(gemm_logits_kernel, dim3((50257 + 127) / 128, 16), dim3(256), 0, stream,
                     Hbf, embed_w, logits, BSROWS, 50257, D_DIM);
}

// Round 5
// 5402.324 us; speedup vs baseline: 5.3871x; 2.3283x over previous
//
#include <hip/hip_runtime.h>
#include <cstdint>
#include <cstddef>

#define S_LEN 1024
#define D_DIM 1024
#define NH 16
#define DHD 64
#define NL 8
#define FF_DIM 4096
#define HI_N 4
#define DI_N 64
#define TOPK_N 512
#define BSROWS 2048  // B * S

// packed projection layout (columns of Hp): [Q|K|V|QI|KI|WT]
#define PLD 3396
#define COL_Q 0
#define COL_K 1024
#define COL_V 2048
#define COL_QI 3072
#define COL_KI 3328
#define COL_WT 3392
#define PROJ_NPAD 3456  // padded row count of BT_proj (multiple of 128)

#define NEGF -3.0e38f

typedef __attribute__((ext_vector_type(8))) short short8;
typedef __attribute__((ext_vector_type(4))) short short4v;
typedef __attribute__((ext_vector_type(4))) float f32x4;

#if __has_builtin(__builtin_amdgcn_mfma_f32_16x16x16bf16_1k)
#define MFMA16(a, b, c) __builtin_amdgcn_mfma_f32_16x16x16bf16_1k((a), (b), (c), 0, 0, 0)
#elif __has_builtin(__builtin_amdgcn_mfma_f32_16x16x16_bf16)
#define MFMA16(a, b, c) __builtin_amdgcn_mfma_f32_16x16x16_bf16((a), (b), (c), 0, 0, 0)
#else
static __device__ __forceinline__ f32x4 mfma16_asm(short4v a, short4v b, f32x4 c) {
  f32x4 d;
  asm volatile("v_mfma_f32_16x16x16_bf16 %0, %1, %2, %3\n\ts_nop 7\n\ts_nop 7"
               : "=v"(d) : "v"(a), "v"(b), "v"(c));
  return d;
}
#define MFMA16(a, b, c) mfma16_asm((a), (b), (c))
#endif

__device__ __forceinline__ short f2bf(float x) {  // RNE fp32->bf16
  unsigned u = __float_as_uint(x);
  u += 0x7FFFu + ((u >> 16) & 1u);
  return (short)(u >> 16);
}
__device__ __forceinline__ float bf2f(short h) {
  return __uint_as_float(((unsigned)(unsigned short)h) << 16);
}
// two-term split: x ~= hi + lo with rel err ~2^-17
__device__ __forceinline__ void split_bf(float x, short& hi, short& lo) {
  hi = f2bf(x);
  lo = f2bf(x - bf2f(hi));
}

// ---------------- embed + positional ----------------
__global__ __launch_bounds__(256) void embed_kernel(
    const int* __restrict__ tokens, const float* __restrict__ E,
    const float* __restrict__ P, float* __restrict__ X)
{
  int bs = blockIdx.x;
  int s = bs & (S_LEN - 1);
  int tid = threadIdx.x;
  int tok = tokens[bs];
  float4 e = ((const float4*)(E + (size_t)tok * D_DIM))[tid];
  float4 p = ((const float4*)(P + (size_t)s * D_DIM))[tid];
  float4 o; o.x = e.x + p.x; o.y = e.y + p.y; o.z = e.z + p.z; o.w = e.w + p.w;
  ((float4*)(X + (size_t)bs * D_DIM))[tid] = o;
}

// ---------------- rmsnorm -> split bf16 (hi plane, lo plane) ----------------
__global__ __launch_bounds__(256) void rmsnorm_split_kernel(
    const float* __restrict__ X, const float* __restrict__ W,
    short* __restrict__ O /* [2][BSROWS][D] */)
{
  int r = blockIdx.x;
  int tid = threadIdx.x;
  float4 v = ((const float4*)(X + (size_t)r * D_DIM))[tid];
  float ss = v.x * v.x + v.y * v.y + v.z * v.z + v.w * v.w;
  __shared__ float red[4];
  __shared__ float sh_inv;
  for (int o = 32; o; o >>= 1) ss += __shfl_down(ss, o);
  if ((tid & 63) == 0) red[tid >> 6] = ss;
  __syncthreads();
  if (tid == 0) {
    float s = red[0] + red[1] + red[2] + red[3];
    sh_inv = 1.0f / (sqrtf(s) * 0.03125f + 1e-6f);
  }
  __syncthreads();
  float inv = sh_inv;
  float4 w = ((const float4*)W)[tid];
  float o0 = w.x * v.x * inv, o1 = w.y * v.y * inv;
  float o2 = w.z * v.z * inv, o3 = w.w * v.w * inv;
  short4 hi, lo;
  split_bf(o0, hi.x, lo.x); split_bf(o1, hi.y, lo.y);
  split_bf(o2, hi.z, lo.z); split_bf(o3, hi.w, lo.w);
  ((short4*)(O + (size_t)r * D_DIM))[tid] = hi;
  ((short4*)(O + (size_t)BSROWS * D_DIM + (size_t)r * D_DIM))[tid] = lo;
}

// ---------------- rmsnorm -> plain bf16 (for logits A-operand) ----------------
__global__ __launch_bounds__(256) void rmsnorm_bf_kernel(
    const float* __restrict__ X, const float* __restrict__ W, short* __restrict__ O)
{
  int r = blockIdx.x;
  int tid = threadIdx.x;
  float4 v = ((const float4*)(X + (size_t)r * D_DIM))[tid];
  float ss = v.x * v.x + v.y * v.y + v.z * v.z + v.w * v.w;
  __shared__ float red[4];
  __shared__ float sh_inv;
  for (int o = 32; o; o >>= 1) ss += __shfl_down(ss, o);
  if ((tid & 63) == 0) red[tid >> 6] = ss;
  __syncthreads();
  if (tid == 0) {
    float s = red[0] + red[1] + red[2] + red[3];
    sh_inv = 1.0f / (sqrtf(s) * 0.03125f + 1e-6f);
  }
  __syncthreads();
  float inv = sh_inv;
  float4 w = ((const float4*)W)[tid];
  short4 o4 = make_short4(f2bf(w.x * v.x * inv), f2bf(w.y * v.y * inv),
                          f2bf(w.z * v.z * inv), f2bf(w.w * v.w * inv));
  ((short4*)(O + (size_t)r * D_DIM))[tid] = o4;
}

// ---------------- transpose-pack W[K][N] fp32 -> BT[2][N][K] split bf16 --------
__global__ __launch_bounds__(256) void packT_split_kernel(
    const float* __restrict__ W, short* __restrict__ BT, size_t plane, int K, int N)
{
  __shared__ float t[32][33];
  int n0 = blockIdx.x * 32, k0 = blockIdx.y * 32;
  int tx = threadIdx.x, ty = threadIdx.y;
#pragma unroll
  for (int r = 0; r < 32; r += 8)
    t[ty + r][tx] = W[(size_t)(k0 + ty + r) * N + n0 + tx];
  __syncthreads();
#pragma unroll
  for (int r = 0; r < 32; r += 8) {
    short hi, lo;
    split_bf(t[tx][ty + r], hi, lo);
    size_t o = (size_t)(n0 + ty + r) * K + k0 + tx;
    BT[o] = hi;
    BT[plane + o] = lo;
  }
}

// pack wq|wk|wv|iq|ik|iw columns into BT_proj [2][PROJ_NPAD][1024] split bf16
__global__ __launch_bounds__(256) void pack_proj_kernel(
    const float* __restrict__ wq, const float* __restrict__ wk,
    const float* __restrict__ wv, const float* __restrict__ iq,
    const float* __restrict__ ik, const float* __restrict__ iw,
    short* __restrict__ BT)
{
  __shared__ float t[32][33];
  const size_t plane = (size_t)PROJ_NPAD * D_DIM;
  int n0 = blockIdx.x * 32, k0 = blockIdx.y * 32;
  int tx = threadIdx.x, ty = threadIdx.y;
  const float* src = nullptr; int ld = 0, c0 = 0;
  if (n0 < 1024)       { src = wq; ld = 1024; c0 = n0; }
  else if (n0 < 2048)  { src = wk; ld = 1024; c0 = n0 - 1024; }
  else if (n0 < 3072)  { src = wv; ld = 1024; c0 = n0 - 2048; }
  else if (n0 < 3328)  { src = iq; ld = 256;  c0 = n0 - 3072; }
  else if (n0 < 3392)  { src = ik; ld = 64;   c0 = n0 - 3328; }
  else if (n0 == 3392) { src = iw; ld = 4;    c0 = 0; }
#pragma unroll
  for (int r = 0; r < 32; r += 8) {
    float v = 0.f;
    int c = c0 + tx;
    if (src && c < ld) v = src[(size_t)(k0 + ty + r) * ld + c];
    t[ty + r][tx] = v;
  }
  __syncthreads();
#pragma unroll
  for (int r = 0; r < 32; r += 8) {
    short hi, lo;
    split_bf(t[tx][ty + r], hi, lo);
    size_t o = (size_t)(n0 + ty + r) * D_DIM + k0 + tx;
    BT[o] = hi;
    BT[plane + o] = lo;
  }
}

// ------- split-bf16 GEMM (fp32-accurate): C = A @ BT^T -------
#define RA 40  // LDS row pitch (elems): 32 + 8 pad, 16B-aligned

__global__ __launch_bounds__(256) void gemm_split_kernel(
    const short* __restrict__ A, size_t aplane,
    const short* __restrict__ BT, size_t bplane,
    const float* __restrict__ R, void* __restrict__ C, size_t cplane,
    int M, int N, int K, int epi)
{
  __shared__ short Al[2 * 128 * RA];
  __shared__ short Bl[2 * 128 * RA];
  int tid = threadIdx.x;
  int wave = tid >> 6, lane = tid & 63;
  int wr = (wave >> 1) * 64, wc = (wave & 1) * 64;
  int lr = lane & 15, lk = lane >> 4;
  int m0 = blockIdx.y * 128, n0 = blockIdx.x * 128;
  f32x4 acc[4][4] = {};

  for (int k0 = 0; k0 < K; k0 += 32) {
    __syncthreads();
#pragma unroll
    for (int f = 0; f < 4; ++f) {
      int idx = tid + f * 256;
      int p = idx >> 9, r2 = idx & 511;
      int row = r2 >> 2, sub = r2 & 3;
      uint4 v = *(const uint4*)(A + (size_t)p * aplane + (size_t)(m0 + row) * K + k0 + sub * 8);
      *(uint4*)(Al + p * 128 * RA + row * RA + sub * 8) = v;
    }
#pragma unroll
    for (int f = 0; f < 4; ++f) {
      int idx = tid + f * 256;
      int p = idx >> 9, r2 = idx & 511;
      int row = r2 >> 2, sub = r2 & 3;
      uint4 v = *(const uint4*)(BT + (size_t)p * bplane + (size_t)(n0 + row) * K + k0 + sub * 8);
      *(uint4*)(Bl + p * 128 * RA + row * RA + sub * 8) = v;
    }
    __syncthreads();
    short8 ah[4], al[4], bh[4], bl[4];
#pragma unroll
    for (int i = 0; i < 4; ++i) {
      ah[i] = *(const short8*)(Al + (wr + i * 16 + lr) * RA + lk * 8);
      al[i] = *(const short8*)(Al + 128 * RA + (wr + i * 16 + lr) * RA + lk * 8);
    }
#pragma unroll
    for (int j = 0; j < 4; ++j) {
      bh[j] = *(const short8*)(Bl + (wc + j * 16 + lr) * RA + lk * 8);
      bl[j] = *(const short8*)(Bl + 128 * RA + (wc + j * 16 + lr) * RA + lk * 8);
    }
#pragma unroll
    for (int i = 0; i < 4; ++i)
#pragma unroll
      for (int j = 0; j < 4; ++j) {
        f32x4 a = acc[i][j];
        a = __builtin_amdgcn_mfma_f32_16x16x32_bf16(al[i], bh[j], a, 0, 0, 0);
        a = __builtin_amdgcn_mfma_f32_16x16x32_bf16(ah[i], bl[j], a, 0, 0, 0);
        a = __builtin_amdgcn_mfma_f32_16x16x32_bf16(ah[i], bh[j], a, 0, 0, 0);
        acc[i][j] = a;
      }
  }
#pragma unroll
  for (int i = 0; i < 4; ++i) {
#pragma unroll
    for (int r = 0; r < 4; ++r) {
      int m = m0 + wr + i * 16 + lk * 4 + r;
#pragma unroll
      for (int j = 0; j < 4; ++j) {
        int n = n0 + wc + j * 16 + lr;
        if (n < N) {
          float v = acc[i][j][r];
          if (epi == 1) v += R[(size_t)m * N + n];
          if (epi == 2) {
            v = 0.5f * v * (1.0f + erff(v * 0.70710678118654752f));
            short hi, lo;
            split_bf(v, hi, lo);
            ((short*)C)[(size_t)m * N + n] = hi;
            ((short*)C)[cplane + (size_t)m * N + n] = lo;
          } else {
            ((float*)C)[(size_t)m * N + n] = v;
          }
        }
      }
    }
  }
}

// ------- plain bf16 GEMM for logits: C = A @ E^T, E fp32 [N][K] inline-cvt -------
__global__ __launch_bounds__(256) void gemm_logits_kernel(
    const short* __restrict__ A, const float* __restrict__ BT,
    float* __restrict__ C, int M, int N, int K)
{
  __shared__ short Al[128 * RA];
  __shared__ short Bl[128 * RA];
  int tid = threadIdx.x;
  int wave = tid >> 6, lane = tid & 63;
  int wr = (wave >> 1) * 64, wc = (wave & 1) * 64;
  int lr = lane & 15, lk = lane >> 4;
  int m0 = blockIdx.y * 128, n0 = blockIdx.x * 128;
  f32x4 acc[4][4] = {};

  for (int k0 = 0; k0 < K; k0 += 32) {
    __syncthreads();
#pragma unroll
    for (int f = 0; f < 2; ++f) {
      int idx = tid + f * 256, row = idx >> 2, sub = idx & 3;
      uint4 v = *(const uint4*)(A + (size_t)(m0 + row) * K + k0 + sub * 8);
      *(uint4*)(Al + row * RA + sub * 8) = v;
    }
#pragma unroll
    for (int f = 0; f < 4; ++f) {
      int idx = tid + f * 256, row = idx >> 3, qq = idx & 7;
      int gn = n0 + row;
      float4 v = make_float4(0.f, 0.f, 0.f, 0.f);
      if (gn < N) v = *(const float4*)(BT + (size_t)gn * K + k0 + qq * 4);
      *(short4*)(Bl + row * RA + qq * 4) =
          make_short4(f2bf(v.x), f2bf(v.y), f2bf(v.z), f2bf(v.w));
    }
    __syncthreads();
    short8 af[4], bfr[4];
#pragma unroll
    for (int i = 0; i < 4; ++i)
      af[i] = *(const short8*)(Al + (wr + i * 16 + lr) * RA + lk * 8);
#pragma unroll
    for (int j = 0; j < 4; ++j)
      bfr[j] = *(const short8*)(Bl + (wc + j * 16 + lr) * RA + lk * 8);
#pragma unroll
    for (int i = 0; i < 4; ++i)
#pragma unroll
      for (int j = 0; j < 4; ++j)
        acc[i][j] = __builtin_amdgcn_mfma_f32_16x16x32_bf16(af[i], bfr[j], acc[i][j], 0, 0, 0);
  }
#pragma unroll
  for (int i = 0; i < 4; ++i)
#pragma unroll
    for (int r = 0; r < 4; ++r) {
      int m = m0 + wr + i * 16 + lk * 4 + r;
#pragma unroll
      for (int j = 0; j < 4; ++j) {
        int n = n0 + wc + j * 16 + lr;
        if (n < N) C[(size_t)m * N + n] = acc[i][j][r];
      }
    }
}

// ---------------- K/V fp32 -> bf16 compact rows ----------------
__global__ __launch_bounds__(256) void kv_cvt_kernel(
    const float* __restrict__ Hp, short* __restrict__ Kbf, short* __restrict__ Vbf)
{
  int bs = blockIdx.x;
  int tid = threadIdx.x;
  const float* row = Hp + (size_t)bs * PLD;
  float4 kv = ((const float4*)(row + COL_K))[tid];
  float4 vv = ((const float4*)(row + COL_V))[tid];
  ((short4*)(Kbf + (size_t)bs * D_DIM))[tid] =
      make_short4(f2bf(kv.x), f2bf(kv.y), f2bf(kv.z), f2bf(kv.w));
  ((short4*)(Vbf + (size_t)bs * D_DIM))[tid] =
      make_short4(f2bf(vv.x), f2bf(vv.y), f2bf(vv.z), f2bf(vv.w));
}

// ---------------- indexer scores + exact stable top-k -> bitmask ----------------
__device__ __forceinline__ unsigned int ford(float f) {
  unsigned int u = __float_as_uint(f);
  return (u & 0x80000000u) ? ~u : (u | 0x80000000u);
}

__global__ __launch_bounds__(256) void idx_topk_kernel(
    const float* __restrict__ Hp, unsigned int* __restrict__ MASK)
{
  int bq = blockIdx.x;
  int q = bq & (S_LEN - 1);
  int b = bq >> 10;
  int tid = threadIdx.x;
  int n = q + 1;
  if (n <= TOPK_N) {
    if (tid < 32) {
      int full = n >> 5, rem = n & 31;
      unsigned int w = 0u;
      if (tid < full) w = 0xFFFFFFFFu;
      else if (tid == full && rem) w = (1u << rem) - 1u;
      MASK[(size_t)bq * 32 + tid] = w;
    }
    return;
  }
  __shared__ float qi_s[HI_N * DI_N];
  __shared__ float wt_s[HI_N];
  __shared__ float sc[S_LEN];
  __shared__ unsigned long long keys[S_LEN];
  __shared__ unsigned int mw[32];
  qi_s[tid] = Hp[(size_t)bq * PLD + COL_QI + tid];
  if (tid < HI_N) wt_s[tid] = Hp[(size_t)bq * PLD + COL_WT + tid];
  __syncthreads();
  for (int k = tid; k < n; k += 256) {
    const float* kr = Hp + (size_t)(b * S_LEN + k) * PLD + COL_KI;
    float d0 = 0.f, d1 = 0.f, d2 = 0.f, d3 = 0.f;
#pragma unroll
    for (int d = 0; d < DI_N; ++d) {
      float kv = kr[d];
      d0 = fmaf(qi_s[d], kv, d0);
      d1 = fmaf(qi_s[64 + d], kv, d1);
      d2 = fmaf(qi_s[128 + d], kv, d2);
      d3 = fmaf(qi_s[192 + d], kv, d3);
    }
    sc[k] = wt_s[0] * fmaxf(d0, 0.f) + wt_s[1] * fmaxf(d1, 0.f)
          + wt_s[2] * fmaxf(d2, 0.f) + wt_s[3] * fmaxf(d3, 0.f);
  }
  __syncthreads();
  for (int i = tid; i < S_LEN; i += 256) {
    unsigned long long kk = 0ull;
    if (i < n) kk = ((unsigned long long)ford(sc[i]) << 32) | (unsigned int)(S_LEN - 1 - i);
    keys[i] = kk;
  }
  __syncthreads();
  for (int size = 2; size <= S_LEN; size <<= 1) {
    for (int stride = size >> 1; stride > 0; stride >>= 1) {
      for (int t = tid; t < S_LEN / 2; t += 256) {
        int j = t & (stride - 1);
        int lo = ((t ^ j) << 1) | j;
        int hi = lo | stride;
        unsigned long long a = keys[lo], c = keys[hi];
        bool desc = ((lo & size) == 0);
        bool sw = desc ? (a < c) : (a > c);
        if (sw) { keys[lo] = c; keys[hi] = a; }
      }
      __syncthreads();
    }
  }
  if (tid < 32) mw[tid] = 0u;
  __syncthreads();
  for (int i = tid; i < TOPK_N; i += 256) {
    int k = S_LEN - 1 - (int)(keys[i] & 0xFFFFFFFFull);
    atomicOr(&mw[k >> 5], 1u << (k & 31));
  }
  __syncthreads();
  if (tid < 32) MASK[(size_t)bq * 32 + tid] = mw[tid];
}

// ------- masked-dense flash attention via 16x16x16 MFMA -------
// Block: (q-tile 64, head, batch). 4 waves; wave w owns q-cols w*16..+16.
// S^T = mfma(A=K-frag, B=Q-frag) -> C[k][q]; in-lane P becomes PV's A-frag
// (K=16 shapes: C k-index (l>>4)*4+r == A/B k-index (l>>4)*4+j).
__global__ __launch_bounds__(256) void attn_mfma_kernel(
    const float* __restrict__ Hp, const short* __restrict__ Kbf,
    const short* __restrict__ Vbf, const unsigned int* __restrict__ MASK,
    short* __restrict__ O /* [2][BSROWS][D] split bf16 */)
{
  __shared__ unsigned int mlds[64 * 32];  // 8KB: mask words for 64 q-rows
  __shared__ short Kl[64 * 72];           // K tile [key][d], pitch 72
  __shared__ short Vtl[64 * 68];          // V^T tile [d][key], pitch 68
  int qt = blockIdx.x, h = blockIdx.y, b = blockIdx.z;
  int tid = threadIdx.x;
  int w = tid >> 6, l = tid & 63;
  int lq = l & 15, g = l >> 4;
  int q0 = qt * 64;

#pragma unroll
  for (int i = 0; i < 8; ++i) {
    int idx = tid + i * 256;
    mlds[idx] = MASK[((size_t)(b * S_LEN + q0 + (idx >> 5))) * 32 + (idx & 31)];
  }
  // Q B-frags (bf16), q = q0 + w*16 + lq, d = dt*16 + g*4 + j
  short4v qf[4];
  {
    const float* qrow = Hp + ((size_t)(b * S_LEN + q0 + w * 16 + lq)) * PLD + COL_Q + h * DHD;
#pragma unroll
    for (int dt = 0; dt < 4; ++dt) {
      short4v t;
#pragma unroll
      for (int j = 0; j < 4; ++j) t[j] = f2bf(qrow[dt * 16 + g * 4 + j]);
      qf[dt] = t;
    }
  }
  f32x4 acc_o[4] = {};
  float m_run = -1.0e30f, l_run = 0.f;
  const short* Kb = Kbf + (size_t)b * S_LEN * D_DIM;
  const short* Vb = Vbf + (size_t)b * S_LEN * D_DIM;
  const int mrow = w * 16 + lq;  // this lane's q-row in mlds

  for (int kt = 0; kt <= qt; ++kt) {
    __syncthreads();
    // stage K tile: [64 key][64 d] -> Kl pitch 72 (uint4, 16B-aligned)
#pragma unroll
    for (int i = 0; i < 2; ++i) {
      int idx = tid + i * 256;  // 0..511
      int row = idx >> 3, sub = idx & 7;
      uint4 v = *(const uint4*)(Kb + (size_t)(kt * 64 + row) * D_DIM + h * DHD + sub * 8);
      *(uint4*)(Kl + row * 72 + sub * 8) = v;
    }
    // stage V^T: [64 d][64 key] pitch 68, 2-key-packed b32 writes
    {
      int u = tid >> 1, half = tid & 1;  // u 0..127
      int kg = u >> 3, dg = u & 7;
      int krow = kt * 64 + kg * 4 + half * 2;
      uint4 v0 = *(const uint4*)(Vb + (size_t)krow * D_DIM + h * DHD + dg * 8);
      uint4 v1 = *(const uint4*)(Vb + (size_t)(krow + 1) * D_DIM + h * DHD + dg * 8);
      const short* s0 = (const short*)&v0;
      const short* s1 = (const short*)&v1;
#pragma unroll
      for (int j = 0; j < 8; ++j)
        *(short2*)(Vtl + (dg * 8 + j) * 68 + kg * 4 + half * 2) = make_short2(s0[j], s1[j]);
    }
    __syncthreads();
    // S^T[key][q] = sum_d K[key][d] Q[q][d]
    f32x4 s[4] = {};
#pragma unroll
    for (int dt = 0; dt < 4; ++dt)
#pragma unroll
      for (int ks = 0; ks < 4; ++ks) {
        short4v kf = *(const short4v*)(Kl + (ks * 16 + lq) * 72 + dt * 16 + g * 4);
        s[ks] = MFMA16(kf, qf[dt], s[ks]);
      }
    // mask + scale; lane holds keys ks*16 + g*4 + r for q-col = lq (use mrow's mask)
    float mx = NEGF;
#pragma unroll
    for (int ks = 0; ks < 4; ++ks) {
      int kbase = kt * 64 + ks * 16 + g * 4;
      unsigned mwv = mlds[mrow * 32 + (kbase >> 5)];
#pragma unroll
      for (int r = 0; r < 4; ++r) {
        float sv = ((mwv >> ((kbase + r) & 31)) & 1u) ? s[ks][r] * 0.125f : NEGF;
        s[ks][r] = sv;
        mx = fmaxf(mx, sv);
      }
    }
    mx = fmaxf(mx, __shfl_xor(mx, 16));
    mx = fmaxf(mx, __shfl_xor(mx, 32));
    float m_new = fmaxf(m_run, mx);
    float scale = __expf(m_run - m_new);
    float lsum = 0.f;
    short4v pf[4];
#pragma unroll
    for (int ks = 0; ks < 4; ++ks) {
      short4v t;
#pragma unroll
      for (int r = 0; r < 4; ++r) {
        float p = __expf(s[ks][r] - m_new);
        lsum += p;
        t[r] = f2bf(p);
      }
      pf[ks] = t;
    }
    lsum += __shfl_xor(lsum, 16);
    lsum += __shfl_xor(lsum, 32);
    l_run = l_run * scale + lsum;
    m_run = m_new;
    // rescale O rows (q = g*4+r): fetch those q's scale from lanes 0..15
    float sc[4];
#pragma unroll
    for (int r = 0; r < 4; ++r) sc[r] = __shfl(scale, g * 4 + r);
#pragma unroll
    for (int dt = 0; dt < 4; ++dt) {
      f32x4 a = acc_o[dt];
      a[0] *= sc[0]; a[1] *= sc[1]; a[2] *= sc[2]; a[3] *= sc[3];
#pragma unroll
      for (int ks = 0; ks < 4; ++ks) {
        short4v vf = *(const short4v*)(Vtl + (dt * 16 + lq) * 68 + ks * 16 + g * 4);
        a = MFMA16(pf[ks], vf, a);  // A = P[q][k], B = V^T[d][k]
      }
      acc_o[dt] = a;
    }
  }
  float linv[4];
#pragma unroll
  for (int r = 0; r < 4; ++r) linv[r] = 1.0f / __shfl(l_run, g * 4 + r);
  // O C-layout: row q = q0 + w*16 + g*4 + r, col d = h*64 + dt*16 + lq
#pragma unroll
  for (int dt = 0; dt < 4; ++dt)
#pragma unroll
    for (int r = 0; r < 4; ++r) {
      int q = q0 + w * 16 + g * 4 + r;
      float o = acc_o[dt][r] * linv[r];
      short hi, lo;
      split_bf(o, hi, lo);
      size_t ofs = (size_t)(b * S_LEN + q) * D_DIM + h * DHD + dt * 16 + lq;
      O[ofs] = hi;
      O[(size_t)BSROWS * D_DIM + ofs] = lo;
    }
}

// ---------------- host orchestration ----------------
extern "C" void kernel_launch(void* const* d_in, const int* in_sizes, int n_in,
                              void* d_out, int out_size, void* d_ws, size_t ws_size,
                              hipStream_t stream) {
  (void)in_sizes; (void)n_in; (void)out_size; (void)ws_size;
  const int*   tokens  = (const int*)d_in[0];
  const float* embed_w = (const float*)d_in[1];
  const float* pos_w   = (const float*)d_in[2];
  const float* wq      = (const float*)d_in[3];
  const float* wk      = (const float*)d_in[4];
  const float* wv      = (const float*)d_in[5];
  const float* wo      = (const float*)d_in[6];
  const float* iqw     = (const float*)d_in[7];
  const float* ikw     = (const float*)d_in[8];
  const float* iww     = (const float*)d_in[9];
  const float* w1      = (const float*)d_in[10];
  const float* w2      = (const float*)d_in[11];
  const float* n1      = (const float*)d_in[12];
  const float* n2      = (const float*)d_in[13];
  const float* nf      = (const float*)d_in[14];
  float* logits = (float*)d_out;

  // final-norm bf16 A operand (must survive to logits GEMM) -> ws
  short* Hbf = (short*)d_ws;
  // everything else in d_out scratch (412 MB; dead before logits GEMM writes)
  float* X     = logits;                                      // [2048,1024] fp32
  float* Hp    = X + (size_t)BSROWS * D_DIM;                  // [2048,3396] fp32
  short* Hsp   = (short*)(Hp + (size_t)BSROWS * PLD);         // [2][2048][1024]
  short* AOsp  = Hsp  + (size_t)2 * BSROWS * D_DIM;           // [2][2048][1024]
  short* FFsp  = AOsp + (size_t)2 * BSROWS * D_DIM;           // [2][2048][4096]
  unsigned int* MASKb = (unsigned int*)(FFsp + (size_t)2 * BSROWS * FF_DIM);  // [2048][32]
  short* BTproj = (short*)(MASKb + (size_t)BSROWS * 32);      // [2][3456][1024]
  short* BTwo  = BTproj + (size_t)2 * PROJ_NPAD * D_DIM;      // [2][1024][1024]
  short* BTw1  = BTwo + (size_t)2 * D_DIM * D_DIM;            // [2][4096][1024]
  short* BTw2  = BTw1 + (size_t)2 * FF_DIM * D_DIM;           // [2][1024][4096]
  short* Kbf   = BTw2 + (size_t)2 * FF_DIM * D_DIM;           // [2048][1024] bf16
  short* Vbf   = Kbf  + (size_t)BSROWS * D_DIM;               // [2048][1024] bf16

  const size_t plH  = (size_t)BSROWS * D_DIM;
  const size_t plFF = (size_t)BSROWS * FF_DIM;
  const size_t plPj = (size_t)PROJ_NPAD * D_DIM;
  const size_t plDD = (size_t)D_DIM * D_DIM;
  const size_t plFD = (size_t)FF_DIM * D_DIM;

  hipLaunchKernelGGL(embed_kernel, dim3(BSROWS), dim3(256), 0, stream,
                     tokens, embed_w, pos_w, X);

  for (int l = 0; l < NL; ++l) {
    const float* lwq = wq + (size_t)l * plDD;
    const float* lwk = wk + (size_t)l * plDD;
    const float* lwv = wv + (size_t)l * plDD;
    const float* lwo = wo + (size_t)l * plDD;
    const float* liq = iqw + (size_t)l * D_DIM * (HI_N * DI_N);
    const float* lik = ikw + (size_t)l * D_DIM * DI_N;
    const float* liw = iww + (size_t)l * D_DIM * HI_N;
    const float* lw1 = w1 + (size_t)l * plFD;
    const float* lw2 = w2 + (size_t)l * plFD;

    hipLaunchKernelGGL(rmsnorm_split_kernel, dim3(BSROWS), dim3(256), 0, stream,
                       X, n1 + (size_t)l * D_DIM, Hsp);
    hipLaunchKernelGGL(pack_proj_kernel, dim3(PROJ_NPAD / 32, 32), dim3(32, 8), 0, stream,
                       lwq, lwk, lwv, liq, lik, liw, BTproj);
    hipLaunchKernelGGL(gemm_split_kernel, dim3(PROJ_NPAD / 128, 16), dim3(256), 0, stream,
                       Hsp, plH, BTproj, plPj, nullptr, Hp, 0, BSROWS, PLD, D_DIM, 0);
    hipLaunchKernelGGL(kv_cvt_kernel, dim3(BSROWS), dim3(256), 0, stream, Hp, Kbf, Vbf);
    hipLaunchKernelGGL(idx_topk_kernel, dim3(BSROWS), dim3(256), 0, stream, Hp, MASKb);
    hipLaunchKernelGGL(attn_mfma_kernel, dim3(S_LEN / 64, NH, 2), dim3(256), 0, stream,
                       Hp, Kbf, Vbf, MASKb, AOsp);
    hipLaunchKernelGGL(packT_split_kernel, dim3(32, 32), dim3(32, 8), 0, stream,
                       lwo, BTwo, plDD, D_DIM, D_DIM);
    hipLaunchKernelGGL(gemm_split_kernel, dim3(8, 16), dim3(256), 0, stream,
                       AOsp, plH, BTwo, plDD, X, X, 0, BSROWS, D_DIM, D_DIM, 1);
    hipLaunchKernelGGL(rmsnorm_split_kernel, dim3(BSROWS), dim3(256), 0, stream,
                       X, n2 + (size_t)l * D_DIM, Hsp);
    hipLaunchKernelGGL(packT_split_kernel, dim3(FF_DIM / 32, 32), dim3(32, 8), 0, stream,
                       lw1, BTw1, plFD, D_DIM, FF_DIM);
    hipLaunchKernelGGL(gemm_split_kernel, dim3(32, 16), dim3(256), 0, stream,
                       Hsp, plH, BTw1, plFD, nullptr, FFsp, plFF, BSROWS, FF_DIM, D_DIM, 2);
    hipLaunchKernelGGL(packT_split_kernel, dim3(D_DIM / 32, FF_DIM / 32), dim3(32, 8), 0, stream,
                       lw2, BTw2, plFD, FF_DIM, D_DIM);
    hipLaunchKernelGGL(gemm_split_kernel, dim3(8, 16), dim3(256), 0, stream,
                       FFsp, plFF, BTw2, plFD, X, X, 0, BSROWS, D_DIM, FF_DIM, 1);
  }

  hipLaunchKernelGGL(rmsnorm_bf_kernel, dim3(BSROWS), dim3(256), 0, stream, X, nf, Hbf);
  hipLaunchKernelGGL(gemm_logits_kernel, dim3((50257 + 127) / 128, 16), dim3(256), 0, stream,
                     Hbf, embed_w, logits, BSROWS, 50257, D_DIM);
}

// Round 6
// 5185.729 us; speedup vs baseline: 5.6121x; 1.0418x over previous
//
#include <hip/hip_runtime.h>
#include <cstdint>
#include <cstddef>

#define S_LEN 1024
#define D_DIM 1024
#define NH 16
#define DHD 64
#define NL 8
#define FF_DIM 4096
#define HI_N 4
#define DI_N 64
#define TOPK_N 512
#define BSROWS 2048  // B * S
#define VOCAB 50257

// compact QKV layout: [Q 0..1023 | K 1024..2047 | V 2048..3071], bf16
#define QKV_LD 3072
// indexer block layout (fp32): [QI 0..255 | KI 256..319 | WT 320..323 | pad..383]
#define IDX_LD 384
#define COL_QI 0
#define COL_KI 256
#define COL_WT 320

#define NEGF -3.0e38f

typedef __attribute__((ext_vector_type(8))) short short8;
typedef __attribute__((ext_vector_type(4))) short short4v;
typedef __attribute__((ext_vector_type(4))) float f32x4;

#if __has_builtin(__builtin_amdgcn_mfma_f32_16x16x16bf16_1k)
#define MFMA16(a, b, c) __builtin_amdgcn_mfma_f32_16x16x16bf16_1k((a), (b), (c), 0, 0, 0)
#elif __has_builtin(__builtin_amdgcn_mfma_f32_16x16x16_bf16)
#define MFMA16(a, b, c) __builtin_amdgcn_mfma_f32_16x16x16_bf16((a), (b), (c), 0, 0, 0)
#else
static __device__ __forceinline__ f32x4 mfma16_asm(short4v a, short4v b, f32x4 c) {
  f32x4 d;
  asm volatile("v_mfma_f32_16x16x16_bf16 %0, %1, %2, %3\n\ts_nop 7\n\ts_nop 7"
               : "=v"(d) : "v"(a), "v"(b), "v"(c));
  return d;
}
#define MFMA16(a, b, c) mfma16_asm((a), (b), (c))
#endif

__device__ __forceinline__ short f2bf(float x) {  // RNE fp32->bf16
  unsigned u = __float_as_uint(x);
  u += 0x7FFFu + ((u >> 16) & 1u);
  return (short)(u >> 16);
}
__device__ __forceinline__ float bf2f(short h) {
  return __uint_as_float(((unsigned)(unsigned short)h) << 16);
}
// two-term split: x ~= hi + lo with rel err ~2^-17
__device__ __forceinline__ void split_bf(float x, short& hi, short& lo) {
  hi = f2bf(x);
  lo = f2bf(x - bf2f(hi));
}

// ---------------- embed + positional ----------------
__global__ __launch_bounds__(256) void embed_kernel(
    const int* __restrict__ tokens, const float* __restrict__ E,
    const float* __restrict__ P, float* __restrict__ X)
{
  int bs = blockIdx.x;
  int s = bs & (S_LEN - 1);
  int tid = threadIdx.x;
  int tok = tokens[bs];
  float4 e = ((const float4*)(E + (size_t)tok * D_DIM))[tid];
  float4 p = ((const float4*)(P + (size_t)s * D_DIM))[tid];
  float4 o; o.x = e.x + p.x; o.y = e.y + p.y; o.z = e.z + p.z; o.w = e.w + p.w;
  ((float4*)(X + (size_t)bs * D_DIM))[tid] = o;
}

// ---------------- embed fp32 -> bf16 (grid-stride) ----------------
__global__ __launch_bounds__(256) void cvt_embed_kernel(
    const float* __restrict__ E, short* __restrict__ Ebf, long total4)
{
  long i = (long)blockIdx.x * 256 + threadIdx.x;
  long stride = (long)gridDim.x * 256;
  for (; i < total4; i += stride) {
    float4 v = ((const float4*)E)[i];
    ((short4*)Ebf)[i] = make_short4(f2bf(v.x), f2bf(v.y), f2bf(v.z), f2bf(v.w));
  }
}

// ---------------- rmsnorm -> split bf16 (hi plane, lo plane) ----------------
__global__ __launch_bounds__(256) void rmsnorm_split_kernel(
    const float* __restrict__ X, const float* __restrict__ W,
    short* __restrict__ O /* [2][BSROWS][D] */)
{
  int r = blockIdx.x;
  int tid = threadIdx.x;
  float4 v = ((const float4*)(X + (size_t)r * D_DIM))[tid];
  float ss = v.x * v.x + v.y * v.y + v.z * v.z + v.w * v.w;
  __shared__ float red[4];
  __shared__ float sh_inv;
  for (int o = 32; o; o >>= 1) ss += __shfl_down(ss, o);
  if ((tid & 63) == 0) red[tid >> 6] = ss;
  __syncthreads();
  if (tid == 0) {
    float s = red[0] + red[1] + red[2] + red[3];
    sh_inv = 1.0f / (sqrtf(s) * 0.03125f + 1e-6f);
  }
  __syncthreads();
  float inv = sh_inv;
  float4 w = ((const float4*)W)[tid];
  float o0 = w.x * v.x * inv, o1 = w.y * v.y * inv;
  float o2 = w.z * v.z * inv, o3 = w.w * v.w * inv;
  short4 hi, lo;
  split_bf(o0, hi.x, lo.x); split_bf(o1, hi.y, lo.y);
  split_bf(o2, hi.z, lo.z); split_bf(o3, hi.w, lo.w);
  ((short4*)(O + (size_t)r * D_DIM))[tid] = hi;
  ((short4*)(O + (size_t)BSROWS * D_DIM + (size_t)r * D_DIM))[tid] = lo;
}

// ---------------- rmsnorm -> plain bf16 (for logits A-operand) ----------------
__global__ __launch_bounds__(256) void rmsnorm_bf_kernel(
    const float* __restrict__ X, const float* __restrict__ W, short* __restrict__ O)
{
  int r = blockIdx.x;
  int tid = threadIdx.x;
  float4 v = ((const float4*)(X + (size_t)r * D_DIM))[tid];
  float ss = v.x * v.x + v.y * v.y + v.z * v.z + v.w * v.w;
  __shared__ float red[4];
  __shared__ float sh_inv;
  for (int o = 32; o; o >>= 1) ss += __shfl_down(ss, o);
  if ((tid & 63) == 0) red[tid >> 6] = ss;
  __syncthreads();
  if (tid == 0) {
    float s = red[0] + red[1] + red[2] + red[3];
    sh_inv = 1.0f / (sqrtf(s) * 0.03125f + 1e-6f);
  }
  __syncthreads();
  float inv = sh_inv;
  float4 w = ((const float4*)W)[tid];
  short4 o4 = make_short4(f2bf(w.x * v.x * inv), f2bf(w.y * v.y * inv),
                          f2bf(w.z * v.z * inv), f2bf(w.w * v.w * inv));
  ((short4*)(O + (size_t)r * D_DIM))[tid] = o4;
}

// ---------------- transpose-pack W[K][N] fp32 -> BT[2][N][K] split bf16 --------
__global__ __launch_bounds__(256) void packT_split_kernel(
    const float* __restrict__ W, short* __restrict__ BT, size_t plane, int K, int N)
{
  __shared__ float t[32][33];
  int n0 = blockIdx.x * 32, k0 = blockIdx.y * 32;
  int tx = threadIdx.x, ty = threadIdx.y;
#pragma unroll
  for (int r = 0; r < 32; r += 8)
    t[ty + r][tx] = W[(size_t)(k0 + ty + r) * N + n0 + tx];
  __syncthreads();
#pragma unroll
  for (int r = 0; r < 32; r += 8) {
    short hi, lo;
    split_bf(t[tx][ty + r], hi, lo);
    size_t o = (size_t)(n0 + ty + r) * K + k0 + tx;
    BT[o] = hi;
    BT[plane + o] = lo;
  }
}

// ------- pack wq|wk|wv cols -> BT_qkv [3072][1024] plain bf16 -------
__global__ __launch_bounds__(256) void pack_qkv_kernel(
    const float* __restrict__ wq, const float* __restrict__ wk,
    const float* __restrict__ wv, short* __restrict__ BT)
{
  __shared__ float t[32][33];
  int n0 = blockIdx.x * 32, k0 = blockIdx.y * 32;
  int tx = threadIdx.x, ty = threadIdx.y;
  const float* src = (n0 < 1024) ? wq : (n0 < 2048) ? wk : wv;
  int c0 = n0 & 1023;
#pragma unroll
  for (int r = 0; r < 32; r += 8)
    t[ty + r][tx] = src[(size_t)(k0 + ty + r) * 1024 + c0 + tx];
  __syncthreads();
#pragma unroll
  for (int r = 0; r < 32; r += 8)
    BT[(size_t)(n0 + ty + r) * D_DIM + k0 + tx] = f2bf(t[tx][ty + r]);
}

// ------- pack iq|ik|iw cols -> BT_idx [2][384][1024] split bf16 (zero pad) -----
__global__ __launch_bounds__(256) void pack_idx_kernel(
    const float* __restrict__ iq, const float* __restrict__ ik,
    const float* __restrict__ iw, short* __restrict__ BT)
{
  __shared__ float t[32][33];
  const size_t plane = (size_t)IDX_LD * D_DIM;
  int n0 = blockIdx.x * 32, k0 = blockIdx.y * 32;
  int tx = threadIdx.x, ty = threadIdx.y;
  const float* src = nullptr; int ld = 0, c0 = 0;
  if (n0 < 256)      { src = iq; ld = 256; c0 = n0; }
  else if (n0 < 320) { src = ik; ld = 64;  c0 = n0 - 256; }
  else if (n0 < 352) { src = iw; ld = 4;   c0 = n0 - 320; }
#pragma unroll
  for (int r = 0; r < 32; r += 8) {
    float v = 0.f;
    int c = c0 + tx;
    if (src && c < ld) v = src[(size_t)(k0 + ty + r) * ld + c];
    t[ty + r][tx] = v;
  }
  __syncthreads();
#pragma unroll
  for (int r = 0; r < 32; r += 8) {
    short hi, lo;
    split_bf(t[tx][ty + r], hi, lo);
    size_t o = (size_t)(n0 + ty + r) * D_DIM + k0 + tx;
    BT[o] = hi;
    BT[plane + o] = lo;
  }
}

// ------- split-bf16 GEMM (fp32-accurate): C = A @ BT^T -------
#define RA 40  // LDS row pitch (elems): 32 + 8 pad, 16B-aligned

__global__ __launch_bounds__(256) void gemm_split_kernel(
    const short* __restrict__ A, size_t aplane,
    const short* __restrict__ BT, size_t bplane,
    const float* __restrict__ R, void* __restrict__ C, size_t cplane,
    int M, int N, int K, int epi)
{
  __shared__ short Al[2 * 128 * RA];
  __shared__ short Bl[2 * 128 * RA];
  int tid = threadIdx.x;
  int wave = tid >> 6, lane = tid & 63;
  int wr = (wave >> 1) * 64, wc = (wave & 1) * 64;
  int lr = lane & 15, lk = lane >> 4;
  int m0 = blockIdx.y * 128, n0 = blockIdx.x * 128;
  f32x4 acc[4][4] = {};

  for (int k0 = 0; k0 < K; k0 += 32) {
    __syncthreads();
#pragma unroll
    for (int f = 0; f < 4; ++f) {
      int idx = tid + f * 256;
      int p = idx >> 9, r2 = idx & 511;
      int row = r2 >> 2, sub = r2 & 3;
      uint4 v = *(const uint4*)(A + (size_t)p * aplane + (size_t)(m0 + row) * K + k0 + sub * 8);
      *(uint4*)(Al + p * 128 * RA + row * RA + sub * 8) = v;
    }
#pragma unroll
    for (int f = 0; f < 4; ++f) {
      int idx = tid + f * 256;
      int p = idx >> 9, r2 = idx & 511;
      int row = r2 >> 2, sub = r2 & 3;
      uint4 v = *(const uint4*)(BT + (size_t)p * bplane + (size_t)(n0 + row) * K + k0 + sub * 8);
      *(uint4*)(Bl + p * 128 * RA + row * RA + sub * 8) = v;
    }
    __syncthreads();
    short8 ah[4], al[4], bh[4], bl[4];
#pragma unroll
    for (int i = 0; i < 4; ++i) {
      ah[i] = *(const short8*)(Al + (wr + i * 16 + lr) * RA + lk * 8);
      al[i] = *(const short8*)(Al + 128 * RA + (wr + i * 16 + lr) * RA + lk * 8);
    }
#pragma unroll
    for (int j = 0; j < 4; ++j) {
      bh[j] = *(const short8*)(Bl + (wc + j * 16 + lr) * RA + lk * 8);
      bl[j] = *(const short8*)(Bl + 128 * RA + (wc + j * 16 + lr) * RA + lk * 8);
    }
#pragma unroll
    for (int i = 0; i < 4; ++i)
#pragma unroll
      for (int j = 0; j < 4; ++j) {
        f32x4 a = acc[i][j];
        a = __builtin_amdgcn_mfma_f32_16x16x32_bf16(al[i], bh[j], a, 0, 0, 0);
        a = __builtin_amdgcn_mfma_f32_16x16x32_bf16(ah[i], bl[j], a, 0, 0, 0);
        a = __builtin_amdgcn_mfma_f32_16x16x32_bf16(ah[i], bh[j], a, 0, 0, 0);
        acc[i][j] = a;
      }
  }
#pragma unroll
  for (int i = 0; i < 4; ++i) {
#pragma unroll
    for (int r = 0; r < 4; ++r) {
      int m = m0 + wr + i * 16 + lk * 4 + r;
#pragma unroll
      for (int j = 0; j < 4; ++j) {
        int n = n0 + wc + j * 16 + lr;
        if (n < N) {
          float v = acc[i][j][r];
          if (epi == 1) v += R[(size_t)m * N + n];
          if (epi == 2) {
            v = 0.5f * v * (1.0f + erff(v * 0.70710678118654752f));
            short hi, lo;
            split_bf(v, hi, lo);
            ((short*)C)[(size_t)m * N + n] = hi;
            ((short*)C)[cplane + (size_t)m * N + n] = lo;
          } else {
            ((float*)C)[(size_t)m * N + n] = v;
          }
        }
      }
    }
  }
}

// ------- plain bf16 GEMM: C = A @ BT^T. OSTORE: 0 fp32, 1 bf16 -------
template<int OSTORE>
__global__ __launch_bounds__(256) void gemm_plain_kernel(
    const short* __restrict__ A, const short* __restrict__ BT,
    void* __restrict__ C, int M, int N, int K)
{
  __shared__ short Al[128 * RA];
  __shared__ short Bl[128 * RA];
  int tid = threadIdx.x;
  int wave = tid >> 6, lane = tid & 63;
  int wr = (wave >> 1) * 64, wc = (wave & 1) * 64;
  int lr = lane & 15, lk = lane >> 4;
  int m0 = blockIdx.y * 128, n0 = blockIdx.x * 128;
  f32x4 acc[4][4] = {};

  for (int k0 = 0; k0 < K; k0 += 32) {
    __syncthreads();
#pragma unroll
    for (int f = 0; f < 2; ++f) {
      int idx = tid + f * 256, row = idx >> 2, sub = idx & 3;
      uint4 v = *(const uint4*)(A + (size_t)(m0 + row) * K + k0 + sub * 8);
      *(uint4*)(Al + row * RA + sub * 8) = v;
    }
#pragma unroll
    for (int f = 0; f < 2; ++f) {
      int idx = tid + f * 256, row = idx >> 2, sub = idx & 3;
      int gn = n0 + row;
      uint4 v = make_uint4(0u, 0u, 0u, 0u);
      if (gn < N) v = *(const uint4*)(BT + (size_t)gn * K + k0 + sub * 8);
      *(uint4*)(Bl + row * RA + sub * 8) = v;
    }
    __syncthreads();
    short8 af[4], bfr[4];
#pragma unroll
    for (int i = 0; i < 4; ++i)
      af[i] = *(const short8*)(Al + (wr + i * 16 + lr) * RA + lk * 8);
#pragma unroll
    for (int j = 0; j < 4; ++j)
      bfr[j] = *(const short8*)(Bl + (wc + j * 16 + lr) * RA + lk * 8);
#pragma unroll
    for (int i = 0; i < 4; ++i)
#pragma unroll
      for (int j = 0; j < 4; ++j)
        acc[i][j] = __builtin_amdgcn_mfma_f32_16x16x32_bf16(af[i], bfr[j], acc[i][j], 0, 0, 0);
  }
#pragma unroll
  for (int i = 0; i < 4; ++i)
#pragma unroll
    for (int r = 0; r < 4; ++r) {
      int m = m0 + wr + i * 16 + lk * 4 + r;
#pragma unroll
      for (int j = 0; j < 4; ++j) {
        int n = n0 + wc + j * 16 + lr;
        if (n < N) {
          if (OSTORE == 0) ((float*)C)[(size_t)m * N + n] = acc[i][j][r];
          else             ((short*)C)[(size_t)m * N + n] = f2bf(acc[i][j][r]);
        }
      }
    }
}

// ------- logits GEMM fallback: B fp32 [N][K] inline-cvt (when ws too small) ----
__global__ __launch_bounds__(256) void gemm_logits_f32b_kernel(
    const short* __restrict__ A, const float* __restrict__ BT,
    float* __restrict__ C, int M, int N, int K)
{
  __shared__ short Al[128 * RA];
  __shared__ short Bl[128 * RA];
  int tid = threadIdx.x;
  int wave = tid >> 6, lane = tid & 63;
  int wr = (wave >> 1) * 64, wc = (wave & 1) * 64;
  int lr = lane & 15, lk = lane >> 4;
  int m0 = blockIdx.y * 128, n0 = blockIdx.x * 128;
  f32x4 acc[4][4] = {};

  for (int k0 = 0; k0 < K; k0 += 32) {
    __syncthreads();
#pragma unroll
    for (int f = 0; f < 2; ++f) {
      int idx = tid + f * 256, row = idx >> 2, sub = idx & 3;
      uint4 v = *(const uint4*)(A + (size_t)(m0 + row) * K + k0 + sub * 8);
      *(uint4*)(Al + row * RA + sub * 8) = v;
    }
#pragma unroll
    for (int f = 0; f < 4; ++f) {
      int idx = tid + f * 256, row = idx >> 3, qq = idx & 7;
      int gn = n0 + row;
      float4 v = make_float4(0.f, 0.f, 0.f, 0.f);
      if (gn < N) v = *(const float4*)(BT + (size_t)gn * K + k0 + qq * 4);
      *(short4*)(Bl + row * RA + qq * 4) =
          make_short4(f2bf(v.x), f2bf(v.y), f2bf(v.z), f2bf(v.w));
    }
    __syncthreads();
    short8 af[4], bfr[4];
#pragma unroll
    for (int i = 0; i < 4; ++i)
      af[i] = *(const short8*)(Al + (wr + i * 16 + lr) * RA + lk * 8);
#pragma unroll
    for (int j = 0; j < 4; ++j)
      bfr[j] = *(const short8*)(Bl + (wc + j * 16 + lr) * RA + lk * 8);
#pragma unroll
    for (int i = 0; i < 4; ++i)
#pragma unroll
      for (int j = 0; j < 4; ++j)
        acc[i][j] = __builtin_amdgcn_mfma_f32_16x16x32_bf16(af[i], bfr[j], acc[i][j], 0, 0, 0);
  }
#pragma unroll
  for (int i = 0; i < 4; ++i)
#pragma unroll
    for (int r = 0; r < 4; ++r) {
      int m = m0 + wr + i * 16 + lk * 4 + r;
#pragma unroll
      for (int j = 0; j < 4; ++j) {
        int n = n0 + wc + j * 16 + lr;
        if (n < N) C[(size_t)m * N + n] = acc[i][j][r];
      }
    }
}

// ---------------- indexer scores + exact stable top-k -> bitmask ----------------
__device__ __forceinline__ unsigned int ford(float f) {
  unsigned int u = __float_as_uint(f);
  return (u & 0x80000000u) ? ~u : (u | 0x80000000u);
}

__global__ __launch_bounds__(256) void idx_topk_kernel(
    const float* __restrict__ Hx, unsigned int* __restrict__ MASK)
{
  int bq = blockIdx.x;
  int q = bq & (S_LEN - 1);
  int b = bq >> 10;
  int tid = threadIdx.x;
  int n = q + 1;
  if (n <= TOPK_N) {
    if (tid < 32) {
      int full = n >> 5, rem = n & 31;
      unsigned int w = 0u;
      if (tid < full) w = 0xFFFFFFFFu;
      else if (tid == full && rem) w = (1u << rem) - 1u;
      MASK[(size_t)bq * 32 + tid] = w;
    }
    return;
  }
  __shared__ float qi_s[HI_N * DI_N];
  __shared__ float wt_s[HI_N];
  __shared__ float sc[S_LEN];
  __shared__ unsigned long long keys[S_LEN];
  __shared__ unsigned int mw[32];
  qi_s[tid] = Hx[(size_t)bq * IDX_LD + COL_QI + tid];
  if (tid < HI_N) wt_s[tid] = Hx[(size_t)bq * IDX_LD + COL_WT + tid];
  __syncthreads();
  for (int k = tid; k < n; k += 256) {
    const float* kr = Hx + (size_t)(b * S_LEN + k) * IDX_LD + COL_KI;
    float d0 = 0.f, d1 = 0.f, d2 = 0.f, d3 = 0.f;
#pragma unroll
    for (int d = 0; d < DI_N; ++d) {
      float kv = kr[d];
      d0 = fmaf(qi_s[d], kv, d0);
      d1 = fmaf(qi_s[64 + d], kv, d1);
      d2 = fmaf(qi_s[128 + d], kv, d2);
      d3 = fmaf(qi_s[192 + d], kv, d3);
    }
    sc[k] = wt_s[0] * fmaxf(d0, 0.f) + wt_s[1] * fmaxf(d1, 0.f)
          + wt_s[2] * fmaxf(d2, 0.f) + wt_s[3] * fmaxf(d3, 0.f);
  }
  __syncthreads();
  for (int i = tid; i < S_LEN; i += 256) {
    unsigned long long kk = 0ull;
    if (i < n) kk = ((unsigned long long)ford(sc[i]) << 32) | (unsigned int)(S_LEN - 1 - i);
    keys[i] = kk;
  }
  __syncthreads();
  for (int size = 2; size <= S_LEN; size <<= 1) {
    for (int stride = size >> 1; stride > 0; stride >>= 1) {
      for (int t = tid; t < S_LEN / 2; t += 256) {
        int j = t & (stride - 1);
        int lo = ((t ^ j) << 1) | j;
        int hi = lo | stride;
        unsigned long long a = keys[lo], c = keys[hi];
        bool desc = ((lo & size) == 0);
        bool sw = desc ? (a < c) : (a > c);
        if (sw) { keys[lo] = c; keys[hi] = a; }
      }
      __syncthreads();
    }
  }
  if (tid < 32) mw[tid] = 0u;
  __syncthreads();
  for (int i = tid; i < TOPK_N; i += 256) {
    int k = S_LEN - 1 - (int)(keys[i] & 0xFFFFFFFFull);
    atomicOr(&mw[k >> 5], 1u << (k & 31));
  }
  __syncthreads();
  if (tid < 32) MASK[(size_t)bq * 32 + tid] = mw[tid];
}

// ------- masked-dense flash attention via 16x16x16 MFMA (QKV compact bf16) -----
__global__ __launch_bounds__(256) void attn_mfma_kernel(
    const short* __restrict__ QKV, const unsigned int* __restrict__ MASK,
    short* __restrict__ O /* [2][BSROWS][D] split bf16 */)
{
  __shared__ unsigned int mlds[64 * 32];  // 8KB: mask words for 64 q-rows
  __shared__ short Kl[64 * 72];           // K tile [key][d], pitch 72
  __shared__ short Vtl[64 * 68];          // V^T tile [d][key], pitch 68
  int qt = blockIdx.x, h = blockIdx.y, b = blockIdx.z;
  int tid = threadIdx.x;
  int w = tid >> 6, l = tid & 63;
  int lq = l & 15, g = l >> 4;
  int q0 = qt * 64;

#pragma unroll
  for (int i = 0; i < 8; ++i) {
    int idx = tid + i * 256;
    mlds[idx] = MASK[((size_t)(b * S_LEN + q0 + (idx >> 5))) * 32 + (idx & 31)];
  }
  // Q B-frags: q = q0 + w*16 + lq, d = dt*16 + g*4 + j (bf16 direct)
  short4v qf[4];
  {
    const short* qrow = QKV + ((size_t)(b * S_LEN + q0 + w * 16 + lq)) * QKV_LD + h * DHD;
#pragma unroll
    for (int dt = 0; dt < 4; ++dt)
      qf[dt] = *(const short4v*)(qrow + dt * 16 + g * 4);
  }
  f32x4 acc_o[4] = {};
  float m_run = -1.0e30f, l_run = 0.f;
  const short* Kb = QKV + (size_t)b * S_LEN * QKV_LD + 1024 + h * DHD;
  const short* Vb = QKV + (size_t)b * S_LEN * QKV_LD + 2048 + h * DHD;
  const int mrow = w * 16 + lq;  // this lane's q-row in mlds

  for (int kt = 0; kt <= qt; ++kt) {
    __syncthreads();
    // stage K tile: [64 key][64 d] -> Kl pitch 72
#pragma unroll
    for (int i = 0; i < 2; ++i) {
      int idx = tid + i * 256;  // 0..511
      int row = idx >> 3, sub = idx & 7;
      uint4 v = *(const uint4*)(Kb + (size_t)(kt * 64 + row) * QKV_LD + sub * 8);
      *(uint4*)(Kl + row * 72 + sub * 8) = v;
    }
    // stage V^T: [64 d][64 key] pitch 68
    {
      int u = tid >> 1, half = tid & 1;  // u 0..127
      int kg = u >> 3, dg = u & 7;
      int krow = kt * 64 + kg * 4 + half * 2;
      uint4 v0 = *(const uint4*)(Vb + (size_t)krow * QKV_LD + dg * 8);
      uint4 v1 = *(const uint4*)(Vb + (size_t)(krow + 1) * QKV_LD + dg * 8);
      const short* s0 = (const short*)&v0;
      const short* s1 = (const short*)&v1;
#pragma unroll
      for (int j = 0; j < 8; ++j)
        *(short2*)(Vtl + (dg * 8 + j) * 68 + kg * 4 + half * 2) = make_short2(s0[j], s1[j]);
    }
    __syncthreads();
    // S^T[key][q] = sum_d K[key][d] Q[q][d]
    f32x4 s[4] = {};
#pragma unroll
    for (int dt = 0; dt < 4; ++dt)
#pragma unroll
      for (int ks = 0; ks < 4; ++ks) {
        short4v kf = *(const short4v*)(Kl + (ks * 16 + lq) * 72 + dt * 16 + g * 4);
        s[ks] = MFMA16(kf, qf[dt], s[ks]);
      }
    // mask + scale
    float mx = NEGF;
#pragma unroll
    for (int ks = 0; ks < 4; ++ks) {
      int kbase = kt * 64 + ks * 16 + g * 4;
      unsigned mwv = mlds[mrow * 32 + (kbase >> 5)];
#pragma unroll
      for (int r = 0; r < 4; ++r) {
        float sv = ((mwv >> ((kbase + r) & 31)) & 1u) ? s[ks][r] * 0.125f : NEGF;
        s[ks][r] = sv;
        mx = fmaxf(mx, sv);
      }
    }
    mx = fmaxf(mx, __shfl_xor(mx, 16));
    mx = fmaxf(mx, __shfl_xor(mx, 32));
    float m_new = fmaxf(m_run, mx);
    float scale = __expf(m_run - m_new);
    float lsum = 0.f;
    short4v pf[4];
#pragma unroll
    for (int ks = 0; ks < 4; ++ks) {
      short4v t;
#pragma unroll
      for (int r = 0; r < 4; ++r) {
        float p = __expf(s[ks][r] - m_new);
        lsum += p;
        t[r] = f2bf(p);
      }
      pf[ks] = t;
    }
    lsum += __shfl_xor(lsum, 16);
    lsum += __shfl_xor(lsum, 32);
    l_run = l_run * scale + lsum;
    m_run = m_new;
    float sc[4];
#pragma unroll
    for (int r = 0; r < 4; ++r) sc[r] = __shfl(scale, g * 4 + r);
#pragma unroll
    for (int dt = 0; dt < 4; ++dt) {
      f32x4 a = acc_o[dt];
      a[0] *= sc[0]; a[1] *= sc[1]; a[2] *= sc[2]; a[3] *= sc[3];
#pragma unroll
      for (int ks = 0; ks < 4; ++ks) {
        short4v vf = *(const short4v*)(Vtl + (dt * 16 + lq) * 68 + ks * 16 + g * 4);
        a = MFMA16(pf[ks], vf, a);  // A = P[q][k], B = V^T[d][k]
      }
      acc_o[dt] = a;
    }
  }
  float linv[4];
#pragma unroll
  for (int r = 0; r < 4; ++r) linv[r] = 1.0f / __shfl(l_run, g * 4 + r);
#pragma unroll
  for (int dt = 0; dt < 4; ++dt)
#pragma unroll
    for (int r = 0; r < 4; ++r) {
      int q = q0 + w * 16 + g * 4 + r;
      float o = acc_o[dt][r] * linv[r];
      short hi, lo;
      split_bf(o, hi, lo);
      size_t ofs = (size_t)(b * S_LEN + q) * D_DIM + h * DHD + dt * 16 + lq;
      O[ofs] = hi;
      O[(size_t)BSROWS * D_DIM + ofs] = lo;
    }
}

// ---------------- host orchestration ----------------
extern "C" void kernel_launch(void* const* d_in, const int* in_sizes, int n_in,
                              void* d_out, int out_size, void* d_ws, size_t ws_size,
                              hipStream_t stream) {
  (void)in_sizes; (void)n_in; (void)out_size;
  const int*   tokens  = (const int*)d_in[0];
  const float* embed_w = (const float*)d_in[1];
  const float* pos_w   = (const float*)d_in[2];
  const float* wq      = (const float*)d_in[3];
  const float* wk      = (const float*)d_in[4];
  const float* wv      = (const float*)d_in[5];
  const float* wo      = (const float*)d_in[6];
  const float* iqw     = (const float*)d_in[7];
  const float* ikw     = (const float*)d_in[8];
  const float* iww     = (const float*)d_in[9];
  const float* w1      = (const float*)d_in[10];
  const float* w2      = (const float*)d_in[11];
  const float* n1      = (const float*)d_in[12];
  const float* n2      = (const float*)d_in[13];
  const float* nf      = (const float*)d_in[14];
  float* logits = (float*)d_out;

  // ws: Hbf (logits A, 4.2 MB) + optionally Ebf (bf16 embed, 103 MB).
  short* Hbf = (short*)d_ws;
  size_t need_ebf = (size_t)BSROWS * D_DIM * 2 + (size_t)VOCAB * D_DIM * 2;
  bool use_ebf = ws_size >= need_ebf;
  short* Ebf = Hbf + (size_t)BSROWS * D_DIM;

  // d_out scratch (all dead before logits GEMM writes)
  char* base = (char*)d_out;
  size_t off = (size_t)BSROWS * D_DIM * 4;
  float* X = logits;
  float* Hx = (float*)(base + off);    off += (size_t)BSROWS * IDX_LD * 4;   // [2048][384] f32
  short* QKVbf = (short*)(base + off); off += (size_t)BSROWS * QKV_LD * 2;   // [2048][3072] bf16
  short* Hsp = (short*)(base + off);   off += (size_t)2 * BSROWS * D_DIM * 2;
  short* AOsp = (short*)(base + off);  off += (size_t)2 * BSROWS * D_DIM * 2;
  short* FFsp = (short*)(base + off);  off += (size_t)2 * BSROWS * FF_DIM * 2;
  unsigned int* MASKb = (unsigned int*)(base + off); off += (size_t)BSROWS * 32 * 4;
  short* BTqkv = (short*)(base + off); off += (size_t)QKV_LD * D_DIM * 2;
  short* BTidx = (short*)(base + off); off += (size_t)2 * IDX_LD * D_DIM * 2;
  short* BTwo = (short*)(base + off);  off += (size_t)2 * D_DIM * D_DIM * 2;
  short* BTw1 = (short*)(base + off);  off += (size_t)2 * FF_DIM * D_DIM * 2;
  short* BTw2 = (short*)(base + off);  off += (size_t)2 * FF_DIM * D_DIM * 2;

  const size_t plH  = (size_t)BSROWS * D_DIM;
  const size_t plFF = (size_t)BSROWS * FF_DIM;
  const size_t plIx = (size_t)IDX_LD * D_DIM;
  const size_t plDD = (size_t)D_DIM * D_DIM;
  const size_t plFD = (size_t)FF_DIM * D_DIM;

  hipLaunchKernelGGL(embed_kernel, dim3(BSROWS), dim3(256), 0, stream,
                     tokens, embed_w, pos_w, X);
  if (use_ebf) {
    long total4 = (long)VOCAB * D_DIM / 4;
    hipLaunchKernelGGL(cvt_embed_kernel, dim3(8192), dim3(256), 0, stream,
                       embed_w, Ebf, total4);
  }

  for (int l = 0; l < NL; ++l) {
    const float* lwq = wq + (size_t)l * plDD;
    const float* lwk = wk + (size_t)l * plDD;
    const float* lwv = wv + (size_t)l * plDD;
    const float* lwo = wo + (size_t)l * plDD;
    const float* liq = iqw + (size_t)l * D_DIM * (HI_N * DI_N);
    const float* lik = ikw + (size_t)l * D_DIM * DI_N;
    const float* liw = iww + (size_t)l * D_DIM * HI_N;
    const float* lw1 = w1 + (size_t)l * plFD;
    const float* lw2 = w2 + (size_t)l * plFD;

    hipLaunchKernelGGL(rmsnorm_split_kernel, dim3(BSROWS), dim3(256), 0, stream,
                       X, n1 + (size_t)l * D_DIM, Hsp);
    hipLaunchKernelGGL(pack_qkv_kernel, dim3(QKV_LD / 32, 32), dim3(32, 8), 0, stream,
                       lwq, lwk, lwv, BTqkv);
    hipLaunchKernelGGL(pack_idx_kernel, dim3(IDX_LD / 32, 32), dim3(32, 8), 0, stream,
                       liq, lik, liw, BTidx);
    // QKV: plain bf16 (A = hi plane of Hsp), bf16 compact out
    hipLaunchKernelGGL((gemm_plain_kernel<1>), dim3(QKV_LD / 128, 16), dim3(256), 0, stream,
                       Hsp, BTqkv, QKVbf, BSROWS, QKV_LD, D_DIM);
    // indexer: split (fp32-accurate) -> Hx
    hipLaunchKernelGGL(gemm_split_kernel, dim3(IDX_LD / 128, 16), dim3(256), 0, stream,
                       Hsp, plH, BTidx, plIx, nullptr, Hx, 0, BSROWS, IDX_LD, D_DIM, 0);
    hipLaunchKernelGGL(idx_topk_kernel, dim3(BSROWS), dim3(256), 0, stream, Hx, MASKb);
    hipLaunchKernelGGL(attn_mfma_kernel, dim3(S_LEN / 64, NH, 2), dim3(256), 0, stream,
                       QKVbf, MASKb, AOsp);
    hipLaunchKernelGGL(packT_split_kernel, dim3(32, 32), dim3(32, 8), 0, stream,
                       lwo, BTwo, plDD, D_DIM, D_DIM);
    hipLaunchKernelGGL(gemm_split_kernel, dim3(8, 16), dim3(256), 0, stream,
                       AOsp, plH, BTwo, plDD, X, X, 0, BSROWS, D_DIM, D_DIM, 1);
    hipLaunchKernelGGL(rmsnorm_split_kernel, dim3(BSROWS), dim3(256), 0, stream,
                       X, n2 + (size_t)l * D_DIM, Hsp);
    hipLaunchKernelGGL(packT_split_kernel, dim3(FF_DIM / 32, 32), dim3(32, 8), 0, stream,
                       lw1, BTw1, plFD, D_DIM, FF_DIM);
    hipLaunchKernelGGL(gemm_split_kernel, dim3(32, 16), dim3(256), 0, stream,
                       Hsp, plH, BTw1, plFD, nullptr, FFsp, plFF, BSROWS, FF_DIM, D_DIM, 2);
    hipLaunchKernelGGL(packT_split_kernel, dim3(D_DIM / 32, FF_DIM / 32), dim3(32, 8), 0, stream,
                       lw2, BTw2, plFD, FF_DIM, D_DIM);
    hipLaunchKernelGGL(gemm_split_kernel, dim3(8, 16), dim3(256), 0, stream,
                       FFsp, plFF, BTw2, plFD, X, X, 0, BSROWS, D_DIM, FF_DIM, 1);
  }

  hipLaunchKernelGGL(rmsnorm_bf_kernel, dim3(BSROWS), dim3(256), 0, stream, X, nf, Hbf);
  if (use_ebf) {
    hipLaunchKernelGGL((gemm_plain_kernel<0>), dim3((VOCAB + 127) / 128, 16), dim3(256), 0, stream,
                       Hbf, Ebf, logits, BSROWS, VOCAB, D_DIM);
  } else {
    hipLaunchKernelGGL(gemm_logits_f32b_kernel, dim3((VOCAB + 127) / 128, 16), dim3(256), 0, stream,
                       Hbf, embed_w, logits, BSROWS, VOCAB, D_DIM);
  }
}

// Round 7
// 4424.657 us; speedup vs baseline: 6.5775x; 1.1720x over previous
//
#include <hip/hip_runtime.h>
#include <cstdint>
#include <cstddef>

#define S_LEN 1024
#define D_DIM 1024
#define NH 16
#define DHD 64
#define NL 8
#define FF_DIM 4096
#define HI_N 4
#define DI_N 64
#define TOPK_N 512
#define BSROWS 2048  // B * S
#define VOCAB 50257
#define NTILES_V 393  // ceil(50257/128)
#define YPX 50        // ceil(393/8) N-panels per XCD for logits

// compact QKV layout: [Q 0..1023 | K 1024..2047 | V 2048..3071], fp16
#define QKV_LD 3072
// indexer block layout (fp32): [QI 0..255 | KI 256..319 | WT 320..323 | pad..383]
#define IDX_LD 384
#define COL_QI 0
#define COL_KI 256
#define COL_WT 320

#define NEGF -3.0e38f

typedef __attribute__((ext_vector_type(8))) _Float16 half8;
typedef __attribute__((ext_vector_type(4))) _Float16 half4v;
typedef __attribute__((ext_vector_type(4))) float f32x4;

#if __has_builtin(__builtin_amdgcn_mfma_f32_16x16x16f16)
#define MFMA16F(a, b, c) __builtin_amdgcn_mfma_f32_16x16x16f16((a), (b), (c), 0, 0, 0)
#else
static __device__ __forceinline__ f32x4 mfma16f_asm(half4v a, half4v b, f32x4 c) {
  f32x4 d;
  asm volatile("v_mfma_f32_16x16x16_f16 %0, %1, %2, %3\n\ts_nop 7\n\ts_nop 7"
               : "=v"(d) : "v"(a), "v"(b), "v"(c));
  return d;
}
#define MFMA16F(a, b, c) mfma16f_asm((a), (b), (c))
#endif

__device__ __forceinline__ short f2h(float x) {  // RNE fp32->fp16 (bits)
  _Float16 h = (_Float16)x;
  return *reinterpret_cast<short*>(&h);
}
__device__ __forceinline__ float h2f(short b) {
  _Float16 h = *reinterpret_cast<_Float16*>(&b);
  return (float)h;
}
// two-term fp16 split: x ~= hi + lo with rel err ~2^-22
__device__ __forceinline__ void split_h(float x, short& hi, short& lo) {
  hi = f2h(x);
  lo = f2h(x - h2f(hi));
}

// ---------------- embed + positional ----------------
__global__ __launch_bounds__(256) void embed_kernel(
    const int* __restrict__ tokens, const float* __restrict__ E,
    const float* __restrict__ P, float* __restrict__ X)
{
  int bs = blockIdx.x;
  int s = bs & (S_LEN - 1);
  int tid = threadIdx.x;
  int tok = tokens[bs];
  float4 e = ((const float4*)(E + (size_t)tok * D_DIM))[tid];
  float4 p = ((const float4*)(P + (size_t)s * D_DIM))[tid];
  float4 o; o.x = e.x + p.x; o.y = e.y + p.y; o.z = e.z + p.z; o.w = e.w + p.w;
  ((float4*)(X + (size_t)bs * D_DIM))[tid] = o;
}

// ---------------- embed fp32 -> fp16 (grid-stride) ----------------
__global__ __launch_bounds__(256) void cvt_embed_kernel(
    const float* __restrict__ E, short* __restrict__ Eh, long total4)
{
  long i = (long)blockIdx.x * 256 + threadIdx.x;
  long stride = (long)gridDim.x * 256;
  for (; i < total4; i += stride) {
    float4 v = ((const float4*)E)[i];
    ((short4*)Eh)[i] = make_short4(f2h(v.x), f2h(v.y), f2h(v.z), f2h(v.w));
  }
}

// ---------------- rmsnorm -> split fp16 (hi plane, lo plane) ----------------
__global__ __launch_bounds__(256) void rmsnorm_split_kernel(
    const float* __restrict__ X, const float* __restrict__ W,
    short* __restrict__ O /* [2][BSROWS][D] */)
{
  int r = blockIdx.x;
  int tid = threadIdx.x;
  float4 v = ((const float4*)(X + (size_t)r * D_DIM))[tid];
  float ss = v.x * v.x + v.y * v.y + v.z * v.z + v.w * v.w;
  __shared__ float red[4];
  __shared__ float sh_inv;
  for (int o = 32; o; o >>= 1) ss += __shfl_down(ss, o);
  if ((tid & 63) == 0) red[tid >> 6] = ss;
  __syncthreads();
  if (tid == 0) {
    float s = red[0] + red[1] + red[2] + red[3];
    sh_inv = 1.0f / (sqrtf(s) * 0.03125f + 1e-6f);
  }
  __syncthreads();
  float inv = sh_inv;
  float4 w = ((const float4*)W)[tid];
  float o0 = w.x * v.x * inv, o1 = w.y * v.y * inv;
  float o2 = w.z * v.z * inv, o3 = w.w * v.w * inv;
  short4 hi, lo;
  split_h(o0, hi.x, lo.x); split_h(o1, hi.y, lo.y);
  split_h(o2, hi.z, lo.z); split_h(o3, hi.w, lo.w);
  ((short4*)(O + (size_t)r * D_DIM))[tid] = hi;
  ((short4*)(O + (size_t)BSROWS * D_DIM + (size_t)r * D_DIM))[tid] = lo;
}

// ---------------- rmsnorm -> plain fp16 ----------------
__global__ __launch_bounds__(256) void rmsnorm_h_kernel(
    const float* __restrict__ X, const float* __restrict__ W, short* __restrict__ O)
{
  int r = blockIdx.x;
  int tid = threadIdx.x;
  float4 v = ((const float4*)(X + (size_t)r * D_DIM))[tid];
  float ss = v.x * v.x + v.y * v.y + v.z * v.z + v.w * v.w;
  __shared__ float red[4];
  __shared__ float sh_inv;
  for (int o = 32; o; o >>= 1) ss += __shfl_down(ss, o);
  if ((tid & 63) == 0) red[tid >> 6] = ss;
  __syncthreads();
  if (tid == 0) {
    float s = red[0] + red[1] + red[2] + red[3];
    sh_inv = 1.0f / (sqrtf(s) * 0.03125f + 1e-6f);
  }
  __syncthreads();
  float inv = sh_inv;
  float4 w = ((const float4*)W)[tid];
  short4 o4 = make_short4(f2h(w.x * v.x * inv), f2h(w.y * v.y * inv),
                          f2h(w.z * v.z * inv), f2h(w.w * v.w * inv));
  ((short4*)(O + (size_t)r * D_DIM))[tid] = o4;
}

// ---------------- transpose-pack W[K][N] fp32 -> BT[N][K] fp16 ----------------
__global__ __launch_bounds__(256) void packT_f16_kernel(
    const float* __restrict__ W, short* __restrict__ BT, int K, int N)
{
  __shared__ float t[32][33];
  int n0 = blockIdx.x * 32, k0 = blockIdx.y * 32;
  int tx = threadIdx.x, ty = threadIdx.y;
#pragma unroll
  for (int r = 0; r < 32; r += 8)
    t[ty + r][tx] = W[(size_t)(k0 + ty + r) * N + n0 + tx];
  __syncthreads();
#pragma unroll
  for (int r = 0; r < 32; r += 8)
    BT[(size_t)(n0 + ty + r) * K + k0 + tx] = f2h(t[tx][ty + r]);
}

// ------- pack wq|wk|wv cols -> BT_qkv [3072][1024] fp16 -------
__global__ __launch_bounds__(256) void pack_qkv_kernel(
    const float* __restrict__ wq, const float* __restrict__ wk,
    const float* __restrict__ wv, short* __restrict__ BT)
{
  __shared__ float t[32][33];
  int n0 = blockIdx.x * 32, k0 = blockIdx.y * 32;
  int tx = threadIdx.x, ty = threadIdx.y;
  const float* src = (n0 < 1024) ? wq : (n0 < 2048) ? wk : wv;
  int c0 = n0 & 1023;
#pragma unroll
  for (int r = 0; r < 32; r += 8)
    t[ty + r][tx] = src[(size_t)(k0 + ty + r) * 1024 + c0 + tx];
  __syncthreads();
#pragma unroll
  for (int r = 0; r < 32; r += 8)
    BT[(size_t)(n0 + ty + r) * D_DIM + k0 + tx] = f2h(t[tx][ty + r]);
}

// ------- pack iq|ik|iw cols -> BT_idx [2][384][1024] split fp16 (zero pad) -----
__global__ __launch_bounds__(256) void pack_idx_kernel(
    const float* __restrict__ iq, const float* __restrict__ ik,
    const float* __restrict__ iw, short* __restrict__ BT)
{
  __shared__ float t[32][33];
  const size_t plane = (size_t)IDX_LD * D_DIM;
  int n0 = blockIdx.x * 32, k0 = blockIdx.y * 32;
  int tx = threadIdx.x, ty = threadIdx.y;
  const float* src = nullptr; int ld = 0, c0 = 0;
  if (n0 < 256)      { src = iq; ld = 256; c0 = n0; }
  else if (n0 < 320) { src = ik; ld = 64;  c0 = n0 - 256; }
  else if (n0 < 352) { src = iw; ld = 4;   c0 = n0 - 320; }
#pragma unroll
  for (int r = 0; r < 32; r += 8) {
    float v = 0.f;
    int c = c0 + tx;
    if (src && c < ld) v = src[(size_t)(k0 + ty + r) * ld + c];
    t[ty + r][tx] = v;
  }
  __syncthreads();
#pragma unroll
  for (int r = 0; r < 32; r += 8) {
    short hi, lo;
    split_h(t[tx][ty + r], hi, lo);
    size_t o = (size_t)(n0 + ty + r) * D_DIM + k0 + tx;
    BT[o] = hi;
    BT[plane + o] = lo;
  }
}

#define RA 40  // LDS row pitch (elems): 32 + 8 pad, 16B-aligned

// ------- split-fp16 GEMM (fp32-accurate), fp32 out: indexer only -------
__global__ __launch_bounds__(256) void gemm_split_kernel(
    const short* __restrict__ A, size_t aplane,
    const short* __restrict__ BT, size_t bplane,
    float* __restrict__ C, int M, int N, int K)
{
  __shared__ short Al[2 * 128 * RA];
  __shared__ short Bl[2 * 128 * RA];
  int tid = threadIdx.x;
  int wave = tid >> 6, lane = tid & 63;
  int wr = (wave >> 1) * 64, wc = (wave & 1) * 64;
  int lr = lane & 15, lk = lane >> 4;
  int m0 = blockIdx.y * 128, n0 = blockIdx.x * 128;
  f32x4 acc[4][4] = {};

  for (int k0 = 0; k0 < K; k0 += 32) {
    __syncthreads();
#pragma unroll
    for (int f = 0; f < 4; ++f) {
      int idx = tid + f * 256;
      int p = idx >> 9, r2 = idx & 511;
      int row = r2 >> 2, sub = r2 & 3;
      uint4 v = *(const uint4*)(A + (size_t)p * aplane + (size_t)(m0 + row) * K + k0 + sub * 8);
      *(uint4*)(Al + p * 128 * RA + row * RA + sub * 8) = v;
    }
#pragma unroll
    for (int f = 0; f < 4; ++f) {
      int idx = tid + f * 256;
      int p = idx >> 9, r2 = idx & 511;
      int row = r2 >> 2, sub = r2 & 3;
      uint4 v = *(const uint4*)(BT + (size_t)p * bplane + (size_t)(n0 + row) * K + k0 + sub * 8);
      *(uint4*)(Bl + p * 128 * RA + row * RA + sub * 8) = v;
    }
    __syncthreads();
    half8 ah[4], al[4], bh[4], bl[4];
#pragma unroll
    for (int i = 0; i < 4; ++i) {
      ah[i] = *(const half8*)(Al + (wr + i * 16 + lr) * RA + lk * 8);
      al[i] = *(const half8*)(Al + 128 * RA + (wr + i * 16 + lr) * RA + lk * 8);
    }
#pragma unroll
    for (int j = 0; j < 4; ++j) {
      bh[j] = *(const half8*)(Bl + (wc + j * 16 + lr) * RA + lk * 8);
      bl[j] = *(const half8*)(Bl + 128 * RA + (wc + j * 16 + lr) * RA + lk * 8);
    }
#pragma unroll
    for (int i = 0; i < 4; ++i)
#pragma unroll
      for (int j = 0; j < 4; ++j) {
        f32x4 a = acc[i][j];
        a = __builtin_amdgcn_mfma_f32_16x16x32_f16(al[i], bh[j], a, 0, 0, 0);
        a = __builtin_amdgcn_mfma_f32_16x16x32_f16(ah[i], bl[j], a, 0, 0, 0);
        a = __builtin_amdgcn_mfma_f32_16x16x32_f16(ah[i], bh[j], a, 0, 0, 0);
        acc[i][j] = a;
      }
  }
#pragma unroll
  for (int i = 0; i < 4; ++i)
#pragma unroll
    for (int r = 0; r < 4; ++r) {
      int m = m0 + wr + i * 16 + lk * 4 + r;
#pragma unroll
      for (int j = 0; j < 4; ++j) {
        int n = n0 + wc + j * 16 + lr;
        if (n < N) C[(size_t)m * N + n] = acc[i][j][r];
      }
    }
}

// ------- plain fp16 GEMM: C = A @ BT^T -------
// EPI: 0 fp32 store; 1 fp16 store; 2 exact-GELU -> fp16 store; 3 fp32 + R
template<int EPI>
__global__ __launch_bounds__(256) void gemm_f16_kernel(
    const short* __restrict__ A, const short* __restrict__ BT,
    const float* __restrict__ R, void* __restrict__ C, int M, int N, int K)
{
  __shared__ short Al[128 * RA];
  __shared__ short Bl[128 * RA];
  int tid = threadIdx.x;
  int wave = tid >> 6, lane = tid & 63;
  int wr = (wave >> 1) * 64, wc = (wave & 1) * 64;
  int lr = lane & 15, lk = lane >> 4;
  int m0 = blockIdx.y * 128, n0 = blockIdx.x * 128;
  f32x4 acc[4][4] = {};

  for (int k0 = 0; k0 < K; k0 += 32) {
    __syncthreads();
#pragma unroll
    for (int f = 0; f < 2; ++f) {
      int idx = tid + f * 256, row = idx >> 2, sub = idx & 3;
      uint4 v = *(const uint4*)(A + (size_t)(m0 + row) * K + k0 + sub * 8);
      *(uint4*)(Al + row * RA + sub * 8) = v;
    }
#pragma unroll
    for (int f = 0; f < 2; ++f) {
      int idx = tid + f * 256, row = idx >> 2, sub = idx & 3;
      int gn = n0 + row;
      uint4 v = make_uint4(0u, 0u, 0u, 0u);
      if (gn < N) v = *(const uint4*)(BT + (size_t)gn * K + k0 + sub * 8);
      *(uint4*)(Bl + row * RA + sub * 8) = v;
    }
    __syncthreads();
    half8 af[4], bfr[4];
#pragma unroll
    for (int i = 0; i < 4; ++i)
      af[i] = *(const half8*)(Al + (wr + i * 16 + lr) * RA + lk * 8);
#pragma unroll
    for (int j = 0; j < 4; ++j)
      bfr[j] = *(const half8*)(Bl + (wc + j * 16 + lr) * RA + lk * 8);
#pragma unroll
    for (int i = 0; i < 4; ++i)
#pragma unroll
      for (int j = 0; j < 4; ++j)
        acc[i][j] = __builtin_amdgcn_mfma_f32_16x16x32_f16(af[i], bfr[j], acc[i][j], 0, 0, 0);
  }
#pragma unroll
  for (int i = 0; i < 4; ++i)
#pragma unroll
    for (int r = 0; r < 4; ++r) {
      int m = m0 + wr + i * 16 + lk * 4 + r;
#pragma unroll
      for (int j = 0; j < 4; ++j) {
        int n = n0 + wc + j * 16 + lr;
        if (n < N) {
          float v = acc[i][j][r];
          if (EPI == 0) {
            ((float*)C)[(size_t)m * N + n] = v;
          } else if (EPI == 1) {
            ((short*)C)[(size_t)m * N + n] = f2h(v);
          } else if (EPI == 2) {
            v = 0.5f * v * (1.0f + erff(v * 0.70710678118654752f));
            ((short*)C)[(size_t)m * N + n] = f2h(v);
          } else {
            ((float*)C)[(size_t)m * N + n] = v + R[(size_t)m * N + n];
          }
        }
      }
    }
}

// ------- logits GEMM, XCD-aware 1D grid: each XCD owns contiguous N-panels -----
__global__ __launch_bounds__(256) void gemm_logits_f16_kernel(
    const short* __restrict__ A, const short* __restrict__ BT,
    float* __restrict__ C, int M, int N, int K)
{
  int bid = blockIdx.x;
  int xcd = bid & 7, idx = bid >> 3;
  int mt = idx & 15, yt = (idx >> 4) + xcd * YPX;
  if (yt >= NTILES_V) return;
  int m0 = mt * 128, n0 = yt * 128;

  __shared__ short Al[128 * RA];
  __shared__ short Bl[128 * RA];
  int tid = threadIdx.x;
  int wave = tid >> 6, lane = tid & 63;
  int wr = (wave >> 1) * 64, wc = (wave & 1) * 64;
  int lr = lane & 15, lk = lane >> 4;
  f32x4 acc[4][4] = {};

  for (int k0 = 0; k0 < K; k0 += 32) {
    __syncthreads();
#pragma unroll
    for (int f = 0; f < 2; ++f) {
      int idx2 = tid + f * 256, row = idx2 >> 2, sub = idx2 & 3;
      uint4 v = *(const uint4*)(A + (size_t)(m0 + row) * K + k0 + sub * 8);
      *(uint4*)(Al + row * RA + sub * 8) = v;
    }
#pragma unroll
    for (int f = 0; f < 2; ++f) {
      int idx2 = tid + f * 256, row = idx2 >> 2, sub = idx2 & 3;
      int gn = n0 + row;
      uint4 v = make_uint4(0u, 0u, 0u, 0u);
      if (gn < N) v = *(const uint4*)(BT + (size_t)gn * K + k0 + sub * 8);
      *(uint4*)(Bl + row * RA + sub * 8) = v;
    }
    __syncthreads();
    half8 af[4], bfr[4];
#pragma unroll
    for (int i = 0; i < 4; ++i)
      af[i] = *(const half8*)(Al + (wr + i * 16 + lr) * RA + lk * 8);
#pragma unroll
    for (int j = 0; j < 4; ++j)
      bfr[j] = *(const half8*)(Bl + (wc + j * 16 + lr) * RA + lk * 8);
#pragma unroll
    for (int i = 0; i < 4; ++i)
#pragma unroll
      for (int j = 0; j < 4; ++j)
        acc[i][j] = __builtin_amdgcn_mfma_f32_16x16x32_f16(af[i], bfr[j], acc[i][j], 0, 0, 0);
  }
#pragma unroll
  for (int i = 0; i < 4; ++i)
#pragma unroll
    for (int r = 0; r < 4; ++r) {
      int m = m0 + wr + i * 16 + lk * 4 + r;
#pragma unroll
      for (int j = 0; j < 4; ++j) {
        int n = n0 + wc + j * 16 + lr;
        if (n < N) C[(size_t)m * N + n] = acc[i][j][r];
      }
    }
}

// ------- logits fallback: B fp32 [N][K] inline-cvt (when ws too small) -------
__global__ __launch_bounds__(256) void gemm_logits_f32b_kernel(
    const short* __restrict__ A, const float* __restrict__ BT,
    float* __restrict__ C, int M, int N, int K)
{
  __shared__ short Al[128 * RA];
  __shared__ short Bl[128 * RA];
  int tid = threadIdx.x;
  int wave = tid >> 6, lane = tid & 63;
  int wr = (wave >> 1) * 64, wc = (wave & 1) * 64;
  int lr = lane & 15, lk = lane >> 4;
  int m0 = blockIdx.y * 128, n0 = blockIdx.x * 128;
  f32x4 acc[4][4] = {};

  for (int k0 = 0; k0 < K; k0 += 32) {
    __syncthreads();
#pragma unroll
    for (int f = 0; f < 2; ++f) {
      int idx = tid + f * 256, row = idx >> 2, sub = idx & 3;
      uint4 v = *(const uint4*)(A + (size_t)(m0 + row) * K + k0 + sub * 8);
      *(uint4*)(Al + row * RA + sub * 8) = v;
    }
#pragma unroll
    for (int f = 0; f < 4; ++f) {
      int idx = tid + f * 256, row = idx >> 3, qq = idx & 7;
      int gn = n0 + row;
      float4 v = make_float4(0.f, 0.f, 0.f, 0.f);
      if (gn < N) v = *(const float4*)(BT + (size_t)gn * K + k0 + qq * 4);
      *(short4*)(Bl + row * RA + qq * 4) =
          make_short4(f2h(v.x), f2h(v.y), f2h(v.z), f2h(v.w));
    }
    __syncthreads();
    half8 af[4], bfr[4];
#pragma unroll
    for (int i = 0; i < 4; ++i)
      af[i] = *(const half8*)(Al + (wr + i * 16 + lr) * RA + lk * 8);
#pragma unroll
    for (int j = 0; j < 4; ++j)
      bfr[j] = *(const half8*)(Bl + (wc + j * 16 + lr) * RA + lk * 8);
#pragma unroll
    for (int i = 0; i < 4; ++i)
#pragma unroll
      for (int j = 0; j < 4; ++j)
        acc[i][j] = __builtin_amdgcn_mfma_f32_16x16x32_f16(af[i], bfr[j], acc[i][j], 0, 0, 0);
  }
#pragma unroll
  for (int i = 0; i < 4; ++i)
#pragma unroll
    for (int r = 0; r < 4; ++r) {
      int m = m0 + wr + i * 16 + lk * 4 + r;
#pragma unroll
      for (int j = 0; j < 4; ++j) {
        int n = n0 + wc + j * 16 + lr;
        if (n < N) C[(size_t)m * N + n] = acc[i][j][r];
      }
    }
}

// ---------------- indexer scores + exact stable top-k -> bitmask ----------------
__device__ __forceinline__ unsigned int ford(float f) {
  unsigned int u = __float_as_uint(f);
  return (u & 0x80000000u) ? ~u : (u | 0x80000000u);
}

__global__ __launch_bounds__(256) void idx_topk_kernel(
    const float* __restrict__ Hx, unsigned int* __restrict__ MASK)
{
  int bq = blockIdx.x;
  int q = bq & (S_LEN - 1);
  int b = bq >> 10;
  int tid = threadIdx.x;
  int n = q + 1;
  if (n <= TOPK_N) {
    if (tid < 32) {
      int full = n >> 5, rem = n & 31;
      unsigned int w = 0u;
      if (tid < full) w = 0xFFFFFFFFu;
      else if (tid == full && rem) w = (1u << rem) - 1u;
      MASK[(size_t)bq * 32 + tid] = w;
    }
    return;
  }
  __shared__ float qi_s[HI_N * DI_N];
  __shared__ float wt_s[HI_N];
  __shared__ float sc[S_LEN];
  __shared__ unsigned long long keys[S_LEN];
  __shared__ unsigned int mw[32];
  qi_s[tid] = Hx[(size_t)bq * IDX_LD + COL_QI + tid];
  if (tid < HI_N) wt_s[tid] = Hx[(size_t)bq * IDX_LD + COL_WT + tid];
  __syncthreads();
  for (int k = tid; k < n; k += 256) {
    const float* kr = Hx + (size_t)(b * S_LEN + k) * IDX_LD + COL_KI;
    float d0 = 0.f, d1 = 0.f, d2 = 0.f, d3 = 0.f;
#pragma unroll
    for (int d = 0; d < DI_N; ++d) {
      float kv = kr[d];
      d0 = fmaf(qi_s[d], kv, d0);
      d1 = fmaf(qi_s[64 + d], kv, d1);
      d2 = fmaf(qi_s[128 + d], kv, d2);
      d3 = fmaf(qi_s[192 + d], kv, d3);
    }
    sc[k] = wt_s[0] * fmaxf(d0, 0.f) + wt_s[1] * fmaxf(d1, 0.f)
          + wt_s[2] * fmaxf(d2, 0.f) + wt_s[3] * fmaxf(d3, 0.f);
  }
  __syncthreads();
  for (int i = tid; i < S_LEN; i += 256) {
    unsigned long long kk = 0ull;
    if (i < n) kk = ((unsigned long long)ford(sc[i]) << 32) | (unsigned int)(S_LEN - 1 - i);
    keys[i] = kk;
  }
  __syncthreads();
  for (int size = 2; size <= S_LEN; size <<= 1) {
    for (int stride = size >> 1; stride > 0; stride >>= 1) {
      for (int t = tid; t < S_LEN / 2; t += 256) {
        int j = t & (stride - 1);
        int lo = ((t ^ j) << 1) | j;
        int hi = lo | stride;
        unsigned long long a = keys[lo], c = keys[hi];
        bool desc = ((lo & size) == 0);
        bool sw = desc ? (a < c) : (a > c);
        if (sw) { keys[lo] = c; keys[hi] = a; }
      }
      __syncthreads();
    }
  }
  if (tid < 32) mw[tid] = 0u;
  __syncthreads();
  for (int i = tid; i < TOPK_N; i += 256) {
    int k = S_LEN - 1 - (int)(keys[i] & 0xFFFFFFFFull);
    atomicOr(&mw[k >> 5], 1u << (k & 31));
  }
  __syncthreads();
  if (tid < 32) MASK[(size_t)bq * 32 + tid] = mw[tid];
}

// ------- masked-dense flash attention via 16x16x16 f16 MFMA -------
__global__ __launch_bounds__(256) void attn_mfma_kernel(
    const short* __restrict__ QKV, const unsigned int* __restrict__ MASK,
    short* __restrict__ O /* [BSROWS][D] fp16 */)
{
  __shared__ unsigned int mlds[64 * 32];  // 8KB: mask words for 64 q-rows
  __shared__ short Kl[64 * 72];           // K tile [key][d], pitch 72
  __shared__ short Vtl[64 * 68];          // V^T tile [d][key], pitch 68
  int qt = blockIdx.x, h = blockIdx.y, b = blockIdx.z;
  int tid = threadIdx.x;
  int w = tid >> 6, l = tid & 63;
  int lq = l & 15, g = l >> 4;
  int q0 = qt * 64;

#pragma unroll
  for (int i = 0; i < 8; ++i) {
    int idx = tid + i * 256;
    mlds[idx] = MASK[((size_t)(b * S_LEN + q0 + (idx >> 5))) * 32 + (idx & 31)];
  }
  // Q B-frags: q = q0 + w*16 + lq, d = dt*16 + g*4 + j (fp16 direct)
  half4v qf[4];
  {
    const short* qrow = QKV + ((size_t)(b * S_LEN + q0 + w * 16 + lq)) * QKV_LD + h * DHD;
#pragma unroll
    for (int dt = 0; dt < 4; ++dt)
      qf[dt] = *(const half4v*)(qrow + dt * 16 + g * 4);
  }
  f32x4 acc_o[4] = {};
  float m_run = -1.0e30f, l_run = 0.f;
  const short* Kb = QKV + (size_t)b * S_LEN * QKV_LD + 1024 + h * DHD;
  const short* Vb = QKV + (size_t)b * S_LEN * QKV_LD + 2048 + h * DHD;
  const int mrow = w * 16 + lq;  // this lane's q-row in mlds

  for (int kt = 0; kt <= qt; ++kt) {
    __syncthreads();
    // stage K tile: [64 key][64 d] -> Kl pitch 72
#pragma unroll
    for (int i = 0; i < 2; ++i) {
      int idx = tid + i * 256;  // 0..511
      int row = idx >> 3, sub = idx & 7;
      uint4 v = *(const uint4*)(Kb + (size_t)(kt * 64 + row) * QKV_LD + sub * 8);
      *(uint4*)(Kl + row * 72 + sub * 8) = v;
    }
    // stage V^T: [64 d][64 key] pitch 68
    {
      int u = tid >> 1, half = tid & 1;  // u 0..127
      int kg = u >> 3, dg = u & 7;
      int krow = kt * 64 + kg * 4 + half * 2;
      uint4 v0 = *(const uint4*)(Vb + (size_t)krow * QKV_LD + dg * 8);
      uint4 v1 = *(const uint4*)(Vb + (size_t)(krow + 1) * QKV_LD + dg * 8);
      const short* s0 = (const short*)&v0;
      const short* s1 = (const short*)&v1;
#pragma unroll
      for (int j = 0; j < 8; ++j)
        *(short2*)(Vtl + (dg * 8 + j) * 68 + kg * 4 + half * 2) = make_short2(s0[j], s1[j]);
    }
    __syncthreads();
    // S^T[key][q] = sum_d K[key][d] Q[q][d]
    f32x4 s[4] = {};
#pragma unroll
    for (int dt = 0; dt < 4; ++dt)
#pragma unroll
      for (int ks = 0; ks < 4; ++ks) {
        half4v kf = *(const half4v*)(Kl + (ks * 16 + lq) * 72 + dt * 16 + g * 4);
        s[ks] = MFMA16F(kf, qf[dt], s[ks]);
      }
    // mask + scale
    float mx = NEGF;
#pragma unroll
    for (int ks = 0; ks < 4; ++ks) {
      int kbase = kt * 64 + ks * 16 + g * 4;
      unsigned mwv = mlds[mrow * 32 + (kbase >> 5)];
#pragma unroll
      for (int r = 0; r < 4; ++r) {
        float sv = ((mwv >> ((kbase + r) & 31)) & 1u) ? s[ks][r] * 0.125f : NEGF;
        s[ks][r] = sv;
        mx = fmaxf(mx, sv);
      }
    }
    mx = fmaxf(mx, __shfl_xor(mx, 16));
    mx = fmaxf(mx, __shfl_xor(mx, 32));
    float m_new = fmaxf(m_run, mx);
    float scale = __expf(m_run - m_new);
    float lsum = 0.f;
    half4v pf[4];
#pragma unroll
    for (int ks = 0; ks < 4; ++ks) {
      half4v t;
#pragma unroll
      for (int r = 0; r < 4; ++r) {
        float p = __expf(s[ks][r] - m_new);
        lsum += p;
        t[r] = (_Float16)p;
      }
      pf[ks] = t;
    }
    lsum += __shfl_xor(lsum, 16);
    lsum += __shfl_xor(lsum, 32);
    l_run = l_run * scale + lsum;
    m_run = m_new;
    float sc[4];
#pragma unroll
    for (int r = 0; r < 4; ++r) sc[r] = __shfl(scale, g * 4 + r);
#pragma unroll
    for (int dt = 0; dt < 4; ++dt) {
      f32x4 a = acc_o[dt];
      a[0] *= sc[0]; a[1] *= sc[1]; a[2] *= sc[2]; a[3] *= sc[3];
#pragma unroll
      for (int ks = 0; ks < 4; ++ks) {
        half4v vf = *(const half4v*)(Vtl + (dt * 16 + lq) * 68 + ks * 16 + g * 4);
        a = MFMA16F(pf[ks], vf, a);  // A = P[q][k], B = V^T[d][k]
      }
      acc_o[dt] = a;
    }
  }
  float linv[4];
#pragma unroll
  for (int r = 0; r < 4; ++r) linv[r] = 1.0f / __shfl(l_run, g * 4 + r);
#pragma unroll
  for (int dt = 0; dt < 4; ++dt)
#pragma unroll
    for (int r = 0; r < 4; ++r) {
      int q = q0 + w * 16 + g * 4 + r;
      float o = acc_o[dt][r] * linv[r];
      O[(size_t)(b * S_LEN + q) * D_DIM + h * DHD + dt * 16 + lq] = f2h(o);
    }
}

// ---------------- host orchestration ----------------
extern "C" void kernel_launch(void* const* d_in, const int* in_sizes, int n_in,
                              void* d_out, int out_size, void* d_ws, size_t ws_size,
                              hipStream_t stream) {
  (void)in_sizes; (void)n_in; (void)out_size;
  const int*   tokens  = (const int*)d_in[0];
  const float* embed_w = (const float*)d_in[1];
  const float* pos_w   = (const float*)d_in[2];
  const float* wq      = (const float*)d_in[3];
  const float* wk      = (const float*)d_in[4];
  const float* wv      = (const float*)d_in[5];
  const float* wo      = (const float*)d_in[6];
  const float* iqw     = (const float*)d_in[7];
  const float* ikw     = (const float*)d_in[8];
  const float* iww     = (const float*)d_in[9];
  const float* w1      = (const float*)d_in[10];
  const float* w2      = (const float*)d_in[11];
  const float* n1      = (const float*)d_in[12];
  const float* n2      = (const float*)d_in[13];
  const float* nf      = (const float*)d_in[14];
  float* logits = (float*)d_out;

  // ws: Hh (logits A, 4 MB) + optionally Eh (fp16 embed, 103 MB)
  short* Hh = (short*)d_ws;
  size_t need_eh = (size_t)BSROWS * D_DIM * 2 + (size_t)VOCAB * D_DIM * 2;
  bool use_eh = ws_size >= need_eh;
  short* Eh = Hh + (size_t)BSROWS * D_DIM;

  // d_out scratch (all dead before logits GEMM writes)
  char* base = (char*)d_out;
  size_t off = (size_t)BSROWS * D_DIM * 4;
  float* X = logits;
  float* Hx = (float*)(base + off);    off += (size_t)BSROWS * IDX_LD * 4;   // [2048][384] f32
  short* QKVh = (short*)(base + off);  off += (size_t)BSROWS * QKV_LD * 2;   // [2048][3072] fp16
  short* Hsp = (short*)(base + off);   off += (size_t)2 * BSROWS * D_DIM * 2;
  short* AOh = (short*)(base + off);   off += (size_t)BSROWS * D_DIM * 2;
  short* FFh = (short*)(base + off);   off += (size_t)BSROWS * FF_DIM * 2;
  unsigned int* MASKb = (unsigned int*)(base + off); off += (size_t)BSROWS * 32 * 4;
  short* BTqkv = (short*)(base + off); off += (size_t)QKV_LD * D_DIM * 2;
  short* BTidx = (short*)(base + off); off += (size_t)2 * IDX_LD * D_DIM * 2;
  short* BTwo = (short*)(base + off);  off += (size_t)D_DIM * D_DIM * 2;
  short* BTw1 = (short*)(base + off);  off += (size_t)FF_DIM * D_DIM * 2;
  short* BTw2 = (short*)(base + off);  off += (size_t)FF_DIM * D_DIM * 2;

  const size_t plH  = (size_t)BSROWS * D_DIM;
  const size_t plIx = (size_t)IDX_LD * D_DIM;
  const size_t plDD = (size_t)D_DIM * D_DIM;
  const size_t plFD = (size_t)FF_DIM * D_DIM;

  hipLaunchKernelGGL(embed_kernel, dim3(BSROWS), dim3(256), 0, stream,
                     tokens, embed_w, pos_w, X);
  if (use_eh) {
    long total4 = (long)VOCAB * D_DIM / 4;
    hipLaunchKernelGGL(cvt_embed_kernel, dim3(8192), dim3(256), 0, stream,
                       embed_w, Eh, total4);
  }

  for (int l = 0; l < NL; ++l) {
    const float* lwq = wq + (size_t)l * plDD;
    const float* lwk = wk + (size_t)l * plDD;
    const float* lwv = wv + (size_t)l * plDD;
    const float* lwo = wo + (size_t)l * plDD;
    const float* liq = iqw + (size_t)l * D_DIM * (HI_N * DI_N);
    const float* lik = ikw + (size_t)l * D_DIM * DI_N;
    const float* liw = iww + (size_t)l * D_DIM * HI_N;
    const float* lw1 = w1 + (size_t)l * plFD;
    const float* lw2 = w2 + (size_t)l * plFD;

    hipLaunchKernelGGL(rmsnorm_split_kernel, dim3(BSROWS), dim3(256), 0, stream,
                       X, n1 + (size_t)l * D_DIM, Hsp);
    hipLaunchKernelGGL(pack_qkv_kernel, dim3(QKV_LD / 32, 32), dim3(32, 8), 0, stream,
                       lwq, lwk, lwv, BTqkv);
    hipLaunchKernelGGL(pack_idx_kernel, dim3(IDX_LD / 32, 32), dim3(32, 8), 0, stream,
                       liq, lik, liw, BTidx);
    // QKV: plain fp16 (A = hi plane of Hsp), fp16 compact out
    hipLaunchKernelGGL((gemm_f16_kernel<1>), dim3(QKV_LD / 128, 16), dim3(256), 0, stream,
                       Hsp, BTqkv, nullptr, QKVh, BSROWS, QKV_LD, D_DIM);
    // indexer: split-fp16 (fp32-accurate) -> Hx
    hipLaunchKernelGGL(gemm_split_kernel, dim3(IDX_LD / 128, 16), dim3(256), 0, stream,
                       Hsp, plH, BTidx, plIx, Hx, BSROWS, IDX_LD, D_DIM);
    hipLaunchKernelGGL(idx_topk_kernel, dim3(BSROWS), dim3(256), 0, stream, Hx, MASKb);
    hipLaunchKernelGGL(attn_mfma_kernel, dim3(S_LEN / 64, NH, 2), dim3(256), 0, stream,
                       QKVh, MASKb, AOh);
    // x = x + AO @ wo
    hipLaunchKernelGGL(packT_f16_kernel, dim3(32, 32), dim3(32, 8), 0, stream,
                       lwo, BTwo, D_DIM, D_DIM);
    hipLaunchKernelGGL((gemm_f16_kernel<3>), dim3(8, 16), dim3(256), 0, stream,
                       AOh, BTwo, X, X, BSROWS, D_DIM, D_DIM);
    // FFN
    hipLaunchKernelGGL(rmsnorm_h_kernel, dim3(BSROWS), dim3(256), 0, stream,
                       X, n2 + (size_t)l * D_DIM, Hsp);
    hipLaunchKernelGGL(packT_f16_kernel, dim3(FF_DIM / 32, 32), dim3(32, 8), 0, stream,
                       lw1, BTw1, D_DIM, FF_DIM);
    hipLaunchKernelGGL((gemm_f16_kernel<2>), dim3(FF_DIM / 128, 16), dim3(256), 0, stream,
                       Hsp, BTw1, nullptr, FFh, BSROWS, FF_DIM, D_DIM);
    hipLaunchKernelGGL(packT_f16_kernel, dim3(D_DIM / 32, FF_DIM / 32), dim3(32, 8), 0, stream,
                       lw2, BTw2, FF_DIM, D_DIM);
    hipLaunchKernelGGL((gemm_f16_kernel<3>), dim3(8, 16), dim3(256), 0, stream,
                       FFh, BTw2, X, X, BSROWS, D_DIM, FF_DIM);
  }

  hipLaunchKernelGGL(rmsnorm_h_kernel, dim3(BSROWS), dim3(256), 0, stream, X, nf, Hh);
  if (use_eh) {
    hipLaunchKernelGGL(gemm_logits_f16_kernel, dim3(8 * YPX * 16), dim3(256), 0, stream,
                       Hh, Eh, logits, BSROWS, VOCAB, D_DIM);
  } else {
    hipLaunchKernelGGL(gemm_logits_f32b_kernel, dim3((VOCAB + 127) / 128, 16), dim3(256), 0, stream,
                       Hh, embed_w, logits, BSROWS, VOCAB, D_DIM);
  }
}

// Round 8
// 3690.617 us; speedup vs baseline: 7.8857x; 1.1989x over previous
//
#include <hip/hip_runtime.h>
#include <cstdint>
#include <cstddef>

#define S_LEN 1024
#define D_DIM 1024
#define NH 16
#define DHD 64
#define NL 8
#define FF_DIM 4096
#define HI_N 4
#define DI_N 64
#define TOPK_N 512
#define BSROWS 2048  // B * S
#define VOCAB 50257
#define VPAD 50304    // VOCAB rounded up to 128
#define NTILES_V 393  // ceil(50257/128)
#define YPX 50        // ceil(393/8) N-panels per XCD for logits

// compact QKV layout: [Q 0..1023 | K 1024..2047 | V 2048..3071], fp16
#define QKV_LD 3072
// indexer block layout (fp32): [QI 0..255 | KI 256..319 | WT 320..323 | pad..383]
#define IDX_LD 384
#define COL_QI 0
#define COL_KI 256
#define COL_WT 320

#define NEGF -3.0e38f

typedef __attribute__((ext_vector_type(8))) _Float16 half8;
typedef __attribute__((ext_vector_type(4))) _Float16 half4v;
typedef __attribute__((ext_vector_type(4))) float f32x4;

#if __has_builtin(__builtin_amdgcn_mfma_f32_16x16x16f16)
#define MFMA16F(a, b, c) __builtin_amdgcn_mfma_f32_16x16x16f16((a), (b), (c), 0, 0, 0)
#else
static __device__ __forceinline__ f32x4 mfma16f_asm(half4v a, half4v b, f32x4 c) {
  f32x4 d;
  asm volatile("v_mfma_f32_16x16x16_f16 %0, %1, %2, %3\n\ts_nop 7\n\ts_nop 7"
               : "=v"(d) : "v"(a), "v"(b), "v"(c));
  return d;
}
#define MFMA16F(a, b, c) mfma16f_asm((a), (b), (c))
#endif

// async global->LDS, 16B per lane; LDS dest must be lane-linear (rule #21)
typedef const __attribute__((address_space(1))) void* gas_ptr;
typedef __attribute__((address_space(3))) void* las_ptr;
__device__ __forceinline__ void gload16(const void* g, void* l) {
#if __has_builtin(__builtin_amdgcn_global_load_lds)
  __builtin_amdgcn_global_load_lds((gas_ptr)g, (las_ptr)l, 16, 0, 0);
#else
  *(uint4*)l = *(const uint4*)g;
#endif
}

__device__ __forceinline__ short f2h(float x) {  // RNE fp32->fp16 (bits)
  _Float16 h = (_Float16)x;
  return *reinterpret_cast<short*>(&h);
}
__device__ __forceinline__ float h2f(short b) {
  _Float16 h = *reinterpret_cast<_Float16*>(&b);
  return (float)h;
}
// two-term fp16 split: x ~= hi + lo with rel err ~2^-22
__device__ __forceinline__ void split_h(float x, short& hi, short& lo) {
  hi = f2h(x);
  lo = f2h(x - h2f(hi));
}

// ---------------- embed + positional ----------------
__global__ __launch_bounds__(256) void embed_kernel(
    const int* __restrict__ tokens, const float* __restrict__ E,
    const float* __restrict__ P, float* __restrict__ X)
{
  int bs = blockIdx.x;
  int s = bs & (S_LEN - 1);
  int tid = threadIdx.x;
  int tok = tokens[bs];
  float4 e = ((const float4*)(E + (size_t)tok * D_DIM))[tid];
  float4 p = ((const float4*)(P + (size_t)s * D_DIM))[tid];
  float4 o; o.x = e.x + p.x; o.y = e.y + p.y; o.z = e.z + p.z; o.w = e.w + p.w;
  ((float4*)(X + (size_t)bs * D_DIM))[tid] = o;
}

// ---------------- embed fp32 -> fp16, zero-padded to VPAD rows ----------------
__global__ __launch_bounds__(256) void cvt_embed_kernel(
    const float* __restrict__ E, short* __restrict__ Eh)
{
  const long valid4 = (long)VOCAB * D_DIM / 4;
  const long total4 = (long)VPAD * D_DIM / 4;
  long i = (long)blockIdx.x * 256 + threadIdx.x;
  long stride = (long)gridDim.x * 256;
  for (; i < total4; i += stride) {
    short4 o = make_short4(0, 0, 0, 0);
    if (i < valid4) {
      float4 v = ((const float4*)E)[i];
      o = make_short4(f2h(v.x), f2h(v.y), f2h(v.z), f2h(v.w));
    }
    ((short4*)Eh)[i] = o;
  }
}

// ---------------- rmsnorm -> split fp16 (hi plane, lo plane) ----------------
__global__ __launch_bounds__(256) void rmsnorm_split_kernel(
    const float* __restrict__ X, const float* __restrict__ W,
    short* __restrict__ O /* [2][BSROWS][D] */)
{
  int r = blockIdx.x;
  int tid = threadIdx.x;
  float4 v = ((const float4*)(X + (size_t)r * D_DIM))[tid];
  float ss = v.x * v.x + v.y * v.y + v.z * v.z + v.w * v.w;
  __shared__ float red[4];
  __shared__ float sh_inv;
  for (int o = 32; o; o >>= 1) ss += __shfl_down(ss, o);
  if ((tid & 63) == 0) red[tid >> 6] = ss;
  __syncthreads();
  if (tid == 0) {
    float s = red[0] + red[1] + red[2] + red[3];
    sh_inv = 1.0f / (sqrtf(s) * 0.03125f + 1e-6f);
  }
  __syncthreads();
  float inv = sh_inv;
  float4 w = ((const float4*)W)[tid];
  float o0 = w.x * v.x * inv, o1 = w.y * v.y * inv;
  float o2 = w.z * v.z * inv, o3 = w.w * v.w * inv;
  short4 hi, lo;
  split_h(o0, hi.x, lo.x); split_h(o1, hi.y, lo.y);
  split_h(o2, hi.z, lo.z); split_h(o3, hi.w, lo.w);
  ((short4*)(O + (size_t)r * D_DIM))[tid] = hi;
  ((short4*)(O + (size_t)BSROWS * D_DIM + (size_t)r * D_DIM))[tid] = lo;
}

// ---------------- rmsnorm -> plain fp16 ----------------
__global__ __launch_bounds__(256) void rmsnorm_h_kernel(
    const float* __restrict__ X, const float* __restrict__ W, short* __restrict__ O)
{
  int r = blockIdx.x;
  int tid = threadIdx.x;
  float4 v = ((const float4*)(X + (size_t)r * D_DIM))[tid];
  float ss = v.x * v.x + v.y * v.y + v.z * v.z + v.w * v.w;
  __shared__ float red[4];
  __shared__ float sh_inv;
  for (int o = 32; o; o >>= 1) ss += __shfl_down(ss, o);
  if ((tid & 63) == 0) red[tid >> 6] = ss;
  __syncthreads();
  if (tid == 0) {
    float s = red[0] + red[1] + red[2] + red[3];
    sh_inv = 1.0f / (sqrtf(s) * 0.03125f + 1e-6f);
  }
  __syncthreads();
  float inv = sh_inv;
  float4 w = ((const float4*)W)[tid];
  short4 o4 = make_short4(f2h(w.x * v.x * inv), f2h(w.y * v.y * inv),
                          f2h(w.z * v.z * inv), f2h(w.w * v.w * inv));
  ((short4*)(O + (size_t)r * D_DIM))[tid] = o4;
}

// ------- all-layer packs (grid.z = layer) -------
__global__ __launch_bounds__(256) void packT_all_kernel(
    const float* __restrict__ W0, short* __restrict__ BT0, int K, int N)
{
  __shared__ float t[32][33];
  int z = blockIdx.z;
  const float* W = W0 + (size_t)z * K * N;
  short* BT = BT0 + (size_t)z * N * K;
  int n0 = blockIdx.x * 32, k0 = blockIdx.y * 32;
  int tx = threadIdx.x, ty = threadIdx.y;
#pragma unroll
  for (int r = 0; r < 32; r += 8)
    t[ty + r][tx] = W[(size_t)(k0 + ty + r) * N + n0 + tx];
  __syncthreads();
#pragma unroll
  for (int r = 0; r < 32; r += 8)
    BT[(size_t)(n0 + ty + r) * K + k0 + tx] = f2h(t[tx][ty + r]);
}

__global__ __launch_bounds__(256) void pack_qkv_all_kernel(
    const float* __restrict__ wq0, const float* __restrict__ wk0,
    const float* __restrict__ wv0, short* __restrict__ BT0)
{
  __shared__ float t[32][33];
  int z = blockIdx.z;
  const float* wq = wq0 + (size_t)z * D_DIM * D_DIM;
  const float* wk = wk0 + (size_t)z * D_DIM * D_DIM;
  const float* wv = wv0 + (size_t)z * D_DIM * D_DIM;
  short* BT = BT0 + (size_t)z * QKV_LD * D_DIM;
  int n0 = blockIdx.x * 32, k0 = blockIdx.y * 32;
  int tx = threadIdx.x, ty = threadIdx.y;
  const float* src = (n0 < 1024) ? wq : (n0 < 2048) ? wk : wv;
  int c0 = n0 & 1023;
#pragma unroll
  for (int r = 0; r < 32; r += 8)
    t[ty + r][tx] = src[(size_t)(k0 + ty + r) * 1024 + c0 + tx];
  __syncthreads();
#pragma unroll
  for (int r = 0; r < 32; r += 8)
    BT[(size_t)(n0 + ty + r) * D_DIM + k0 + tx] = f2h(t[tx][ty + r]);
}

__global__ __launch_bounds__(256) void pack_idx_all_kernel(
    const float* __restrict__ iq0, const float* __restrict__ ik0,
    const float* __restrict__ iw0, short* __restrict__ BT0)
{
  __shared__ float t[32][33];
  const size_t plane = (size_t)IDX_LD * D_DIM;
  int z = blockIdx.z;
  const float* iq = iq0 + (size_t)z * D_DIM * (HI_N * DI_N);
  const float* ik = ik0 + (size_t)z * D_DIM * DI_N;
  const float* iw = iw0 + (size_t)z * D_DIM * HI_N;
  short* BT = BT0 + (size_t)z * 2 * plane;
  int n0 = blockIdx.x * 32, k0 = blockIdx.y * 32;
  int tx = threadIdx.x, ty = threadIdx.y;
  const float* src = nullptr; int ld = 0, c0 = 0;
  if (n0 < 256)      { src = iq; ld = 256; c0 = n0; }
  else if (n0 < 320) { src = ik; ld = 64;  c0 = n0 - 256; }
  else if (n0 < 352) { src = iw; ld = 4;   c0 = n0 - 320; }
#pragma unroll
  for (int r = 0; r < 32; r += 8) {
    float v = 0.f;
    int c = c0 + tx;
    if (src && c < ld) v = src[(size_t)(k0 + ty + r) * ld + c];
    t[ty + r][tx] = v;
  }
  __syncthreads();
#pragma unroll
  for (int r = 0; r < 32; r += 8) {
    short hi, lo;
    split_h(t[tx][ty + r], hi, lo);
    size_t o = (size_t)(n0 + ty + r) * D_DIM + k0 + tx;
    BT[o] = hi;
    BT[plane + o] = lo;
  }
}

#define RA 40  // padded LDS pitch for reg-staged split GEMM

// ------- split-fp16 GEMM (fp32-accurate), fp32 out: indexer only -------
__global__ __launch_bounds__(256) void gemm_split_kernel(
    const short* __restrict__ A, size_t aplane,
    const short* __restrict__ BT, size_t bplane,
    float* __restrict__ C, int M, int N, int K)
{
  __shared__ short Al[2 * 128 * RA];
  __shared__ short Bl[2 * 128 * RA];
  int tid = threadIdx.x;
  int wave = tid >> 6, lane = tid & 63;
  int wr = (wave >> 1) * 64, wc = (wave & 1) * 64;
  int lr = lane & 15, lk = lane >> 4;
  int m0 = blockIdx.y * 128, n0 = blockIdx.x * 128;
  f32x4 acc[4][4] = {};

  for (int k0 = 0; k0 < K; k0 += 32) {
    __syncthreads();
#pragma unroll
    for (int f = 0; f < 4; ++f) {
      int idx = tid + f * 256;
      int p = idx >> 9, r2 = idx & 511;
      int row = r2 >> 2, sub = r2 & 3;
      uint4 v = *(const uint4*)(A + (size_t)p * aplane + (size_t)(m0 + row) * K + k0 + sub * 8);
      *(uint4*)(Al + p * 128 * RA + row * RA + sub * 8) = v;
    }
#pragma unroll
    for (int f = 0; f < 4; ++f) {
      int idx = tid + f * 256;
      int p = idx >> 9, r2 = idx & 511;
      int row = r2 >> 2, sub = r2 & 3;
      uint4 v = *(const uint4*)(BT + (size_t)p * bplane + (size_t)(n0 + row) * K + k0 + sub * 8);
      *(uint4*)(Bl + p * 128 * RA + row * RA + sub * 8) = v;
    }
    __syncthreads();
    half8 ah[4], al[4], bh[4], bl[4];
#pragma unroll
    for (int i = 0; i < 4; ++i) {
      ah[i] = *(const half8*)(Al + (wr + i * 16 + lr) * RA + lk * 8);
      al[i] = *(const half8*)(Al + 128 * RA + (wr + i * 16 + lr) * RA + lk * 8);
    }
#pragma unroll
    for (int j = 0; j < 4; ++j) {
      bh[j] = *(const half8*)(Bl + (wc + j * 16 + lr) * RA + lk * 8);
      bl[j] = *(const half8*)(Bl + 128 * RA + (wc + j * 16 + lr) * RA + lk * 8);
    }
#pragma unroll
    for (int i = 0; i < 4; ++i)
#pragma unroll
      for (int j = 0; j < 4; ++j) {
        f32x4 a = acc[i][j];
        a = __builtin_amdgcn_mfma_f32_16x16x32_f16(al[i], bh[j], a, 0, 0, 0);
        a = __builtin_amdgcn_mfma_f32_16x16x32_f16(ah[i], bl[j], a, 0, 0, 0);
        a = __builtin_amdgcn_mfma_f32_16x16x32_f16(ah[i], bh[j], a, 0, 0, 0);
        acc[i][j] = a;
      }
  }
#pragma unroll
  for (int i = 0; i < 4; ++i)
#pragma unroll
    for (int r = 0; r < 4; ++r) {
      int m = m0 + wr + i * 16 + lk * 4 + r;
#pragma unroll
      for (int j = 0; j < 4; ++j) {
        int n = n0 + wc + j * 16 + lr;
        if (n < N) C[(size_t)m * N + n] = acc[i][j][r];
      }
    }
}

// ------- plain fp16 GEMM, global_load_lds staging, linear LDS -------
// Requires: M % BM == 0, N % 128 == 0, K % 32 == 0 (no tile predicates).
// EPI: 1 fp16 store; 2 exact-GELU -> fp16 store; 3 fp32 + R
template<int BM, int EPI>
__global__ __launch_bounds__(256) void gemm_g_kernel(
    const short* __restrict__ A, const short* __restrict__ BT,
    const float* __restrict__ R, void* __restrict__ C, int M, int N, int K)
{
  constexpr int MI = BM / 32;          // M-frags per wave (128->4, 64->2)
  __shared__ short Al[BM * 32];        // linear [row][32]
  __shared__ short Bl[128 * 32];
  int tid = threadIdx.x;
  int wave = tid >> 6, lane = tid & 63;
  int wr = (wave >> 1) * (BM / 2), wc = (wave & 1) * 64;
  int lr = lane & 15, lk = lane >> 4;
  int m0 = blockIdx.y * BM, n0 = blockIdx.x * 128;
  f32x4 acc[MI][4] = {};

  for (int k0 = 0; k0 < K; k0 += 32) {
    __syncthreads();  // previous frag reads complete before overwrite
#pragma unroll
    for (int f = 0; f < BM / 64; ++f) {
      int idx = tid + f * 256;
      gload16(A + (size_t)(m0 + (idx >> 2)) * K + k0 + (idx & 3) * 8, Al + idx * 8);
    }
#pragma unroll
    for (int f = 0; f < 2; ++f) {
      int idx = tid + f * 256;
      gload16(BT + (size_t)(n0 + (idx >> 2)) * K + k0 + (idx & 3) * 8, Bl + idx * 8);
    }
    __syncthreads();  // drains vmcnt -> LDS visible
    half8 af[MI], bfr[4];
#pragma unroll
    for (int i = 0; i < MI; ++i)
      af[i] = *(const half8*)(Al + (wr + i * 16 + lr) * 32 + lk * 8);
#pragma unroll
    for (int j = 0; j < 4; ++j)
      bfr[j] = *(const half8*)(Bl + (wc + j * 16 + lr) * 32 + lk * 8);
#pragma unroll
    for (int i = 0; i < MI; ++i)
#pragma unroll
      for (int j = 0; j < 4; ++j)
        acc[i][j] = __builtin_amdgcn_mfma_f32_16x16x32_f16(af[i], bfr[j], acc[i][j], 0, 0, 0);
  }
#pragma unroll
  for (int i = 0; i < MI; ++i)
#pragma unroll
    for (int r = 0; r < 4; ++r) {
      int m = m0 + wr + i * 16 + lk * 4 + r;
#pragma unroll
      for (int j = 0; j < 4; ++j) {
        int n = n0 + wc + j * 16 + lr;
        float v = acc[i][j][r];
        if (EPI == 1) {
          ((short*)C)[(size_t)m * N + n] = f2h(v);
        } else if (EPI == 2) {
          v = 0.5f * v * (1.0f + erff(v * 0.70710678118654752f));
          ((short*)C)[(size_t)m * N + n] = f2h(v);
        } else {
          ((float*)C)[(size_t)m * N + n] = v + R[(size_t)m * N + n];
        }
      }
    }
}

// ------- logits GEMM: gload staging + XCD-aware 1D grid; B padded to VPAD -----
__global__ __launch_bounds__(256) void gemm_logits_g_kernel(
    const short* __restrict__ A, const short* __restrict__ BT,
    float* __restrict__ C, int M, int N, int K)
{
  int bid = blockIdx.x;
  int xcd = bid & 7, idx = bid >> 3;
  int mt = idx & 15, yt = (idx >> 4) + xcd * YPX;
  if (yt >= NTILES_V) return;
  int m0 = mt * 128, n0 = yt * 128;

  __shared__ short Al[128 * 32];
  __shared__ short Bl[128 * 32];
  int tid = threadIdx.x;
  int wave = tid >> 6, lane = tid & 63;
  int wr = (wave >> 1) * 64, wc = (wave & 1) * 64;
  int lr = lane & 15, lk = lane >> 4;
  f32x4 acc[4][4] = {};

  for (int k0 = 0; k0 < K; k0 += 32) {
    __syncthreads();
#pragma unroll
    for (int f = 0; f < 2; ++f) {
      int i2 = tid + f * 256;
      gload16(A + (size_t)(m0 + (i2 >> 2)) * K + k0 + (i2 & 3) * 8, Al + i2 * 8);
    }
#pragma unroll
    for (int f = 0; f < 2; ++f) {
      int i2 = tid + f * 256;
      gload16(BT + (size_t)(n0 + (i2 >> 2)) * K + k0 + (i2 & 3) * 8, Bl + i2 * 8);
    }
    __syncthreads();
    half8 af[4], bfr[4];
#pragma unroll
    for (int i = 0; i < 4; ++i)
      af[i] = *(const half8*)(Al + (wr + i * 16 + lr) * 32 + lk * 8);
#pragma unroll
    for (int j = 0; j < 4; ++j)
      bfr[j] = *(const half8*)(Bl + (wc + j * 16 + lr) * 32 + lk * 8);
#pragma unroll
    for (int i = 0; i < 4; ++i)
#pragma unroll
      for (int j = 0; j < 4; ++j)
        acc[i][j] = __builtin_amdgcn_mfma_f32_16x16x32_f16(af[i], bfr[j], acc[i][j], 0, 0, 0);
  }
#pragma unroll
  for (int i = 0; i < 4; ++i)
#pragma unroll
    for (int r = 0; r < 4; ++r) {
      int m = m0 + wr + i * 16 + lk * 4 + r;
#pragma unroll
      for (int j = 0; j < 4; ++j) {
        int n = n0 + wc + j * 16 + lr;
        if (n < N) C[(size_t)m * N + n] = acc[i][j][r];
      }
    }
}

// ------- logits fallback: B fp32 [N][K] inline-cvt (when ws too small) -------
__global__ __launch_bounds__(256) void gemm_logits_f32b_kernel(
    const short* __restrict__ A, const float* __restrict__ BT,
    float* __restrict__ C, int M, int N, int K)
{
  __shared__ short Al[128 * RA];
  __shared__ short Bl[128 * RA];
  int tid = threadIdx.x;
  int wave = tid >> 6, lane = tid & 63;
  int wr = (wave >> 1) * 64, wc = (wave & 1) * 64;
  int lr = lane & 15, lk = lane >> 4;
  int m0 = blockIdx.y * 128, n0 = blockIdx.x * 128;
  f32x4 acc[4][4] = {};

  for (int k0 = 0; k0 < K; k0 += 32) {
    __syncthreads();
#pragma unroll
    for (int f = 0; f < 2; ++f) {
      int idx = tid + f * 256, row = idx >> 2, sub = idx & 3;
      uint4 v = *(const uint4*)(A + (size_t)(m0 + row) * K + k0 + sub * 8);
      *(uint4*)(Al + row * RA + sub * 8) = v;
    }
#pragma unroll
    for (int f = 0; f < 4; ++f) {
      int idx = tid + f * 256, row = idx >> 3, qq = idx & 7;
      int gn = n0 + row;
      float4 v = make_float4(0.f, 0.f, 0.f, 0.f);
      if (gn < N) v = *(const float4*)(BT + (size_t)gn * K + k0 + qq * 4);
      *(short4*)(Bl + row * RA + qq * 4) =
          make_short4(f2h(v.x), f2h(v.y), f2h(v.z), f2h(v.w));
    }
    __syncthreads();
    half8 af[4], bfr[4];
#pragma unroll
    for (int i = 0; i < 4; ++i)
      af[i] = *(const half8*)(Al + (wr + i * 16 + lr) * RA + lk * 8);
#pragma unroll
    for (int j = 0; j < 4; ++j)
      bfr[j] = *(const half8*)(Bl + (wc + j * 16 + lr) * RA + lk * 8);
#pragma unroll
    for (int i = 0; i < 4; ++i)
#pragma unroll
      for (int j = 0; j < 4; ++j)
        acc[i][j] = __builtin_amdgcn_mfma_f32_16x16x32_f16(af[i], bfr[j], acc[i][j], 0, 0, 0);
  }
#pragma unroll
  for (int i = 0; i < 4; ++i)
#pragma unroll
    for (int r = 0; r < 4; ++r) {
      int m = m0 + wr + i * 16 + lk * 4 + r;
#pragma unroll
      for (int j = 0; j < 4; ++j) {
        int n = n0 + wc + j * 16 + lr;
        if (n < N) C[(size_t)m * N + n] = acc[i][j][r];
      }
    }
}

// ---------------- indexer scores + exact stable top-k -> bitmask ----------------
__device__ __forceinline__ unsigned int ford(float f) {
  unsigned int u = __float_as_uint(f);
  return (u & 0x80000000u) ? ~u : (u | 0x80000000u);
}

__global__ __launch_bounds__(256) void idx_topk_kernel(
    const float* __restrict__ Hx, unsigned int* __restrict__ MASK)
{
  int bq = blockIdx.x;
  int q = bq & (S_LEN - 1);
  int b = bq >> 10;
  int tid = threadIdx.x;
  int n = q + 1;
  if (n <= TOPK_N) {
    if (tid < 32) {
      int full = n >> 5, rem = n & 31;
      unsigned int w = 0u;
      if (tid < full) w = 0xFFFFFFFFu;
      else if (tid == full && rem) w = (1u << rem) - 1u;
      MASK[(size_t)bq * 32 + tid] = w;
    }
    return;
  }
  __shared__ float qi_s[HI_N * DI_N];
  __shared__ float wt_s[HI_N];
  __shared__ float sc[S_LEN];
  __shared__ unsigned long long keys[S_LEN];
  __shared__ unsigned int mw[32];
  qi_s[tid] = Hx[(size_t)bq * IDX_LD + COL_QI + tid];
  if (tid < HI_N) wt_s[tid] = Hx[(size_t)bq * IDX_LD + COL_WT + tid];
  __syncthreads();
  for (int k = tid; k < n; k += 256) {
    const float* kr = Hx + (size_t)(b * S_LEN + k) * IDX_LD + COL_KI;
    float d0 = 0.f, d1 = 0.f, d2 = 0.f, d3 = 0.f;
#pragma unroll
    for (int d = 0; d < DI_N; ++d) {
      float kv = kr[d];
      d0 = fmaf(qi_s[d], kv, d0);
      d1 = fmaf(qi_s[64 + d], kv, d1);
      d2 = fmaf(qi_s[128 + d], kv, d2);
      d3 = fmaf(qi_s[192 + d], kv, d3);
    }
    sc[k] = wt_s[0] * fmaxf(d0, 0.f) + wt_s[1] * fmaxf(d1, 0.f)
          + wt_s[2] * fmaxf(d2, 0.f) + wt_s[3] * fmaxf(d3, 0.f);
  }
  __syncthreads();
  for (int i = tid; i < S_LEN; i += 256) {
    unsigned long long kk = 0ull;
    if (i < n) kk = ((unsigned long long)ford(sc[i]) << 32) | (unsigned int)(S_LEN - 1 - i);
    keys[i] = kk;
  }
  __syncthreads();
  for (int size = 2; size <= S_LEN; size <<= 1) {
    for (int stride = size >> 1; stride > 0; stride >>= 1) {
      for (int t = tid; t < S_LEN / 2; t += 256) {
        int j = t & (stride - 1);
        int lo = ((t ^ j) << 1) | j;
        int hi = lo | stride;
        unsigned long long a = keys[lo], c = keys[hi];
        bool desc = ((lo & size) == 0);
        bool sw = desc ? (a < c) : (a > c);
        if (sw) { keys[lo] = c; keys[hi] = a; }
      }
      __syncthreads();
    }
  }
  if (tid < 32) mw[tid] = 0u;
  __syncthreads();
  for (int i = tid; i < TOPK_N; i += 256) {
    int k = S_LEN - 1 - (int)(keys[i] & 0xFFFFFFFFull);
    atomicOr(&mw[k >> 5], 1u << (k & 31));
  }
  __syncthreads();
  if (tid < 32) MASK[(size_t)bq * 32 + tid] = mw[tid];
}

// ------- masked-dense flash attention via 16x16x16 f16 MFMA -------
__global__ __launch_bounds__(256) void attn_mfma_kernel(
    const short* __restrict__ QKV, const unsigned int* __restrict__ MASK,
    short* __restrict__ O /* [BSROWS][D] fp16 */)
{
  __shared__ unsigned int mlds[64 * 32];  // 8KB: mask words for 64 q-rows
  __shared__ short Kl[64 * 72];           // K tile [key][d], pitch 72
  __shared__ short Vtl[64 * 68];          // V^T tile [d][key], pitch 68
  int qt = blockIdx.x, h = blockIdx.y, b = blockIdx.z;
  int tid = threadIdx.x;
  int w = tid >> 6, l = tid & 63;
  int lq = l & 15, g = l >> 4;
  int q0 = qt * 64;

#pragma unroll
  for (int i = 0; i < 8; ++i) {
    int idx = tid + i * 256;
    mlds[idx] = MASK[((size_t)(b * S_LEN + q0 + (idx >> 5))) * 32 + (idx & 31)];
  }
  half4v qf[4];
  {
    const short* qrow = QKV + ((size_t)(b * S_LEN + q0 + w * 16 + lq)) * QKV_LD + h * DHD;
#pragma unroll
    for (int dt = 0; dt < 4; ++dt)
      qf[dt] = *(const half4v*)(qrow + dt * 16 + g * 4);
  }
  f32x4 acc_o[4] = {};
  float m_run = -1.0e30f, l_run = 0.f;
  const short* Kb = QKV + (size_t)b * S_LEN * QKV_LD + 1024 + h * DHD;
  const short* Vb = QKV + (size_t)b * S_LEN * QKV_LD + 2048 + h * DHD;
  const int mrow = w * 16 + lq;

  for (int kt = 0; kt <= qt; ++kt) {
    __syncthreads();
#pragma unroll
    for (int i = 0; i < 2; ++i) {
      int idx = tid + i * 256;
      int row = idx >> 3, sub = idx & 7;
      uint4 v = *(const uint4*)(Kb + (size_t)(kt * 64 + row) * QKV_LD + sub * 8);
      *(uint4*)(Kl + row * 72 + sub * 8) = v;
    }
    {
      int u = tid >> 1, half = tid & 1;
      int kg = u >> 3, dg = u & 7;
      int krow = kt * 64 + kg * 4 + half * 2;
      uint4 v0 = *(const uint4*)(Vb + (size_t)krow * QKV_LD + dg * 8);
      uint4 v1 = *(const uint4*)(Vb + (size_t)(krow + 1) * QKV_LD + dg * 8);
      const short* s0 = (const short*)&v0;
      const short* s1 = (const short*)&v1;
#pragma unroll
      for (int j = 0; j < 8; ++j)
        *(short2*)(Vtl + (dg * 8 + j) * 68 + kg * 4 + half * 2) = make_short2(s0[j], s1[j]);
    }
    __syncthreads();
    f32x4 s[4] = {};
#pragma unroll
    for (int dt = 0; dt < 4; ++dt)
#pragma unroll
      for (int ks = 0; ks < 4; ++ks) {
        half4v kf = *(const half4v*)(Kl + (ks * 16 + lq) * 72 + dt * 16 + g * 4);
        s[ks] = MFMA16F(kf, qf[dt], s[ks]);
      }
    float mx = NEGF;
#pragma unroll
    for (int ks = 0; ks < 4; ++ks) {
      int kbase = kt * 64 + ks * 16 + g * 4;
      unsigned mwv = mlds[mrow * 32 + (kbase >> 5)];
#pragma unroll
      for (int r = 0; r < 4; ++r) {
        float sv = ((mwv >> ((kbase + r) & 31)) & 1u) ? s[ks][r] * 0.125f : NEGF;
        s[ks][r] = sv;
        mx = fmaxf(mx, sv);
      }
    }
    mx = fmaxf(mx, __shfl_xor(mx, 16));
    mx = fmaxf(mx, __shfl_xor(mx, 32));
    float m_new = fmaxf(m_run, mx);
    float scale = __expf(m_run - m_new);
    float lsum = 0.f;
    half4v pf[4];
#pragma unroll
    for (int ks = 0; ks < 4; ++ks) {
      half4v t;
#pragma unroll
      for (int r = 0; r < 4; ++r) {
        float p = __expf(s[ks][r] - m_new);
        lsum += p;
        t[r] = (_Float16)p;
      }
      pf[ks] = t;
    }
    lsum += __shfl_xor(lsum, 16);
    lsum += __shfl_xor(lsum, 32);
    l_run = l_run * scale + lsum;
    m_run = m_new;
    float sc[4];
#pragma unroll
    for (int r = 0; r < 4; ++r) sc[r] = __shfl(scale, g * 4 + r);
#pragma unroll
    for (int dt = 0; dt < 4; ++dt) {
      f32x4 a = acc_o[dt];
      a[0] *= sc[0]; a[1] *= sc[1]; a[2] *= sc[2]; a[3] *= sc[3];
#pragma unroll
      for (int ks = 0; ks < 4; ++ks) {
        half4v vf = *(const half4v*)(Vtl + (dt * 16 + lq) * 68 + ks * 16 + g * 4);
        a = MFMA16F(pf[ks], vf, a);
      }
      acc_o[dt] = a;
    }
  }
  float linv[4];
#pragma unroll
  for (int r = 0; r < 4; ++r) linv[r] = 1.0f / __shfl(l_run, g * 4 + r);
#pragma unroll
  for (int dt = 0; dt < 4; ++dt)
#pragma unroll
    for (int r = 0; r < 4; ++r) {
      int q = q0 + w * 16 + g * 4 + r;
      float o = acc_o[dt][r] * linv[r];
      O[(size_t)(b * S_LEN + q) * D_DIM + h * DHD + dt * 16 + lq] = f2h(o);
    }
}

// ---------------- host orchestration ----------------
extern "C" void kernel_launch(void* const* d_in, const int* in_sizes, int n_in,
                              void* d_out, int out_size, void* d_ws, size_t ws_size,
                              hipStream_t stream) {
  (void)in_sizes; (void)n_in; (void)out_size;
  const int*   tokens  = (const int*)d_in[0];
  const float* embed_w = (const float*)d_in[1];
  const float* pos_w   = (const float*)d_in[2];
  const float* wq      = (const float*)d_in[3];
  const float* wk      = (const float*)d_in[4];
  const float* wv      = (const float*)d_in[5];
  const float* wo      = (const float*)d_in[6];
  const float* iqw     = (const float*)d_in[7];
  const float* ikw     = (const float*)d_in[8];
  const float* iww     = (const float*)d_in[9];
  const float* w1      = (const float*)d_in[10];
  const float* w2      = (const float*)d_in[11];
  const float* n1      = (const float*)d_in[12];
  const float* n2      = (const float*)d_in[13];
  const float* nf      = (const float*)d_in[14];
  float* logits = (float*)d_out;

  // ws: Hh (logits A, 4 MB) + Eh (fp16 embed padded to VPAD rows, 103 MB)
  short* Hh = (short*)d_ws;
  size_t need_eh = ((size_t)BSROWS * D_DIM + (size_t)VPAD * D_DIM) * 2;
  bool use_eh = ws_size >= need_eh;
  short* Eh = Hh + (size_t)BSROWS * D_DIM;

  // d_out scratch (all dead before logits GEMM writes)
  char* base = (char*)d_out;
  size_t off = (size_t)BSROWS * D_DIM * 4;
  float* X = logits;
  float* Hx = (float*)(base + off);    off += (size_t)BSROWS * IDX_LD * 4;
  short* QKVh = (short*)(base + off);  off += (size_t)BSROWS * QKV_LD * 2;
  short* Hsp = (short*)(base + off);   off += (size_t)2 * BSROWS * D_DIM * 2;
  short* AOh = (short*)(base + off);   off += (size_t)BSROWS * D_DIM * 2;
  short* FFh = (short*)(base + off);   off += (size_t)BSROWS * FF_DIM * 2;
  unsigned int* MASKb = (unsigned int*)(base + off); off += (size_t)BSROWS * 32 * 4;
  short* BTqkvA = (short*)(base + off); off += (size_t)NL * QKV_LD * D_DIM * 2;
  short* BTidxA = (short*)(base + off); off += (size_t)NL * 2 * IDX_LD * D_DIM * 2;
  short* BTwoA = (short*)(base + off);  off += (size_t)NL * D_DIM * D_DIM * 2;
  short* BTw1A = (short*)(base + off);  off += (size_t)NL * FF_DIM * D_DIM * 2;
  short* BTw2A = (short*)(base + off);  off += (size_t)NL * FF_DIM * D_DIM * 2;

  const size_t plH  = (size_t)BSROWS * D_DIM;
  const size_t plIx = (size_t)IDX_LD * D_DIM;

  hipLaunchKernelGGL(embed_kernel, dim3(BSROWS), dim3(256), 0, stream,
                     tokens, embed_w, pos_w, X);
  if (use_eh)
    hipLaunchKernelGGL(cvt_embed_kernel, dim3(8192), dim3(256), 0, stream, embed_w, Eh);

  // all-layer weight packs (5 dispatches total)
  hipLaunchKernelGGL(pack_qkv_all_kernel, dim3(QKV_LD / 32, 32, NL), dim3(32, 8), 0, stream,
                     wq, wk, wv, BTqkvA);
  hipLaunchKernelGGL(pack_idx_all_kernel, dim3(IDX_LD / 32, 32, NL), dim3(32, 8), 0, stream,
                     iqw, ikw, iww, BTidxA);
  hipLaunchKernelGGL(packT_all_kernel, dim3(32, 32, NL), dim3(32, 8), 0, stream,
                     wo, BTwoA, D_DIM, D_DIM);
  hipLaunchKernelGGL(packT_all_kernel, dim3(FF_DIM / 32, 32, NL), dim3(32, 8), 0, stream,
                     w1, BTw1A, D_DIM, FF_DIM);
  hipLaunchKernelGGL(packT_all_kernel, dim3(D_DIM / 32, FF_DIM / 32, NL), dim3(32, 8), 0, stream,
                     w2, BTw2A, FF_DIM, D_DIM);

  for (int l = 0; l < NL; ++l) {
    short* BTqkv = BTqkvA + (size_t)l * QKV_LD * D_DIM;
    short* BTidx = BTidxA + (size_t)l * 2 * IDX_LD * D_DIM;
    short* BTwo  = BTwoA + (size_t)l * D_DIM * D_DIM;
    short* BTw1  = BTw1A + (size_t)l * FF_DIM * D_DIM;
    short* BTw2  = BTw2A + (size_t)l * FF_DIM * D_DIM;

    hipLaunchKernelGGL(rmsnorm_split_kernel, dim3(BSROWS), dim3(256), 0, stream,
                       X, n1 + (size_t)l * D_DIM, Hsp);
    hipLaunchKernelGGL((gemm_g_kernel<128, 1>), dim3(QKV_LD / 128, 16), dim3(256), 0, stream,
                       Hsp, BTqkv, nullptr, QKVh, BSROWS, QKV_LD, D_DIM);
    hipLaunchKernelGGL(gemm_split_kernel, dim3(IDX_LD / 128, 16), dim3(256), 0, stream,
                       Hsp, plH, BTidx, plIx, Hx, BSROWS, IDX_LD, D_DIM);
    hipLaunchKernelGGL(idx_topk_kernel, dim3(BSROWS), dim3(256), 0, stream, Hx, MASKb);
    hipLaunchKernelGGL(attn_mfma_kernel, dim3(S_LEN / 64, NH, 2), dim3(256), 0, stream,
                       QKVh, MASKb, AOh);
    hipLaunchKernelGGL((gemm_g_kernel<64, 3>), dim3(8, 32), dim3(256), 0, stream,
                       AOh, BTwo, X, X, BSROWS, D_DIM, D_DIM);
    hipLaunchKernelGGL(rmsnorm_h_kernel, dim3(BSROWS), dim3(256), 0, stream,
                       X, n2 + (size_t)l * D_DIM, Hsp);
    hipLaunchKernelGGL((gemm_g_kernel<128, 2>), dim3(FF_DIM / 128, 16), dim3(256), 0, stream,
                       Hsp, BTw1, nullptr, FFh, BSROWS, FF_DIM, D_DIM);
    hipLaunchKernelGGL((gemm_g_kernel<64, 3>), dim3(8, 32), dim3(256), 0, stream,
                       FFh, BTw2, X, X, BSROWS, D_DIM, FF_DIM);
  }

  hipLaunchKernelGGL(rmsnorm_h_kernel, dim3(BSROWS), dim3(256), 0, stream, X, nf, Hh);
  if (use_eh) {
    hipLaunchKernelGGL(gemm_logits_g_kernel, dim3(8 * YPX * 16), dim3(256), 0, stream,
                       Hh, Eh, logits, BSROWS, VOCAB, D_DIM);
  } else {
    hipLaunchKernelGGL(gemm_logits_f32b_kernel, dim3((VOCAB + 127) / 128, 16), dim3(256), 0, stream,
                       Hh, embed_w, logits, BSROWS, VOCAB, D_DIM);
  }
}

// Round 9
// 3630.856 us; speedup vs baseline: 8.0155x; 1.0165x over previous
//
#include <hip/hip_runtime.h>
#include <cstdint>
#include <cstddef>

#define S_LEN 1024
#define D_DIM 1024
#define NH 16
#define DHD 64
#define NL 8
#define FF_DIM 4096
#define HI_N 4
#define DI_N 64
#define TOPK_N 512
#define BSROWS 2048  // B * S
#define VOCAB 50257
#define VPAD 50304    // VOCAB rounded up to 128
#define NTILES_V 393  // ceil(50257/128)
#define YPX 50        // ceil(393/8) N-panels per XCD for logits

// compact QKV layout: [Q 0..1023 | K 1024..2047 | V 2048..3071], fp16
#define QKV_LD 3072
// indexer block layout (fp32): [QI 0..255 | KI 256..319 | WT 320..323 | pad..383]
#define IDX_LD 384
#define COL_QI 0
#define COL_KI 256
#define COL_WT 320

#define NEGF -3.0e38f

typedef __attribute__((ext_vector_type(8))) _Float16 half8;
typedef __attribute__((ext_vector_type(4))) _Float16 half4v;
typedef __attribute__((ext_vector_type(4))) float f32x4;

#if __has_builtin(__builtin_amdgcn_mfma_f32_16x16x16f16)
#define MFMA16F(a, b, c) __builtin_amdgcn_mfma_f32_16x16x16f16((a), (b), (c), 0, 0, 0)
#else
static __device__ __forceinline__ f32x4 mfma16f_asm(half4v a, half4v b, f32x4 c) {
  f32x4 d;
  asm volatile("v_mfma_f32_16x16x16_f16 %0, %1, %2, %3\n\ts_nop 7\n\ts_nop 7"
               : "=v"(d) : "v"(a), "v"(b), "v"(c));
  return d;
}
#define MFMA16F(a, b, c) mfma16f_asm((a), (b), (c))
#endif

// async global->LDS, 16B per lane; LDS dest must be lane-linear (rule #21)
typedef const __attribute__((address_space(1))) void* gas_ptr;
typedef __attribute__((address_space(3))) void* las_ptr;
__device__ __forceinline__ void gload16(const void* g, void* l) {
#if __has_builtin(__builtin_amdgcn_global_load_lds)
  __builtin_amdgcn_global_load_lds((gas_ptr)g, (las_ptr)l, 16, 0, 0);
#else
  *(uint4*)l = *(const uint4*)g;
#endif
}

__device__ __forceinline__ short f2h(float x) {  // RNE fp32->fp16 (bits)
  _Float16 h = (_Float16)x;
  return *reinterpret_cast<short*>(&h);
}
__device__ __forceinline__ float h2f(short b) {
  _Float16 h = *reinterpret_cast<_Float16*>(&b);
  return (float)h;
}
// two-term fp16 split: x ~= hi + lo with rel err ~2^-22
__device__ __forceinline__ void split_h(float x, short& hi, short& lo) {
  hi = f2h(x);
  lo = f2h(x - h2f(hi));
}

// ---------------- embed + positional ----------------
__global__ __launch_bounds__(256) void embed_kernel(
    const int* __restrict__ tokens, const float* __restrict__ E,
    const float* __restrict__ P, float* __restrict__ X)
{
  int bs = blockIdx.x;
  int s = bs & (S_LEN - 1);
  int tid = threadIdx.x;
  int tok = tokens[bs];
  float4 e = ((const float4*)(E + (size_t)tok * D_DIM))[tid];
  float4 p = ((const float4*)(P + (size_t)s * D_DIM))[tid];
  float4 o; o.x = e.x + p.x; o.y = e.y + p.y; o.z = e.z + p.z; o.w = e.w + p.w;
  ((float4*)(X + (size_t)bs * D_DIM))[tid] = o;
}

// ---------------- embed fp32 -> fp16, zero-padded to VPAD rows ----------------
__global__ __launch_bounds__(256) void cvt_embed_kernel(
    const float* __restrict__ E, short* __restrict__ Eh)
{
  const long valid4 = (long)VOCAB * D_DIM / 4;
  const long total4 = (long)VPAD * D_DIM / 4;
  long i = (long)blockIdx.x * 256 + threadIdx.x;
  long stride = (long)gridDim.x * 256;
  for (; i < total4; i += stride) {
    short4 o = make_short4(0, 0, 0, 0);
    if (i < valid4) {
      float4 v = ((const float4*)E)[i];
      o = make_short4(f2h(v.x), f2h(v.y), f2h(v.z), f2h(v.w));
    }
    ((short4*)Eh)[i] = o;
  }
}

// ---------------- rmsnorm -> split fp16 (hi plane, lo plane) ----------------
__global__ __launch_bounds__(256) void rmsnorm_split_kernel(
    const float* __restrict__ X, const float* __restrict__ W,
    short* __restrict__ O /* [2][BSROWS][D] */)
{
  int r = blockIdx.x;
  int tid = threadIdx.x;
  float4 v = ((const float4*)(X + (size_t)r * D_DIM))[tid];
  float ss = v.x * v.x + v.y * v.y + v.z * v.z + v.w * v.w;
  __shared__ float red[4];
  __shared__ float sh_inv;
  for (int o = 32; o; o >>= 1) ss += __shfl_down(ss, o);
  if ((tid & 63) == 0) red[tid >> 6] = ss;
  __syncthreads();
  if (tid == 0) {
    float s = red[0] + red[1] + red[2] + red[3];
    sh_inv = 1.0f / (sqrtf(s) * 0.03125f + 1e-6f);
  }
  __syncthreads();
  float inv = sh_inv;
  float4 w = ((const float4*)W)[tid];
  float o0 = w.x * v.x * inv, o1 = w.y * v.y * inv;
  float o2 = w.z * v.z * inv, o3 = w.w * v.w * inv;
  short4 hi, lo;
  split_h(o0, hi.x, lo.x); split_h(o1, hi.y, lo.y);
  split_h(o2, hi.z, lo.z); split_h(o3, hi.w, lo.w);
  ((short4*)(O + (size_t)r * D_DIM))[tid] = hi;
  ((short4*)(O + (size_t)BSROWS * D_DIM + (size_t)r * D_DIM))[tid] = lo;
}

// ---------------- rmsnorm -> plain fp16 ----------------
__global__ __launch_bounds__(256) void rmsnorm_h_kernel(
    const float* __restrict__ X, const float* __restrict__ W, short* __restrict__ O)
{
  int r = blockIdx.x;
  int tid = threadIdx.x;
  float4 v = ((const float4*)(X + (size_t)r * D_DIM))[tid];
  float ss = v.x * v.x + v.y * v.y + v.z * v.z + v.w * v.w;
  __shared__ float red[4];
  __shared__ float sh_inv;
  for (int o = 32; o; o >>= 1) ss += __shfl_down(ss, o);
  if ((tid & 63) == 0) red[tid >> 6] = ss;
  __syncthreads();
  if (tid == 0) {
    float s = red[0] + red[1] + red[2] + red[3];
    sh_inv = 1.0f / (sqrtf(s) * 0.03125f + 1e-6f);
  }
  __syncthreads();
  float inv = sh_inv;
  float4 w = ((const float4*)W)[tid];
  short4 o4 = make_short4(f2h(w.x * v.x * inv), f2h(w.y * v.y * inv),
                          f2h(w.z * v.z * inv), f2h(w.w * v.w * inv));
  ((short4*)(O + (size_t)r * D_DIM))[tid] = o4;
}

// ------- all-layer packs (grid.z = layer) -------
__global__ __launch_bounds__(256) void packT_all_kernel(
    const float* __restrict__ W0, short* __restrict__ BT0, int K, int N)
{
  __shared__ float t[32][33];
  int z = blockIdx.z;
  const float* W = W0 + (size_t)z * K * N;
  short* BT = BT0 + (size_t)z * N * K;
  int n0 = blockIdx.x * 32, k0 = blockIdx.y * 32;
  int tx = threadIdx.x, ty = threadIdx.y;
#pragma unroll
  for (int r = 0; r < 32; r += 8)
    t[ty + r][tx] = W[(size_t)(k0 + ty + r) * N + n0 + tx];
  __syncthreads();
#pragma unroll
  for (int r = 0; r < 32; r += 8)
    BT[(size_t)(n0 + ty + r) * K + k0 + tx] = f2h(t[tx][ty + r]);
}

__global__ __launch_bounds__(256) void pack_qkv_all_kernel(
    const float* __restrict__ wq0, const float* __restrict__ wk0,
    const float* __restrict__ wv0, short* __restrict__ BT0)
{
  __shared__ float t[32][33];
  int z = blockIdx.z;
  const float* wq = wq0 + (size_t)z * D_DIM * D_DIM;
  const float* wk = wk0 + (size_t)z * D_DIM * D_DIM;
  const float* wv = wv0 + (size_t)z * D_DIM * D_DIM;
  short* BT = BT0 + (size_t)z * QKV_LD * D_DIM;
  int n0 = blockIdx.x * 32, k0 = blockIdx.y * 32;
  int tx = threadIdx.x, ty = threadIdx.y;
  const float* src = (n0 < 1024) ? wq : (n0 < 2048) ? wk : wv;
  int c0 = n0 & 1023;
#pragma unroll
  for (int r = 0; r < 32; r += 8)
    t[ty + r][tx] = src[(size_t)(k0 + ty + r) * 1024 + c0 + tx];
  __syncthreads();
#pragma unroll
  for (int r = 0; r < 32; r += 8)
    BT[(size_t)(n0 + ty + r) * D_DIM + k0 + tx] = f2h(t[tx][ty + r]);
}

__global__ __launch_bounds__(256) void pack_idx_all_kernel(
    const float* __restrict__ iq0, const float* __restrict__ ik0,
    const float* __restrict__ iw0, short* __restrict__ BT0)
{
  __shared__ float t[32][33];
  const size_t plane = (size_t)IDX_LD * D_DIM;
  int z = blockIdx.z;
  const float* iq = iq0 + (size_t)z * D_DIM * (HI_N * DI_N);
  const float* ik = ik0 + (size_t)z * D_DIM * DI_N;
  const float* iw = iw0 + (size_t)z * D_DIM * HI_N;
  short* BT = BT0 + (size_t)z * 2 * plane;
  int n0 = blockIdx.x * 32, k0 = blockIdx.y * 32;
  int tx = threadIdx.x, ty = threadIdx.y;
  const float* src = nullptr; int ld = 0, c0 = 0;
  if (n0 < 256)      { src = iq; ld = 256; c0 = n0; }
  else if (n0 < 320) { src = ik; ld = 64;  c0 = n0 - 256; }
  else if (n0 < 352) { src = iw; ld = 4;   c0 = n0 - 320; }
#pragma unroll
  for (int r = 0; r < 32; r += 8) {
    float v = 0.f;
    int c = c0 + tx;
    if (src && c < ld) v = src[(size_t)(k0 + ty + r) * ld + c];
    t[ty + r][tx] = v;
  }
  __syncthreads();
#pragma unroll
  for (int r = 0; r < 32; r += 8) {
    short hi, lo;
    split_h(t[tx][ty + r], hi, lo);
    size_t o = (size_t)(n0 + ty + r) * D_DIM + k0 + tx;
    BT[o] = hi;
    BT[plane + o] = lo;
  }
}

#define RA 40  // padded LDS pitch for reg-staged split GEMM

// ------- split-fp16 GEMM (fp32-accurate), fp32 out: indexer only -------
template<int BM>
__global__ __launch_bounds__(256) void gemm_split_kernel(
    const short* __restrict__ A, size_t aplane,
    const short* __restrict__ BT, size_t bplane,
    float* __restrict__ C, int M, int N, int K)
{
  constexpr int MI = BM / 32;
  __shared__ short Al[2 * BM * RA];
  __shared__ short Bl[2 * 128 * RA];
  int tid = threadIdx.x;
  int wave = tid >> 6, lane = tid & 63;
  int wr = (wave >> 1) * (BM / 2), wc = (wave & 1) * 64;
  int lr = lane & 15, lk = lane >> 4;
  int m0 = blockIdx.y * BM, n0 = blockIdx.x * 128;
  f32x4 acc[MI][4] = {};

  for (int k0 = 0; k0 < K; k0 += 32) {
    __syncthreads();
#pragma unroll
    for (int f = 0; f < BM / 32; ++f) {
      int idx = tid + f * 256;
      int p = idx / (BM * 4), r2 = idx % (BM * 4);
      int row = r2 >> 2, sub = r2 & 3;
      uint4 v = *(const uint4*)(A + (size_t)p * aplane + (size_t)(m0 + row) * K + k0 + sub * 8);
      *(uint4*)(Al + p * BM * RA + row * RA + sub * 8) = v;
    }
#pragma unroll
    for (int f = 0; f < 4; ++f) {
      int idx = tid + f * 256;
      int p = idx >> 9, r2 = idx & 511;
      int row = r2 >> 2, sub = r2 & 3;
      uint4 v = *(const uint4*)(BT + (size_t)p * bplane + (size_t)(n0 + row) * K + k0 + sub * 8);
      *(uint4*)(Bl + p * 128 * RA + row * RA + sub * 8) = v;
    }
    __syncthreads();
    half8 ah[MI], al_[MI], bh[4], bl_[4];
#pragma unroll
    for (int i = 0; i < MI; ++i) {
      ah[i] = *(const half8*)(Al + (wr + i * 16 + lr) * RA + lk * 8);
      al_[i] = *(const half8*)(Al + BM * RA + (wr + i * 16 + lr) * RA + lk * 8);
    }
#pragma unroll
    for (int j = 0; j < 4; ++j) {
      bh[j] = *(const half8*)(Bl + (wc + j * 16 + lr) * RA + lk * 8);
      bl_[j] = *(const half8*)(Bl + 128 * RA + (wc + j * 16 + lr) * RA + lk * 8);
    }
#pragma unroll
    for (int i = 0; i < MI; ++i)
#pragma unroll
      for (int j = 0; j < 4; ++j) {
        f32x4 a = acc[i][j];
        a = __builtin_amdgcn_mfma_f32_16x16x32_f16(al_[i], bh[j], a, 0, 0, 0);
        a = __builtin_amdgcn_mfma_f32_16x16x32_f16(ah[i], bl_[j], a, 0, 0, 0);
        a = __builtin_amdgcn_mfma_f32_16x16x32_f16(ah[i], bh[j], a, 0, 0, 0);
        acc[i][j] = a;
      }
  }
#pragma unroll
  for (int i = 0; i < MI; ++i)
#pragma unroll
    for (int r = 0; r < 4; ++r) {
      int m = m0 + wr + i * 16 + lk * 4 + r;
#pragma unroll
      for (int j = 0; j < 4; ++j) {
        int n = n0 + wc + j * 16 + lr;
        if (n < N) C[(size_t)m * N + n] = acc[i][j][r];
      }
    }
}

// ------- plain fp16 GEMM, global_load_lds staging, linear LDS -------
// Requires: M % BM == 0, N % 128 == 0, K % 32 == 0 (no tile predicates).
// EPI: 1 fp16 store; 2 exact-GELU -> fp16 store; 3 fp32 + R
template<int BM, int EPI>
__global__ __launch_bounds__(256) void gemm_g_kernel(
    const short* __restrict__ A, const short* __restrict__ BT,
    const float* __restrict__ R, void* __restrict__ C, int M, int N, int K)
{
  constexpr int MI = BM / 32;          // M-frags per wave (128->4, 64->2)
  __shared__ short Al[BM * 32];        // linear [row][32]
  __shared__ short Bl[128 * 32];
  int tid = threadIdx.x;
  int wave = tid >> 6, lane = tid & 63;
  int wr = (wave >> 1) * (BM / 2), wc = (wave & 1) * 64;
  int lr = lane & 15, lk = lane >> 4;
  int m0 = blockIdx.y * BM, n0 = blockIdx.x * 128;
  f32x4 acc[MI][4] = {};

  for (int k0 = 0; k0 < K; k0 += 32) {
    __syncthreads();  // previous frag reads complete before overwrite
#pragma unroll
    for (int f = 0; f < BM / 64; ++f) {
      int idx = tid + f * 256;
      gload16(A + (size_t)(m0 + (idx >> 2)) * K + k0 + (idx & 3) * 8, Al + idx * 8);
    }
#pragma unroll
    for (int f = 0; f < 2; ++f) {
      int idx = tid + f * 256;
      gload16(BT + (size_t)(n0 + (idx >> 2)) * K + k0 + (idx & 3) * 8, Bl + idx * 8);
    }
    __syncthreads();  // drains vmcnt -> LDS visible
    half8 af[MI], bfr[4];
#pragma unroll
    for (int i = 0; i < MI; ++i)
      af[i] = *(const half8*)(Al + (wr + i * 16 + lr) * 32 + lk * 8);
#pragma unroll
    for (int j = 0; j < 4; ++j)
      bfr[j] = *(const half8*)(Bl + (wc + j * 16 + lr) * 32 + lk * 8);
#pragma unroll
    for (int i = 0; i < MI; ++i)
#pragma unroll
      for (int j = 0; j < 4; ++j)
        acc[i][j] = __builtin_amdgcn_mfma_f32_16x16x32_f16(af[i], bfr[j], acc[i][j], 0, 0, 0);
  }
#pragma unroll
  for (int i = 0; i < MI; ++i)
#pragma unroll
    for (int r = 0; r < 4; ++r) {
      int m = m0 + wr + i * 16 + lk * 4 + r;
#pragma unroll
      for (int j = 0; j < 4; ++j) {
        int n = n0 + wc + j * 16 + lr;
        float v = acc[i][j][r];
        if (EPI == 1) {
          ((short*)C)[(size_t)m * N + n] = f2h(v);
        } else if (EPI == 2) {
          v = 0.5f * v * (1.0f + erff(v * 0.70710678118654752f));
          ((short*)C)[(size_t)m * N + n] = f2h(v);
        } else {
          ((float*)C)[(size_t)m * N + n] = v + R[(size_t)m * N + n];
        }
      }
    }
}

// ------- logits GEMM: gload staging + XCD-aware 1D grid; B padded to VPAD -----
__global__ __launch_bounds__(256) void gemm_logits_g_kernel(
    const short* __restrict__ A, const short* __restrict__ BT,
    float* __restrict__ C, int M, int N, int K)
{
  int bid = blockIdx.x;
  int xcd = bid & 7, idx = bid >> 3;
  int mt = idx & 15, yt = (idx >> 4) + xcd * YPX;
  if (yt >= NTILES_V) return;
  int m0 = mt * 128, n0 = yt * 128;

  __shared__ short Al[128 * 32];
  __shared__ short Bl[128 * 32];
  int tid = threadIdx.x;
  int wave = tid >> 6, lane = tid & 63;
  int wr = (wave >> 1) * 64, wc = (wave & 1) * 64;
  int lr = lane & 15, lk = lane >> 4;
  f32x4 acc[4][4] = {};

  for (int k0 = 0; k0 < K; k0 += 32) {
    __syncthreads();
#pragma unroll
    for (int f = 0; f < 2; ++f) {
      int i2 = tid + f * 256;
      gload16(A + (size_t)(m0 + (i2 >> 2)) * K + k0 + (i2 & 3) * 8, Al + i2 * 8);
    }
#pragma unroll
    for (int f = 0; f < 2; ++f) {
      int i2 = tid + f * 256;
      gload16(BT + (size_t)(n0 + (i2 >> 2)) * K + k0 + (i2 & 3) * 8, Bl + i2 * 8);
    }
    __syncthreads();
    half8 af[4], bfr[4];
#pragma unroll
    for (int i = 0; i < 4; ++i)
      af[i] = *(const half8*)(Al + (wr + i * 16 + lr) * 32 + lk * 8);
#pragma unroll
    for (int j = 0; j < 4; ++j)
      bfr[j] = *(const half8*)(Bl + (wc + j * 16 + lr) * 32 + lk * 8);
#pragma unroll
    for (int i = 0; i < 4; ++i)
#pragma unroll
      for (int j = 0; j < 4; ++j)
        acc[i][j] = __builtin_amdgcn_mfma_f32_16x16x32_f16(af[i], bfr[j], acc[i][j], 0, 0, 0);
  }
#pragma unroll
  for (int i = 0; i < 4; ++i)
#pragma unroll
    for (int r = 0; r < 4; ++r) {
      int m = m0 + wr + i * 16 + lk * 4 + r;
#pragma unroll
      for (int j = 0; j < 4; ++j) {
        int n = n0 + wc + j * 16 + lr;
        if (n < N) C[(size_t)m * N + n] = acc[i][j][r];
      }
    }
}

// ------- logits fallback: B fp32 [N][K] inline-cvt (when ws too small) -------
__global__ __launch_bounds__(256) void gemm_logits_f32b_kernel(
    const short* __restrict__ A, const float* __restrict__ BT,
    float* __restrict__ C, int M, int N, int K)
{
  __shared__ short Al[128 * RA];
  __shared__ short Bl[128 * RA];
  int tid = threadIdx.x;
  int wave = tid >> 6, lane = tid & 63;
  int wr = (wave >> 1) * 64, wc = (wave & 1) * 64;
  int lr = lane & 15, lk = lane >> 4;
  int m0 = blockIdx.y * 128, n0 = blockIdx.x * 128;
  f32x4 acc[4][4] = {};

  for (int k0 = 0; k0 < K; k0 += 32) {
    __syncthreads();
#pragma unroll
    for (int f = 0; f < 2; ++f) {
      int idx = tid + f * 256, row = idx >> 2, sub = idx & 3;
      uint4 v = *(const uint4*)(A + (size_t)(m0 + row) * K + k0 + sub * 8);
      *(uint4*)(Al + row * RA + sub * 8) = v;
    }
#pragma unroll
    for (int f = 0; f < 4; ++f) {
      int idx = tid + f * 256, row = idx >> 3, qq = idx & 7;
      int gn = n0 + row;
      float4 v = make_float4(0.f, 0.f, 0.f, 0.f);
      if (gn < N) v = *(const float4*)(BT + (size_t)gn * K + k0 + qq * 4);
      *(short4*)(Bl + row * RA + qq * 4) =
          make_short4(f2h(v.x), f2h(v.y), f2h(v.z), f2h(v.w));
    }
    __syncthreads();
    half8 af[4], bfr[4];
#pragma unroll
    for (int i = 0; i < 4; ++i)
      af[i] = *(const half8*)(Al + (wr + i * 16 + lr) * RA + lk * 8);
#pragma unroll
    for (int j = 0; j < 4; ++j)
      bfr[j] = *(const half8*)(Bl + (wc + j * 16 + lr) * RA + lk * 8);
#pragma unroll
    for (int i = 0; i < 4; ++i)
#pragma unroll
      for (int j = 0; j < 4; ++j)
        acc[i][j] = __builtin_amdgcn_mfma_f32_16x16x32_f16(af[i], bfr[j], acc[i][j], 0, 0, 0);
  }
#pragma unroll
  for (int i = 0; i < 4; ++i)
#pragma unroll
    for (int r = 0; r < 4; ++r) {
      int m = m0 + wr + i * 16 + lk * 4 + r;
#pragma unroll
      for (int j = 0; j < 4; ++j) {
        int n = n0 + wc + j * 16 + lr;
        if (n < N) C[(size_t)m * N + n] = acc[i][j][r];
      }
    }
}

// ---------------- indexer scores + exact stable top-k -> bitmask ----------------
__device__ __forceinline__ unsigned int ford(float f) {
  unsigned int u = __float_as_uint(f);
  return (u & 0x80000000u) ? ~u : (u | 0x80000000u);
}

__global__ __launch_bounds__(256) void idx_topk_kernel(
    const float* __restrict__ Hx, unsigned int* __restrict__ MASK)
{
  int bq = blockIdx.x;
  int q = bq & (S_LEN - 1);
  int b = bq >> 10;
  int tid = threadIdx.x;
  int n = q + 1;
  if (n <= TOPK_N) {
    if (tid < 32) {
      int full = n >> 5, rem = n & 31;
      unsigned int w = 0u;
      if (tid < full) w = 0xFFFFFFFFu;
      else if (tid == full && rem) w = (1u << rem) - 1u;
      MASK[(size_t)bq * 32 + tid] = w;
    }
    return;
  }
  __shared__ float qi_s[HI_N * DI_N];
  __shared__ float wt_s[HI_N];
  __shared__ float sc[S_LEN];
  __shared__ unsigned long long keys[S_LEN];
  __shared__ unsigned int mw[32];
  qi_s[tid] = Hx[(size_t)bq * IDX_LD + COL_QI + tid];
  if (tid < HI_N) wt_s[tid] = Hx[(size_t)bq * IDX_LD + COL_WT + tid];
  __syncthreads();
  for (int k = tid; k < n; k += 256) {
    const float* kr = Hx + (size_t)(b * S_LEN + k) * IDX_LD + COL_KI;
    float d0 = 0.f, d1 = 0.f, d2 = 0.f, d3 = 0.f;
#pragma unroll
    for (int d = 0; d < DI_N; ++d) {
      float kv = kr[d];
      d0 = fmaf(qi_s[d], kv, d0);
      d1 = fmaf(qi_s[64 + d], kv, d1);
      d2 = fmaf(qi_s[128 + d], kv, d2);
      d3 = fmaf(qi_s[192 + d], kv, d3);
    }
    sc[k] = wt_s[0] * fmaxf(d0, 0.f) + wt_s[1] * fmaxf(d1, 0.f)
          + wt_s[2] * fmaxf(d2, 0.f) + wt_s[3] * fmaxf(d3, 0.f);
  }
  __syncthreads();
  for (int i = tid; i < S_LEN; i += 256) {
    unsigned long long kk = 0ull;
    if (i < n) kk = ((unsigned long long)ford(sc[i]) << 32) | (unsigned int)(S_LEN - 1 - i);
    keys[i] = kk;
  }
  __syncthreads();
  for (int size = 2; size <= S_LEN; size <<= 1) {
    for (int stride = size >> 1; stride > 0; stride >>= 1) {
      for (int t = tid; t < S_LEN / 2; t += 256) {
        int j = t & (stride - 1);
        int lo = ((t ^ j) << 1) | j;
        int hi = lo | stride;
        unsigned long long a = keys[lo], c = keys[hi];
        bool desc = ((lo & size) == 0);
        bool sw = desc ? (a < c) : (a > c);
        if (sw) { keys[lo] = c; keys[hi] = a; }
      }
      __syncthreads();
    }
  }
  if (tid < 32) mw[tid] = 0u;
  __syncthreads();
  for (int i = tid; i < TOPK_N; i += 256) {
    int k = S_LEN - 1 - (int)(keys[i] & 0xFFFFFFFFull);
    atomicOr(&mw[k >> 5], 1u << (k & 31));
  }
  __syncthreads();
  if (tid < 32) MASK[(size_t)bq * 32 + tid] = mw[tid];
}

// ------- masked-dense flash attention: x32 QK^T + x16 PV, 1-barrier pipeline ---
// K staged via global_load_lds with pre-swizzled source (slot ^= row&7);
// V^T reg-staged double-buffered; next tile issued before current compute.
__global__ __launch_bounds__(256) void attn_mfma_kernel(
    const short* __restrict__ QKV, const unsigned int* __restrict__ MASK,
    short* __restrict__ O /* [BSROWS][D] fp16 */)
{
  __shared__ unsigned int mlds[64 * 32];   // 8KB mask words for 64 q-rows
  __shared__ short Kl[2][64 * 64];         // K tiles, linear [key][64], swizzled cols
  __shared__ short Vtl[2][64 * 68];        // V^T tiles [d][key], pitch 68
  int qt = blockIdx.x, h = blockIdx.y, b = blockIdx.z;
  int tid = threadIdx.x;
  int w = tid >> 6, l = tid & 63;
  int lq = l & 15, g = l >> 4;
  int q0 = qt * 64;
  const short* Kb = QKV + (size_t)b * S_LEN * QKV_LD + 1024 + h * DHD;
  const short* Vb = QKV + (size_t)b * S_LEN * QKV_LD + 2048 + h * DHD;
  // V-stage thread mapping
  int vu = tid >> 1, vhalf = tid & 1, vkg = vu >> 3, vdg = vu & 7;

#pragma unroll
  for (int i = 0; i < 8; ++i) {
    int idx = tid + i * 256;
    mlds[idx] = MASK[((size_t)(b * S_LEN + q0 + (idx >> 5))) * 32 + (idx & 31)];
  }
  // Q B-frags (x32): q = q0+w*16+lq, k=d = dt2*32 + g*8 + j  (contiguous half8)
  half8 qf[2];
  {
    const short* qrow = QKV + ((size_t)(b * S_LEN + q0 + w * 16 + lq)) * QKV_LD + h * DHD;
    qf[0] = *(const half8*)(qrow + g * 8);
    qf[1] = *(const half8*)(qrow + 32 + g * 8);
  }
  // prologue: stage tile 0 into buf 0
  {
#pragma unroll
    for (int i = 0; i < 2; ++i) {
      int idx = tid + i * 256;
      int row = idx >> 3, sub = idx & 7;
      gload16(Kb + (size_t)row * QKV_LD + (size_t)((sub ^ (row & 7)) * 8), &Kl[0][idx * 8]);
    }
    int krow = vkg * 4 + vhalf * 2;
    uint4 v0 = *(const uint4*)(Vb + (size_t)krow * QKV_LD + vdg * 8);
    uint4 v1 = *(const uint4*)(Vb + (size_t)(krow + 1) * QKV_LD + vdg * 8);
    const short* s0 = (const short*)&v0;
    const short* s1 = (const short*)&v1;
#pragma unroll
    for (int j = 0; j < 8; ++j)
      *(short2*)(&Vtl[0][(vdg * 8 + j) * 68 + vkg * 4 + vhalf * 2]) = make_short2(s0[j], s1[j]);
  }
  __syncthreads();  // drains gload vmcnt; mask + V^T visible

  f32x4 acc_o[4] = {};
  float m_run = -1.0e30f, l_run = 0.f;
  const int mrow = w * 16 + lq;
  int cur = 0;

  for (int kt = 0; kt <= qt; ++kt) {
    bool more = kt < qt;
    uint4 v0, v1;
    if (more) {  // issue next tile: K gload (async) + V reg loads (async until use)
#pragma unroll
      for (int i = 0; i < 2; ++i) {
        int idx = tid + i * 256;
        int row = idx >> 3, sub = idx & 7;
        gload16(Kb + (size_t)((kt + 1) * 64 + row) * QKV_LD + (size_t)((sub ^ (row & 7)) * 8),
                &Kl[cur ^ 1][idx * 8]);
      }
      int krow = (kt + 1) * 64 + vkg * 4 + vhalf * 2;
      v0 = *(const uint4*)(Vb + (size_t)krow * QKV_LD + vdg * 8);
      v1 = *(const uint4*)(Vb + (size_t)(krow + 1) * QKV_LD + vdg * 8);
    }
    // ---- S^T[key][q] via 2 x32 MFMA per 16-key block ----
    f32x4 s[4] = {};
    __builtin_amdgcn_s_setprio(1);
#pragma unroll
    for (int ks = 0; ks < 4; ++ks) {
      half8 kf0 = *(const half8*)(&Kl[cur][(ks * 16 + lq) * 64 + ((g ^ (lq & 7)) * 8)]);
      half8 kf1 = *(const half8*)(&Kl[cur][(ks * 16 + lq) * 64 + (((4 + g) ^ (lq & 7)) * 8)]);
      s[ks] = __builtin_amdgcn_mfma_f32_16x16x32_f16(kf0, qf[0], s[ks], 0, 0, 0);
      s[ks] = __builtin_amdgcn_mfma_f32_16x16x32_f16(kf1, qf[1], s[ks], 0, 0, 0);
    }
    __builtin_amdgcn_s_setprio(0);
    // mask + scale; lane holds keys ks*16 + g*4 + r for q-col lq (mask row mrow)
    float mx = NEGF;
#pragma unroll
    for (int ks = 0; ks < 4; ++ks) {
      int kbase = kt * 64 + ks * 16 + g * 4;
      unsigned mwv = mlds[mrow * 32 + (kbase >> 5)];
#pragma unroll
      for (int r = 0; r < 4; ++r) {
        float sv = ((mwv >> ((kbase + r) & 31)) & 1u) ? s[ks][r] * 0.125f : NEGF;
        s[ks][r] = sv;
        mx = fmaxf(mx, sv);
      }
    }
    mx = fmaxf(mx, __shfl_xor(mx, 16));
    mx = fmaxf(mx, __shfl_xor(mx, 32));
    float m_new = fmaxf(m_run, mx);
    float scale = __expf(m_run - m_new);
    float lsum = 0.f;
    half4v pf[4];
#pragma unroll
    for (int ks = 0; ks < 4; ++ks) {
      half4v t;
#pragma unroll
      for (int r = 0; r < 4; ++r) {
        float p = __expf(s[ks][r] - m_new);
        lsum += p;
        t[r] = (_Float16)p;
      }
      pf[ks] = t;
    }
    lsum += __shfl_xor(lsum, 16);
    lsum += __shfl_xor(lsum, 32);
    l_run = l_run * scale + lsum;
    m_run = m_new;
    float sc[4];
#pragma unroll
    for (int r = 0; r < 4; ++r) sc[r] = __shfl(scale, g * 4 + r);
    __builtin_amdgcn_s_setprio(1);
#pragma unroll
    for (int dt = 0; dt < 4; ++dt) {
      f32x4 a = acc_o[dt];
      a[0] *= sc[0]; a[1] *= sc[1]; a[2] *= sc[2]; a[3] *= sc[3];
#pragma unroll
      for (int ks = 0; ks < 4; ++ks) {
        half4v vf = *(const half4v*)(&Vtl[cur][(dt * 16 + lq) * 68 + ks * 16 + g * 4]);
        a = MFMA16F(pf[ks], vf, a);  // A = P[q][k] (in-lane), B = V^T[d][k]
      }
      acc_o[dt] = a;
    }
    __builtin_amdgcn_s_setprio(0);
    // ---- write next V^T (buf nxt idle: last read ended before prev barrier) ----
    if (more) {
      const short* s0 = (const short*)&v0;
      const short* s1 = (const short*)&v1;
#pragma unroll
      for (int j = 0; j < 8; ++j)
        *(short2*)(&Vtl[cur ^ 1][(vdg * 8 + j) * 68 + vkg * 4 + vhalf * 2]) = make_short2(s0[j], s1[j]);
    }
    __syncthreads();  // all compute(cur) done; V^T(nxt) visible; gloads drained
    cur ^= 1;
  }
  float linv[4];
#pragma unroll
  for (int r = 0; r < 4; ++r) linv[r] = 1.0f / __shfl(l_run, g * 4 + r);
#pragma unroll
  for (int dt = 0; dt < 4; ++dt)
#pragma unroll
    for (int r = 0; r < 4; ++r) {
      int q = q0 + w * 16 + g * 4 + r;
      float o = acc_o[dt][r] * linv[r];
      O[(size_t)(b * S_LEN + q) * D_DIM + h * DHD + dt * 16 + lq] = f2h(o);
    }
}

// ---------------- host orchestration ----------------
extern "C" void kernel_launch(void* const* d_in, const int* in_sizes, int n_in,
                              void* d_out, int out_size, void* d_ws, size_t ws_size,
                              hipStream_t stream) {
  (void)in_sizes; (void)n_in; (void)out_size;
  const int*   tokens  = (const int*)d_in[0];
  const float* embed_w = (const float*)d_in[1];
  const float* pos_w   = (const float*)d_in[2];
  const float* wq      = (const float*)d_in[3];
  const float* wk      = (const float*)d_in[4];
  const float* wv      = (const float*)d_in[5];
  const float* wo      = (const float*)d_in[6];
  const float* iqw     = (const float*)d_in[7];
  const float* ikw     = (const float*)d_in[8];
  const float* iww     = (const float*)d_in[9];
  const float* w1      = (const float*)d_in[10];
  const float* w2      = (const float*)d_in[11];
  const float* n1      = (const float*)d_in[12];
  const float* n2      = (const float*)d_in[13];
  const float* nf      = (const float*)d_in[14];
  float* logits = (float*)d_out;

  // ws: Hh (logits A, 4 MB) + Eh (fp16 embed padded to VPAD rows, 103 MB)
  short* Hh = (short*)d_ws;
  size_t need_eh = ((size_t)BSROWS * D_DIM + (size_t)VPAD * D_DIM) * 2;
  bool use_eh = ws_size >= need_eh;
  short* Eh = Hh + (size_t)BSROWS * D_DIM;

  // d_out scratch (all dead before logits GEMM writes)
  char* base = (char*)d_out;
  size_t off = (size_t)BSROWS * D_DIM * 4;
  float* X = logits;
  float* Hx = (float*)(base + off);    off += (size_t)BSROWS * IDX_LD * 4;
  short* QKVh = (short*)(base + off);  off += (size_t)BSROWS * QKV_LD * 2;
  short* Hsp = (short*)(base + off);   off += (size_t)2 * BSROWS * D_DIM * 2;
  short* AOh = (short*)(base + off);   off += (size_t)BSROWS * D_DIM * 2;
  short* FFh = (short*)(base + off);   off += (size_t)BSROWS * FF_DIM * 2;
  unsigned int* MASKb = (unsigned int*)(base + off); off += (size_t)BSROWS * 32 * 4;
  short* BTqkvA = (short*)(base + off); off += (size_t)NL * QKV_LD * D_DIM * 2;
  short* BTidxA = (short*)(base + off); off += (size_t)NL * 2 * IDX_LD * D_DIM * 2;
  short* BTwoA = (short*)(base + off);  off += (size_t)NL * D_DIM * D_DIM * 2;
  short* BTw1A = (short*)(base + off);  off += (size_t)NL * FF_DIM * D_DIM * 2;
  short* BTw2A = (short*)(base + off);  off += (size_t)NL * FF_DIM * D_DIM * 2;

  const size_t plH  = (size_t)BSROWS * D_DIM;
  const size_t plIx = (size_t)IDX_LD * D_DIM;

  hipLaunchKernelGGL(embed_kernel, dim3(BSROWS), dim3(256), 0, stream,
                     tokens, embed_w, pos_w, X);
  if (use_eh)
    hipLaunchKernelGGL(cvt_embed_kernel, dim3(8192), dim3(256), 0, stream, embed_w, Eh);

  // all-layer weight packs (5 dispatches total)
  hipLaunchKernelGGL(pack_qkv_all_kernel, dim3(QKV_LD / 32, 32, NL), dim3(32, 8), 0, stream,
                     wq, wk, wv, BTqkvA);
  hipLaunchKernelGGL(pack_idx_all_kernel, dim3(IDX_LD / 32, 32, NL), dim3(32, 8), 0, stream,
                     iqw, ikw, iww, BTidxA);
  hipLaunchKernelGGL(packT_all_kernel, dim3(32, 32, NL), dim3(32, 8), 0, stream,
                     wo, BTwoA, D_DIM, D_DIM);
  hipLaunchKernelGGL(packT_all_kernel, dim3(FF_DIM / 32, 32, NL), dim3(32, 8), 0, stream,
                     w1, BTw1A, D_DIM, FF_DIM);
  hipLaunchKernelGGL(packT_all_kernel, dim3(D_DIM / 32, FF_DIM / 32, NL), dim3(32, 8), 0, stream,
                     w2, BTw2A, FF_DIM, D_DIM);

  for (int l = 0; l < NL; ++l) {
    short* BTqkv = BTqkvA + (size_t)l * QKV_LD * D_DIM;
    short* BTidx = BTidxA + (size_t)l * 2 * IDX_LD * D_DIM;
    short* BTwo  = BTwoA + (size_t)l * D_DIM * D_DIM;
    short* BTw1  = BTw1A + (size_t)l * FF_DIM * D_DIM;
    short* BTw2  = BTw2A + (size_t)l * FF_DIM * D_DIM;

    hipLaunchKernelGGL(rmsnorm_split_kernel, dim3(BSROWS), dim3(256), 0, stream,
                       X, n1 + (size_t)l * D_DIM, Hsp);
    hipLaunchKernelGGL((gemm_g_kernel<128, 1>), dim3(QKV_LD / 128, 16), dim3(256), 0, stream,
                       Hsp, BTqkv, nullptr, QKVh, BSROWS, QKV_LD, D_DIM);
    hipLaunchKernelGGL((gemm_split_kernel<64>), dim3(IDX_LD / 128, 32), dim3(256), 0, stream,
                       Hsp, plH, BTidx, plIx, Hx, BSROWS, IDX_LD, D_DIM);
    hipLaunchKernelGGL(idx_topk_kernel, dim3(BSROWS), dim3(256), 0, stream, Hx, MASKb);
    hipLaunchKernelGGL(attn_mfma_kernel, dim3(S_LEN / 64, NH, 2), dim3(256), 0, stream,
                       QKVh, MASKb, AOh);
    hipLaunchKernelGGL((gemm_g_kernel<64, 3>), dim3(8, 32), dim3(256), 0, stream,
                       AOh, BTwo, X, X, BSROWS, D_DIM, D_DIM);
    hipLaunchKernelGGL(rmsnorm_h_kernel, dim3(BSROWS), dim3(256), 0, stream,
                       X, n2 + (size_t)l * D_DIM, Hsp);
    hipLaunchKernelGGL((gemm_g_kernel<128, 2>), dim3(FF_DIM / 128, 16), dim3(256), 0, stream,
                       Hsp, BTw1, nullptr, FFh, BSROWS, FF_DIM, D_DIM);
    hipLaunchKernelGGL((gemm_g_kernel<64, 3>), dim3(8, 32), dim3(256), 0, stream,
                       FFh, BTw2, X, X, BSROWS, D_DIM, FF_DIM);
  }

  hipLaunchKernelGGL(rmsnorm_h_kernel, dim3(BSROWS), dim3(256), 0, stream, X, nf, Hh);
  if (use_eh) {
    hipLaunchKernelGGL(gemm_logits_g_kernel, dim3(8 * YPX * 16), dim3(256), 0, stream,
                       Hh, Eh, logits, BSROWS, VOCAB, D_DIM);
  } else {
    hipLaunchKernelGGL(gemm_logits_f32b_kernel, dim3((VOCAB + 127) / 128, 16), dim3(256), 0, stream,
                       Hh, embed_w, logits, BSROWS, VOCAB, D_DIM);
  }
}

// Round 10
// 3614.748 us; speedup vs baseline: 8.0512x; 1.0045x over previous
//
#include <hip/hip_runtime.h>
#include <cstdint>
#include <cstddef>

#define S_LEN 1024
#define D_DIM 1024
#define NH 16
#define DHD 64
#define NL 8
#define FF_DIM 4096
#define HI_N 4
#define DI_N 64
#define TOPK_N 512
#define BSROWS 2048  // B * S
#define VOCAB 50257
#define VPAD 50304    // VOCAB rounded up to 128
#define NTILES_V 393  // ceil(50257/128)
#define YPX 50        // ceil(393/8) N-panels per XCD for logits

// compact QKV layout: [Q 0..1023 | K 1024..2047 | V 2048..3071], fp16
#define QKV_LD 3072
// indexer block layout (fp32): [QI 0..255 | KI 256..319 | WT 320..323 | pad..383]
#define IDX_LD 384
#define COL_QI 0
#define COL_KI 256
#define COL_WT 320

#define NEGF -3.0e38f

typedef __attribute__((ext_vector_type(8))) _Float16 half8;
typedef __attribute__((ext_vector_type(4))) _Float16 half4v;
typedef __attribute__((ext_vector_type(4))) float f32x4;

#if __has_builtin(__builtin_amdgcn_mfma_f32_16x16x16f16)
#define MFMA16F(a, b, c) __builtin_amdgcn_mfma_f32_16x16x16f16((a), (b), (c), 0, 0, 0)
#else
static __device__ __forceinline__ f32x4 mfma16f_asm(half4v a, half4v b, f32x4 c) {
  f32x4 d;
  asm volatile("v_mfma_f32_16x16x16_f16 %0, %1, %2, %3\n\ts_nop 7\n\ts_nop 7"
               : "=v"(d) : "v"(a), "v"(b), "v"(c));
  return d;
}
#define MFMA16F(a, b, c) mfma16f_asm((a), (b), (c))
#endif

// async global->LDS, 16B per lane; LDS dest must be lane-linear (rule #21)
typedef const __attribute__((address_space(1))) void* gas_ptr;
typedef __attribute__((address_space(3))) void* las_ptr;
__device__ __forceinline__ void gload16(const void* g, void* l) {
#if __has_builtin(__builtin_amdgcn_global_load_lds)
  __builtin_amdgcn_global_load_lds((gas_ptr)g, (las_ptr)l, 16, 0, 0);
#else
  *(uint4*)l = *(const uint4*)g;
#endif
}

__device__ __forceinline__ short f2h(float x) {  // RNE fp32->fp16 (bits)
  _Float16 h = (_Float16)x;
  return *reinterpret_cast<short*>(&h);
}
__device__ __forceinline__ float h2f(short b) {
  _Float16 h = *reinterpret_cast<_Float16*>(&b);
  return (float)h;
}
// two-term fp16 split: x ~= hi + lo with rel err ~2^-22
__device__ __forceinline__ void split_h(float x, short& hi, short& lo) {
  hi = f2h(x);
  lo = f2h(x - h2f(hi));
}

// ---------------- embed + positional ----------------
__global__ __launch_bounds__(256) void embed_kernel(
    const int* __restrict__ tokens, const float* __restrict__ E,
    const float* __restrict__ P, float* __restrict__ X)
{
  int bs = blockIdx.x;
  int s = bs & (S_LEN - 1);
  int tid = threadIdx.x;
  int tok = tokens[bs];
  float4 e = ((const float4*)(E + (size_t)tok * D_DIM))[tid];
  float4 p = ((const float4*)(P + (size_t)s * D_DIM))[tid];
  float4 o; o.x = e.x + p.x; o.y = e.y + p.y; o.z = e.z + p.z; o.w = e.w + p.w;
  ((float4*)(X + (size_t)bs * D_DIM))[tid] = o;
}

// ---------------- embed fp32 -> fp16, zero-padded to VPAD rows ----------------
__global__ __launch_bounds__(256) void cvt_embed_kernel(
    const float* __restrict__ E, short* __restrict__ Eh)
{
  const long valid4 = (long)VOCAB * D_DIM / 4;
  const long total4 = (long)VPAD * D_DIM / 4;
  long i = (long)blockIdx.x * 256 + threadIdx.x;
  long stride = (long)gridDim.x * 256;
  for (; i < total4; i += stride) {
    short4 o = make_short4(0, 0, 0, 0);
    if (i < valid4) {
      float4 v = ((const float4*)E)[i];
      o = make_short4(f2h(v.x), f2h(v.y), f2h(v.z), f2h(v.w));
    }
    ((short4*)Eh)[i] = o;
  }
}

// ---------------- rmsnorm -> split fp16 (hi plane, lo plane) ----------------
__global__ __launch_bounds__(256) void rmsnorm_split_kernel(
    const float* __restrict__ X, const float* __restrict__ W,
    short* __restrict__ O /* [2][BSROWS][D] */)
{
  int r = blockIdx.x;
  int tid = threadIdx.x;
  float4 v = ((const float4*)(X + (size_t)r * D_DIM))[tid];
  float ss = v.x * v.x + v.y * v.y + v.z * v.z + v.w * v.w;
  __shared__ float red[4];
  __shared__ float sh_inv;
  for (int o = 32; o; o >>= 1) ss += __shfl_down(ss, o);
  if ((tid & 63) == 0) red[tid >> 6] = ss;
  __syncthreads();
  if (tid == 0) {
    float s = red[0] + red[1] + red[2] + red[3];
    sh_inv = 1.0f / (sqrtf(s) * 0.03125f + 1e-6f);
  }
  __syncthreads();
  float inv = sh_inv;
  float4 w = ((const float4*)W)[tid];
  float o0 = w.x * v.x * inv, o1 = w.y * v.y * inv;
  float o2 = w.z * v.z * inv, o3 = w.w * v.w * inv;
  short4 hi, lo;
  split_h(o0, hi.x, lo.x); split_h(o1, hi.y, lo.y);
  split_h(o2, hi.z, lo.z); split_h(o3, hi.w, lo.w);
  ((short4*)(O + (size_t)r * D_DIM))[tid] = hi;
  ((short4*)(O + (size_t)BSROWS * D_DIM + (size_t)r * D_DIM))[tid] = lo;
}

// ---------------- rmsnorm -> plain fp16 ----------------
__global__ __launch_bounds__(256) void rmsnorm_h_kernel(
    const float* __restrict__ X, const float* __restrict__ W, short* __restrict__ O)
{
  int r = blockIdx.x;
  int tid = threadIdx.x;
  float4 v = ((const float4*)(X + (size_t)r * D_DIM))[tid];
  float ss = v.x * v.x + v.y * v.y + v.z * v.z + v.w * v.w;
  __shared__ float red[4];
  __shared__ float sh_inv;
  for (int o = 32; o; o >>= 1) ss += __shfl_down(ss, o);
  if ((tid & 63) == 0) red[tid >> 6] = ss;
  __syncthreads();
  if (tid == 0) {
    float s = red[0] + red[1] + red[2] + red[3];
    sh_inv = 1.0f / (sqrtf(s) * 0.03125f + 1e-6f);
  }
  __syncthreads();
  float inv = sh_inv;
  float4 w = ((const float4*)W)[tid];
  short4 o4 = make_short4(f2h(w.x * v.x * inv), f2h(w.y * v.y * inv),
                          f2h(w.z * v.z * inv), f2h(w.w * v.w * inv));
  ((short4*)(O + (size_t)r * D_DIM))[tid] = o4;
}

// ------- all-layer packs (grid.z = layer) -------
__global__ __launch_bounds__(256) void packT_all_kernel(
    const float* __restrict__ W0, short* __restrict__ BT0, int K, int N)
{
  __shared__ float t[32][33];
  int z = blockIdx.z;
  const float* W = W0 + (size_t)z * K * N;
  short* BT = BT0 + (size_t)z * N * K;
  int n0 = blockIdx.x * 32, k0 = blockIdx.y * 32;
  int tx = threadIdx.x, ty = threadIdx.y;
#pragma unroll
  for (int r = 0; r < 32; r += 8)
    t[ty + r][tx] = W[(size_t)(k0 + ty + r) * N + n0 + tx];
  __syncthreads();
#pragma unroll
  for (int r = 0; r < 32; r += 8)
    BT[(size_t)(n0 + ty + r) * K + k0 + tx] = f2h(t[tx][ty + r]);
}

__global__ __launch_bounds__(256) void pack_qkv_all_kernel(
    const float* __restrict__ wq0, const float* __restrict__ wk0,
    const float* __restrict__ wv0, short* __restrict__ BT0)
{
  __shared__ float t[32][33];
  int z = blockIdx.z;
  const float* wq = wq0 + (size_t)z * D_DIM * D_DIM;
  const float* wk = wk0 + (size_t)z * D_DIM * D_DIM;
  const float* wv = wv0 + (size_t)z * D_DIM * D_DIM;
  short* BT = BT0 + (size_t)z * QKV_LD * D_DIM;
  int n0 = blockIdx.x * 32, k0 = blockIdx.y * 32;
  int tx = threadIdx.x, ty = threadIdx.y;
  const float* src = (n0 < 1024) ? wq : (n0 < 2048) ? wk : wv;
  int c0 = n0 & 1023;
#pragma unroll
  for (int r = 0; r < 32; r += 8)
    t[ty + r][tx] = src[(size_t)(k0 + ty + r) * 1024 + c0 + tx];
  __syncthreads();
#pragma unroll
  for (int r = 0; r < 32; r += 8)
    BT[(size_t)(n0 + ty + r) * D_DIM + k0 + tx] = f2h(t[tx][ty + r]);
}

__global__ __launch_bounds__(256) void pack_idx_all_kernel(
    const float* __restrict__ iq0, const float* __restrict__ ik0,
    const float* __restrict__ iw0, short* __restrict__ BT0)
{
  __shared__ float t[32][33];
  const size_t plane = (size_t)IDX_LD * D_DIM;
  int z = blockIdx.z;
  const float* iq = iq0 + (size_t)z * D_DIM * (HI_N * DI_N);
  const float* ik = ik0 + (size_t)z * D_DIM * DI_N;
  const float* iw = iw0 + (size_t)z * D_DIM * HI_N;
  short* BT = BT0 + (size_t)z * 2 * plane;
  int n0 = blockIdx.x * 32, k0 = blockIdx.y * 32;
  int tx = threadIdx.x, ty = threadIdx.y;
  const float* src = nullptr; int ld = 0, c0 = 0;
  if (n0 < 256)      { src = iq; ld = 256; c0 = n0; }
  else if (n0 < 320) { src = ik; ld = 64;  c0 = n0 - 256; }
  else if (n0 < 352) { src = iw; ld = 4;   c0 = n0 - 320; }
#pragma unroll
  for (int r = 0; r < 32; r += 8) {
    float v = 0.f;
    int c = c0 + tx;
    if (src && c < ld) v = src[(size_t)(k0 + ty + r) * ld + c];
    t[ty + r][tx] = v;
  }
  __syncthreads();
#pragma unroll
  for (int r = 0; r < 32; r += 8) {
    short hi, lo;
    split_h(t[tx][ty + r], hi, lo);
    size_t o = (size_t)(n0 + ty + r) * D_DIM + k0 + tx;
    BT[o] = hi;
    BT[plane + o] = lo;
  }
}

#define RA 40  // padded LDS pitch for reg-staged split GEMM

// ------- split-fp16 GEMM (fp32-accurate), fp32 out: indexer only -------
template<int BM>
__global__ __launch_bounds__(256) void gemm_split_kernel(
    const short* __restrict__ A, size_t aplane,
    const short* __restrict__ BT, size_t bplane,
    float* __restrict__ C, int M, int N, int K)
{
  constexpr int MI = BM / 32;
  __shared__ short Al[2 * BM * RA];
  __shared__ short Bl[2 * 128 * RA];
  int tid = threadIdx.x;
  int wave = tid >> 6, lane = tid & 63;
  int wr = (wave >> 1) * (BM / 2), wc = (wave & 1) * 64;
  int lr = lane & 15, lk = lane >> 4;
  int m0 = blockIdx.y * BM, n0 = blockIdx.x * 128;
  f32x4 acc[MI][4] = {};

  for (int k0 = 0; k0 < K; k0 += 32) {
    __syncthreads();
#pragma unroll
    for (int f = 0; f < BM / 32; ++f) {
      int idx = tid + f * 256;
      int p = idx / (BM * 4), r2 = idx % (BM * 4);
      int row = r2 >> 2, sub = r2 & 3;
      uint4 v = *(const uint4*)(A + (size_t)p * aplane + (size_t)(m0 + row) * K + k0 + sub * 8);
      *(uint4*)(Al + p * BM * RA + row * RA + sub * 8) = v;
    }
#pragma unroll
    for (int f = 0; f < 4; ++f) {
      int idx = tid + f * 256;
      int p = idx >> 9, r2 = idx & 511;
      int row = r2 >> 2, sub = r2 & 3;
      uint4 v = *(const uint4*)(BT + (size_t)p * bplane + (size_t)(n0 + row) * K + k0 + sub * 8);
      *(uint4*)(Bl + p * 128 * RA + row * RA + sub * 8) = v;
    }
    __syncthreads();
    half8 ah[MI], al_[MI], bh[4], bl_[4];
#pragma unroll
    for (int i = 0; i < MI; ++i) {
      ah[i] = *(const half8*)(Al + (wr + i * 16 + lr) * RA + lk * 8);
      al_[i] = *(const half8*)(Al + BM * RA + (wr + i * 16 + lr) * RA + lk * 8);
    }
#pragma unroll
    for (int j = 0; j < 4; ++j) {
      bh[j] = *(const half8*)(Bl + (wc + j * 16 + lr) * RA + lk * 8);
      bl_[j] = *(const half8*)(Bl + 128 * RA + (wc + j * 16 + lr) * RA + lk * 8);
    }
#pragma unroll
    for (int i = 0; i < MI; ++i)
#pragma unroll
      for (int j = 0; j < 4; ++j) {
        f32x4 a = acc[i][j];
        a = __builtin_amdgcn_mfma_f32_16x16x32_f16(al_[i], bh[j], a, 0, 0, 0);
        a = __builtin_amdgcn_mfma_f32_16x16x32_f16(ah[i], bl_[j], a, 0, 0, 0);
        a = __builtin_amdgcn_mfma_f32_16x16x32_f16(ah[i], bh[j], a, 0, 0, 0);
        acc[i][j] = a;
      }
  }
#pragma unroll
  for (int i = 0; i < MI; ++i)
#pragma unroll
    for (int r = 0; r < 4; ++r) {
      int m = m0 + wr + i * 16 + lk * 4 + r;
#pragma unroll
      for (int j = 0; j < 4; ++j) {
        int n = n0 + wc + j * 16 + lr;
        if (n < N) C[(size_t)m * N + n] = acc[i][j][r];
      }
    }
}

// ------- plain fp16 GEMM, global_load_lds staging, linear LDS -------
// Requires: M % BM == 0, N % 128 == 0, K % 32 == 0 (no tile predicates).
// EPI: 1 fp16 store; 2 exact-GELU -> fp16 store; 3 fp32 + R
template<int BM, int EPI>
__global__ __launch_bounds__(256) void gemm_g_kernel(
    const short* __restrict__ A, const short* __restrict__ BT,
    const float* __restrict__ R, void* __restrict__ C, int M, int N, int K)
{
  constexpr int MI = BM / 32;          // M-frags per wave (128->4, 64->2)
  __shared__ short Al[BM * 32];        // linear [row][32]
  __shared__ short Bl[128 * 32];
  int tid = threadIdx.x;
  int wave = tid >> 6, lane = tid & 63;
  int wr = (wave >> 1) * (BM / 2), wc = (wave & 1) * 64;
  int lr = lane & 15, lk = lane >> 4;
  int m0 = blockIdx.y * BM, n0 = blockIdx.x * 128;
  f32x4 acc[MI][4] = {};

  for (int k0 = 0; k0 < K; k0 += 32) {
    __syncthreads();  // previous frag reads complete before overwrite
#pragma unroll
    for (int f = 0; f < BM / 64; ++f) {
      int idx = tid + f * 256;
      gload16(A + (size_t)(m0 + (idx >> 2)) * K + k0 + (idx & 3) * 8, Al + idx * 8);
    }
#pragma unroll
    for (int f = 0; f < 2; ++f) {
      int idx = tid + f * 256;
      gload16(BT + (size_t)(n0 + (idx >> 2)) * K + k0 + (idx & 3) * 8, Bl + idx * 8);
    }
    __syncthreads();  // drains vmcnt -> LDS visible
    half8 af[MI], bfr[4];
#pragma unroll
    for (int i = 0; i < MI; ++i)
      af[i] = *(const half8*)(Al + (wr + i * 16 + lr) * 32 + lk * 8);
#pragma unroll
    for (int j = 0; j < 4; ++j)
      bfr[j] = *(const half8*)(Bl + (wc + j * 16 + lr) * 32 + lk * 8);
#pragma unroll
    for (int i = 0; i < MI; ++i)
#pragma unroll
      for (int j = 0; j < 4; ++j)
        acc[i][j] = __builtin_amdgcn_mfma_f32_16x16x32_f16(af[i], bfr[j], acc[i][j], 0, 0, 0);
  }
#pragma unroll
  for (int i = 0; i < MI; ++i)
#pragma unroll
    for (int r = 0; r < 4; ++r) {
      int m = m0 + wr + i * 16 + lk * 4 + r;
#pragma unroll
      for (int j = 0; j < 4; ++j) {
        int n = n0 + wc + j * 16 + lr;
        float v = acc[i][j][r];
        if (EPI == 1) {
          ((short*)C)[(size_t)m * N + n] = f2h(v);
        } else if (EPI == 2) {
          v = 0.5f * v * (1.0f + erff(v * 0.70710678118654752f));
          ((short*)C)[(size_t)m * N + n] = f2h(v);
        } else {
          ((float*)C)[(size_t)m * N + n] = v + R[(size_t)m * N + n];
        }
      }
    }
}

// ------- logits GEMM: gload staging + XCD-aware 1D grid; B padded to VPAD -----
// Output stored nontemporal (write-once, never re-read) to avoid L2 pollution.
__global__ __launch_bounds__(256) void gemm_logits_g_kernel(
    const short* __restrict__ A, const short* __restrict__ BT,
    float* __restrict__ C, int M, int N, int K)
{
  int bid = blockIdx.x;
  int xcd = bid & 7, idx = bid >> 3;
  int mt = idx & 15, yt = (idx >> 4) + xcd * YPX;
  if (yt >= NTILES_V) return;
  int m0 = mt * 128, n0 = yt * 128;

  __shared__ short Al[128 * 32];
  __shared__ short Bl[128 * 32];
  int tid = threadIdx.x;
  int wave = tid >> 6, lane = tid & 63;
  int wr = (wave >> 1) * 64, wc = (wave & 1) * 64;
  int lr = lane & 15, lk = lane >> 4;
  f32x4 acc[4][4] = {};

  for (int k0 = 0; k0 < K; k0 += 32) {
    __syncthreads();
#pragma unroll
    for (int f = 0; f < 2; ++f) {
      int i2 = tid + f * 256;
      gload16(A + (size_t)(m0 + (i2 >> 2)) * K + k0 + (i2 & 3) * 8, Al + i2 * 8);
    }
#pragma unroll
    for (int f = 0; f < 2; ++f) {
      int i2 = tid + f * 256;
      gload16(BT + (size_t)(n0 + (i2 >> 2)) * K + k0 + (i2 & 3) * 8, Bl + i2 * 8);
    }
    __syncthreads();
    half8 af[4], bfr[4];
#pragma unroll
    for (int i = 0; i < 4; ++i)
      af[i] = *(const half8*)(Al + (wr + i * 16 + lr) * 32 + lk * 8);
#pragma unroll
    for (int j = 0; j < 4; ++j)
      bfr[j] = *(const half8*)(Bl + (wc + j * 16 + lr) * 32 + lk * 8);
#pragma unroll
    for (int i = 0; i < 4; ++i)
#pragma unroll
      for (int j = 0; j < 4; ++j)
        acc[i][j] = __builtin_amdgcn_mfma_f32_16x16x32_f16(af[i], bfr[j], acc[i][j], 0, 0, 0);
  }
#pragma unroll
  for (int i = 0; i < 4; ++i)
#pragma unroll
    for (int r = 0; r < 4; ++r) {
      int m = m0 + wr + i * 16 + lk * 4 + r;
#pragma unroll
      for (int j = 0; j < 4; ++j) {
        int n = n0 + wc + j * 16 + lr;
        if (n < N)
          __builtin_nontemporal_store(acc[i][j][r], &C[(size_t)m * N + n]);
      }
    }
}

// ------- logits fallback: B fp32 [N][K] inline-cvt (when ws too small) -------
__global__ __launch_bounds__(256) void gemm_logits_f32b_kernel(
    const short* __restrict__ A, const float* __restrict__ BT,
    float* __restrict__ C, int M, int N, int K)
{
  __shared__ short Al[128 * RA];
  __shared__ short Bl[128 * RA];
  int tid = threadIdx.x;
  int wave = tid >> 6, lane = tid & 63;
  int wr = (wave >> 1) * 64, wc = (wave & 1) * 64;
  int lr = lane & 15, lk = lane >> 4;
  int m0 = blockIdx.y * 128, n0 = blockIdx.x * 128;
  f32x4 acc[4][4] = {};

  for (int k0 = 0; k0 < K; k0 += 32) {
    __syncthreads();
#pragma unroll
    for (int f = 0; f < 2; ++f) {
      int idx = tid + f * 256, row = idx >> 2, sub = idx & 3;
      uint4 v = *(const uint4*)(A + (size_t)(m0 + row) * K + k0 + sub * 8);
      *(uint4*)(Al + row * RA + sub * 8) = v;
    }
#pragma unroll
    for (int f = 0; f < 4; ++f) {
      int idx = tid + f * 256, row = idx >> 3, qq = idx & 7;
      int gn = n0 + row;
      float4 v = make_float4(0.f, 0.f, 0.f, 0.f);
      if (gn < N) v = *(const float4*)(BT + (size_t)gn * K + k0 + qq * 4);
      *(short4*)(Bl + row * RA + qq * 4) =
          make_short4(f2h(v.x), f2h(v.y), f2h(v.z), f2h(v.w));
    }
    __syncthreads();
    half8 af[4], bfr[4];
#pragma unroll
    for (int i = 0; i < 4; ++i)
      af[i] = *(const half8*)(Al + (wr + i * 16 + lr) * RA + lk * 8);
#pragma unroll
    for (int j = 0; j < 4; ++j)
      bfr[j] = *(const half8*)(Bl + (wc + j * 16 + lr) * RA + lk * 8);
#pragma unroll
    for (int i = 0; i < 4; ++i)
#pragma unroll
      for (int j = 0; j < 4; ++j)
        acc[i][j] = __builtin_amdgcn_mfma_f32_16x16x32_f16(af[i], bfr[j], acc[i][j], 0, 0, 0);
  }
#pragma unroll
  for (int i = 0; i < 4; ++i)
#pragma unroll
    for (int r = 0; r < 4; ++r) {
      int m = m0 + wr + i * 16 + lk * 4 + r;
#pragma unroll
      for (int j = 0; j < 4; ++j) {
        int n = n0 + wc + j * 16 + lr;
        if (n < N) C[(size_t)m * N + n] = acc[i][j][r];
      }
    }
}

// ---------------- indexer scores + exact stable top-k -> bitmask ----------------
__device__ __forceinline__ unsigned int ford(float f) {
  unsigned int u = __float_as_uint(f);
  return (u & 0x80000000u) ? ~u : (u | 0x80000000u);
}

__global__ __launch_bounds__(256) void idx_topk_kernel(
    const float* __restrict__ Hx, unsigned int* __restrict__ MASK)
{
  int bq = blockIdx.x;
  int q = bq & (S_LEN - 1);
  int b = bq >> 10;
  int tid = threadIdx.x;
  int n = q + 1;
  if (n <= TOPK_N) {
    if (tid < 32) {
      int full = n >> 5, rem = n & 31;
      unsigned int w = 0u;
      if (tid < full) w = 0xFFFFFFFFu;
      else if (tid == full && rem) w = (1u << rem) - 1u;
      MASK[(size_t)bq * 32 + tid] = w;
    }
    return;
  }
  __shared__ float qi_s[HI_N * DI_N];
  __shared__ float wt_s[HI_N];
  __shared__ float sc[S_LEN];
  __shared__ unsigned long long keys[S_LEN];
  __shared__ unsigned int mw[32];
  qi_s[tid] = Hx[(size_t)bq * IDX_LD + COL_QI + tid];
  if (tid < HI_N) wt_s[tid] = Hx[(size_t)bq * IDX_LD + COL_WT + tid];
  __syncthreads();
  for (int k = tid; k < n; k += 256) {
    const float* kr = Hx + (size_t)(b * S_LEN + k) * IDX_LD + COL_KI;
    float d0 = 0.f, d1 = 0.f, d2 = 0.f, d3 = 0.f;
#pragma unroll
    for (int d = 0; d < DI_N; ++d) {
      float kv = kr[d];
      d0 = fmaf(qi_s[d], kv, d0);
      d1 = fmaf(qi_s[64 + d], kv, d1);
      d2 = fmaf(qi_s[128 + d], kv, d2);
      d3 = fmaf(qi_s[192 + d], kv, d3);
    }
    sc[k] = wt_s[0] * fmaxf(d0, 0.f) + wt_s[1] * fmaxf(d1, 0.f)
          + wt_s[2] * fmaxf(d2, 0.f) + wt_s[3] * fmaxf(d3, 0.f);
  }
  __syncthreads();
  for (int i = tid; i < S_LEN; i += 256) {
    unsigned long long kk = 0ull;
    if (i < n) kk = ((unsigned long long)ford(sc[i]) << 32) | (unsigned int)(S_LEN - 1 - i);
    keys[i] = kk;
  }
  __syncthreads();
  for (int size = 2; size <= S_LEN; size <<= 1) {
    for (int stride = size >> 1; stride > 0; stride >>= 1) {
      for (int t = tid; t < S_LEN / 2; t += 256) {
        int j = t & (stride - 1);
        int lo = ((t ^ j) << 1) | j;
        int hi = lo | stride;
        unsigned long long a = keys[lo], c = keys[hi];
        bool desc = ((lo & size) == 0);
        bool sw = desc ? (a < c) : (a > c);
        if (sw) { keys[lo] = c; keys[hi] = a; }
      }
      __syncthreads();
    }
  }
  if (tid < 32) mw[tid] = 0u;
  __syncthreads();
  for (int i = tid; i < TOPK_N; i += 256) {
    int k = S_LEN - 1 - (int)(keys[i] & 0xFFFFFFFFull);
    atomicOr(&mw[k >> 5], 1u << (k & 31));
  }
  __syncthreads();
  if (tid < 32) MASK[(size_t)bq * 32 + tid] = mw[tid];
}

// ------- masked-dense flash attention: x32 QK^T + x16 PV, 1-barrier pipeline ---
// 1D grid (512) with PAIR-BALANCED qt decode: blocks i and i+256 co-reside on
// one CU (round-robin); qt(i)+qt(i+256)=15 -> every CU does ~17 tile-iters.
// Stride-32 ids of one (h,b) share an XCD -> K/V panel stays in that L2.
__global__ __launch_bounds__(256) void attn_mfma_kernel(
    const short* __restrict__ QKV, const unsigned int* __restrict__ MASK,
    short* __restrict__ O /* [BSROWS][D] fp16 */)
{
  __shared__ unsigned int mlds[64 * 32];   // 8KB mask words for 64 q-rows
  __shared__ short Kl[2][64 * 64];         // K tiles, linear [key][64], swizzled cols
  __shared__ short Vtl[2][64 * 68];        // V^T tiles [d][key], pitch 68
  int i = blockIdx.x;
  int p = i >> 5;
  int qt = (p < 8) ? p : 23 - p;           // pair-balanced: qt(p)+qt(p+8)=15
  int h = (i >> 1) & 15;
  int b = i & 1;
  int tid = threadIdx.x;
  int w = tid >> 6, l = tid & 63;
  int lq = l & 15, g = l >> 4;
  int q0 = qt * 64;
  const short* Kb = QKV + (size_t)b * S_LEN * QKV_LD + 1024 + h * DHD;
  const short* Vb = QKV + (size_t)b * S_LEN * QKV_LD + 2048 + h * DHD;
  // V-stage thread mapping
  int vu = tid >> 1, vhalf = tid & 1, vkg = vu >> 3, vdg = vu & 7;

#pragma unroll
  for (int i2 = 0; i2 < 8; ++i2) {
    int idx = tid + i2 * 256;
    mlds[idx] = MASK[((size_t)(b * S_LEN + q0 + (idx >> 5))) * 32 + (idx & 31)];
  }
  // Q B-frags (x32): q = q0+w*16+lq, k=d = dt2*32 + g*8 + j  (contiguous half8)
  half8 qf[2];
  {
    const short* qrow = QKV + ((size_t)(b * S_LEN + q0 + w * 16 + lq)) * QKV_LD + h * DHD;
    qf[0] = *(const half8*)(qrow + g * 8);
    qf[1] = *(const half8*)(qrow + 32 + g * 8);
  }
  // prologue: stage tile 0 into buf 0
  {
#pragma unroll
    for (int i2 = 0; i2 < 2; ++i2) {
      int idx = tid + i2 * 256;
      int row = idx >> 3, sub = idx & 7;
      gload16(Kb + (size_t)row * QKV_LD + (size_t)((sub ^ (row & 7)) * 8), &Kl[0][idx * 8]);
    }
    int krow = vkg * 4 + vhalf * 2;
    uint4 v0 = *(const uint4*)(Vb + (size_t)krow * QKV_LD + vdg * 8);
    uint4 v1 = *(const uint4*)(Vb + (size_t)(krow + 1) * QKV_LD + vdg * 8);
    const short* s0 = (const short*)&v0;
    const short* s1 = (const short*)&v1;
#pragma unroll
    for (int j = 0; j < 8; ++j)
      *(short2*)(&Vtl[0][(vdg * 8 + j) * 68 + vkg * 4 + vhalf * 2]) = make_short2(s0[j], s1[j]);
  }
  __syncthreads();  // drains gload vmcnt; mask + V^T visible

  f32x4 acc_o[4] = {};
  float m_run = -1.0e30f, l_run = 0.f;
  const int mrow = w * 16 + lq;
  int cur = 0;

  for (int kt = 0; kt <= qt; ++kt) {
    bool more = kt < qt;
    uint4 v0, v1;
    if (more) {  // issue next tile: K gload (async) + V reg loads (async until use)
#pragma unroll
      for (int i2 = 0; i2 < 2; ++i2) {
        int idx = tid + i2 * 256;
        int row = idx >> 3, sub = idx & 7;
        gload16(Kb + (size_t)((kt + 1) * 64 + row) * QKV_LD + (size_t)((sub ^ (row & 7)) * 8),
                &Kl[cur ^ 1][idx * 8]);
      }
      int krow = (kt + 1) * 64 + vkg * 4 + vhalf * 2;
      v0 = *(const uint4*)(Vb + (size_t)krow * QKV_LD + vdg * 8);
      v1 = *(const uint4*)(Vb + (size_t)(krow + 1) * QKV_LD + vdg * 8);
    }
    // ---- S^T[key][q] via 2 x32 MFMA per 16-key block ----
    f32x4 s[4] = {};
    __builtin_amdgcn_s_setprio(1);
#pragma unroll
    for (int ks = 0; ks < 4; ++ks) {
      half8 kf0 = *(const half8*)(&Kl[cur][(ks * 16 + lq) * 64 + ((g ^ (lq & 7)) * 8)]);
      half8 kf1 = *(const half8*)(&Kl[cur][(ks * 16 + lq) * 64 + (((4 + g) ^ (lq & 7)) * 8)]);
      s[ks] = __builtin_amdgcn_mfma_f32_16x16x32_f16(kf0, qf[0], s[ks], 0, 0, 0);
      s[ks] = __builtin_amdgcn_mfma_f32_16x16x32_f16(kf1, qf[1], s[ks], 0, 0, 0);
    }
    __builtin_amdgcn_s_setprio(0);
    // mask + scale; lane holds keys ks*16 + g*4 + r for q-col lq (mask row mrow)
    float mx = NEGF;
#pragma unroll
    for (int ks = 0; ks < 4; ++ks) {
      int kbase = kt * 64 + ks * 16 + g * 4;
      unsigned mwv = mlds[mrow * 32 + (kbase >> 5)];
#pragma unroll
      for (int r = 0; r < 4; ++r) {
        float sv = ((mwv >> ((kbase + r) & 31)) & 1u) ? s[ks][r] * 0.125f : NEGF;
        s[ks][r] = sv;
        mx = fmaxf(mx, sv);
      }
    }
    mx = fmaxf(mx, __shfl_xor(mx, 16));
    mx = fmaxf(mx, __shfl_xor(mx, 32));
    float m_new = fmaxf(m_run, mx);
    float scale = __expf(m_run - m_new);
    float lsum = 0.f;
    half4v pf[4];
#pragma unroll
    for (int ks = 0; ks < 4; ++ks) {
      half4v t;
#pragma unroll
      for (int r = 0; r < 4; ++r) {
        float pp = __expf(s[ks][r] - m_new);
        lsum += pp;
        t[r] = (_Float16)pp;
      }
      pf[ks] = t;
    }
    lsum += __shfl_xor(lsum, 16);
    lsum += __shfl_xor(lsum, 32);
    l_run = l_run * scale + lsum;
    m_run = m_new;
    float sc[4];
#pragma unroll
    for (int r = 0; r < 4; ++r) sc[r] = __shfl(scale, g * 4 + r);
    __builtin_amdgcn_s_setprio(1);
#pragma unroll
    for (int dt = 0; dt < 4; ++dt) {
      f32x4 a = acc_o[dt];
      a[0] *= sc[0]; a[1] *= sc[1]; a[2] *= sc[2]; a[3] *= sc[3];
#pragma unroll
      for (int ks = 0; ks < 4; ++ks) {
        half4v vf = *(const half4v*)(&Vtl[cur][(dt * 16 + lq) * 68 + ks * 16 + g * 4]);
        a = MFMA16F(pf[ks], vf, a);  // A = P[q][k] (in-lane), B = V^T[d][k]
      }
      acc_o[dt] = a;
    }
    __builtin_amdgcn_s_setprio(0);
    // ---- write next V^T (buf nxt idle: last read ended before prev barrier) ----
    if (more) {
      const short* s0 = (const short*)&v0;
      const short* s1 = (const short*)&v1;
#pragma unroll
      for (int j = 0; j < 8; ++j)
        *(short2*)(&Vtl[cur ^ 1][(vdg * 8 + j) * 68 + vkg * 4 + vhalf * 2]) = make_short2(s0[j], s1[j]);
    }
    __syncthreads();  // all compute(cur) done; V^T(nxt) visible; gloads drained
    cur ^= 1;
  }
  float linv[4];
#pragma unroll
  for (int r = 0; r < 4; ++r) linv[r] = 1.0f / __shfl(l_run, g * 4 + r);
#pragma unroll
  for (int dt = 0; dt < 4; ++dt)
#pragma unroll
    for (int r = 0; r < 4; ++r) {
      int q = q0 + w * 16 + g * 4 + r;
      float o = acc_o[dt][r] * linv[r];
      O[(size_t)(b * S_LEN + q) * D_DIM + h * DHD + dt * 16 + lq] = f2h(o);
    }
}

// ---------------- host orchestration ----------------
extern "C" void kernel_launch(void* const* d_in, const int* in_sizes, int n_in,
                              void* d_out, int out_size, void* d_ws, size_t ws_size,
                              hipStream_t stream) {
  (void)in_sizes; (void)n_in; (void)out_size;
  const int*   tokens  = (const int*)d_in[0];
  const float* embed_w = (const float*)d_in[1];
  const float* pos_w   = (const float*)d_in[2];
  const float* wq      = (const float*)d_in[3];
  const float* wk      = (const float*)d_in[4];
  const float* wv      = (const float*)d_in[5];
  const float* wo      = (const float*)d_in[6];
  const float* iqw     = (const float*)d_in[7];
  const float* ikw     = (const float*)d_in[8];
  const float* iww     = (const float*)d_in[9];
  const float* w1      = (const float*)d_in[10];
  const float* w2      = (const float*)d_in[11];
  const float* n1      = (const float*)d_in[12];
  const float* n2      = (const float*)d_in[13];
  const float* nf      = (const float*)d_in[14];
  float* logits = (float*)d_out;

  // ws: Hh (logits A, 4 MB) + Eh (fp16 embed padded to VPAD rows, 103 MB)
  short* Hh = (short*)d_ws;
  size_t need_eh = ((size_t)BSROWS * D_DIM + (size_t)VPAD * D_DIM) * 2;
  bool use_eh = ws_size >= need_eh;
  short* Eh = Hh + (size_t)BSROWS * D_DIM;

  // d_out scratch (all dead before logits GEMM writes)
  char* base = (char*)d_out;
  size_t off = (size_t)BSROWS * D_DIM * 4;
  float* X = logits;
  float* Hx = (float*)(base + off);    off += (size_t)BSROWS * IDX_LD * 4;
  short* QKVh = (short*)(base + off);  off += (size_t)BSROWS * QKV_LD * 2;
  short* Hsp = (short*)(base + off);   off += (size_t)2 * BSROWS * D_DIM * 2;
  short* AOh = (short*)(base + off);   off += (size_t)BSROWS * D_DIM * 2;
  short* FFh = (short*)(base + off);   off += (size_t)BSROWS * FF_DIM * 2;
  unsigned int* MASKb = (unsigned int*)(base + off); off += (size_t)BSROWS * 32 * 4;
  short* BTqkvA = (short*)(base + off); off += (size_t)NL * QKV_LD * D_DIM * 2;
  short* BTidxA = (short*)(base + off); off += (size_t)NL * 2 * IDX_LD * D_DIM * 2;
  short* BTwoA = (short*)(base + off);  off += (size_t)NL * D_DIM * D_DIM * 2;
  short* BTw1A = (short*)(base + off);  off += (size_t)NL * FF_DIM * D_DIM * 2;
  short* BTw2A = (short*)(base + off);  off += (size_t)NL * FF_DIM * D_DIM * 2;

  const size_t plH  = (size_t)BSROWS * D_DIM;
  const size_t plIx = (size_t)IDX_LD * D_DIM;

  hipLaunchKernelGGL(embed_kernel, dim3(BSROWS), dim3(256), 0, stream,
                     tokens, embed_w, pos_w, X);
  if (use_eh)
    hipLaunchKernelGGL(cvt_embed_kernel, dim3(8192), dim3(256), 0, stream, embed_w, Eh);

  // all-layer weight packs (5 dispatches total)
  hipLaunchKernelGGL(pack_qkv_all_kernel, dim3(QKV_LD / 32, 32, NL), dim3(32, 8), 0, stream,
                     wq, wk, wv, BTqkvA);
  hipLaunchKernelGGL(pack_idx_all_kernel, dim3(IDX_LD / 32, 32, NL), dim3(32, 8), 0, stream,
                     iqw, ikw, iww, BTidxA);
  hipLaunchKernelGGL(packT_all_kernel, dim3(32, 32, NL), dim3(32, 8), 0, stream,
                     wo, BTwoA, D_DIM, D_DIM);
  hipLaunchKernelGGL(packT_all_kernel, dim3(FF_DIM / 32, 32, NL), dim3(32, 8), 0, stream,
                     w1, BTw1A, D_DIM, FF_DIM);
  hipLaunchKernelGGL(packT_all_kernel, dim3(D_DIM / 32, FF_DIM / 32, NL), dim3(32, 8), 0, stream,
                     w2, BTw2A, FF_DIM, D_DIM);

  for (int l = 0; l < NL; ++l) {
    short* BTqkv = BTqkvA + (size_t)l * QKV_LD * D_DIM;
    short* BTidx = BTidxA + (size_t)l * 2 * IDX_LD * D_DIM;
    short* BTwo  = BTwoA + (size_t)l * D_DIM * D_DIM;
    short* BTw1  = BTw1A + (size_t)l * FF_DIM * D_DIM;
    short* BTw2  = BTw2A + (size_t)l * FF_DIM * D_DIM;

    hipLaunchKernelGGL(rmsnorm_split_kernel, dim3(BSROWS), dim3(256), 0, stream,
                       X, n1 + (size_t)l * D_DIM, Hsp);
    hipLaunchKernelGGL((gemm_g_kernel<128, 1>), dim3(QKV_LD / 128, 16), dim3(256), 0, stream,
                       Hsp, BTqkv, nullptr, QKVh, BSROWS, QKV_LD, D_DIM);
    hipLaunchKernelGGL((gemm_split_kernel<64>), dim3(IDX_LD / 128, 32), dim3(256), 0, stream,
                       Hsp, plH, BTidx, plIx, Hx, BSROWS, IDX_LD, D_DIM);
    hipLaunchKernelGGL(idx_topk_kernel, dim3(BSROWS), dim3(256), 0, stream, Hx, MASKb);
    hipLaunchKernelGGL(attn_mfma_kernel, dim3(512), dim3(256), 0, stream,
                       QKVh, MASKb, AOh);
    hipLaunchKernelGGL((gemm_g_kernel<64, 3>), dim3(8, 32), dim3(256), 0, stream,
                       AOh, BTwo, X, X, BSROWS, D_DIM, D_DIM);
    hipLaunchKernelGGL(rmsnorm_h_kernel, dim3(BSROWS), dim3(256), 0, stream,
                       X, n2 + (size_t)l * D_DIM, Hsp);
    hipLaunchKernelGGL((gemm_g_kernel<128, 2>), dim3(FF_DIM / 128, 16), dim3(256), 0, stream,
                       Hsp, BTw1, nullptr, FFh, BSROWS, FF_DIM, D_DIM);
    hipLaunchKernelGGL((gemm_g_kernel<64, 3>), dim3(8, 32), dim3(256), 0, stream,
                       FFh, BTw2, X, X, BSROWS, D_DIM, FF_DIM);
  }

  hipLaunchKernelGGL(rmsnorm_h_kernel, dim3(BSROWS), dim3(256), 0, stream, X, nf, Hh);
  if (use_eh) {
    hipLaunchKernelGGL(gemm_logits_g_kernel, dim3(8 * YPX * 16), dim3(256), 0, stream,
                       Hh, Eh, logits, BSROWS, VOCAB, D_DIM);
  } else {
    hipLaunchKernelGGL(gemm_logits_f32b_kernel, dim3((VOCAB + 127) / 128, 16), dim3(256), 0, stream,
                       Hh, embed_w, logits, BSROWS, VOCAB, D_DIM);
  }
}

// Round 11
// 3431.710 us; speedup vs baseline: 8.4806x; 1.0533x over previous
//
#include <hip/hip_runtime.h>
#include <cstdint>
#include <cstddef>

#define S_LEN 1024
#define D_DIM 1024
#define NH 16
#define DHD 64
#define NL 8
#define FF_DIM 4096
#define HI_N 4
#define DI_N 64
#define TOPK_N 512
#define BSROWS 2048  // B * S
#define VOCAB 50257
#define VPAD 50304    // VOCAB rounded up to 128
#define NTILES_V 393  // ceil(50257/128)
#define YPX 50        // ceil(393/8) N-panels per XCD for logits

// compact QKV layout: [Q 0..1023 | K 1024..2047 | V 2048..3071], fp16
#define QKV_LD 3072
// indexer block layout (fp32): [QI 0..255 | KI 256..319 | WT 320..323 | pad..383]
#define IDX_LD 384
#define COL_QI 0
#define COL_KI 256
#define COL_WT 320

#define NEGF -3.0e38f

typedef __attribute__((ext_vector_type(8))) _Float16 half8;
typedef __attribute__((ext_vector_type(4))) _Float16 half4v;
typedef __attribute__((ext_vector_type(4))) float f32x4;

#if __has_builtin(__builtin_amdgcn_mfma_f32_16x16x16f16)
#define MFMA16F(a, b, c) __builtin_amdgcn_mfma_f32_16x16x16f16((a), (b), (c), 0, 0, 0)
#else
static __device__ __forceinline__ f32x4 mfma16f_asm(half4v a, half4v b, f32x4 c) {
  f32x4 d;
  asm volatile("v_mfma_f32_16x16x16_f16 %0, %1, %2, %3\n\ts_nop 7\n\ts_nop 7"
               : "=v"(d) : "v"(a), "v"(b), "v"(c));
  return d;
}
#define MFMA16F(a, b, c) mfma16f_asm((a), (b), (c))
#endif

// async global->LDS, 16B per lane; LDS dest must be lane-linear (rule #21)
typedef const __attribute__((address_space(1))) void* gas_ptr;
typedef __attribute__((address_space(3))) void* las_ptr;
__device__ __forceinline__ void gload16(const void* g, void* l) {
#if __has_builtin(__builtin_amdgcn_global_load_lds)
  __builtin_amdgcn_global_load_lds((gas_ptr)g, (las_ptr)l, 16, 0, 0);
#else
  *(uint4*)l = *(const uint4*)g;
#endif
}

__device__ __forceinline__ short f2h(float x) {  // RNE fp32->fp16 (bits)
  _Float16 h = (_Float16)x;
  return *reinterpret_cast<short*>(&h);
}
__device__ __forceinline__ float h2f(short b) {
  _Float16 h = *reinterpret_cast<_Float16*>(&b);
  return (float)h;
}
// two-term fp16 split: x ~= hi + lo with rel err ~2^-22
__device__ __forceinline__ void split_h(float x, short& hi, short& lo) {
  hi = f2h(x);
  lo = f2h(x - h2f(hi));
}

// ---------------- embed + positional ----------------
__global__ __launch_bounds__(256) void embed_kernel(
    const int* __restrict__ tokens, const float* __restrict__ E,
    const float* __restrict__ P, float* __restrict__ X)
{
  int bs = blockIdx.x;
  int s = bs & (S_LEN - 1);
  int tid = threadIdx.x;
  int tok = tokens[bs];
  float4 e = ((const float4*)(E + (size_t)tok * D_DIM))[tid];
  float4 p = ((const float4*)(P + (size_t)s * D_DIM))[tid];
  float4 o; o.x = e.x + p.x; o.y = e.y + p.y; o.z = e.z + p.z; o.w = e.w + p.w;
  ((float4*)(X + (size_t)bs * D_DIM))[tid] = o;
}

// ---------------- embed fp32 -> fp16, zero-padded to VPAD rows ----------------
__global__ __launch_bounds__(256) void cvt_embed_kernel(
    const float* __restrict__ E, short* __restrict__ Eh)
{
  const long valid4 = (long)VOCAB * D_DIM / 4;
  const long total4 = (long)VPAD * D_DIM / 4;
  long i = (long)blockIdx.x * 256 + threadIdx.x;
  long stride = (long)gridDim.x * 256;
  for (; i < total4; i += stride) {
    short4 o = make_short4(0, 0, 0, 0);
    if (i < valid4) {
      float4 v = ((const float4*)E)[i];
      o = make_short4(f2h(v.x), f2h(v.y), f2h(v.z), f2h(v.w));
    }
    ((short4*)Eh)[i] = o;
  }
}

// ---------------- rmsnorm -> split fp16 (hi plane, lo plane) ----------------
__global__ __launch_bounds__(256) void rmsnorm_split_kernel(
    const float* __restrict__ X, const float* __restrict__ W,
    short* __restrict__ O /* [2][BSROWS][D] */)
{
  int r = blockIdx.x;
  int tid = threadIdx.x;
  float4 v = ((const float4*)(X + (size_t)r * D_DIM))[tid];
  float ss = v.x * v.x + v.y * v.y + v.z * v.z + v.w * v.w;
  __shared__ float red[4];
  __shared__ float sh_inv;
  for (int o = 32; o; o >>= 1) ss += __shfl_down(ss, o);
  if ((tid & 63) == 0) red[tid >> 6] = ss;
  __syncthreads();
  if (tid == 0) {
    float s = red[0] + red[1] + red[2] + red[3];
    sh_inv = 1.0f / (sqrtf(s) * 0.03125f + 1e-6f);
  }
  __syncthreads();
  float inv = sh_inv;
  float4 w = ((const float4*)W)[tid];
  float o0 = w.x * v.x * inv, o1 = w.y * v.y * inv;
  float o2 = w.z * v.z * inv, o3 = w.w * v.w * inv;
  short4 hi, lo;
  split_h(o0, hi.x, lo.x); split_h(o1, hi.y, lo.y);
  split_h(o2, hi.z, lo.z); split_h(o3, hi.w, lo.w);
  ((short4*)(O + (size_t)r * D_DIM))[tid] = hi;
  ((short4*)(O + (size_t)BSROWS * D_DIM + (size_t)r * D_DIM))[tid] = lo;
}

// ---------------- rmsnorm -> plain fp16 ----------------
__global__ __launch_bounds__(256) void rmsnorm_h_kernel(
    const float* __restrict__ X, const float* __restrict__ W, short* __restrict__ O)
{
  int r = blockIdx.x;
  int tid = threadIdx.x;
  float4 v = ((const float4*)(X + (size_t)r * D_DIM))[tid];
  float ss = v.x * v.x + v.y * v.y + v.z * v.z + v.w * v.w;
  __shared__ float red[4];
  __shared__ float sh_inv;
  for (int o = 32; o; o >>= 1) ss += __shfl_down(ss, o);
  if ((tid & 63) == 0) red[tid >> 6] = ss;
  __syncthreads();
  if (tid == 0) {
    float s = red[0] + red[1] + red[2] + red[3];
    sh_inv = 1.0f / (sqrtf(s) * 0.03125f + 1e-6f);
  }
  __syncthreads();
  float inv = sh_inv;
  float4 w = ((const float4*)W)[tid];
  short4 o4 = make_short4(f2h(w.x * v.x * inv), f2h(w.y * v.y * inv),
                          f2h(w.z * v.z * inv), f2h(w.w * v.w * inv));
  ((short4*)(O + (size_t)r * D_DIM))[tid] = o4;
}

// ------- all-layer packs (grid.z = layer) -------
__global__ __launch_bounds__(256) void packT_all_kernel(
    const float* __restrict__ W0, short* __restrict__ BT0, int K, int N)
{
  __shared__ float t[32][33];
  int z = blockIdx.z;
  const float* W = W0 + (size_t)z * K * N;
  short* BT = BT0 + (size_t)z * N * K;
  int n0 = blockIdx.x * 32, k0 = blockIdx.y * 32;
  int tx = threadIdx.x, ty = threadIdx.y;
#pragma unroll
  for (int r = 0; r < 32; r += 8)
    t[ty + r][tx] = W[(size_t)(k0 + ty + r) * N + n0 + tx];
  __syncthreads();
#pragma unroll
  for (int r = 0; r < 32; r += 8)
    BT[(size_t)(n0 + ty + r) * K + k0 + tx] = f2h(t[tx][ty + r]);
}

__global__ __launch_bounds__(256) void pack_qkv_all_kernel(
    const float* __restrict__ wq0, const float* __restrict__ wk0,
    const float* __restrict__ wv0, short* __restrict__ BT0)
{
  __shared__ float t[32][33];
  int z = blockIdx.z;
  const float* wq = wq0 + (size_t)z * D_DIM * D_DIM;
  const float* wk = wk0 + (size_t)z * D_DIM * D_DIM;
  const float* wv = wv0 + (size_t)z * D_DIM * D_DIM;
  short* BT = BT0 + (size_t)z * QKV_LD * D_DIM;
  int n0 = blockIdx.x * 32, k0 = blockIdx.y * 32;
  int tx = threadIdx.x, ty = threadIdx.y;
  const float* src = (n0 < 1024) ? wq : (n0 < 2048) ? wk : wv;
  int c0 = n0 & 1023;
#pragma unroll
  for (int r = 0; r < 32; r += 8)
    t[ty + r][tx] = src[(size_t)(k0 + ty + r) * 1024 + c0 + tx];
  __syncthreads();
#pragma unroll
  for (int r = 0; r < 32; r += 8)
    BT[(size_t)(n0 + ty + r) * D_DIM + k0 + tx] = f2h(t[tx][ty + r]);
}

__global__ __launch_bounds__(256) void pack_idx_all_kernel(
    const float* __restrict__ iq0, const float* __restrict__ ik0,
    const float* __restrict__ iw0, short* __restrict__ BT0)
{
  __shared__ float t[32][33];
  const size_t plane = (size_t)IDX_LD * D_DIM;
  int z = blockIdx.z;
  const float* iq = iq0 + (size_t)z * D_DIM * (HI_N * DI_N);
  const float* ik = ik0 + (size_t)z * D_DIM * DI_N;
  const float* iw = iw0 + (size_t)z * D_DIM * HI_N;
  short* BT = BT0 + (size_t)z * 2 * plane;
  int n0 = blockIdx.x * 32, k0 = blockIdx.y * 32;
  int tx = threadIdx.x, ty = threadIdx.y;
  const float* src = nullptr; int ld = 0, c0 = 0;
  if (n0 < 256)      { src = iq; ld = 256; c0 = n0; }
  else if (n0 < 320) { src = ik; ld = 64;  c0 = n0 - 256; }
  else if (n0 < 352) { src = iw; ld = 4;   c0 = n0 - 320; }
#pragma unroll
  for (int r = 0; r < 32; r += 8) {
    float v = 0.f;
    int c = c0 + tx;
    if (src && c < ld) v = src[(size_t)(k0 + ty + r) * ld + c];
    t[ty + r][tx] = v;
  }
  __syncthreads();
#pragma unroll
  for (int r = 0; r < 32; r += 8) {
    short hi, lo;
    split_h(t[tx][ty + r], hi, lo);
    size_t o = (size_t)(n0 + ty + r) * D_DIM + k0 + tx;
    BT[o] = hi;
    BT[plane + o] = lo;
  }
}

#define RA 40  // padded LDS pitch for reg-staged split GEMM

// ------- split-fp16 GEMM (fp32-accurate), fp32 out: indexer only -------
template<int BM>
__global__ __launch_bounds__(256) void gemm_split_kernel(
    const short* __restrict__ A, size_t aplane,
    const short* __restrict__ BT, size_t bplane,
    float* __restrict__ C, int M, int N, int K)
{
  constexpr int MI = BM / 32;
  __shared__ short Al[2 * BM * RA];
  __shared__ short Bl[2 * 128 * RA];
  int tid = threadIdx.x;
  int wave = tid >> 6, lane = tid & 63;
  int wr = (wave >> 1) * (BM / 2), wc = (wave & 1) * 64;
  int lr = lane & 15, lk = lane >> 4;
  int m0 = blockIdx.y * BM, n0 = blockIdx.x * 128;
  f32x4 acc[MI][4] = {};

  for (int k0 = 0; k0 < K; k0 += 32) {
    __syncthreads();
#pragma unroll
    for (int f = 0; f < BM / 32; ++f) {
      int idx = tid + f * 256;
      int p = idx / (BM * 4), r2 = idx % (BM * 4);
      int row = r2 >> 2, sub = r2 & 3;
      uint4 v = *(const uint4*)(A + (size_t)p * aplane + (size_t)(m0 + row) * K + k0 + sub * 8);
      *(uint4*)(Al + p * BM * RA + row * RA + sub * 8) = v;
    }
#pragma unroll
    for (int f = 0; f < 4; ++f) {
      int idx = tid + f * 256;
      int p = idx >> 9, r2 = idx & 511;
      int row = r2 >> 2, sub = r2 & 3;
      uint4 v = *(const uint4*)(BT + (size_t)p * bplane + (size_t)(n0 + row) * K + k0 + sub * 8);
      *(uint4*)(Bl + p * 128 * RA + row * RA + sub * 8) = v;
    }
    __syncthreads();
    half8 ah[MI], al_[MI], bh[4], bl_[4];
#pragma unroll
    for (int i = 0; i < MI; ++i) {
      ah[i] = *(const half8*)(Al + (wr + i * 16 + lr) * RA + lk * 8);
      al_[i] = *(const half8*)(Al + BM * RA + (wr + i * 16 + lr) * RA + lk * 8);
    }
#pragma unroll
    for (int j = 0; j < 4; ++j) {
      bh[j] = *(const half8*)(Bl + (wc + j * 16 + lr) * RA + lk * 8);
      bl_[j] = *(const half8*)(Bl + 128 * RA + (wc + j * 16 + lr) * RA + lk * 8);
    }
#pragma unroll
    for (int i = 0; i < MI; ++i)
#pragma unroll
      for (int j = 0; j < 4; ++j) {
        f32x4 a = acc[i][j];
        a = __builtin_amdgcn_mfma_f32_16x16x32_f16(al_[i], bh[j], a, 0, 0, 0);
        a = __builtin_amdgcn_mfma_f32_16x16x32_f16(ah[i], bl_[j], a, 0, 0, 0);
        a = __builtin_amdgcn_mfma_f32_16x16x32_f16(ah[i], bh[j], a, 0, 0, 0);
        acc[i][j] = a;
      }
  }
#pragma unroll
  for (int i = 0; i < MI; ++i)
#pragma unroll
    for (int r = 0; r < 4; ++r) {
      int m = m0 + wr + i * 16 + lk * 4 + r;
#pragma unroll
      for (int j = 0; j < 4; ++j) {
        int n = n0 + wc + j * 16 + lr;
        if (n < N) C[(size_t)m * N + n] = acc[i][j][r];
      }
    }
}

// ------- plain fp16 GEMM, global_load_lds staging, linear LDS -------
// Requires: M % BM == 0, N % 128 == 0, K % 32 == 0 (no tile predicates).
// EPI: 1 fp16 store; 2 exact-GELU -> fp16 store; 3 fp32 + R
template<int BM, int EPI>
__global__ __launch_bounds__(256) void gemm_g_kernel(
    const short* __restrict__ A, const short* __restrict__ BT,
    const float* __restrict__ R, void* __restrict__ C, int M, int N, int K)
{
  constexpr int MI = BM / 32;          // M-frags per wave (128->4, 64->2, 32->1)
  __shared__ short Al[BM * 32];        // linear [row][32]
  __shared__ short Bl[128 * 32];
  int tid = threadIdx.x;
  int wave = tid >> 6, lane = tid & 63;
  int wr = (wave >> 1) * (BM / 2), wc = (wave & 1) * 64;
  int lr = lane & 15, lk = lane >> 4;
  int m0 = blockIdx.y * BM, n0 = blockIdx.x * 128;
  f32x4 acc[MI][4] = {};

  for (int k0 = 0; k0 < K; k0 += 32) {
    __syncthreads();  // previous frag reads complete before overwrite
    if constexpr (BM >= 64) {
#pragma unroll
      for (int f = 0; f < BM / 64; ++f) {
        int idx = tid + f * 256;
        gload16(A + (size_t)(m0 + (idx >> 2)) * K + k0 + (idx & 3) * 8, Al + idx * 8);
      }
    } else {
      if (tid < BM * 4)
        gload16(A + (size_t)(m0 + (tid >> 2)) * K + k0 + (tid & 3) * 8, Al + tid * 8);
    }
#pragma unroll
    for (int f = 0; f < 2; ++f) {
      int idx = tid + f * 256;
      gload16(BT + (size_t)(n0 + (idx >> 2)) * K + k0 + (idx & 3) * 8, Bl + idx * 8);
    }
    __syncthreads();  // drains vmcnt -> LDS visible
    half8 af[MI], bfr[4];
#pragma unroll
    for (int i = 0; i < MI; ++i)
      af[i] = *(const half8*)(Al + (wr + i * 16 + lr) * 32 + lk * 8);
#pragma unroll
    for (int j = 0; j < 4; ++j)
      bfr[j] = *(const half8*)(Bl + (wc + j * 16 + lr) * 32 + lk * 8);
#pragma unroll
    for (int i = 0; i < MI; ++i)
#pragma unroll
      for (int j = 0; j < 4; ++j)
        acc[i][j] = __builtin_amdgcn_mfma_f32_16x16x32_f16(af[i], bfr[j], acc[i][j], 0, 0, 0);
  }
#pragma unroll
  for (int i = 0; i < MI; ++i)
#pragma unroll
    for (int r = 0; r < 4; ++r) {
      int m = m0 + wr + i * 16 + lk * 4 + r;
#pragma unroll
      for (int j = 0; j < 4; ++j) {
        int n = n0 + wc + j * 16 + lr;
        float v = acc[i][j][r];
        if (EPI == 1) {
          ((short*)C)[(size_t)m * N + n] = f2h(v);
        } else if (EPI == 2) {
          v = 0.5f * v * (1.0f + erff(v * 0.70710678118654752f));
          ((short*)C)[(size_t)m * N + n] = f2h(v);
        } else {
          ((float*)C)[(size_t)m * N + n] = v + R[(size_t)m * N + n];
        }
      }
    }
}

// ------- logits GEMM: gload staging + XCD-aware 1D grid; B padded to VPAD -----
__global__ __launch_bounds__(256) void gemm_logits_g_kernel(
    const short* __restrict__ A, const short* __restrict__ BT,
    float* __restrict__ C, int M, int N, int K)
{
  int bid = blockIdx.x;
  int xcd = bid & 7, idx = bid >> 3;
  int mt = idx & 15, yt = (idx >> 4) + xcd * YPX;
  if (yt >= NTILES_V) return;
  int m0 = mt * 128, n0 = yt * 128;

  __shared__ short Al[128 * 32];
  __shared__ short Bl[128 * 32];
  int tid = threadIdx.x;
  int wave = tid >> 6, lane = tid & 63;
  int wr = (wave >> 1) * 64, wc = (wave & 1) * 64;
  int lr = lane & 15, lk = lane >> 4;
  f32x4 acc[4][4] = {};

  for (int k0 = 0; k0 < K; k0 += 32) {
    __syncthreads();
#pragma unroll
    for (int f = 0; f < 2; ++f) {
      int i2 = tid + f * 256;
      gload16(A + (size_t)(m0 + (i2 >> 2)) * K + k0 + (i2 & 3) * 8, Al + i2 * 8);
    }
#pragma unroll
    for (int f = 0; f < 2; ++f) {
      int i2 = tid + f * 256;
      gload16(BT + (size_t)(n0 + (i2 >> 2)) * K + k0 + (i2 & 3) * 8, Bl + i2 * 8);
    }
    __syncthreads();
    half8 af[4], bfr[4];
#pragma unroll
    for (int i = 0; i < 4; ++i)
      af[i] = *(const half8*)(Al + (wr + i * 16 + lr) * 32 + lk * 8);
#pragma unroll
    for (int j = 0; j < 4; ++j)
      bfr[j] = *(const half8*)(Bl + (wc + j * 16 + lr) * 32 + lk * 8);
#pragma unroll
    for (int i = 0; i < 4; ++i)
#pragma unroll
      for (int j = 0; j < 4; ++j)
        acc[i][j] = __builtin_amdgcn_mfma_f32_16x16x32_f16(af[i], bfr[j], acc[i][j], 0, 0, 0);
  }
#pragma unroll
  for (int i = 0; i < 4; ++i)
#pragma unroll
    for (int r = 0; r < 4; ++r) {
      int m = m0 + wr + i * 16 + lk * 4 + r;
#pragma unroll
      for (int j = 0; j < 4; ++j) {
        int n = n0 + wc + j * 16 + lr;
        if (n < N) C[(size_t)m * N + n] = acc[i][j][r];
      }
    }
}

// ------- logits fallback: B fp32 [N][K] inline-cvt (when ws too small) -------
__global__ __launch_bounds__(256) void gemm_logits_f32b_kernel(
    const short* __restrict__ A, const float* __restrict__ BT,
    float* __restrict__ C, int M, int N, int K)
{
  __shared__ short Al[128 * RA];
  __shared__ short Bl[128 * RA];
  int tid = threadIdx.x;
  int wave = tid >> 6, lane = tid & 63;
  int wr = (wave >> 1) * 64, wc = (wave & 1) * 64;
  int lr = lane & 15, lk = lane >> 4;
  int m0 = blockIdx.y * 128, n0 = blockIdx.x * 128;
  f32x4 acc[4][4] = {};

  for (int k0 = 0; k0 < K; k0 += 32) {
    __syncthreads();
#pragma unroll
    for (int f = 0; f < 2; ++f) {
      int idx = tid + f * 256, row = idx >> 2, sub = idx & 3;
      uint4 v = *(const uint4*)(A + (size_t)(m0 + row) * K + k0 + sub * 8);
      *(uint4*)(Al + row * RA + sub * 8) = v;
    }
#pragma unroll
    for (int f = 0; f < 4; ++f) {
      int idx = tid + f * 256, row = idx >> 3, qq = idx & 7;
      int gn = n0 + row;
      float4 v = make_float4(0.f, 0.f, 0.f, 0.f);
      if (gn < N) v = *(const float4*)(BT + (size_t)gn * K + k0 + qq * 4);
      *(short4*)(Bl + row * RA + qq * 4) =
          make_short4(f2h(v.x), f2h(v.y), f2h(v.z), f2h(v.w));
    }
    __syncthreads();
    half8 af[4], bfr[4];
#pragma unroll
    for (int i = 0; i < 4; ++i)
      af[i] = *(const half8*)(Al + (wr + i * 16 + lr) * RA + lk * 8);
#pragma unroll
    for (int j = 0; j < 4; ++j)
      bfr[j] = *(const half8*)(Bl + (wc + j * 16 + lr) * RA + lk * 8);
#pragma unroll
    for (int i = 0; i < 4; ++i)
#pragma unroll
      for (int j = 0; j < 4; ++j)
        acc[i][j] = __builtin_amdgcn_mfma_f32_16x16x32_f16(af[i], bfr[j], acc[i][j], 0, 0, 0);
  }
#pragma unroll
  for (int i = 0; i < 4; ++i)
#pragma unroll
    for (int r = 0; r < 4; ++r) {
      int m = m0 + wr + i * 16 + lk * 4 + r;
#pragma unroll
      for (int j = 0; j < 4; ++j) {
        int n = n0 + wc + j * 16 + lr;
        if (n < N) C[(size_t)m * N + n] = acc[i][j][r];
      }
    }
}

// ---------------- indexer scores + exact stable top-k -> bitmask ----------------
__device__ __forceinline__ unsigned int ford(float f) {
  unsigned int u = __float_as_uint(f);
  return (u & 0x80000000u) ? ~u : (u | 0x80000000u);
}

__global__ __launch_bounds__(256) void idx_topk_kernel(
    const float* __restrict__ Hx, unsigned int* __restrict__ MASK)
{
  int bq = blockIdx.x;
  int q = bq & (S_LEN - 1);
  int b = bq >> 10;
  int tid = threadIdx.x;
  int n = q + 1;
  if (n <= TOPK_N) {
    if (tid < 32) {
      int full = n >> 5, rem = n & 31;
      unsigned int w = 0u;
      if (tid < full) w = 0xFFFFFFFFu;
      else if (tid == full && rem) w = (1u << rem) - 1u;
      MASK[(size_t)bq * 32 + tid] = w;
    }
    return;
  }
  __shared__ float qi_s[HI_N * DI_N];
  __shared__ float wt_s[HI_N];
  __shared__ float sc[S_LEN];
  __shared__ unsigned long long keys[S_LEN];
  __shared__ unsigned int mw[32];
  qi_s[tid] = Hx[(size_t)bq * IDX_LD + COL_QI + tid];
  if (tid < HI_N) wt_s[tid] = Hx[(size_t)bq * IDX_LD + COL_WT + tid];
  __syncthreads();
  for (int k = tid; k < n; k += 256) {
    const float* kr = Hx + (size_t)(b * S_LEN + k) * IDX_LD + COL_KI;
    float d0 = 0.f, d1 = 0.f, d2 = 0.f, d3 = 0.f;
#pragma unroll
    for (int d = 0; d < DI_N; ++d) {
      float kv = kr[d];
      d0 = fmaf(qi_s[d], kv, d0);
      d1 = fmaf(qi_s[64 + d], kv, d1);
      d2 = fmaf(qi_s[128 + d], kv, d2);
      d3 = fmaf(qi_s[192 + d], kv, d3);
    }
    sc[k] = wt_s[0] * fmaxf(d0, 0.f) + wt_s[1] * fmaxf(d1, 0.f)
          + wt_s[2] * fmaxf(d2, 0.f) + wt_s[3] * fmaxf(d3, 0.f);
  }
  __syncthreads();
  for (int i = tid; i < S_LEN; i += 256) {
    unsigned long long kk = 0ull;
    if (i < n) kk = ((unsigned long long)ford(sc[i]) << 32) | (unsigned int)(S_LEN - 1 - i);
    keys[i] = kk;
  }
  __syncthreads();
  for (int size = 2; size <= S_LEN; size <<= 1) {
    for (int stride = size >> 1; stride > 0; stride >>= 1) {
      for (int t = tid; t < S_LEN / 2; t += 256) {
        int j = t & (stride - 1);
        int lo = ((t ^ j) << 1) | j;
        int hi = lo | stride;
        unsigned long long a = keys[lo], c = keys[hi];
        bool desc = ((lo & size) == 0);
        bool sw = desc ? (a < c) : (a > c);
        if (sw) { keys[lo] = c; keys[hi] = a; }
      }
      __syncthreads();
    }
  }
  if (tid < 32) mw[tid] = 0u;
  __syncthreads();
  for (int i = tid; i < TOPK_N; i += 256) {
    int k = S_LEN - 1 - (int)(keys[i] & 0xFFFFFFFFull);
    atomicOr(&mw[k >> 5], 1u << (k & 31));
  }
  __syncthreads();
  if (tid < 32) MASK[(size_t)bq * 32 + tid] = mw[tid];
}

// ------- masked-dense flash attention: x32 QK^T + x16 PV, 1-barrier pipeline ---
__global__ __launch_bounds__(256) void attn_mfma_kernel(
    const short* __restrict__ QKV, const unsigned int* __restrict__ MASK,
    short* __restrict__ O /* [BSROWS][D] fp16 */)
{
  __shared__ unsigned int mlds[64 * 32];   // 8KB mask words for 64 q-rows
  __shared__ short Kl[2][64 * 64];         // K tiles, linear [key][64], swizzled cols
  __shared__ short Vtl[2][64 * 68];        // V^T tiles [d][key], pitch 68
  int i = blockIdx.x;
  int p = i >> 5;
  int qt = (p < 8) ? p : 23 - p;           // pair-balanced: qt(p)+qt(p+8)=15
  int h = (i >> 1) & 15;
  int b = i & 1;
  int tid = threadIdx.x;
  int w = tid >> 6, l = tid & 63;
  int lq = l & 15, g = l >> 4;
  int q0 = qt * 64;
  const short* Kb = QKV + (size_t)b * S_LEN * QKV_LD + 1024 + h * DHD;
  const short* Vb = QKV + (size_t)b * S_LEN * QKV_LD + 2048 + h * DHD;
  int vu = tid >> 1, vhalf = tid & 1, vkg = vu >> 3, vdg = vu & 7;

#pragma unroll
  for (int i2 = 0; i2 < 8; ++i2) {
    int idx = tid + i2 * 256;
    mlds[idx] = MASK[((size_t)(b * S_LEN + q0 + (idx >> 5))) * 32 + (idx & 31)];
  }
  half8 qf[2];
  {
    const short* qrow = QKV + ((size_t)(b * S_LEN + q0 + w * 16 + lq)) * QKV_LD + h * DHD;
    qf[0] = *(const half8*)(qrow + g * 8);
    qf[1] = *(const half8*)(qrow + 32 + g * 8);
  }
  {
#pragma unroll
    for (int i2 = 0; i2 < 2; ++i2) {
      int idx = tid + i2 * 256;
      int row = idx >> 3, sub = idx & 7;
      gload16(Kb + (size_t)row * QKV_LD + (size_t)((sub ^ (row & 7)) * 8), &Kl[0][idx * 8]);
    }
    int krow = vkg * 4 + vhalf * 2;
    uint4 v0 = *(const uint4*)(Vb + (size_t)krow * QKV_LD + vdg * 8);
    uint4 v1 = *(const uint4*)(Vb + (size_t)(krow + 1) * QKV_LD + vdg * 8);
    const short* s0 = (const short*)&v0;
    const short* s1 = (const short*)&v1;
#pragma unroll
    for (int j = 0; j < 8; ++j)
      *(short2*)(&Vtl[0][(vdg * 8 + j) * 68 + vkg * 4 + vhalf * 2]) = make_short2(s0[j], s1[j]);
  }
  __syncthreads();

  f32x4 acc_o[4] = {};
  float m_run = -1.0e30f, l_run = 0.f;
  const int mrow = w * 16 + lq;
  int cur = 0;

  for (int kt = 0; kt <= qt; ++kt) {
    bool more = kt < qt;
    uint4 v0, v1;
    if (more) {
#pragma unroll
      for (int i2 = 0; i2 < 2; ++i2) {
        int idx = tid + i2 * 256;
        int row = idx >> 3, sub = idx & 7;
        gload16(Kb + (size_t)((kt + 1) * 64 + row) * QKV_LD + (size_t)((sub ^ (row & 7)) * 8),
                &Kl[cur ^ 1][idx * 8]);
      }
      int krow = (kt + 1) * 64 + vkg * 4 + vhalf * 2;
      v0 = *(const uint4*)(Vb + (size_t)krow * QKV_LD + vdg * 8);
      v1 = *(const uint4*)(Vb + (size_t)(krow + 1) * QKV_LD + vdg * 8);
    }
    f32x4 s[4] = {};
    __builtin_amdgcn_s_setprio(1);
#pragma unroll
    for (int ks = 0; ks < 4; ++ks) {
      half8 kf0 = *(const half8*)(&Kl[cur][(ks * 16 + lq) * 64 + ((g ^ (lq & 7)) * 8)]);
      half8 kf1 = *(const half8*)(&Kl[cur][(ks * 16 + lq) * 64 + (((4 + g) ^ (lq & 7)) * 8)]);
      s[ks] = __builtin_amdgcn_mfma_f32_16x16x32_f16(kf0, qf[0], s[ks], 0, 0, 0);
      s[ks] = __builtin_amdgcn_mfma_f32_16x16x32_f16(kf1, qf[1], s[ks], 0, 0, 0);
    }
    __builtin_amdgcn_s_setprio(0);
    float mx = NEGF;
#pragma unroll
    for (int ks = 0; ks < 4; ++ks) {
      int kbase = kt * 64 + ks * 16 + g * 4;
      unsigned mwv = mlds[mrow * 32 + (kbase >> 5)];
#pragma unroll
      for (int r = 0; r < 4; ++r) {
        float sv = ((mwv >> ((kbase + r) & 31)) & 1u) ? s[ks][r] * 0.125f : NEGF;
        s[ks][r] = sv;
        mx = fmaxf(mx, sv);
      }
    }
    mx = fmaxf(mx, __shfl_xor(mx, 16));
    mx = fmaxf(mx, __shfl_xor(mx, 32));
    float m_new = fmaxf(m_run, mx);
    float scale = __expf(m_run - m_new);
    float lsum = 0.f;
    half4v pf[4];
#pragma unroll
    for (int ks = 0; ks < 4; ++ks) {
      half4v t;
#pragma unroll
      for (int r = 0; r < 4; ++r) {
        float pp = __expf(s[ks][r] - m_new);
        lsum += pp;
        t[r] = (_Float16)pp;
      }
      pf[ks] = t;
    }
    lsum += __shfl_xor(lsum, 16);
    lsum += __shfl_xor(lsum, 32);
    l_run = l_run * scale + lsum;
    m_run = m_new;
    float sc[4];
#pragma unroll
    for (int r = 0; r < 4; ++r) sc[r] = __shfl(scale, g * 4 + r);
    __builtin_amdgcn_s_setprio(1);
#pragma unroll
    for (int dt = 0; dt < 4; ++dt) {
      f32x4 a = acc_o[dt];
      a[0] *= sc[0]; a[1] *= sc[1]; a[2] *= sc[2]; a[3] *= sc[3];
#pragma unroll
      for (int ks = 0; ks < 4; ++ks) {
        half4v vf = *(const half4v*)(&Vtl[cur][(dt * 16 + lq) * 68 + ks * 16 + g * 4]);
        a = MFMA16F(pf[ks], vf, a);
      }
      acc_o[dt] = a;
    }
    __builtin_amdgcn_s_setprio(0);
    if (more) {
      const short* s0 = (const short*)&v0;
      const short* s1 = (const short*)&v1;
#pragma unroll
      for (int j = 0; j < 8; ++j)
        *(short2*)(&Vtl[cur ^ 1][(vdg * 8 + j) * 68 + vkg * 4 + vhalf * 2]) = make_short2(s0[j], s1[j]);
    }
    __syncthreads();
    cur ^= 1;
  }
  float linv[4];
#pragma unroll
  for (int r = 0; r < 4; ++r) linv[r] = 1.0f / __shfl(l_run, g * 4 + r);
#pragma unroll
  for (int dt = 0; dt < 4; ++dt)
#pragma unroll
    for (int r = 0; r < 4; ++r) {
      int q = q0 + w * 16 + g * 4 + r;
      float o = acc_o[dt][r] * linv[r];
      O[(size_t)(b * S_LEN + q) * D_DIM + h * DHD + dt * 16 + lq] = f2h(o);
    }
}

// ---------------- host orchestration ----------------
extern "C" void kernel_launch(void* const* d_in, const int* in_sizes, int n_in,
                              void* d_out, int out_size, void* d_ws, size_t ws_size,
                              hipStream_t stream) {
  (void)in_sizes; (void)n_in; (void)out_size;
  const int*   tokens  = (const int*)d_in[0];
  const float* embed_w = (const float*)d_in[1];
  const float* pos_w   = (const float*)d_in[2];
  const float* wq      = (const float*)d_in[3];
  const float* wk      = (const float*)d_in[4];
  const float* wv      = (const float*)d_in[5];
  const float* wo      = (const float*)d_in[6];
  const float* iqw     = (const float*)d_in[7];
  const float* ikw     = (const float*)d_in[8];
  const float* iww     = (const float*)d_in[9];
  const float* w1      = (const float*)d_in[10];
  const float* w2      = (const float*)d_in[11];
  const float* n1      = (const float*)d_in[12];
  const float* n2      = (const float*)d_in[13];
  const float* nf      = (const float*)d_in[14];
  float* logits = (float*)d_out;

  // ws: Hh (logits A, 4 MB) + Eh (fp16 embed padded to VPAD rows, 103 MB)
  short* Hh = (short*)d_ws;
  size_t need_eh = ((size_t)BSROWS * D_DIM + (size_t)VPAD * D_DIM) * 2;
  bool use_eh = ws_size >= need_eh;
  short* Eh = Hh + (size_t)BSROWS * D_DIM;

  // d_out scratch (all dead before logits GEMM writes)
  char* base = (char*)d_out;
  size_t off = (size_t)BSROWS * D_DIM * 4;
  float* X = logits;
  float* Hx = (float*)(base + off);    off += (size_t)BSROWS * IDX_LD * 4;
  short* QKVh = (short*)(base + off);  off += (size_t)BSROWS * QKV_LD * 2;
  short* Hsp = (short*)(base + off);   off += (size_t)2 * BSROWS * D_DIM * 2;
  short* AOh = (short*)(base + off);   off += (size_t)BSROWS * D_DIM * 2;
  short* FFh = (short*)(base + off);   off += (size_t)BSROWS * FF_DIM * 2;
  unsigned int* MASKb = (unsigned int*)(base + off); off += (size_t)BSROWS * 32 * 4;
  short* BTqkvA = (short*)(base + off); off += (size_t)NL * QKV_LD * D_DIM * 2;
  short* BTidxA = (short*)(base + off); off += (size_t)NL * 2 * IDX_LD * D_DIM * 2;
  short* BTwoA = (short*)(base + off);  off += (size_t)NL * D_DIM * D_DIM * 2;
  short* BTw1A = (short*)(base + off);  off += (size_t)NL * FF_DIM * D_DIM * 2;
  short* BTw2A = (short*)(base + off);  off += (size_t)NL * FF_DIM * D_DIM * 2;

  const size_t plH  = (size_t)BSROWS * D_DIM;
  const size_t plIx = (size_t)IDX_LD * D_DIM;

  hipLaunchKernelGGL(embed_kernel, dim3(BSROWS), dim3(256), 0, stream,
                     tokens, embed_w, pos_w, X);
  if (use_eh)
    hipLaunchKernelGGL(cvt_embed_kernel, dim3(8192), dim3(256), 0, stream, embed_w, Eh);

  // all-layer weight packs (5 dispatches total)
  hipLaunchKernelGGL(pack_qkv_all_kernel, dim3(QKV_LD / 32, 32, NL), dim3(32, 8), 0, stream,
                     wq, wk, wv, BTqkvA);
  hipLaunchKernelGGL(pack_idx_all_kernel, dim3(IDX_LD / 32, 32, NL), dim3(32, 8), 0, stream,
                     iqw, ikw, iww, BTidxA);
  hipLaunchKernelGGL(packT_all_kernel, dim3(32, 32, NL), dim3(32, 8), 0, stream,
                     wo, BTwoA, D_DIM, D_DIM);
  hipLaunchKernelGGL(packT_all_kernel, dim3(FF_DIM / 32, 32, NL), dim3(32, 8), 0, stream,
                     w1, BTw1A, D_DIM, FF_DIM);
  hipLaunchKernelGGL(packT_all_kernel, dim3(D_DIM / 32, FF_DIM / 32, NL), dim3(32, 8), 0, stream,
                     w2, BTw2A, FF_DIM, D_DIM);

  for (int l = 0; l < NL; ++l) {
    short* BTqkv = BTqkvA + (size_t)l * QKV_LD * D_DIM;
    short* BTidx = BTidxA + (size_t)l * 2 * IDX_LD * D_DIM;
    short* BTwo  = BTwoA + (size_t)l * D_DIM * D_DIM;
    short* BTw1  = BTw1A + (size_t)l * FF_DIM * D_DIM;
    short* BTw2  = BTw2A + (size_t)l * FF_DIM * D_DIM;

    hipLaunchKernelGGL(rmsnorm_split_kernel, dim3(BSROWS), dim3(256), 0, stream,
                       X, n1 + (size_t)l * D_DIM, Hsp);
    // QKV: BM=64 -> 768 blocks (3/CU resident)
    hipLaunchKernelGGL((gemm_g_kernel<64, 1>), dim3(QKV_LD / 128, 32), dim3(256), 0, stream,
                       Hsp, BTqkv, nullptr, QKVh, BSROWS, QKV_LD, D_DIM);
    // indexer: BM=32 -> 192 blocks
    hipLaunchKernelGGL((gemm_split_kernel<32>), dim3(IDX_LD / 128, 64), dim3(256), 0, stream,
                       Hsp, plH, BTidx, plIx, Hx, BSROWS, IDX_LD, D_DIM);
    hipLaunchKernelGGL(idx_topk_kernel, dim3(BSROWS), dim3(256), 0, stream, Hx, MASKb);
    hipLaunchKernelGGL(attn_mfma_kernel, dim3(512), dim3(256), 0, stream,
                       QKVh, MASKb, AOh);
    // wo: BM=32 -> 512 blocks (2/CU)
    hipLaunchKernelGGL((gemm_g_kernel<32, 3>), dim3(8, 64), dim3(256), 0, stream,
                       AOh, BTwo, X, X, BSROWS, D_DIM, D_DIM);
    hipLaunchKernelGGL(rmsnorm_h_kernel, dim3(BSROWS), dim3(256), 0, stream,
                       X, n2 + (size_t)l * D_DIM, Hsp);
    // w1: BM=64 -> 1024 blocks (4/CU)
    hipLaunchKernelGGL((gemm_g_kernel<64, 2>), dim3(FF_DIM / 128, 32), dim3(256), 0, stream,
                       Hsp, BTw1, nullptr, FFh, BSROWS, FF_DIM, D_DIM);
    // w2: BM=32 -> 512 blocks (2/CU); B re-reads stay L2-resident (8 MB)
    hipLaunchKernelGGL((gemm_g_kernel<32, 3>), dim3(8, 64), dim3(256), 0, stream,
                       FFh, BTw2, X, X, BSROWS, D_DIM, FF_DIM);
  }

  hipLaunchKernelGGL(rmsnorm_h_kernel, dim3(BSROWS), dim3(256), 0, stream, X, nf, Hh);
  if (use_eh) {
    hipLaunchKernelGGL(gemm_logits_g_kernel, dim3(8 * YPX * 16), dim3(256), 0, stream,
                       Hh, Eh, logits, BSROWS, VOCAB, D_DIM);
  } else {
    hipLaunchKernelGGL(gemm_logits_f32b_kernel, dim3((VOCAB + 127) / 128, 16), dim3(256), 0, stream,
                       Hh, embed_w, logits, BSROWS, VOCAB, D_DIM);
  }
}

// Round 12
// 3419.041 us; speedup vs baseline: 8.5120x; 1.0037x over previous
//
#include <hip/hip_runtime.h>
#include <cstdint>
#include <cstddef>

#define S_LEN 1024
#define D_DIM 1024
#define NH 16
#define DHD 64
#define NL 8
#define FF_DIM 4096
#define HI_N 4
#define DI_N 64
#define TOPK_N 512
#define BSROWS 2048  // B * S
#define VOCAB 50257
#define VPAD 50304    // VOCAB rounded up to 128
#define NTILES_V 393  // ceil(50257/128)
#define YPX 50        // ceil(393/8) N-panels per XCD for logits

// compact QKV layout: [Q 0..1023 | K 1024..2047 | V 2048..3071], fp16
#define QKV_LD 3072
// indexer block layout (fp32): [QI 0..255 | KI 256..319 | WT 320..323 | pad..383]
#define IDX_LD 384
#define COL_QI 0
#define COL_KI 256
#define COL_WT 320

#define NEGF -3.0e38f

typedef __attribute__((ext_vector_type(8))) _Float16 half8;
typedef __attribute__((ext_vector_type(4))) _Float16 half4v;
typedef __attribute__((ext_vector_type(4))) float f32x4;

#if __has_builtin(__builtin_amdgcn_mfma_f32_16x16x16f16)
#define MFMA16F(a, b, c) __builtin_amdgcn_mfma_f32_16x16x16f16((a), (b), (c), 0, 0, 0)
#else
static __device__ __forceinline__ f32x4 mfma16f_asm(half4v a, half4v b, f32x4 c) {
  f32x4 d;
  asm volatile("v_mfma_f32_16x16x16_f16 %0, %1, %2, %3\n\ts_nop 7\n\ts_nop 7"
               : "=v"(d) : "v"(a), "v"(b), "v"(c));
  return d;
}
#define MFMA16F(a, b, c) mfma16f_asm((a), (b), (c))
#endif

// async global->LDS, 16B per lane; LDS dest must be lane-linear (rule #21)
typedef const __attribute__((address_space(1))) void* gas_ptr;
typedef __attribute__((address_space(3))) void* las_ptr;
__device__ __forceinline__ void gload16(const void* g, void* l) {
#if __has_builtin(__builtin_amdgcn_global_load_lds)
  __builtin_amdgcn_global_load_lds((gas_ptr)g, (las_ptr)l, 16, 0, 0);
#else
  *(uint4*)l = *(const uint4*)g;
#endif
}

__device__ __forceinline__ short f2h(float x) {  // RNE fp32->fp16 (bits)
  _Float16 h = (_Float16)x;
  return *reinterpret_cast<short*>(&h);
}
__device__ __forceinline__ float h2f(short b) {
  _Float16 h = *reinterpret_cast<_Float16*>(&b);
  return (float)h;
}
// two-term fp16 split: x ~= hi + lo with rel err ~2^-22
__device__ __forceinline__ void split_h(float x, short& hi, short& lo) {
  hi = f2h(x);
  lo = f2h(x - h2f(hi));
}

// ---------------- embed + positional ----------------
__global__ __launch_bounds__(256) void embed_kernel(
    const int* __restrict__ tokens, const float* __restrict__ E,
    const float* __restrict__ P, float* __restrict__ X)
{
  int bs = blockIdx.x;
  int s = bs & (S_LEN - 1);
  int tid = threadIdx.x;
  int tok = tokens[bs];
  float4 e = ((const float4*)(E + (size_t)tok * D_DIM))[tid];
  float4 p = ((const float4*)(P + (size_t)s * D_DIM))[tid];
  float4 o; o.x = e.x + p.x; o.y = e.y + p.y; o.z = e.z + p.z; o.w = e.w + p.w;
  ((float4*)(X + (size_t)bs * D_DIM))[tid] = o;
}

// ---------------- embed fp32 -> fp16, zero-padded to VPAD rows ----------------
__global__ __launch_bounds__(256) void cvt_embed_kernel(
    const float* __restrict__ E, short* __restrict__ Eh)
{
  const long valid4 = (long)VOCAB * D_DIM / 4;
  const long total4 = (long)VPAD * D_DIM / 4;
  long i = (long)blockIdx.x * 256 + threadIdx.x;
  long stride = (long)gridDim.x * 256;
  for (; i < total4; i += stride) {
    short4 o = make_short4(0, 0, 0, 0);
    if (i < valid4) {
      float4 v = ((const float4*)E)[i];
      o = make_short4(f2h(v.x), f2h(v.y), f2h(v.z), f2h(v.w));
    }
    ((short4*)Eh)[i] = o;
  }
}

// ---------------- rmsnorm -> split fp16 (hi plane, lo plane) ----------------
__global__ __launch_bounds__(256) void rmsnorm_split_kernel(
    const float* __restrict__ X, const float* __restrict__ W,
    short* __restrict__ O /* [2][BSROWS][D] */)
{
  int r = blockIdx.x;
  int tid = threadIdx.x;
  float4 v = ((const float4*)(X + (size_t)r * D_DIM))[tid];
  float ss = v.x * v.x + v.y * v.y + v.z * v.z + v.w * v.w;
  __shared__ float red[4];
  __shared__ float sh_inv;
  for (int o = 32; o; o >>= 1) ss += __shfl_down(ss, o);
  if ((tid & 63) == 0) red[tid >> 6] = ss;
  __syncthreads();
  if (tid == 0) {
    float s = red[0] + red[1] + red[2] + red[3];
    sh_inv = 1.0f / (sqrtf(s) * 0.03125f + 1e-6f);
  }
  __syncthreads();
  float inv = sh_inv;
  float4 w = ((const float4*)W)[tid];
  float o0 = w.x * v.x * inv, o1 = w.y * v.y * inv;
  float o2 = w.z * v.z * inv, o3 = w.w * v.w * inv;
  short4 hi, lo;
  split_h(o0, hi.x, lo.x); split_h(o1, hi.y, lo.y);
  split_h(o2, hi.z, lo.z); split_h(o3, hi.w, lo.w);
  ((short4*)(O + (size_t)r * D_DIM))[tid] = hi;
  ((short4*)(O + (size_t)BSROWS * D_DIM + (size_t)r * D_DIM))[tid] = lo;
}

// ---------------- rmsnorm -> plain fp16 ----------------
__global__ __launch_bounds__(256) void rmsnorm_h_kernel(
    const float* __restrict__ X, const float* __restrict__ W, short* __restrict__ O)
{
  int r = blockIdx.x;
  int tid = threadIdx.x;
  float4 v = ((const float4*)(X + (size_t)r * D_DIM))[tid];
  float ss = v.x * v.x + v.y * v.y + v.z * v.z + v.w * v.w;
  __shared__ float red[4];
  __shared__ float sh_inv;
  for (int o = 32; o; o >>= 1) ss += __shfl_down(ss, o);
  if ((tid & 63) == 0) red[tid >> 6] = ss;
  __syncthreads();
  if (tid == 0) {
    float s = red[0] + red[1] + red[2] + red[3];
    sh_inv = 1.0f / (sqrtf(s) * 0.03125f + 1e-6f);
  }
  __syncthreads();
  float inv = sh_inv;
  float4 w = ((const float4*)W)[tid];
  short4 o4 = make_short4(f2h(w.x * v.x * inv), f2h(w.y * v.y * inv),
                          f2h(w.z * v.z * inv), f2h(w.w * v.w * inv));
  ((short4*)(O + (size_t)r * D_DIM))[tid] = o4;
}

// ------- all-layer packs (grid.z = layer) -------
__global__ __launch_bounds__(256) void packT_all_kernel(
    const float* __restrict__ W0, short* __restrict__ BT0, int K, int N)
{
  __shared__ float t[32][33];
  int z = blockIdx.z;
  const float* W = W0 + (size_t)z * K * N;
  short* BT = BT0 + (size_t)z * N * K;
  int n0 = blockIdx.x * 32, k0 = blockIdx.y * 32;
  int tx = threadIdx.x, ty = threadIdx.y;
#pragma unroll
  for (int r = 0; r < 32; r += 8)
    t[ty + r][tx] = W[(size_t)(k0 + ty + r) * N + n0 + tx];
  __syncthreads();
#pragma unroll
  for (int r = 0; r < 32; r += 8)
    BT[(size_t)(n0 + ty + r) * K + k0 + tx] = f2h(t[tx][ty + r]);
}

__global__ __launch_bounds__(256) void pack_qkv_all_kernel(
    const float* __restrict__ wq0, const float* __restrict__ wk0,
    const float* __restrict__ wv0, short* __restrict__ BT0)
{
  __shared__ float t[32][33];
  int z = blockIdx.z;
  const float* wq = wq0 + (size_t)z * D_DIM * D_DIM;
  const float* wk = wk0 + (size_t)z * D_DIM * D_DIM;
  const float* wv = wv0 + (size_t)z * D_DIM * D_DIM;
  short* BT = BT0 + (size_t)z * QKV_LD * D_DIM;
  int n0 = blockIdx.x * 32, k0 = blockIdx.y * 32;
  int tx = threadIdx.x, ty = threadIdx.y;
  const float* src = (n0 < 1024) ? wq : (n0 < 2048) ? wk : wv;
  int c0 = n0 & 1023;
#pragma unroll
  for (int r = 0; r < 32; r += 8)
    t[ty + r][tx] = src[(size_t)(k0 + ty + r) * 1024 + c0 + tx];
  __syncthreads();
#pragma unroll
  for (int r = 0; r < 32; r += 8)
    BT[(size_t)(n0 + ty + r) * D_DIM + k0 + tx] = f2h(t[tx][ty + r]);
}

__global__ __launch_bounds__(256) void pack_idx_all_kernel(
    const float* __restrict__ iq0, const float* __restrict__ ik0,
    const float* __restrict__ iw0, short* __restrict__ BT0)
{
  __shared__ float t[32][33];
  const size_t plane = (size_t)IDX_LD * D_DIM;
  int z = blockIdx.z;
  const float* iq = iq0 + (size_t)z * D_DIM * (HI_N * DI_N);
  const float* ik = ik0 + (size_t)z * D_DIM * DI_N;
  const float* iw = iw0 + (size_t)z * D_DIM * HI_N;
  short* BT = BT0 + (size_t)z * 2 * plane;
  int n0 = blockIdx.x * 32, k0 = blockIdx.y * 32;
  int tx = threadIdx.x, ty = threadIdx.y;
  const float* src = nullptr; int ld = 0, c0 = 0;
  if (n0 < 256)      { src = iq; ld = 256; c0 = n0; }
  else if (n0 < 320) { src = ik; ld = 64;  c0 = n0 - 256; }
  else if (n0 < 352) { src = iw; ld = 4;   c0 = n0 - 320; }
#pragma unroll
  for (int r = 0; r < 32; r += 8) {
    float v = 0.f;
    int c = c0 + tx;
    if (src && c < ld) v = src[(size_t)(k0 + ty + r) * ld + c];
    t[ty + r][tx] = v;
  }
  __syncthreads();
#pragma unroll
  for (int r = 0; r < 32; r += 8) {
    short hi, lo;
    split_h(t[tx][ty + r], hi, lo);
    size_t o = (size_t)(n0 + ty + r) * D_DIM + k0 + tx;
    BT[o] = hi;
    BT[plane + o] = lo;
  }
}

#define RA 40  // padded LDS pitch for reg-staged split GEMM

// ------- split-fp16 GEMM (fp32-accurate), fp32 out: indexer only -------
template<int BM>
__global__ __launch_bounds__(256) void gemm_split_kernel(
    const short* __restrict__ A, size_t aplane,
    const short* __restrict__ BT, size_t bplane,
    float* __restrict__ C, int M, int N, int K)
{
  constexpr int MI = BM / 32;
  __shared__ short Al[2 * BM * RA];
  __shared__ short Bl[2 * 128 * RA];
  int tid = threadIdx.x;
  int wave = tid >> 6, lane = tid & 63;
  int wr = (wave >> 1) * (BM / 2), wc = (wave & 1) * 64;
  int lr = lane & 15, lk = lane >> 4;
  int m0 = blockIdx.y * BM, n0 = blockIdx.x * 128;
  f32x4 acc[MI][4] = {};

  for (int k0 = 0; k0 < K; k0 += 32) {
    __syncthreads();
#pragma unroll
    for (int f = 0; f < BM / 32; ++f) {
      int idx = tid + f * 256;
      int p = idx / (BM * 4), r2 = idx % (BM * 4);
      int row = r2 >> 2, sub = r2 & 3;
      uint4 v = *(const uint4*)(A + (size_t)p * aplane + (size_t)(m0 + row) * K + k0 + sub * 8);
      *(uint4*)(Al + p * BM * RA + row * RA + sub * 8) = v;
    }
#pragma unroll
    for (int f = 0; f < 4; ++f) {
      int idx = tid + f * 256;
      int p = idx >> 9, r2 = idx & 511;
      int row = r2 >> 2, sub = r2 & 3;
      uint4 v = *(const uint4*)(BT + (size_t)p * bplane + (size_t)(n0 + row) * K + k0 + sub * 8);
      *(uint4*)(Bl + p * 128 * RA + row * RA + sub * 8) = v;
    }
    __syncthreads();
    half8 ah[MI], al_[MI], bh[4], bl_[4];
#pragma unroll
    for (int i = 0; i < MI; ++i) {
      ah[i] = *(const half8*)(Al + (wr + i * 16 + lr) * RA + lk * 8);
      al_[i] = *(const half8*)(Al + BM * RA + (wr + i * 16 + lr) * RA + lk * 8);
    }
#pragma unroll
    for (int j = 0; j < 4; ++j) {
      bh[j] = *(const half8*)(Bl + (wc + j * 16 + lr) * RA + lk * 8);
      bl_[j] = *(const half8*)(Bl + 128 * RA + (wc + j * 16 + lr) * RA + lk * 8);
    }
#pragma unroll
    for (int i = 0; i < MI; ++i)
#pragma unroll
      for (int j = 0; j < 4; ++j) {
        f32x4 a = acc[i][j];
        a = __builtin_amdgcn_mfma_f32_16x16x32_f16(al_[i], bh[j], a, 0, 0, 0);
        a = __builtin_amdgcn_mfma_f32_16x16x32_f16(ah[i], bl_[j], a, 0, 0, 0);
        a = __builtin_amdgcn_mfma_f32_16x16x32_f16(ah[i], bh[j], a, 0, 0, 0);
        acc[i][j] = a;
      }
  }
#pragma unroll
  for (int i = 0; i < MI; ++i)
#pragma unroll
    for (int r = 0; r < 4; ++r) {
      int m = m0 + wr + i * 16 + lk * 4 + r;
#pragma unroll
      for (int j = 0; j < 4; ++j) {
        int n = n0 + wc + j * 16 + lr;
        if (n < N) C[(size_t)m * N + n] = acc[i][j][r];
      }
    }
}

// ------- plain fp16 GEMM, gload staging, hoisted addrs, slot^row&3 swizzle ----
// LDS[row][s] = global[row][s ^ (row&3)] (linear dest, pre-swizzled source);
// fragment reads use slot = lk ^ (row&3) -> 4-way (was 8-way) bank conflicts.
// Requires: M % BM == 0, N % 128 == 0, K % 32 == 0.
// EPI: 1 fp16 store; 2 exact-GELU -> fp16 store; 3 fp32 + R
template<int BM, int EPI>
__global__ __launch_bounds__(256) void gemm_g_kernel(
    const short* __restrict__ A, const short* __restrict__ BT,
    const float* __restrict__ R, void* __restrict__ C, int M, int N, int K)
{
  constexpr int MI = BM / 32;          // M-frags per wave (128->4, 64->2, 32->1)
  constexpr int AF = (BM >= 64) ? BM / 64 : 1;
  __shared__ short Al[BM * 32];        // linear [row][32]
  __shared__ short Bl[128 * 32];
  int tid = threadIdx.x;
  int wave = tid >> 6, lane = tid & 63;
  int wr = (wave >> 1) * (BM / 2), wc = (wave & 1) * 64;
  int lr = lane & 15, lk = lane >> 4;
  int m0 = blockIdx.y * BM, n0 = blockIdx.x * 128;
  f32x4 acc[MI][4] = {};

  // hoisted staging pointers
  const short* ap[AF]; short* ad[AF];
#pragma unroll
  for (int f = 0; f < AF; ++f) {
    int idx = tid + f * 256;
    int row = idx >> 2, slot = idx & 3;
    ap[f] = A + (size_t)(m0 + row) * K + ((slot ^ (row & 3)) * 8);
    ad[f] = Al + idx * 8;
  }
  const bool a_act = (BM >= 64) || (tid < BM * 4);
  const short* bp[2]; short* bd[2];
#pragma unroll
  for (int f = 0; f < 2; ++f) {
    int idx = tid + f * 256;
    int row = idx >> 2, slot = idx & 3;
    bp[f] = BT + (size_t)(n0 + row) * K + ((slot ^ (row & 3)) * 8);
    bd[f] = Bl + idx * 8;
  }
  // hoisted swizzled read offsets (elements)
  int aoff[MI], boff[4];
#pragma unroll
  for (int i = 0; i < MI; ++i) {
    int row = wr + i * 16 + lr;
    aoff[i] = row * 32 + ((lk ^ (row & 3)) * 8);
  }
#pragma unroll
  for (int j = 0; j < 4; ++j) {
    int row = wc + j * 16 + lr;
    boff[j] = row * 32 + ((lk ^ (row & 3)) * 8);
  }

  for (int k0 = 0; k0 < K; k0 += 32) {
    __syncthreads();  // previous frag reads complete before overwrite
#pragma unroll
    for (int f = 0; f < AF; ++f)
      if (a_act) { gload16(ap[f], ad[f]); ap[f] += 32; }
#pragma unroll
    for (int f = 0; f < 2; ++f) { gload16(bp[f], bd[f]); bp[f] += 32; }
    __syncthreads();  // drains vmcnt -> LDS visible
    half8 af[MI], bfr[4];
#pragma unroll
    for (int i = 0; i < MI; ++i) af[i] = *(const half8*)(Al + aoff[i]);
#pragma unroll
    for (int j = 0; j < 4; ++j) bfr[j] = *(const half8*)(Bl + boff[j]);
#pragma unroll
    for (int i = 0; i < MI; ++i)
#pragma unroll
      for (int j = 0; j < 4; ++j)
        acc[i][j] = __builtin_amdgcn_mfma_f32_16x16x32_f16(af[i], bfr[j], acc[i][j], 0, 0, 0);
  }
#pragma unroll
  for (int i = 0; i < MI; ++i)
#pragma unroll
    for (int r = 0; r < 4; ++r) {
      int m = m0 + wr + i * 16 + lk * 4 + r;
#pragma unroll
      for (int j = 0; j < 4; ++j) {
        int n = n0 + wc + j * 16 + lr;
        float v = acc[i][j][r];
        if (EPI == 1) {
          ((short*)C)[(size_t)m * N + n] = f2h(v);
        } else if (EPI == 2) {
          v = 0.5f * v * (1.0f + erff(v * 0.70710678118654752f));
          ((short*)C)[(size_t)m * N + n] = f2h(v);
        } else {
          ((float*)C)[(size_t)m * N + n] = v + R[(size_t)m * N + n];
        }
      }
    }
}

// ------- logits GEMM: hoisted/swizzled gload staging + XCD-aware 1D grid ------
__global__ __launch_bounds__(256) void gemm_logits_g_kernel(
    const short* __restrict__ A, const short* __restrict__ BT,
    float* __restrict__ C, int M, int N, int K)
{
  int bid = blockIdx.x;
  int xcd = bid & 7, idx0 = bid >> 3;
  int mt = idx0 & 15, yt = (idx0 >> 4) + xcd * YPX;
  if (yt >= NTILES_V) return;
  int m0 = mt * 128, n0 = yt * 128;

  __shared__ short Al[128 * 32];
  __shared__ short Bl[128 * 32];
  int tid = threadIdx.x;
  int wave = tid >> 6, lane = tid & 63;
  int wr = (wave >> 1) * 64, wc = (wave & 1) * 64;
  int lr = lane & 15, lk = lane >> 4;
  f32x4 acc[4][4] = {};

  const short* ap[2]; short* ad[2];
  const short* bp[2]; short* bd[2];
#pragma unroll
  for (int f = 0; f < 2; ++f) {
    int idx = tid + f * 256;
    int row = idx >> 2, slot = idx & 3;
    ap[f] = A + (size_t)(m0 + row) * K + ((slot ^ (row & 3)) * 8);
    ad[f] = Al + idx * 8;
    bp[f] = BT + (size_t)(n0 + row) * K + ((slot ^ (row & 3)) * 8);
    bd[f] = Bl + idx * 8;
  }
  int aoff[4], boff[4];
#pragma unroll
  for (int i = 0; i < 4; ++i) {
    int row = wr + i * 16 + lr;
    aoff[i] = row * 32 + ((lk ^ (row & 3)) * 8);
    int rowb = wc + i * 16 + lr;
    boff[i] = rowb * 32 + ((lk ^ (rowb & 3)) * 8);
  }

  for (int k0 = 0; k0 < K; k0 += 32) {
    __syncthreads();
#pragma unroll
    for (int f = 0; f < 2; ++f) { gload16(ap[f], ad[f]); ap[f] += 32; }
#pragma unroll
    for (int f = 0; f < 2; ++f) { gload16(bp[f], bd[f]); bp[f] += 32; }
    __syncthreads();
    half8 af[4], bfr[4];
#pragma unroll
    for (int i = 0; i < 4; ++i) af[i] = *(const half8*)(Al + aoff[i]);
#pragma unroll
    for (int j = 0; j < 4; ++j) bfr[j] = *(const half8*)(Bl + boff[j]);
#pragma unroll
    for (int i = 0; i < 4; ++i)
#pragma unroll
      for (int j = 0; j < 4; ++j)
        acc[i][j] = __builtin_amdgcn_mfma_f32_16x16x32_f16(af[i], bfr[j], acc[i][j], 0, 0, 0);
  }
#pragma unroll
  for (int i = 0; i < 4; ++i)
#pragma unroll
    for (int r = 0; r < 4; ++r) {
      int m = m0 + wr + i * 16 + lk * 4 + r;
#pragma unroll
      for (int j = 0; j < 4; ++j) {
        int n = n0 + wc + j * 16 + lr;
        if (n < N) C[(size_t)m * N + n] = acc[i][j][r];
      }
    }
}

// ------- logits fallback: B fp32 [N][K] inline-cvt (when ws too small) -------
__global__ __launch_bounds__(256) void gemm_logits_f32b_kernel(
    const short* __restrict__ A, const float* __restrict__ BT,
    float* __restrict__ C, int M, int N, int K)
{
  __shared__ short Al[128 * RA];
  __shared__ short Bl[128 * RA];
  int tid = threadIdx.x;
  int wave = tid >> 6, lane = tid & 63;
  int wr = (wave >> 1) * 64, wc = (wave & 1) * 64;
  int lr = lane & 15, lk = lane >> 4;
  int m0 = blockIdx.y * 128, n0 = blockIdx.x * 128;
  f32x4 acc[4][4] = {};

  for (int k0 = 0; k0 < K; k0 += 32) {
    __syncthreads();
#pragma unroll
    for (int f = 0; f < 2; ++f) {
      int idx = tid + f * 256, row = idx >> 2, sub = idx & 3;
      uint4 v = *(const uint4*)(A + (size_t)(m0 + row) * K + k0 + sub * 8);
      *(uint4*)(Al + row * RA + sub * 8) = v;
    }
#pragma unroll
    for (int f = 0; f < 4; ++f) {
      int idx = tid + f * 256, row = idx >> 3, qq = idx & 7;
      int gn = n0 + row;
      float4 v = make_float4(0.f, 0.f, 0.f, 0.f);
      if (gn < N) v = *(const float4*)(BT + (size_t)gn * K + k0 + qq * 4);
      *(short4*)(Bl + row * RA + qq * 4) =
          make_short4(f2h(v.x), f2h(v.y), f2h(v.z), f2h(v.w));
    }
    __syncthreads();
    half8 af[4], bfr[4];
#pragma unroll
    for (int i = 0; i < 4; ++i)
      af[i] = *(const half8*)(Al + (wr + i * 16 + lr) * RA + lk * 8);
#pragma unroll
    for (int j = 0; j < 4; ++j)
      bfr[j] = *(const half8*)(Bl + (wc + j * 16 + lr) * RA + lk * 8);
#pragma unroll
    for (int i = 0; i < 4; ++i)
#pragma unroll
      for (int j = 0; j < 4; ++j)
        acc[i][j] = __builtin_amdgcn_mfma_f32_16x16x32_f16(af[i], bfr[j], acc[i][j], 0, 0, 0);
  }
#pragma unroll
  for (int i = 0; i < 4; ++i)
#pragma unroll
    for (int r = 0; r < 4; ++r) {
      int m = m0 + wr + i * 16 + lk * 4 + r;
#pragma unroll
      for (int j = 0; j < 4; ++j) {
        int n = n0 + wc + j * 16 + lr;
        if (n < N) C[(size_t)m * N + n] = acc[i][j][r];
      }
    }
}

// ---------------- indexer scores + exact stable top-k -> bitmask ----------------
__device__ __forceinline__ unsigned int ford(float f) {
  unsigned int u = __float_as_uint(f);
  return (u & 0x80000000u) ? ~u : (u | 0x80000000u);
}

__global__ __launch_bounds__(256) void idx_topk_kernel(
    const float* __restrict__ Hx, unsigned int* __restrict__ MASK)
{
  int bq = blockIdx.x;
  int q = bq & (S_LEN - 1);
  int b = bq >> 10;
  int tid = threadIdx.x;
  int n = q + 1;
  if (n <= TOPK_N) {
    if (tid < 32) {
      int full = n >> 5, rem = n & 31;
      unsigned int w = 0u;
      if (tid < full) w = 0xFFFFFFFFu;
      else if (tid == full && rem) w = (1u << rem) - 1u;
      MASK[(size_t)bq * 32 + tid] = w;
    }
    return;
  }
  __shared__ float qi_s[HI_N * DI_N];
  __shared__ float wt_s[HI_N];
  __shared__ float sc[S_LEN];
  __shared__ unsigned long long keys[S_LEN];
  __shared__ unsigned int mw[32];
  qi_s[tid] = Hx[(size_t)bq * IDX_LD + COL_QI + tid];
  if (tid < HI_N) wt_s[tid] = Hx[(size_t)bq * IDX_LD + COL_WT + tid];
  __syncthreads();
  for (int k = tid; k < n; k += 256) {
    const float* kr = Hx + (size_t)(b * S_LEN + k) * IDX_LD + COL_KI;
    float d0 = 0.f, d1 = 0.f, d2 = 0.f, d3 = 0.f;
#pragma unroll
    for (int d = 0; d < DI_N; ++d) {
      float kv = kr[d];
      d0 = fmaf(qi_s[d], kv, d0);
      d1 = fmaf(qi_s[64 + d], kv, d1);
      d2 = fmaf(qi_s[128 + d], kv, d2);
      d3 = fmaf(qi_s[192 + d], kv, d3);
    }
    sc[k] = wt_s[0] * fmaxf(d0, 0.f) + wt_s[1] * fmaxf(d1, 0.f)
          + wt_s[2] * fmaxf(d2, 0.f) + wt_s[3] * fmaxf(d3, 0.f);
  }
  __syncthreads();
  for (int i = tid; i < S_LEN; i += 256) {
    unsigned long long kk = 0ull;
    if (i < n) kk = ((unsigned long long)ford(sc[i]) << 32) | (unsigned int)(S_LEN - 1 - i);
    keys[i] = kk;
  }
  __syncthreads();
  for (int size = 2; size <= S_LEN; size <<= 1) {
    for (int stride = size >> 1; stride > 0; stride >>= 1) {
      for (int t = tid; t < S_LEN / 2; t += 256) {
        int j = t & (stride - 1);
        int lo = ((t ^ j) << 1) | j;
        int hi = lo | stride;
        unsigned long long a = keys[lo], c = keys[hi];
        bool desc = ((lo & size) == 0);
        bool sw = desc ? (a < c) : (a > c);
        if (sw) { keys[lo] = c; keys[hi] = a; }
      }
      __syncthreads();
    }
  }
  if (tid < 32) mw[tid] = 0u;
  __syncthreads();
  for (int i = tid; i < TOPK_N; i += 256) {
    int k = S_LEN - 1 - (int)(keys[i] & 0xFFFFFFFFull);
    atomicOr(&mw[k >> 5], 1u << (k & 31));
  }
  __syncthreads();
  if (tid < 32) MASK[(size_t)bq * 32 + tid] = mw[tid];
}

// ------- masked-dense flash attention: x32 QK^T + x16 PV, 1-barrier pipeline ---
__global__ __launch_bounds__(256) void attn_mfma_kernel(
    const short* __restrict__ QKV, const unsigned int* __restrict__ MASK,
    short* __restrict__ O /* [BSROWS][D] fp16 */)
{
  __shared__ unsigned int mlds[64 * 32];   // 8KB mask words for 64 q-rows
  __shared__ short Kl[2][64 * 64];         // K tiles, linear [key][64], swizzled cols
  __shared__ short Vtl[2][64 * 68];        // V^T tiles [d][key], pitch 68
  int i = blockIdx.x;
  int p = i >> 5;
  int qt = (p < 8) ? p : 23 - p;           // pair-balanced: qt(p)+qt(p+8)=15
  int h = (i >> 1) & 15;
  int b = i & 1;
  int tid = threadIdx.x;
  int w = tid >> 6, l = tid & 63;
  int lq = l & 15, g = l >> 4;
  int q0 = qt * 64;
  const short* Kb = QKV + (size_t)b * S_LEN * QKV_LD + 1024 + h * DHD;
  const short* Vb = QKV + (size_t)b * S_LEN * QKV_LD + 2048 + h * DHD;
  int vu = tid >> 1, vhalf = tid & 1, vkg = vu >> 3, vdg = vu & 7;

#pragma unroll
  for (int i2 = 0; i2 < 8; ++i2) {
    int idx = tid + i2 * 256;
    mlds[idx] = MASK[((size_t)(b * S_LEN + q0 + (idx >> 5))) * 32 + (idx & 31)];
  }
  half8 qf[2];
  {
    const short* qrow = QKV + ((size_t)(b * S_LEN + q0 + w * 16 + lq)) * QKV_LD + h * DHD;
    qf[0] = *(const half8*)(qrow + g * 8);
    qf[1] = *(const half8*)(qrow + 32 + g * 8);
  }
  {
#pragma unroll
    for (int i2 = 0; i2 < 2; ++i2) {
      int idx = tid + i2 * 256;
      int row = idx >> 3, sub = idx & 7;
      gload16(Kb + (size_t)row * QKV_LD + (size_t)((sub ^ (row & 7)) * 8), &Kl[0][idx * 8]);
    }
    int krow = vkg * 4 + vhalf * 2;
    uint4 v0 = *(const uint4*)(Vb + (size_t)krow * QKV_LD + vdg * 8);
    uint4 v1 = *(const uint4*)(Vb + (size_t)(krow + 1) * QKV_LD + vdg * 8);
    const short* s0 = (const short*)&v0;
    const short* s1 = (const short*)&v1;
#pragma unroll
    for (int j = 0; j < 8; ++j)
      *(short2*)(&Vtl[0][(vdg * 8 + j) * 68 + vkg * 4 + vhalf * 2]) = make_short2(s0[j], s1[j]);
  }
  __syncthreads();

  f32x4 acc_o[4] = {};
  float m_run = -1.0e30f, l_run = 0.f;
  const int mrow = w * 16 + lq;
  int cur = 0;

  for (int kt = 0; kt <= qt; ++kt) {
    bool more = kt < qt;
    uint4 v0, v1;
    if (more) {
#pragma unroll
      for (int i2 = 0; i2 < 2; ++i2) {
        int idx = tid + i2 * 256;
        int row = idx >> 3, sub = idx & 7;
        gload16(Kb + (size_t)((kt + 1) * 64 + row) * QKV_LD + (size_t)((sub ^ (row & 7)) * 8),
                &Kl[cur ^ 1][idx * 8]);
      }
      int krow = (kt + 1) * 64 + vkg * 4 + vhalf * 2;
      v0 = *(const uint4*)(Vb + (size_t)krow * QKV_LD + vdg * 8);
      v1 = *(const uint4*)(Vb + (size_t)(krow + 1) * QKV_LD + vdg * 8);
    }
    f32x4 s[4] = {};
    __builtin_amdgcn_s_setprio(1);
#pragma unroll
    for (int ks = 0; ks < 4; ++ks) {
      half8 kf0 = *(const half8*)(&Kl[cur][(ks * 16 + lq) * 64 + ((g ^ (lq & 7)) * 8)]);
      half8 kf1 = *(const half8*)(&Kl[cur][(ks * 16 + lq) * 64 + (((4 + g) ^ (lq & 7)) * 8)]);
      s[ks] = __builtin_amdgcn_mfma_f32_16x16x32_f16(kf0, qf[0], s[ks], 0, 0, 0);
      s[ks] = __builtin_amdgcn_mfma_f32_16x16x32_f16(kf1, qf[1], s[ks], 0, 0, 0);
    }
    __builtin_amdgcn_s_setprio(0);
    float mx = NEGF;
#pragma unroll
    for (int ks = 0; ks < 4; ++ks) {
      int kbase = kt * 64 + ks * 16 + g * 4;
      unsigned mwv = mlds[mrow * 32 + (kbase >> 5)];
#pragma unroll
      for (int r = 0; r < 4; ++r) {
        float sv = ((mwv >> ((kbase + r) & 31)) & 1u) ? s[ks][r] * 0.125f : NEGF;
        s[ks][r] = sv;
        mx = fmaxf(mx, sv);
      }
    }
    mx = fmaxf(mx, __shfl_xor(mx, 16));
    mx = fmaxf(mx, __shfl_xor(mx, 32));
    float m_new = fmaxf(m_run, mx);
    float scale = __expf(m_run - m_new);
    float lsum = 0.f;
    half4v pf[4];
#pragma unroll
    for (int ks = 0; ks < 4; ++ks) {
      half4v t;
#pragma unroll
      for (int r = 0; r < 4; ++r) {
        float pp = __expf(s[ks][r] - m_new);
        lsum += pp;
        t[r] = (_Float16)pp;
      }
      pf[ks] = t;
    }
    lsum += __shfl_xor(lsum, 16);
    lsum += __shfl_xor(lsum, 32);
    l_run = l_run * scale + lsum;
    m_run = m_new;
    float sc[4];
#pragma unroll
    for (int r = 0; r < 4; ++r) sc[r] = __shfl(scale, g * 4 + r);
    __builtin_amdgcn_s_setprio(1);
#pragma unroll
    for (int dt = 0; dt < 4; ++dt) {
      f32x4 a = acc_o[dt];
      a[0] *= sc[0]; a[1] *= sc[1]; a[2] *= sc[2]; a[3] *= sc[3];
#pragma unroll
      for (int ks = 0; ks < 4; ++ks) {
        half4v vf = *(const half4v*)(&Vtl[cur][(dt * 16 + lq) * 68 + ks * 16 + g * 4]);
        a = MFMA16F(pf[ks], vf, a);
      }
      acc_o[dt] = a;
    }
    __builtin_amdgcn_s_setprio(0);
    if (more) {
      const short* s0 = (const short*)&v0;
      const short* s1 = (const short*)&v1;
#pragma unroll
      for (int j = 0; j < 8; ++j)
        *(short2*)(&Vtl[cur ^ 1][(vdg * 8 + j) * 68 + vkg * 4 + vhalf * 2]) = make_short2(s0[j], s1[j]);
    }
    __syncthreads();
    cur ^= 1;
  }
  float linv[4];
#pragma unroll
  for (int r = 0; r < 4; ++r) linv[r] = 1.0f / __shfl(l_run, g * 4 + r);
#pragma unroll
  for (int dt = 0; dt < 4; ++dt)
#pragma unroll
    for (int r = 0; r < 4; ++r) {
      int q = q0 + w * 16 + g * 4 + r;
      float o = acc_o[dt][r] * linv[r];
      O[(size_t)(b * S_LEN + q) * D_DIM + h * DHD + dt * 16 + lq] = f2h(o);
    }
}

// ---------------- host orchestration ----------------
extern "C" void kernel_launch(void* const* d_in, const int* in_sizes, int n_in,
                              void* d_out, int out_size, void* d_ws, size_t ws_size,
                              hipStream_t stream) {
  (void)in_sizes; (void)n_in; (void)out_size;
  const int*   tokens  = (const int*)d_in[0];
  const float* embed_w = (const float*)d_in[1];
  const float* pos_w   = (const float*)d_in[2];
  const float* wq      = (const float*)d_in[3];
  const float* wk      = (const float*)d_in[4];
  const float* wv      = (const float*)d_in[5];
  const float* wo      = (const float*)d_in[6];
  const float* iqw     = (const float*)d_in[7];
  const float* ikw     = (const float*)d_in[8];
  const float* iww     = (const float*)d_in[9];
  const float* w1      = (const float*)d_in[10];
  const float* w2      = (const float*)d_in[11];
  const float* n1      = (const float*)d_in[12];
  const float* n2      = (const float*)d_in[13];
  const float* nf      = (const float*)d_in[14];
  float* logits = (float*)d_out;

  // ws: Hh (logits A, 4 MB) + Eh (fp16 embed padded to VPAD rows, 103 MB)
  short* Hh = (short*)d_ws;
  size_t need_eh = ((size_t)BSROWS * D_DIM + (size_t)VPAD * D_DIM) * 2;
  bool use_eh = ws_size >= need_eh;
  short* Eh = Hh + (size_t)BSROWS * D_DIM;

  // d_out scratch (all dead before logits GEMM writes)
  char* base = (char*)d_out;
  size_t off = (size_t)BSROWS * D_DIM * 4;
  float* X = logits;
  float* Hx = (float*)(base + off);    off += (size_t)BSROWS * IDX_LD * 4;
  short* QKVh = (short*)(base + off);  off += (size_t)BSROWS * QKV_LD * 2;
  short* Hsp = (short*)(base + off);   off += (size_t)2 * BSROWS * D_DIM * 2;
  short* AOh = (short*)(base + off);   off += (size_t)BSROWS * D_DIM * 2;
  short* FFh = (short*)(base + off);   off += (size_t)BSROWS * FF_DIM * 2;
  unsigned int* MASKb = (unsigned int*)(base + off); off += (size_t)BSROWS * 32 * 4;
  short* BTqkvA = (short*)(base + off); off += (size_t)NL * QKV_LD * D_DIM * 2;
  short* BTidxA = (short*)(base + off); off += (size_t)NL * 2 * IDX_LD * D_DIM * 2;
  short* BTwoA = (short*)(base + off);  off += (size_t)NL * D_DIM * D_DIM * 2;
  short* BTw1A = (short*)(base + off);  off += (size_t)NL * FF_DIM * D_DIM * 2;
  short* BTw2A = (short*)(base + off);  off += (size_t)NL * FF_DIM * D_DIM * 2;

  const size_t plH  = (size_t)BSROWS * D_DIM;
  const size_t plIx = (size_t)IDX_LD * D_DIM;

  hipLaunchKernelGGL(embed_kernel, dim3(BSROWS), dim3(256), 0, stream,
                     tokens, embed_w, pos_w, X);
  if (use_eh)
    hipLaunchKernelGGL(cvt_embed_kernel, dim3(8192), dim3(256), 0, stream, embed_w, Eh);

  // all-layer weight packs (5 dispatches total)
  hipLaunchKernelGGL(pack_qkv_all_kernel, dim3(QKV_LD / 32, 32, NL), dim3(32, 8), 0, stream,
                     wq, wk, wv, BTqkvA);
  hipLaunchKernelGGL(pack_idx_all_kernel, dim3(IDX_LD / 32, 32, NL), dim3(32, 8), 0, stream,
                     iqw, ikw, iww, BTidxA);
  hipLaunchKernelGGL(packT_all_kernel, dim3(32, 32, NL), dim3(32, 8), 0, stream,
                     wo, BTwoA, D_DIM, D_DIM);
  hipLaunchKernelGGL(packT_all_kernel, dim3(FF_DIM / 32, 32, NL), dim3(32, 8), 0, stream,
                     w1, BTw1A, D_DIM, FF_DIM);
  hipLaunchKernelGGL(packT_all_kernel, dim3(D_DIM / 32, FF_DIM / 32, NL), dim3(32, 8), 0, stream,
                     w2, BTw2A, FF_DIM, D_DIM);

  for (int l = 0; l < NL; ++l) {
    short* BTqkv = BTqkvA + (size_t)l * QKV_LD * D_DIM;
    short* BTidx = BTidxA + (size_t)l * 2 * IDX_LD * D_DIM;
    short* BTwo  = BTwoA + (size_t)l * D_DIM * D_DIM;
    short* BTw1  = BTw1A + (size_t)l * FF_DIM * D_DIM;
    short* BTw2  = BTw2A + (size_t)l * FF_DIM * D_DIM;

    hipLaunchKernelGGL(rmsnorm_split_kernel, dim3(BSROWS), dim3(256), 0, stream,
                       X, n1 + (size_t)l * D_DIM, Hsp);
    // QKV: BM=64 -> 768 blocks (3/CU resident)
    hipLaunchKernelGGL((gemm_g_kernel<64, 1>), dim3(QKV_LD / 128, 32), dim3(256), 0, stream,
                       Hsp, BTqkv, nullptr, QKVh, BSROWS, QKV_LD, D_DIM);
    // indexer: BM=32 -> 192 blocks
    hipLaunchKernelGGL((gemm_split_kernel<32>), dim3(IDX_LD / 128, 64), dim3(256), 0, stream,
                       Hsp, plH, BTidx, plIx, Hx, BSROWS, IDX_LD, D_DIM);
    hipLaunchKernelGGL(idx_topk_kernel, dim3(BSROWS), dim3(256), 0, stream, Hx, MASKb);
    hipLaunchKernelGGL(attn_mfma_kernel, dim3(512), dim3(256), 0, stream,
                       QKVh, MASKb, AOh);
    // wo: BM=32 -> 512 blocks (2/CU)
    hipLaunchKernelGGL((gemm_g_kernel<32, 3>), dim3(8, 64), dim3(256), 0, stream,
                       AOh, BTwo, X, X, BSROWS, D_DIM, D_DIM);
    hipLaunchKernelGGL(rmsnorm_h_kernel, dim3(BSROWS), dim3(256), 0, stream,
                       X, n2 + (size_t)l * D_DIM, Hsp);
    // w1: BM=64 -> 1024 blocks (4/CU)
    hipLaunchKernelGGL((gemm_g_kernel<64, 2>), dim3(FF_DIM / 128, 32), dim3(256), 0, stream,
                       Hsp, BTw1, nullptr, FFh, BSROWS, FF_DIM, D_DIM);
    // w2: BM=32 -> 512 blocks (2/CU); B re-reads stay L2-resident (8 MB)
    hipLaunchKernelGGL((gemm_g_kernel<32, 3>), dim3(8, 64), dim3(256), 0, stream,
                       FFh, BTw2, X, X, BSROWS, D_DIM, FF_DIM);
  }

  hipLaunchKernelGGL(rmsnorm_h_kernel, dim3(BSROWS), dim3(256), 0, stream, X, nf, Hh);
  if (use_eh) {
    hipLaunchKernelGGL(gemm_logits_g_kernel, dim3(8 * YPX * 16), dim3(256), 0, stream,
                       Hh, Eh, logits, BSROWS, VOCAB, D_DIM);
  } else {
    hipLaunchKernelGGL(gemm_logits_f32b_kernel, dim3((VOCAB + 127) / 128, 16), dim3(256), 0, stream,
                       Hh, embed_w, logits, BSROWS, VOCAB, D_DIM);
  }
}

// Round 13
// 3297.929 us; speedup vs baseline: 8.8246x; 1.0367x over previous
//
#include <hip/hip_runtime.h>
#include <cstdint>
#include <cstddef>

#define S_LEN 1024
#define D_DIM 1024
#define NH 16
#define DHD 64
#define NL 8
#define FF_DIM 4096
#define HI_N 4
#define DI_N 64
#define TOPK_N 512
#define BSROWS 2048  // B * S
#define VOCAB 50257
#define VPAD 50304    // VOCAB rounded up to 128
#define NTILES_V 393  // ceil(50257/128)
#define YPX 50        // ceil(393/8) N-panels per XCD for logits

// compact QKV layout: [Q 0..1023 | K 1024..2047 | V 2048..3071], fp16
#define QKV_LD 3072
// indexer block layout (fp32): [QI 0..255 | KI 256..319 | WT 320..323 | pad..383]
#define IDX_LD 384
#define COL_QI 0
#define COL_KI 256
#define COL_WT 320

#define NEGF -3.0e38f

typedef __attribute__((ext_vector_type(8))) _Float16 half8;
typedef __attribute__((ext_vector_type(4))) _Float16 half4v;
typedef __attribute__((ext_vector_type(4))) float f32x4;

#if __has_builtin(__builtin_amdgcn_mfma_f32_16x16x16f16)
#define MFMA16F(a, b, c) __builtin_amdgcn_mfma_f32_16x16x16f16((a), (b), (c), 0, 0, 0)
#else
static __device__ __forceinline__ f32x4 mfma16f_asm(half4v a, half4v b, f32x4 c) {
  f32x4 d;
  asm volatile("v_mfma_f32_16x16x16_f16 %0, %1, %2, %3\n\ts_nop 7\n\ts_nop 7"
               : "=v"(d) : "v"(a), "v"(b), "v"(c));
  return d;
}
#define MFMA16F(a, b, c) mfma16f_asm((a), (b), (c))
#endif

// async global->LDS, 16B per lane; LDS dest must be lane-linear (rule #21)
typedef const __attribute__((address_space(1))) void* gas_ptr;
typedef __attribute__((address_space(3))) void* las_ptr;
__device__ __forceinline__ void gload16(const void* g, void* l) {
#if __has_builtin(__builtin_amdgcn_global_load_lds)
  __builtin_amdgcn_global_load_lds((gas_ptr)g, (las_ptr)l, 16, 0, 0);
#else
  *(uint4*)l = *(const uint4*)g;
#endif
}

__device__ __forceinline__ short f2h(float x) {  // RNE fp32->fp16 (bits)
  _Float16 h = (_Float16)x;
  return *reinterpret_cast<short*>(&h);
}
__device__ __forceinline__ float h2f(short b) {
  _Float16 h = *reinterpret_cast<_Float16*>(&b);
  return (float)h;
}
// two-term fp16 split: x ~= hi + lo with rel err ~2^-22
__device__ __forceinline__ void split_h(float x, short& hi, short& lo) {
  hi = f2h(x);
  lo = f2h(x - h2f(hi));
}

// ---------------- embed + positional ----------------
__global__ __launch_bounds__(256) void embed_kernel(
    const int* __restrict__ tokens, const float* __restrict__ E,
    const float* __restrict__ P, float* __restrict__ X)
{
  int bs = blockIdx.x;
  int s = bs & (S_LEN - 1);
  int tid = threadIdx.x;
  int tok = tokens[bs];
  float4 e = ((const float4*)(E + (size_t)tok * D_DIM))[tid];
  float4 p = ((const float4*)(P + (size_t)s * D_DIM))[tid];
  float4 o; o.x = e.x + p.x; o.y = e.y + p.y; o.z = e.z + p.z; o.w = e.w + p.w;
  ((float4*)(X + (size_t)bs * D_DIM))[tid] = o;
}

// ---------------- embed fp32 -> fp16, zero-padded to VPAD rows ----------------
__global__ __launch_bounds__(256) void cvt_embed_kernel(
    const float* __restrict__ E, short* __restrict__ Eh)
{
  const long valid4 = (long)VOCAB * D_DIM / 4;
  const long total4 = (long)VPAD * D_DIM / 4;
  long i = (long)blockIdx.x * 256 + threadIdx.x;
  long stride = (long)gridDim.x * 256;
  for (; i < total4; i += stride) {
    short4 o = make_short4(0, 0, 0, 0);
    if (i < valid4) {
      float4 v = ((const float4*)E)[i];
      o = make_short4(f2h(v.x), f2h(v.y), f2h(v.z), f2h(v.w));
    }
    ((short4*)Eh)[i] = o;
  }
}

// ---------------- rmsnorm -> split fp16 (hi plane, lo plane) ----------------
__global__ __launch_bounds__(256) void rmsnorm_split_kernel(
    const float* __restrict__ X, const float* __restrict__ W,
    short* __restrict__ O /* [2][BSROWS][D] */)
{
  int r = blockIdx.x;
  int tid = threadIdx.x;
  float4 v = ((const float4*)(X + (size_t)r * D_DIM))[tid];
  float ss = v.x * v.x + v.y * v.y + v.z * v.z + v.w * v.w;
  __shared__ float red[4];
  __shared__ float sh_inv;
  for (int o = 32; o; o >>= 1) ss += __shfl_down(ss, o);
  if ((tid & 63) == 0) red[tid >> 6] = ss;
  __syncthreads();
  if (tid == 0) {
    float s = red[0] + red[1] + red[2] + red[3];
    sh_inv = 1.0f / (sqrtf(s) * 0.03125f + 1e-6f);
  }
  __syncthreads();
  float inv = sh_inv;
  float4 w = ((const float4*)W)[tid];
  float o0 = w.x * v.x * inv, o1 = w.y * v.y * inv;
  float o2 = w.z * v.z * inv, o3 = w.w * v.w * inv;
  short4 hi, lo;
  split_h(o0, hi.x, lo.x); split_h(o1, hi.y, lo.y);
  split_h(o2, hi.z, lo.z); split_h(o3, hi.w, lo.w);
  ((short4*)(O + (size_t)r * D_DIM))[tid] = hi;
  ((short4*)(O + (size_t)BSROWS * D_DIM + (size_t)r * D_DIM))[tid] = lo;
}

// ---------------- rmsnorm -> plain fp16 ----------------
__global__ __launch_bounds__(256) void rmsnorm_h_kernel(
    const float* __restrict__ X, const float* __restrict__ W, short* __restrict__ O)
{
  int r = blockIdx.x;
  int tid = threadIdx.x;
  float4 v = ((const float4*)(X + (size_t)r * D_DIM))[tid];
  float ss = v.x * v.x + v.y * v.y + v.z * v.z + v.w * v.w;
  __shared__ float red[4];
  __shared__ float sh_inv;
  for (int o = 32; o; o >>= 1) ss += __shfl_down(ss, o);
  if ((tid & 63) == 0) red[tid >> 6] = ss;
  __syncthreads();
  if (tid == 0) {
    float s = red[0] + red[1] + red[2] + red[3];
    sh_inv = 1.0f / (sqrtf(s) * 0.03125f + 1e-6f);
  }
  __syncthreads();
  float inv = sh_inv;
  float4 w = ((const float4*)W)[tid];
  short4 o4 = make_short4(f2h(w.x * v.x * inv), f2h(w.y * v.y * inv),
                          f2h(w.z * v.z * inv), f2h(w.w * v.w * inv));
  ((short4*)(O + (size_t)r * D_DIM))[tid] = o4;
}

// ------- all-layer packs (grid.z = layer) -------
__global__ __launch_bounds__(256) void packT_all_kernel(
    const float* __restrict__ W0, short* __restrict__ BT0, int K, int N)
{
  __shared__ float t[32][33];
  int z = blockIdx.z;
  const float* W = W0 + (size_t)z * K * N;
  short* BT = BT0 + (size_t)z * N * K;
  int n0 = blockIdx.x * 32, k0 = blockIdx.y * 32;
  int tx = threadIdx.x, ty = threadIdx.y;
#pragma unroll
  for (int r = 0; r < 32; r += 8)
    t[ty + r][tx] = W[(size_t)(k0 + ty + r) * N + n0 + tx];
  __syncthreads();
#pragma unroll
  for (int r = 0; r < 32; r += 8)
    BT[(size_t)(n0 + ty + r) * K + k0 + tx] = f2h(t[tx][ty + r]);
}

__global__ __launch_bounds__(256) void pack_qkv_all_kernel(
    const float* __restrict__ wq0, const float* __restrict__ wk0,
    const float* __restrict__ wv0, short* __restrict__ BT0)
{
  __shared__ float t[32][33];
  int z = blockIdx.z;
  const float* wq = wq0 + (size_t)z * D_DIM * D_DIM;
  const float* wk = wk0 + (size_t)z * D_DIM * D_DIM;
  const float* wv = wv0 + (size_t)z * D_DIM * D_DIM;
  short* BT = BT0 + (size_t)z * QKV_LD * D_DIM;
  int n0 = blockIdx.x * 32, k0 = blockIdx.y * 32;
  int tx = threadIdx.x, ty = threadIdx.y;
  const float* src = (n0 < 1024) ? wq : (n0 < 2048) ? wk : wv;
  int c0 = n0 & 1023;
#pragma unroll
  for (int r = 0; r < 32; r += 8)
    t[ty + r][tx] = src[(size_t)(k0 + ty + r) * 1024 + c0 + tx];
  __syncthreads();
#pragma unroll
  for (int r = 0; r < 32; r += 8)
    BT[(size_t)(n0 + ty + r) * D_DIM + k0 + tx] = f2h(t[tx][ty + r]);
}

__global__ __launch_bounds__(256) void pack_idx_all_kernel(
    const float* __restrict__ iq0, const float* __restrict__ ik0,
    const float* __restrict__ iw0, short* __restrict__ BT0)
{
  __shared__ float t[32][33];
  const size_t plane = (size_t)IDX_LD * D_DIM;
  int z = blockIdx.z;
  const float* iq = iq0 + (size_t)z * D_DIM * (HI_N * DI_N);
  const float* ik = ik0 + (size_t)z * D_DIM * DI_N;
  const float* iw = iw0 + (size_t)z * D_DIM * HI_N;
  short* BT = BT0 + (size_t)z * 2 * plane;
  int n0 = blockIdx.x * 32, k0 = blockIdx.y * 32;
  int tx = threadIdx.x, ty = threadIdx.y;
  const float* src = nullptr; int ld = 0, c0 = 0;
  if (n0 < 256)      { src = iq; ld = 256; c0 = n0; }
  else if (n0 < 320) { src = ik; ld = 64;  c0 = n0 - 256; }
  else if (n0 < 352) { src = iw; ld = 4;   c0 = n0 - 320; }
#pragma unroll
  for (int r = 0; r < 32; r += 8) {
    float v = 0.f;
    int c = c0 + tx;
    if (src && c < ld) v = src[(size_t)(k0 + ty + r) * ld + c];
    t[ty + r][tx] = v;
  }
  __syncthreads();
#pragma unroll
  for (int r = 0; r < 32; r += 8) {
    short hi, lo;
    split_h(t[tx][ty + r], hi, lo);
    size_t o = (size_t)(n0 + ty + r) * D_DIM + k0 + tx;
    BT[o] = hi;
    BT[plane + o] = lo;
  }
}

#define RA 40  // padded LDS pitch for reg-staged split GEMM

// ------- split-fp16 GEMM (fp32-accurate), fp32 out: indexer only -------
template<int BM>
__global__ __launch_bounds__(256) void gemm_split_kernel(
    const short* __restrict__ A, size_t aplane,
    const short* __restrict__ BT, size_t bplane,
    float* __restrict__ C, int M, int N, int K)
{
  constexpr int MI = BM / 32;
  __shared__ short Al[2 * BM * RA];
  __shared__ short Bl[2 * 128 * RA];
  int tid = threadIdx.x;
  int wave = tid >> 6, lane = tid & 63;
  int wr = (wave >> 1) * (BM / 2), wc = (wave & 1) * 64;
  int lr = lane & 15, lk = lane >> 4;
  int m0 = blockIdx.y * BM, n0 = blockIdx.x * 128;
  f32x4 acc[MI][4] = {};

  for (int k0 = 0; k0 < K; k0 += 32) {
    __syncthreads();
#pragma unroll
    for (int f = 0; f < BM / 32; ++f) {
      int idx = tid + f * 256;
      int p = idx / (BM * 4), r2 = idx % (BM * 4);
      int row = r2 >> 2, sub = r2 & 3;
      uint4 v = *(const uint4*)(A + (size_t)p * aplane + (size_t)(m0 + row) * K + k0 + sub * 8);
      *(uint4*)(Al + p * BM * RA + row * RA + sub * 8) = v;
    }
#pragma unroll
    for (int f = 0; f < 4; ++f) {
      int idx = tid + f * 256;
      int p = idx >> 9, r2 = idx & 511;
      int row = r2 >> 2, sub = r2 & 3;
      uint4 v = *(const uint4*)(BT + (size_t)p * bplane + (size_t)(n0 + row) * K + k0 + sub * 8);
      *(uint4*)(Bl + p * 128 * RA + row * RA + sub * 8) = v;
    }
    __syncthreads();
    half8 ah[MI], al_[MI], bh[4], bl_[4];
#pragma unroll
    for (int i = 0; i < MI; ++i) {
      ah[i] = *(const half8*)(Al + (wr + i * 16 + lr) * RA + lk * 8);
      al_[i] = *(const half8*)(Al + BM * RA + (wr + i * 16 + lr) * RA + lk * 8);
    }
#pragma unroll
    for (int j = 0; j < 4; ++j) {
      bh[j] = *(const half8*)(Bl + (wc + j * 16 + lr) * RA + lk * 8);
      bl_[j] = *(const half8*)(Bl + 128 * RA + (wc + j * 16 + lr) * RA + lk * 8);
    }
#pragma unroll
    for (int i = 0; i < MI; ++i)
#pragma unroll
      for (int j = 0; j < 4; ++j) {
        f32x4 a = acc[i][j];
        a = __builtin_amdgcn_mfma_f32_16x16x32_f16(al_[i], bh[j], a, 0, 0, 0);
        a = __builtin_amdgcn_mfma_f32_16x16x32_f16(ah[i], bl_[j], a, 0, 0, 0);
        a = __builtin_amdgcn_mfma_f32_16x16x32_f16(ah[i], bh[j], a, 0, 0, 0);
        acc[i][j] = a;
      }
  }
#pragma unroll
  for (int i = 0; i < MI; ++i)
#pragma unroll
    for (int r = 0; r < 4; ++r) {
      int m = m0 + wr + i * 16 + lk * 4 + r;
#pragma unroll
      for (int j = 0; j < 4; ++j) {
        int n = n0 + wc + j * 16 + lr;
        if (n < N) C[(size_t)m * N + n] = acc[i][j][r];
      }
    }
}

// ------- plain fp16 GEMM: 2-phase double-buffered gload pipeline -------
// Issue next K-tile's global_load_lds into buf^1 BEFORE computing buf[cur];
// single barrier per tile drains prefetch AFTER compute (load/compute overlap).
// Requires: M % BM == 0, N % 128 == 0, K % 32 == 0.
// EPI: 1 fp16 store; 2 exact-GELU -> fp16 store; 3 fp32 + R
template<int BM, int EPI>
__global__ __launch_bounds__(256) void gemm_g_kernel(
    const short* __restrict__ A, const short* __restrict__ BT,
    const float* __restrict__ R, void* __restrict__ C, int M, int N, int K)
{
  constexpr int MI = BM / 32;          // M-frags per wave (128->4, 64->2, 32->1)
  constexpr int AF = (BM >= 64) ? BM / 64 : 1;
  __shared__ short Al[2][BM * 32];     // double-buffered linear [row][32]
  __shared__ short Bl[2][128 * 32];
  int tid = threadIdx.x;
  int wave = tid >> 6, lane = tid & 63;
  int wr = (wave >> 1) * (BM / 2), wc = (wave & 1) * 64;
  int lr = lane & 15, lk = lane >> 4;
  int m0 = blockIdx.y * BM, n0 = blockIdx.x * 128;
  f32x4 acc[MI][4] = {};

  // hoisted staging pointers (advance 32 elems per issued K-tile)
  const short* ap[AF]; int ad[AF];
#pragma unroll
  for (int f = 0; f < AF; ++f) {
    int idx = tid + f * 256;
    int row = idx >> 2, slot = idx & 3;
    ap[f] = A + (size_t)(m0 + row) * K + ((slot ^ (row & 3)) * 8);
    ad[f] = idx * 8;
  }
  const bool a_act = (BM >= 64) || (tid < BM * 4);
  const short* bp[2]; int bd[2];
#pragma unroll
  for (int f = 0; f < 2; ++f) {
    int idx = tid + f * 256;
    int row = idx >> 2, slot = idx & 3;
    bp[f] = BT + (size_t)(n0 + row) * K + ((slot ^ (row & 3)) * 8);
    bd[f] = idx * 8;
  }
  // hoisted swizzled read offsets
  int aoff[MI], boff[4];
#pragma unroll
  for (int i = 0; i < MI; ++i) {
    int row = wr + i * 16 + lr;
    aoff[i] = row * 32 + ((lk ^ (row & 3)) * 8);
  }
#pragma unroll
  for (int j = 0; j < 4; ++j) {
    int row = wc + j * 16 + lr;
    boff[j] = row * 32 + ((lk ^ (row & 3)) * 8);
  }

  // prologue: stage K-tile 0 into buf 0
#pragma unroll
  for (int f = 0; f < AF; ++f)
    if (a_act) { gload16(ap[f], &Al[0][ad[f]]); ap[f] += 32; }
#pragma unroll
  for (int f = 0; f < 2; ++f) { gload16(bp[f], &Bl[0][bd[f]]); bp[f] += 32; }
  __syncthreads();  // compiler drains vmcnt before barrier -> buf0 valid

  const int nt = K >> 5;
  int cur = 0;
  for (int t = 0; t < nt; ++t) {
    if (t + 1 < nt) {  // prefetch next tile (drained at end-of-iter barrier)
#pragma unroll
      for (int f = 0; f < AF; ++f)
        if (a_act) { gload16(ap[f], &Al[cur ^ 1][ad[f]]); ap[f] += 32; }
#pragma unroll
      for (int f = 0; f < 2; ++f) { gload16(bp[f], &Bl[cur ^ 1][bd[f]]); bp[f] += 32; }
    }
    half8 af[MI], bfr[4];
#pragma unroll
    for (int i = 0; i < MI; ++i) af[i] = *(const half8*)(&Al[cur][aoff[i]]);
#pragma unroll
    for (int j = 0; j < 4; ++j) bfr[j] = *(const half8*)(&Bl[cur][boff[j]]);
#pragma unroll
    for (int i = 0; i < MI; ++i)
#pragma unroll
      for (int j = 0; j < 4; ++j)
        acc[i][j] = __builtin_amdgcn_mfma_f32_16x16x32_f16(af[i], bfr[j], acc[i][j], 0, 0, 0);
    __syncthreads();  // frag reads done + prefetch drained -> swap safe
    cur ^= 1;
  }
#pragma unroll
  for (int i = 0; i < MI; ++i)
#pragma unroll
    for (int r = 0; r < 4; ++r) {
      int m = m0 + wr + i * 16 + lk * 4 + r;
#pragma unroll
      for (int j = 0; j < 4; ++j) {
        int n = n0 + wc + j * 16 + lr;
        float v = acc[i][j][r];
        if (EPI == 1) {
          ((short*)C)[(size_t)m * N + n] = f2h(v);
        } else if (EPI == 2) {
          v = 0.5f * v * (1.0f + erff(v * 0.70710678118654752f));
          ((short*)C)[(size_t)m * N + n] = f2h(v);
        } else {
          ((float*)C)[(size_t)m * N + n] = v + R[(size_t)m * N + n];
        }
      }
    }
}

// ------- logits GEMM: 2-phase dbuf gload pipeline + XCD-aware 1D grid ---------
__global__ __launch_bounds__(256) void gemm_logits_g_kernel(
    const short* __restrict__ A, const short* __restrict__ BT,
    float* __restrict__ C, int M, int N, int K)
{
  int bid = blockIdx.x;
  int xcd = bid & 7, idx0 = bid >> 3;
  int mt = idx0 & 15, yt = (idx0 >> 4) + xcd * YPX;
  if (yt >= NTILES_V) return;
  int m0 = mt * 128, n0 = yt * 128;

  __shared__ short Al[2][128 * 32];
  __shared__ short Bl[2][128 * 32];
  int tid = threadIdx.x;
  int wave = tid >> 6, lane = tid & 63;
  int wr = (wave >> 1) * 64, wc = (wave & 1) * 64;
  int lr = lane & 15, lk = lane >> 4;
  f32x4 acc[4][4] = {};

  const short* ap[2]; int ad[2];
  const short* bp[2]; int bd[2];
#pragma unroll
  for (int f = 0; f < 2; ++f) {
    int idx = tid + f * 256;
    int row = idx >> 2, slot = idx & 3;
    ap[f] = A + (size_t)(m0 + row) * K + ((slot ^ (row & 3)) * 8);
    ad[f] = idx * 8;
    bp[f] = BT + (size_t)(n0 + row) * K + ((slot ^ (row & 3)) * 8);
    bd[f] = idx * 8;
  }
  int aoff[4], boff[4];
#pragma unroll
  for (int i = 0; i < 4; ++i) {
    int row = wr + i * 16 + lr;
    aoff[i] = row * 32 + ((lk ^ (row & 3)) * 8);
    int rowb = wc + i * 16 + lr;
    boff[i] = rowb * 32 + ((lk ^ (rowb & 3)) * 8);
  }

  // prologue: stage K-tile 0 into buf 0
#pragma unroll
  for (int f = 0; f < 2; ++f) { gload16(ap[f], &Al[0][ad[f]]); ap[f] += 32; }
#pragma unroll
  for (int f = 0; f < 2; ++f) { gload16(bp[f], &Bl[0][bd[f]]); bp[f] += 32; }
  __syncthreads();

  const int nt = K >> 5;
  int cur = 0;
  for (int t = 0; t < nt; ++t) {
    if (t + 1 < nt) {
#pragma unroll
      for (int f = 0; f < 2; ++f) { gload16(ap[f], &Al[cur ^ 1][ad[f]]); ap[f] += 32; }
#pragma unroll
      for (int f = 0; f < 2; ++f) { gload16(bp[f], &Bl[cur ^ 1][bd[f]]); bp[f] += 32; }
    }
    half8 af[4], bfr[4];
#pragma unroll
    for (int i = 0; i < 4; ++i) af[i] = *(const half8*)(&Al[cur][aoff[i]]);
#pragma unroll
    for (int j = 0; j < 4; ++j) bfr[j] = *(const half8*)(&Bl[cur][boff[j]]);
#pragma unroll
    for (int i = 0; i < 4; ++i)
#pragma unroll
      for (int j = 0; j < 4; ++j)
        acc[i][j] = __builtin_amdgcn_mfma_f32_16x16x32_f16(af[i], bfr[j], acc[i][j], 0, 0, 0);
    __syncthreads();
    cur ^= 1;
  }
#pragma unroll
  for (int i = 0; i < 4; ++i)
#pragma unroll
    for (int r = 0; r < 4; ++r) {
      int m = m0 + wr + i * 16 + lk * 4 + r;
#pragma unroll
      for (int j = 0; j < 4; ++j) {
        int n = n0 + wc + j * 16 + lr;
        if (n < N) C[(size_t)m * N + n] = acc[i][j][r];
      }
    }
}

// ------- logits fallback: B fp32 [N][K] inline-cvt (when ws too small) -------
__global__ __launch_bounds__(256) void gemm_logits_f32b_kernel(
    const short* __restrict__ A, const float* __restrict__ BT,
    float* __restrict__ C, int M, int N, int K)
{
  __shared__ short Al[128 * RA];
  __shared__ short Bl[128 * RA];
  int tid = threadIdx.x;
  int wave = tid >> 6, lane = tid & 63;
  int wr = (wave >> 1) * 64, wc = (wave & 1) * 64;
  int lr = lane & 15, lk = lane >> 4;
  int m0 = blockIdx.y * 128, n0 = blockIdx.x * 128;
  f32x4 acc[4][4] = {};

  for (int k0 = 0; k0 < K; k0 += 32) {
    __syncthreads();
#pragma unroll
    for (int f = 0; f < 2; ++f) {
      int idx = tid + f * 256, row = idx >> 2, sub = idx & 3;
      uint4 v = *(const uint4*)(A + (size_t)(m0 + row) * K + k0 + sub * 8);
      *(uint4*)(Al + row * RA + sub * 8) = v;
    }
#pragma unroll
    for (int f = 0; f < 4; ++f) {
      int idx = tid + f * 256, row = idx >> 3, qq = idx & 7;
      int gn = n0 + row;
      float4 v = make_float4(0.f, 0.f, 0.f, 0.f);
      if (gn < N) v = *(const float4*)(BT + (size_t)gn * K + k0 + qq * 4);
      *(short4*)(Bl + row * RA + qq * 4) =
          make_short4(f2h(v.x), f2h(v.y), f2h(v.z), f2h(v.w));
    }
    __syncthreads();
    half8 af[4], bfr[4];
#pragma unroll
    for (int i = 0; i < 4; ++i)
      af[i] = *(const half8*)(Al + (wr + i * 16 + lr) * RA + lk * 8);
#pragma unroll
    for (int j = 0; j < 4; ++j)
      bfr[j] = *(const half8*)(Bl + (wc + j * 16 + lr) * RA + lk * 8);
#pragma unroll
    for (int i = 0; i < 4; ++i)
#pragma unroll
      for (int j = 0; j < 4; ++j)
        acc[i][j] = __builtin_amdgcn_mfma_f32_16x16x32_f16(af[i], bfr[j], acc[i][j], 0, 0, 0);
  }
#pragma unroll
  for (int i = 0; i < 4; ++i)
#pragma unroll
    for (int r = 0; r < 4; ++r) {
      int m = m0 + wr + i * 16 + lk * 4 + r;
#pragma unroll
      for (int j = 0; j < 4; ++j) {
        int n = n0 + wc + j * 16 + lr;
        if (n < N) C[(size_t)m * N + n] = acc[i][j][r];
      }
    }
}

// ---------------- indexer scores + exact stable top-k -> bitmask ----------------
__device__ __forceinline__ unsigned int ford(float f) {
  unsigned int u = __float_as_uint(f);
  return (u & 0x80000000u) ? ~u : (u | 0x80000000u);
}

__global__ __launch_bounds__(256) void idx_topk_kernel(
    const float* __restrict__ Hx, unsigned int* __restrict__ MASK)
{
  int bq = blockIdx.x;
  int q = bq & (S_LEN - 1);
  int b = bq >> 10;
  int tid = threadIdx.x;
  int n = q + 1;
  if (n <= TOPK_N) {
    if (tid < 32) {
      int full = n >> 5, rem = n & 31;
      unsigned int w = 0u;
      if (tid < full) w = 0xFFFFFFFFu;
      else if (tid == full && rem) w = (1u << rem) - 1u;
      MASK[(size_t)bq * 32 + tid] = w;
    }
    return;
  }
  __shared__ float qi_s[HI_N * DI_N];
  __shared__ float wt_s[HI_N];
  __shared__ float sc[S_LEN];
  __shared__ unsigned long long keys[S_LEN];
  __shared__ unsigned int mw[32];
  qi_s[tid] = Hx[(size_t)bq * IDX_LD + COL_QI + tid];
  if (tid < HI_N) wt_s[tid] = Hx[(size_t)bq * IDX_LD + COL_WT + tid];
  __syncthreads();
  for (int k = tid; k < n; k += 256) {
    const float* kr = Hx + (size_t)(b * S_LEN + k) * IDX_LD + COL_KI;
    float d0 = 0.f, d1 = 0.f, d2 = 0.f, d3 = 0.f;
#pragma unroll
    for (int d = 0; d < DI_N; ++d) {
      float kv = kr[d];
      d0 = fmaf(qi_s[d], kv, d0);
      d1 = fmaf(qi_s[64 + d], kv, d1);
      d2 = fmaf(qi_s[128 + d], kv, d2);
      d3 = fmaf(qi_s[192 + d], kv, d3);
    }
    sc[k] = wt_s[0] * fmaxf(d0, 0.f) + wt_s[1] * fmaxf(d1, 0.f)
          + wt_s[2] * fmaxf(d2, 0.f) + wt_s[3] * fmaxf(d3, 0.f);
  }
  __syncthreads();
  for (int i = tid; i < S_LEN; i += 256) {
    unsigned long long kk = 0ull;
    if (i < n) kk = ((unsigned long long)ford(sc[i]) << 32) | (unsigned int)(S_LEN - 1 - i);
    keys[i] = kk;
  }
  __syncthreads();
  for (int size = 2; size <= S_LEN; size <<= 1) {
    for (int stride = size >> 1; stride > 0; stride >>= 1) {
      for (int t = tid; t < S_LEN / 2; t += 256) {
        int j = t & (stride - 1);
        int lo = ((t ^ j) << 1) | j;
        int hi = lo | stride;
        unsigned long long a = keys[lo], c = keys[hi];
        bool desc = ((lo & size) == 0);
        bool sw = desc ? (a < c) : (a > c);
        if (sw) { keys[lo] = c; keys[hi] = a; }
      }
      __syncthreads();
    }
  }
  if (tid < 32) mw[tid] = 0u;
  __syncthreads();
  for (int i = tid; i < TOPK_N; i += 256) {
    int k = S_LEN - 1 - (int)(keys[i] & 0xFFFFFFFFull);
    atomicOr(&mw[k >> 5], 1u << (k & 31));
  }
  __syncthreads();
  if (tid < 32) MASK[(size_t)bq * 32 + tid] = mw[tid];
}

// ------- masked-dense flash attention: x32 QK^T + x16 PV, 1-barrier pipeline ---
// Mask kept in 2 registers per K-tile (per-lane q-row), prefetched from L2 one
// tile ahead -> no mask LDS; 33 KB LDS -> 4 blocks/CU.
__global__ __launch_bounds__(256) void attn_mfma_kernel(
    const short* __restrict__ QKV, const unsigned int* __restrict__ MASK,
    short* __restrict__ O /* [BSROWS][D] fp16 */)
{
  __shared__ short Kl[2][64 * 64];         // K tiles, linear [key][64], swizzled cols
  __shared__ short Vtl[2][64 * 68];        // V^T tiles [d][key], pitch 68
  int i = blockIdx.x;
  int p = i >> 5;
  int qt = (p < 8) ? p : 23 - p;           // pair-balanced: qt(p)+qt(p+8)=15
  int h = (i >> 1) & 15;
  int b = i & 1;
  int tid = threadIdx.x;
  int w = tid >> 6, l = tid & 63;
  int lq = l & 15, g = l >> 4;
  int q0 = qt * 64;
  const short* Kb = QKV + (size_t)b * S_LEN * QKV_LD + 1024 + h * DHD;
  const short* Vb = QKV + (size_t)b * S_LEN * QKV_LD + 2048 + h * DHD;
  int vu = tid >> 1, vhalf = tid & 1, vkg = vu >> 3, vdg = vu & 7;
  const int mrow = w * 16 + lq;
  const unsigned int* mp = MASK + (size_t)(b * S_LEN + q0 + mrow) * 32;

  half8 qf[2];
  {
    const short* qrow = QKV + ((size_t)(b * S_LEN + q0 + mrow)) * QKV_LD + h * DHD;
    qf[0] = *(const half8*)(qrow + g * 8);
    qf[1] = *(const half8*)(qrow + 32 + g * 8);
  }
  unsigned int mw0 = mp[0], mw1 = mp[1];
  {
#pragma unroll
    for (int i2 = 0; i2 < 2; ++i2) {
      int idx = tid + i2 * 256;
      int row = idx >> 3, sub = idx & 7;
      gload16(Kb + (size_t)row * QKV_LD + (size_t)((sub ^ (row & 7)) * 8), &Kl[0][idx * 8]);
    }
    int krow = vkg * 4 + vhalf * 2;
    uint4 v0 = *(const uint4*)(Vb + (size_t)krow * QKV_LD + vdg * 8);
    uint4 v1 = *(const uint4*)(Vb + (size_t)(krow + 1) * QKV_LD + vdg * 8);
    const short* s0 = (const short*)&v0;
    const short* s1 = (const short*)&v1;
#pragma unroll
    for (int j = 0; j < 8; ++j)
      *(short2*)(&Vtl[0][(vdg * 8 + j) * 68 + vkg * 4 + vhalf * 2]) = make_short2(s0[j], s1[j]);
  }
  __syncthreads();

  f32x4 acc_o[4] = {};
  float m_run = -1.0e30f, l_run = 0.f;
  int cur = 0;

  for (int kt = 0; kt <= qt; ++kt) {
    bool more = kt < qt;
    uint4 v0, v1;
    unsigned int nmw0 = 0u, nmw1 = 0u;
    if (more) {
#pragma unroll
      for (int i2 = 0; i2 < 2; ++i2) {
        int idx = tid + i2 * 256;
        int row = idx >> 3, sub = idx & 7;
        gload16(Kb + (size_t)((kt + 1) * 64 + row) * QKV_LD + (size_t)((sub ^ (row & 7)) * 8),
                &Kl[cur ^ 1][idx * 8]);
      }
      int krow = (kt + 1) * 64 + vkg * 4 + vhalf * 2;
      v0 = *(const uint4*)(Vb + (size_t)krow * QKV_LD + vdg * 8);
      v1 = *(const uint4*)(Vb + (size_t)(krow + 1) * QKV_LD + vdg * 8);
      nmw0 = mp[2 * (kt + 1)];
      nmw1 = mp[2 * (kt + 1) + 1];
    }
    f32x4 s[4] = {};
    __builtin_amdgcn_s_setprio(1);
#pragma unroll
    for (int ks = 0; ks < 4; ++ks) {
      half8 kf0 = *(const half8*)(&Kl[cur][(ks * 16 + lq) * 64 + ((g ^ (lq & 7)) * 8)]);
      half8 kf1 = *(const half8*)(&Kl[cur][(ks * 16 + lq) * 64 + (((4 + g) ^ (lq & 7)) * 8)]);
      s[ks] = __builtin_amdgcn_mfma_f32_16x16x32_f16(kf0, qf[0], s[ks], 0, 0, 0);
      s[ks] = __builtin_amdgcn_mfma_f32_16x16x32_f16(kf1, qf[1], s[ks], 0, 0, 0);
    }
    __builtin_amdgcn_s_setprio(0);
    float mx = NEGF;
#pragma unroll
    for (int ks = 0; ks < 4; ++ks) {
      unsigned int mwv = (ks < 2) ? mw0 : mw1;
      int bb = (ks & 1) * 16 + g * 4;
#pragma unroll
      for (int r = 0; r < 4; ++r) {
        float sv = ((mwv >> (bb + r)) & 1u) ? s[ks][r] * 0.125f : NEGF;
        s[ks][r] = sv;
        mx = fmaxf(mx, sv);
      }
    }
    mx = fmaxf(mx, __shfl_xor(mx, 16));
    mx = fmaxf(mx, __shfl_xor(mx, 32));
    float m_new = fmaxf(m_run, mx);
    float scale = __expf(m_run - m_new);
    float lsum = 0.f;
    half4v pf[4];
#pragma unroll
    for (int ks = 0; ks < 4; ++ks) {
      half4v t;
#pragma unroll
      for (int r = 0; r < 4; ++r) {
        float pp = __expf(s[ks][r] - m_new);
        lsum += pp;
        t[r] = (_Float16)pp;
      }
      pf[ks] = t;
    }
    lsum += __shfl_xor(lsum, 16);
    lsum += __shfl_xor(lsum, 32);
    l_run = l_run * scale + lsum;
    m_run = m_new;
    float sc[4];
#pragma unroll
    for (int r = 0; r < 4; ++r) sc[r] = __shfl(scale, g * 4 + r);
    __builtin_amdgcn_s_setprio(1);
#pragma unroll
    for (int dt = 0; dt < 4; ++dt) {
      f32x4 a = acc_o[dt];
      a[0] *= sc[0]; a[1] *= sc[1]; a[2] *= sc[2]; a[3] *= sc[3];
#pragma unroll
      for (int ks = 0; ks < 4; ++ks) {
        half4v vf = *(const half4v*)(&Vtl[cur][(dt * 16 + lq) * 68 + ks * 16 + g * 4]);
        a = MFMA16F(pf[ks], vf, a);
      }
      acc_o[dt] = a;
    }
    __builtin_amdgcn_s_setprio(0);
    if (more) {
      const short* s0 = (const short*)&v0;
      const short* s1 = (const short*)&v1;
#pragma unroll
      for (int j = 0; j < 8; ++j)
        *(short2*)(&Vtl[cur ^ 1][(vdg * 8 + j) * 68 + vkg * 4 + vhalf * 2]) = make_short2(s0[j], s1[j]);
      mw0 = nmw0;
      mw1 = nmw1;
    }
    __syncthreads();
    cur ^= 1;
  }
  float linv[4];
#pragma unroll
  for (int r = 0; r < 4; ++r) linv[r] = 1.0f / __shfl(l_run, g * 4 + r);
#pragma unroll
  for (int dt = 0; dt < 4; ++dt)
#pragma unroll
    for (int r = 0; r < 4; ++r) {
      int q = q0 + w * 16 + g * 4 + r;
      float o = acc_o[dt][r] * linv[r];
      O[(size_t)(b * S_LEN + q) * D_DIM + h * DHD + dt * 16 + lq] = f2h(o);
    }
}

// ---------------- host orchestration ----------------
extern "C" void kernel_launch(void* const* d_in, const int* in_sizes, int n_in,
                              void* d_out, int out_size, void* d_ws, size_t ws_size,
                              hipStream_t stream) {
  (void)in_sizes; (void)n_in; (void)out_size;
  const int*   tokens  = (const int*)d_in[0];
  const float* embed_w = (const float*)d_in[1];
  const float* pos_w   = (const float*)d_in[2];
  const float* wq      = (const float*)d_in[3];
  const float* wk      = (const float*)d_in[4];
  const float* wv      = (const float*)d_in[5];
  const float* wo      = (const float*)d_in[6];
  const float* iqw     = (const float*)d_in[7];
  const float* ikw     = (const float*)d_in[8];
  const float* iww     = (const float*)d_in[9];
  const float* w1      = (const float*)d_in[10];
  const float* w2      = (const float*)d_in[11];
  const float* n1      = (const float*)d_in[12];
  const float* n2      = (const float*)d_in[13];
  const float* nf      = (const float*)d_in[14];
  float* logits = (float*)d_out;

  // ws: Hh (logits A, 4 MB) + Eh (fp16 embed padded to VPAD rows, 103 MB)
  short* Hh = (short*)d_ws;
  size_t need_eh = ((size_t)BSROWS * D_DIM + (size_t)VPAD * D_DIM) * 2;
  bool use_eh = ws_size >= need_eh;
  short* Eh = Hh + (size_t)BSROWS * D_DIM;

  // d_out scratch (all dead before logits GEMM writes)
  char* base = (char*)d_out;
  size_t off = (size_t)BSROWS * D_DIM * 4;
  float* X = logits;
  float* Hx = (float*)(base + off);    off += (size_t)BSROWS * IDX_LD * 4;
  short* QKVh = (short*)(base + off);  off += (size_t)BSROWS * QKV_LD * 2;
  short* Hsp = (short*)(base + off);   off += (size_t)2 * BSROWS * D_DIM * 2;
  short* AOh = (short*)(base + off);   off += (size_t)BSROWS * D_DIM * 2;
  short* FFh = (short*)(base + off);   off += (size_t)BSROWS * FF_DIM * 2;
  unsigned int* MASKb = (unsigned int*)(base + off); off += (size_t)BSROWS * 32 * 4;
  short* BTqkvA = (short*)(base + off); off += (size_t)NL * QKV_LD * D_DIM * 2;
  short* BTidxA = (short*)(base + off); off += (size_t)NL * 2 * IDX_LD * D_DIM * 2;
  short* BTwoA = (short*)(base + off);  off += (size_t)NL * D_DIM * D_DIM * 2;
  short* BTw1A = (short*)(base + off);  off += (size_t)NL * FF_DIM * D_DIM * 2;
  short* BTw2A = (short*)(base + off);  off += (size_t)NL * FF_DIM * D_DIM * 2;

  const size_t plH  = (size_t)BSROWS * D_DIM;
  const size_t plIx = (size_t)IDX_LD * D_DIM;

  hipLaunchKernelGGL(embed_kernel, dim3(BSROWS), dim3(256), 0, stream,
                     tokens, embed_w, pos_w, X);
  if (use_eh)
    hipLaunchKernelGGL(cvt_embed_kernel, dim3(8192), dim3(256), 0, stream, embed_w, Eh);

  // all-layer weight packs (5 dispatches total)
  hipLaunchKernelGGL(pack_qkv_all_kernel, dim3(QKV_LD / 32, 32, NL), dim3(32, 8), 0, stream,
                     wq, wk, wv, BTqkvA);
  hipLaunchKernelGGL(pack_idx_all_kernel, dim3(IDX_LD / 32, 32, NL), dim3(32, 8), 0, stream,
                     iqw, ikw, iww, BTidxA);
  hipLaunchKernelGGL(packT_all_kernel, dim3(32, 32, NL), dim3(32, 8), 0, stream,
                     wo, BTwoA, D_DIM, D_DIM);
  hipLaunchKernelGGL(packT_all_kernel, dim3(FF_DIM / 32, 32, NL), dim3(32, 8), 0, stream,
                     w1, BTw1A, D_DIM, FF_DIM);
  hipLaunchKernelGGL(packT_all_kernel, dim3(D_DIM / 32, FF_DIM / 32, NL), dim3(32, 8), 0, stream,
                     w2, BTw2A, FF_DIM, D_DIM);

  for (int l = 0; l < NL; ++l) {
    short* BTqkv = BTqkvA + (size_t)l * QKV_LD * D_DIM;
    short* BTidx = BTidxA + (size_t)l * 2 * IDX_LD * D_DIM;
    short* BTwo  = BTwoA + (size_t)l * D_DIM * D_DIM;
    short* BTw1  = BTw1A + (size_t)l * FF_DIM * D_DIM;
    short* BTw2  = BTw2A + (size_t)l * FF_DIM * D_DIM;

    hipLaunchKernelGGL(rmsnorm_split_kernel, dim3(BSROWS), dim3(256), 0, stream,
                       X, n1 + (size_t)l * D_DIM, Hsp);
    // QKV: BM=64 -> 768 blocks
    hipLaunchKernelGGL((gemm_g_kernel<64, 1>), dim3(QKV_LD / 128, 32), dim3(256), 0, stream,
                       Hsp, BTqkv, nullptr, QKVh, BSROWS, QKV_LD, D_DIM);
    // indexer: BM=32 -> 192 blocks
    hipLaunchKernelGGL((gemm_split_kernel<32>), dim3(IDX_LD / 128, 64), dim3(256), 0, stream,
                       Hsp, plH, BTidx, plIx, Hx, BSROWS, IDX_LD, D_DIM);
    hipLaunchKernelGGL(idx_topk_kernel, dim3(BSROWS), dim3(256), 0, stream, Hx, MASKb);
    hipLaunchKernelGGL(attn_mfma_kernel, dim3(512), dim3(256), 0, stream,
                       QKVh, MASKb, AOh);
    // wo: BM=32 -> 512 blocks
    hipLaunchKernelGGL((gemm_g_kernel<32, 3>), dim3(8, 64), dim3(256), 0, stream,
                       AOh, BTwo, X, X, BSROWS, D_DIM, D_DIM);
    hipLaunchKernelGGL(rmsnorm_h_kernel, dim3(BSROWS), dim3(256), 0, stream,
                       X, n2 + (size_t)l * D_DIM, Hsp);
    // w1: BM=64 -> 1024 blocks
    hipLaunchKernelGGL((gemm_g_kernel<64, 2>), dim3(FF_DIM / 128, 32), dim3(256), 0, stream,
                       Hsp, BTw1, nullptr, FFh, BSROWS, FF_DIM, D_DIM);
    // w2: BM=32 -> 512 blocks
    hipLaunchKernelGGL((gemm_g_kernel<32, 3>), dim3(8, 64), dim3(256), 0, stream,
                       FFh, BTw2, X, X, BSROWS, D_DIM, FF_DIM);
  }

  hipLaunchKernelGGL(rmsnorm_h_kernel, dim3(BSROWS), dim3(256), 0, stream, X, nf, Hh);
  if (use_eh) {
    hipLaunchKernelGGL(gemm_logits_g_kernel, dim3(8 * YPX * 16), dim3(256), 0, stream,
                       Hh, Eh, logits, BSROWS, VOCAB, D_DIM);
  } else {
    hipLaunchKernelGGL(gemm_logits_f32b_kernel, dim3((VOCAB + 127) / 128, 16), dim3(256), 0, stream,
                       Hh, embed_w, logits, BSROWS, VOCAB, D_DIM);
  }
}